// Round 4
// baseline (4849.859 us; speedup 1.0000x reference)
//
#include <hip/hip_runtime.h>
#include <math.h>

// ---------------- constants ----------------
constexpr int ROWS_PER_B = 12 * 1024;    // rows (b,t,n) per batch element

// ---------------- graph workspace (float offsets, < 524288) ----------------
constexpr size_t F_N1 = 0;              // 1024*40
constexpr size_t F_N2 = 40960;
constexpr size_t F_ANVAL = 81920;       // 1024*11
constexpr size_t F_ROWVAL = 93184;      // 1024*10
constexpr size_t F_COLSUM = 103424;     // 1024
constexpr size_t F_INVCS = 104448;      // 1024
constexpr size_t F_ATVAL = 105472;      // 10240
constexpr size_t I_ANIDX = 115712;      // ints stored in float slots
constexpr size_t I_ROWIDX = 126976;
constexpr size_t I_COLCNT = 137216;
constexpr size_t I_COLOFF = 138240;     // 1025
constexpr size_t I_COLFILL = 139265;
constexpr size_t I_ATIDX = 140289;      // ends 150529 < 524288
constexpr size_t GRAPH_FLOATS = 524288;

// per-chunk float counts (per batch element)
constexpr size_t PB_GATED = (size_t)ROWS_PER_B * 128;   // 1572864
constexpr size_t PB_HD = (size_t)ROWS_PER_B * 64;       // 786432
constexpr size_t PB_XS = (size_t)32 * 1024 * 64;        // 2097152
constexpr size_t PB_MIX = (size_t)32 * 1024 * 256;      // 8388608
constexpr size_t PB_TOTAL = PB_GATED + PB_HD + 3 * PB_XS + PB_MIX; // 17039360

// ---------------- graph kernels ----------------

__global__ void k_init(int* cnt, int* fill, float* csum) {
    int t = blockIdx.x * 256 + threadIdx.x;
    if (t < 1024) { cnt[t] = 0; fill[t] = 0; csum[t] = 0.f; }
}

__global__ void k_embed(const float* e1, const float* e2, const float* w1, const float* b1,
                        const float* w2, const float* b2, float* n1, float* n2) {
    int idx = blockIdx.x * 256 + threadIdx.x;   // < 81920
    if (idx >= 81920) return;
    int m = idx / 40960, rem = idx - m * 40960;
    int i = rem / 40, j = rem - i * 40;
    const float* e = m ? e2 : e1;
    const float* w = m ? w2 : w1;
    const float* bv = m ? b2 : b1;
    float a = bv[j];
    for (int k = 0; k < 40; k++) a += e[i * 40 + k] * w[k * 40 + j];
    (m ? n2 : n1)[i * 40 + j] = tanhf(3.0f * a);
}

__global__ __launch_bounds__(256) void k_adj(const float* n1, const float* n2,
        float* aN_val, int* aN_idx, float* row_val, int* row_idx,
        int* col_cnt, float* col_sum) {
    __shared__ float arow[1024];
    __shared__ float n1v[40], n2v[40];
    __shared__ float rv[256];
    __shared__ int ri[256];
    __shared__ float topv[10];
    __shared__ int topi[10];
    int v = blockIdx.x, t = threadIdx.x;
    if (t < 40) { n1v[t] = n1[v * 40 + t]; n2v[t] = n2[v * 40 + t]; }
    __syncthreads();
    for (int j = t; j < 1024; j += 256) {
        float d1 = 0.f, d2 = 0.f;
        for (int k = 0; k < 40; k++) {
            d1 += n1v[k] * n2[j * 40 + k];
            d2 += n2v[k] * n1[j * 40 + k];
        }
        float a = tanhf(3.0f * (d1 - d2));
        arow[j] = a > 0.f ? a : 0.f;
    }
    __syncthreads();
    for (int r = 0; r < 10; r++) {
        float bv = -1.f; int bi = 1 << 30;
        for (int j = t; j < 1024; j += 256) {
            float x = arow[j];
            if (x > bv || (x == bv && j < bi)) { bv = x; bi = j; }
        }
        rv[t] = bv; ri[t] = bi;
        __syncthreads();
        for (int s = 128; s > 0; s >>= 1) {
            if (t < s) {
                float ov = rv[t + s]; int oi = ri[t + s];
                if (ov > rv[t] || (ov == rv[t] && oi < ri[t])) { rv[t] = ov; ri[t] = oi; }
            }
            __syncthreads();
        }
        if (t == 0) { topv[r] = rv[0]; topi[r] = ri[0]; arow[ri[0]] = -1.f; }
        __syncthreads();
    }
    if (t == 0) {
        float s = 1.f;
        for (int r = 0; r < 10; r++) s += topv[r];
        float inv = 1.f / s;
        for (int r = 0; r < 10; r++) {
            aN_idx[v * 11 + r] = topi[r];
            aN_val[v * 11 + r] = topv[r] * inv;
            row_idx[v * 10 + r] = topi[r];
            row_val[v * 10 + r] = topv[r];
            atomicAdd(&col_cnt[topi[r]], 1);
            atomicAdd(&col_sum[topi[r]], topv[r]);
        }
        aN_idx[v * 11 + 10] = v;
        aN_val[v * 11 + 10] = inv;
    }
}

__global__ __launch_bounds__(1024) void k_scan(const int* cnt, int* off,
                                               const float* csum, float* inv) {
    __shared__ int tmp[1024];
    int t = threadIdx.x;
    tmp[t] = cnt[t];
    __syncthreads();
    for (int s = 1; s < 1024; s <<= 1) {
        int v = 0;
        if (t >= s) v = tmp[t - s];
        __syncthreads();
        tmp[t] += v;
        __syncthreads();
    }
    off[t + 1] = tmp[t];
    if (t == 0) off[0] = 0;
    inv[t] = 1.0f / (csum[t] + 1.0f);
}

__global__ void k_scatter(const int* row_idx, const float* row_val, const int* off,
                          int* fill, int* aT_idx, float* aT_val) {
    int e = blockIdx.x * 256 + threadIdx.x;
    if (e >= 10240) return;
    int v = e / 10;
    int j = row_idx[e];
    int pos = off[j] + atomicAdd(&fill[j], 1);
    aT_idx[pos] = v;
    aT_val[pos] = row_val[e];
}

// ---------------- per-chunk kernels ----------------

// gate MLP + embed; grid = CB*3072
__global__ __launch_bounds__(256) void k_gate(const float* hist, const float* nodeu,
        const float* tide, const float* diwe,
        const float* Wg1, const float* bg1, const float* Wg2, const float* bg2,
        const float* Wemb, const float* bemb, float* gated, float* hd_emb) {
    __shared__ float w1[4096], w2[4096];
    __shared__ float gin[4][64], hid[4][64];
    __shared__ float sb1[64], sb2[64], we[128], be[64];
    int t = threadIdx.x;
    for (int i = t; i < 4096; i += 256) { w1[i] = Wg1[i]; w2[i] = Wg2[i]; }
    if (t < 64) { sb1[t] = bg1[t]; sb2[t] = bg2[t]; be[t] = bemb[t]; }
    if (t < 128) we[t] = Wemb[t];
    int r = t >> 6, lane = t & 63;
    int row = blockIdx.x * 4 + r;
    int n = row & 1023;
    const float* hrow = hist + (size_t)row * 4;
    float f0 = hrow[0], f1 = hrow[1];
    int tid_i = (int)(hrow[2] * 288.0f);
    int diw_i = (int)hrow[3];
    float g;
    if (lane < 40) g = nodeu[n * 40 + lane];
    else if (lane < 52) g = tide[tid_i * 12 + lane - 40];
    else g = diwe[diw_i * 12 + lane - 52];
    gin[r][lane] = g;
    __syncthreads();
    float acc = sb1[lane];
    for (int k = 0; k < 64; k++) acc += gin[r][k] * w1[k * 64 + lane];
    hid[r][lane] = acc > 0.f ? acc : 0.f;
    __syncthreads();
    acc = sb2[lane];
    for (int k = 0; k < 64; k++) acc += hid[r][k] * w2[k * 64 + lane];
    float gate = 1.f / (1.f + expf(-acc));
    float hd = f0 * we[lane] + f1 * we[64 + lane] + be[lane];
    float x1 = gate * hd;
    gated[(size_t)row * 128 + lane] = x1;
    gated[(size_t)row * 128 + 64 + lane] = hd - x1;
    hd_emb[(size_t)row * 64 + lane] = hd;
}

// xs[b,o,n,h] = relu(sum_t gated*Wsc + bsc); grid = CB*256
__global__ __launch_bounds__(256) void k_wsc(const float* gated, const float* Wsc,
                                             const float* bsc, float* xs, int xoff) {
    __shared__ float w[384];
    __shared__ float sb[32];
    int t = threadIdx.x;
    if (t < 384) w[t] = Wsc[t];
    if (t < 32) sb[t] = bsc[t];
    __syncthreads();
    int idx = blockIdx.x * 256 + t;
    int h = idx & 63, n = (idx >> 6) & 1023, b = idx >> 16;
    float xv[12];
#pragma unroll
    for (int tt = 0; tt < 12; tt++)
        xv[tt] = gated[(size_t)((b * 12 + tt) * 1024 + n) * 128 + xoff + h];
#pragma unroll
    for (int o = 0; o < 32; o++) {
        float a = sb[o];
#pragma unroll
        for (int tt = 0; tt < 12; tt++) a += xv[tt] * w[o * 12 + tt];
        xs[(size_t)((b * 32 + o) * 1024 + n) * 64 + h] = a > 0.f ? a : 0.f;
    }
}

// out = 0.05*x + 0.95*(A_norm @ hin), float4 lanes; grid = CB*2048 (16 rows/block)
__global__ __launch_bounds__(256) void k_spmm(float* out, const float* x, const float* hin,
        const int* aN_idx, const float* aN_val,
        const int* aT_idx, const float* aT_val,
        const int* off, const float* inv_cs, int mode) {
    int t = threadIdx.x;
    int l4 = t & 15, r = t >> 4;            // 16 rows x 16 float4-lanes
    int g = blockIdx.x * 16 + r;            // row id (bc, v)
    int v = g & 1023, bc = g >> 10;
    const float4* base = (const float4*)hin + (size_t)bc * 16384;
    float4 s;
    if (mode == 0) {
        s.x = s.y = s.z = s.w = 0.f;
#pragma unroll
        for (int e = 0; e < 11; e++) {
            int w = aN_idx[v * 11 + e];
            float a = aN_val[v * 11 + e];
            float4 hv = base[w * 16 + l4];
            s.x += a * hv.x; s.y += a * hv.y; s.z += a * hv.z; s.w += a * hv.w;
        }
    } else {
        s = base[v * 16 + l4];
        int e0 = off[v], e1 = off[v + 1];
        for (int e = e0; e < e1; e++) {
            int w = aT_idx[e];
            float a = aT_val[e];
            float4 hv = base[w * 16 + l4];
            s.x += a * hv.x; s.y += a * hv.y; s.z += a * hv.z; s.w += a * hv.w;
        }
        float ic = inv_cs[v];
        s.x *= ic; s.y *= ic; s.z *= ic; s.w *= ic;
    }
    size_t oi = (size_t)g * 16 + l4;
    float4 xv = ((const float4*)x)[oi];
    float4 o;
    o.x = 0.05f * xv.x + 0.95f * s.x;
    o.y = 0.05f * xv.y + 0.95f * s.y;
    o.z = 0.05f * xv.z + 0.95f * s.z;
    o.w = 0.05f * xv.w + 0.95f * s.w;
    ((float4*)out)[oi] = o;
}

// mix projection; grid = CB*1024
__global__ __launch_bounds__(256) void k_proj(const float* xs, const float* h1, const float* h2,
        const float* mw, const float* m1b, const float* m2b,
        float* mix, int xp, int cp) {
    __shared__ float Wl[96 * 64];
    __shared__ float Bt[96 * 64];
    int t = threadIdx.x;
    int b = blockIdx.x >> 10, n = blockIdx.x & 1023;
    for (int i = t; i < 6144; i += 256) {
        int k = i >> 6, col = i & 63;
        Wl[i] = mw[col * 96 + k];
    }
    for (int i = t; i < 6144; i += 256) {
        int k = i >> 6, l = i & 63;
        int q = k >> 5, c = k & 31;
        const float* Hq = (q == 0) ? xs : (q == 1 ? h1 : h2);
        Bt[i] = Hq[(size_t)((b * 32 + c) * 1024 + n) * 64 + l];
    }
    __syncthreads();
    int tx = t & 15, ty = t >> 4;
    int o0 = tx * 4, l0 = ty * 4;
    float acc[4][4];
#pragma unroll
    for (int io = 0; io < 4; io++) {
        float bias = 0.f;
        if (cp == 0) { int rrow = o0 + io; bias = m1b[rrow] + m2b[rrow]; }
#pragma unroll
        for (int il = 0; il < 4; il++) acc[io][il] = bias;
    }
    for (int k = 0; k < 96; k++) {
        float4 a = *(const float4*)&Wl[k * 64 + o0];
        float4 bb = *(const float4*)&Bt[k * 64 + l0];
        acc[0][0] += a.x * bb.x; acc[0][1] += a.x * bb.y; acc[0][2] += a.x * bb.z; acc[0][3] += a.x * bb.w;
        acc[1][0] += a.y * bb.x; acc[1][1] += a.y * bb.y; acc[1][2] += a.y * bb.z; acc[1][3] += a.y * bb.w;
        acc[2][0] += a.z * bb.x; acc[2][1] += a.z * bb.y; acc[2][2] += a.z * bb.z; acc[2][3] += a.z * bb.w;
        acc[3][0] += a.w * bb.x; acc[3][1] += a.w * bb.y; acc[3][2] += a.w * bb.z; acc[3][3] += a.w * bb.w;
    }
#pragma unroll
    for (int io = 0; io < 4; io++) {
        int rrow = o0 + io;
        int i2 = rrow >> 5, o = rrow & 31;
        float* gp = &mix[(size_t)((b * 32 + o) * 1024 + n) * 256 + (i2 * 2 + xp) * 64 + l0];
        if (cp == 0) {
#pragma unroll
            for (int il = 0; il < 4; il++) gp[il] = acc[io][il];
        } else {
#pragma unroll
            for (int il = 0; il < 4; il++) gp[il] += acc[io][il];
        }
    }
}

// fused Wtf1(relu)Wtf2 in-place on mix: 16 rows/block (32KB LDS -> 5 blocks/CU)
__global__ __launch_bounds__(256) void k_tf(float* mix, const float* W1, const float* B1,
                                            const float* W2, const float* B2) {
    __shared__ float A[16][256];
    __shared__ float Hd[16][256];
    int t = threadIdx.x;
    size_t row0 = (size_t)blockIdx.x * 16;
    for (int i = t; i < 4096; i += 256) A[i >> 8][i & 255] = mix[row0 * 256 + i];
    __syncthreads();
    int cg = t & 63, rg = t >> 6;
    int c0 = cg * 4, r0 = rg * 4;
    float acc[4][4];
    {
        float4 bb = *(const float4*)&B1[c0];
#pragma unroll
        for (int ri = 0; ri < 4; ri++) { acc[ri][0] = bb.x; acc[ri][1] = bb.y; acc[ri][2] = bb.z; acc[ri][3] = bb.w; }
    }
    for (int k = 0; k < 256; k += 4) {
        float4 w0 = *(const float4*)&W1[(k + 0) * 256 + c0];
        float4 w1 = *(const float4*)&W1[(k + 1) * 256 + c0];
        float4 w2 = *(const float4*)&W1[(k + 2) * 256 + c0];
        float4 w3 = *(const float4*)&W1[(k + 3) * 256 + c0];
#pragma unroll
        for (int ri = 0; ri < 4; ri++) {
            float4 a = *(const float4*)&A[r0 + ri][k];
            acc[ri][0] += a.x * w0.x + a.y * w1.x + a.z * w2.x + a.w * w3.x;
            acc[ri][1] += a.x * w0.y + a.y * w1.y + a.z * w2.y + a.w * w3.y;
            acc[ri][2] += a.x * w0.z + a.y * w1.z + a.z * w2.z + a.w * w3.z;
            acc[ri][3] += a.x * w0.w + a.y * w1.w + a.z * w2.w + a.w * w3.w;
        }
    }
#pragma unroll
    for (int ri = 0; ri < 4; ri++) {
        float4 h;
        h.x = fmaxf(acc[ri][0], 0.f); h.y = fmaxf(acc[ri][1], 0.f);
        h.z = fmaxf(acc[ri][2], 0.f); h.w = fmaxf(acc[ri][3], 0.f);
        *(float4*)&Hd[r0 + ri][c0] = h;
    }
    __syncthreads();
    {
        float4 bb = *(const float4*)&B2[c0];
#pragma unroll
        for (int ri = 0; ri < 4; ri++) { acc[ri][0] = bb.x; acc[ri][1] = bb.y; acc[ri][2] = bb.z; acc[ri][3] = bb.w; }
    }
    for (int k = 0; k < 256; k += 4) {
        float4 w0 = *(const float4*)&W2[(k + 0) * 256 + c0];
        float4 w1 = *(const float4*)&W2[(k + 1) * 256 + c0];
        float4 w2 = *(const float4*)&W2[(k + 2) * 256 + c0];
        float4 w3 = *(const float4*)&W2[(k + 3) * 256 + c0];
#pragma unroll
        for (int ri = 0; ri < 4; ri++) {
            float4 a = *(const float4*)&Hd[r0 + ri][k];
            acc[ri][0] += a.x * w0.x + a.y * w1.x + a.z * w2.x + a.w * w3.x;
            acc[ri][1] += a.x * w0.y + a.y * w1.y + a.z * w2.y + a.w * w3.y;
            acc[ri][2] += a.x * w0.z + a.y * w1.z + a.z * w2.z + a.w * w3.z;
            acc[ri][3] += a.x * w0.w + a.y * w1.w + a.z * w2.w + a.w * w3.w;
        }
    }
#pragma unroll
    for (int ri = 0; ri < 4; ri++) {
        float4 o;
        o.x = acc[ri][0]; o.y = acc[ri][1]; o.z = acc[ri][2]; o.w = acc[ri][3];
        *(float4*)&mix[(row0 + r0 + ri) * 256 + c0] = o;
    }
}

// fused ec1(relu)+ec2: weights via wave-uniform (scalar) global reads; grid = CB*1024
__global__ __launch_bounds__(256) void k_ec(const float* tfo, const float* W1, const float* B1,
                                            const float* W2, const float* B2, float* eco) {
    __shared__ float X[32][256];
    int t = threadIdx.x;
    int b = blockIdx.x >> 10, n = blockIdx.x & 1023;
    for (int i = t; i < 8192; i += 256) {
        int c = i >> 8, l = i & 255;
        X[c][l] = tfo[(size_t)((b * 32 + c) * 1024 + n) * 256 + l];
    }
    __syncthreads();
    float x[32];
#pragma unroll
    for (int c = 0; c < 32; c++) x[c] = X[c][t];
    float out[12];
#pragma unroll
    for (int p = 0; p < 12; p++) out[p] = B2[p];      // uniform -> s_load
#pragma unroll 2
    for (int o = 0; o < 128; o++) {
        float a = B1[o];                               // uniform
        const float* wr = &W1[o * 32];                 // uniform base
#pragma unroll
        for (int c = 0; c < 32; c++) a += wr[c] * x[c];
        a = a > 0.f ? a : 0.f;
#pragma unroll
        for (int p = 0; p < 12; p++) out[p] += W2[p * 128 + o] * a;  // uniform
    }
#pragma unroll
    for (int p = 0; p < 12; p++)
        eco[(size_t)((b * 12 + p) * 1024 + n) * 256 + t] = out[p];
}

// fused fc1(relu)+fc2: 8 rows/block (31.5KB LDS -> 5 blocks/CU); grid = CB*1536
__global__ __launch_bounds__(256) void k_fc(const float* gated, const float* eco,
        const float* hd_emb, const float* hist, const float* tide, const float* diwe,
        const float* W1, const float* B1, const float* W2, const float* B2, float* fbuf) {
    __shared__ float A[8][472];
    __shared__ float Hd[8][512];
    float* redp = (float*)A;   // reused after A is dead (post fc1 k-loop)
    int t = threadIdx.x;
    int row0 = blockIdx.x * 8;
    for (int r = 0; r < 8; r++) {
        int row = row0 + r;
        int n = row & 1023, bt = row >> 10;
        int b = bt / 12, tt = bt - b * 12;
        const float* hrow = &hist[(size_t)row * 4];
        int tid_i = (int)(hrow[2] * 288.0f);
        int diw_i = (int)hrow[3];
        for (int j = t; j < 472; j += 256) {
            float v;
            if (j < 128) v = gated[(size_t)row * 128 + j];
            else if (j < 384) v = eco[(size_t)((b * 12 + tt) * 1024 + n) * 256 + (j - 128)];
            else if (j < 396) v = tide[tid_i * 12 + j - 384];
            else if (j < 408) v = diwe[diw_i * 12 + j - 396];
            else v = hd_emb[(size_t)row * 64 + j - 408];
            A[r][j] = fmaxf(v, 0.f);
        }
    }
    __syncthreads();
    float acc0[8], acc1[8];
    float b1a = B1[t], b1b = B1[t + 256];
#pragma unroll
    for (int r = 0; r < 8; r++) { acc0[r] = b1a; acc1[r] = b1b; }
    for (int k = 0; k < 472; k += 4) {
        float wa[4], wb[4];
#pragma unroll
        for (int q = 0; q < 4; q++) {
            wa[q] = W1[(k + q) * 512 + t];
            wb[q] = W1[(k + q) * 512 + t + 256];
        }
#pragma unroll
        for (int r = 0; r < 8; r++) {
            float4 a = *(const float4*)&A[r][k];
            acc0[r] += a.x * wa[0] + a.y * wa[1] + a.z * wa[2] + a.w * wa[3];
            acc1[r] += a.x * wb[0] + a.y * wb[1] + a.z * wb[2] + a.w * wb[3];
        }
    }
    __syncthreads();   // all A reads done before redp overwrites A
#pragma unroll
    for (int r = 0; r < 8; r++) {
        Hd[r][t] = fmaxf(acc0[r], 0.f);
        Hd[r][t + 256] = fmaxf(acc1[r], 0.f);
    }
    __syncthreads();
    {
        int r = t >> 5, seg = t & 31;    // 8 rows x 32 segs
        float p0 = 0.f, p1 = 0.f, p2 = 0.f;
        for (int j = 0; j < 16; j++) {
            int k = seg + j * 32;        // stride-1 across lanes: no bank conflict
            float h = Hd[r][k];
            p0 += h * W2[k * 3];
            p1 += h * W2[k * 3 + 1];
            p2 += h * W2[k * 3 + 2];
        }
        redp[r * 96 + seg] = p0;
        redp[r * 96 + 32 + seg] = p1;
        redp[r * 96 + 64 + seg] = p2;
    }
    __syncthreads();
    if (t < 24) {
        int rr = t / 3, p = t - rr * 3;
        float s = B2[p];
        for (int seg = 0; seg < 32; seg++) s += redp[rr * 96 + p * 32 + seg];
        fbuf[(size_t)(row0 + rr) * 3 + p] = s;
    }
}

// final conv1x1 over time + transpose; grid = CB*48
__global__ void k_ec3(const float* f, const float* W, const float* bv, float* out) {
    int idx = blockIdx.x * 256 + threadIdx.x;
    int l = idx % 3;
    int rest = idx / 3;
    int o = rest & 3;
    int n = (rest >> 2) & 1023;
    int b = rest >> 12;
    float s = bv[o];
#pragma unroll
    for (int c = 0; c < 12; c++)
        s += f[(size_t)((b * 12 + c) * 1024 + n) * 3 + l] * W[o * 12 + c];
    out[idx] = s;
}

// ---------------- launcher ----------------
extern "C" void kernel_launch(void* const* d_in, const int* in_sizes, int n_in,
                              void* d_out, int out_size, void* d_ws, size_t ws_size,
                              hipStream_t stream) {
    const float* hist = (const float*)d_in[0];
    const float* node_emb_u = (const float*)d_in[1];
    const float* T_i_D_emb = (const float*)d_in[2];
    const float* D_i_W_emb = (const float*)d_in[3];
    const float* gc_emb1 = (const float*)d_in[4];
    const float* gc_emb2 = (const float*)d_in[5];
    const float* gc_w1 = (const float*)d_in[6];
    const float* gc_b1 = (const float*)d_in[7];
    const float* gc_w2 = (const float*)d_in[8];
    const float* gc_b2 = (const float*)d_in[9];
    const float* W_emb = (const float*)d_in[10];
    const float* b_emb = (const float*)d_in[11];
    const float* Wg1 = (const float*)d_in[12];
    const float* bg1 = (const float*)d_in[13];
    const float* Wg2 = (const float*)d_in[14];
    const float* bg2 = (const float*)d_in[15];
    const float* Wsc = (const float*)d_in[16];
    const float* bsc = (const float*)d_in[17];
    const float* mix1_w = (const float*)d_in[18];
    const float* mix1_b = (const float*)d_in[19];
    const float* mix2_w = (const float*)d_in[20];
    const float* mix2_b = (const float*)d_in[21];
    const float* Wtf1 = (const float*)d_in[22];
    const float* btf1 = (const float*)d_in[23];
    const float* Wtf2 = (const float*)d_in[24];
    const float* btf2 = (const float*)d_in[25];
    const float* Wec1 = (const float*)d_in[26];
    const float* bec1 = (const float*)d_in[27];
    const float* Wec2 = (const float*)d_in[28];
    const float* bec2 = (const float*)d_in[29];
    const float* Wfc1 = (const float*)d_in[30];
    const float* bfc1 = (const float*)d_in[31];
    const float* Wfc2 = (const float*)d_in[32];
    const float* bfc2 = (const float*)d_in[33];
    const float* Wec3 = (const float*)d_in[34];
    const float* bec3 = (const float*)d_in[35];

    float* ws = (float*)d_ws;
    float* n1 = ws + F_N1;
    float* n2 = ws + F_N2;
    float* aN_val = ws + F_ANVAL;
    float* row_val = ws + F_ROWVAL;
    float* col_sum = ws + F_COLSUM;
    float* inv_cs = ws + F_INVCS;
    float* aT_val = ws + F_ATVAL;
    int* aN_idx = (int*)(ws + I_ANIDX);
    int* row_idx = (int*)(ws + I_ROWIDX);
    int* col_cnt = (int*)(ws + I_COLCNT);
    int* col_off = (int*)(ws + I_COLOFF);
    int* col_fill = (int*)(ws + I_COLFILL);
    int* aT_idx = (int*)(ws + I_ATIDX);

    // pick largest batch-chunk CB that fits the workspace
    size_t avail = ws_size / 4;   // floats
    int CB = 8;
    while (CB > 1 && GRAPH_FLOATS + (size_t)CB * PB_TOTAL > avail) CB >>= 1;
    int nchunk = 8 / CB;

    float* gated = ws + GRAPH_FLOATS;
    float* hd_emb = gated + (size_t)CB * PB_GATED;
    float* xs = hd_emb + (size_t)CB * PB_HD;
    float* h1 = xs + (size_t)CB * PB_XS;
    float* h2 = h1 + (size_t)CB * PB_XS;
    float* mix = h2 + (size_t)CB * PB_XS;
    float* eco = xs;    // alias: xs+h1 region >= eco
    float* fbuf = h2;   // alias: h2 dead by k_fc

    // ---- graph construction (once) ----
    k_init<<<4, 256, 0, stream>>>(col_cnt, col_fill, col_sum);
    k_embed<<<320, 256, 0, stream>>>(gc_emb1, gc_emb2, gc_w1, gc_b1, gc_w2, gc_b2, n1, n2);
    k_adj<<<1024, 256, 0, stream>>>(n1, n2, aN_val, aN_idx, row_val, row_idx, col_cnt, col_sum);
    k_scan<<<1, 1024, 0, stream>>>(col_cnt, col_off, col_sum, inv_cs);
    k_scatter<<<40, 256, 0, stream>>>(row_idx, row_val, col_off, col_fill, aT_idx, aT_val);

    // ---- per-chunk pipeline ----
    for (int ch = 0; ch < nchunk; ch++) {
        const float* hist_c = hist + (size_t)ch * CB * ROWS_PER_B * 4;
        float* out_c = (float*)d_out + (size_t)ch * CB * ROWS_PER_B;

        k_gate<<<CB * 3072, 256, 0, stream>>>(hist_c, node_emb_u, T_i_D_emb, D_i_W_emb,
                                              Wg1, bg1, Wg2, bg2, W_emb, b_emb, gated, hd_emb);
        for (int xp = 0; xp < 2; xp++) {
            k_wsc<<<CB * 256, 256, 0, stream>>>(gated, Wsc, bsc, xs, xp * 64);
            for (int cp = 0; cp < 2; cp++) {
                k_spmm<<<CB * 2048, 256, 0, stream>>>(h1, xs, xs, aN_idx, aN_val, aT_idx, aT_val,
                                                      col_off, inv_cs, cp);
                k_spmm<<<CB * 2048, 256, 0, stream>>>(h2, xs, h1, aN_idx, aN_val, aT_idx, aT_val,
                                                      col_off, inv_cs, cp);
                k_proj<<<CB * 1024, 256, 0, stream>>>(xs, h1, h2, cp ? mix2_w : mix1_w,
                                                      mix1_b, mix2_b, mix, xp, cp);
            }
        }
        k_tf<<<CB * 2048, 256, 0, stream>>>(mix, Wtf1, btf1, Wtf2, btf2);
        k_ec<<<CB * 1024, 256, 0, stream>>>(mix, Wec1, bec1, Wec2, bec2, eco);
        k_fc<<<CB * 1536, 256, 0, stream>>>(gated, eco, hd_emb, hist_c, T_i_D_emb, D_i_W_emb,
                                            Wfc1, bfc1, Wfc2, bfc2, fbuf);
        k_ec3<<<CB * 48, 256, 0, stream>>>(fbuf, Wec3, bec3, out_c);
    }
}

// Round 5
// 3796.057 us; speedup vs baseline: 1.2776x; 1.2776x over previous
//
#include <hip/hip_runtime.h>
#include <math.h>

// ---------------- constants ----------------
constexpr int ROWS_PER_B = 12 * 1024;    // rows (b,t,n) per batch element

// ---------------- graph workspace (float offsets, < 524288) ----------------
constexpr size_t F_N1 = 0;              // 1024*40
constexpr size_t F_N2 = 40960;
constexpr size_t F_ANVAL = 81920;       // 1024*11
constexpr size_t F_ROWVAL = 93184;      // 1024*10
constexpr size_t F_COLSUM = 103424;     // 1024
constexpr size_t F_INVCS = 104448;      // 1024
constexpr size_t F_ATVAL = 105472;      // 10240
constexpr size_t I_ANIDX = 115712;      // ints stored in float slots
constexpr size_t I_ROWIDX = 126976;
constexpr size_t I_COLCNT = 137216;
constexpr size_t I_COLOFF = 138240;     // 1025
constexpr size_t I_COLFILL = 139265;
constexpr size_t I_ATIDX = 140289;      // ends 150529
constexpr size_t F_W1P = 151552;        // packed bf16 Wtf1: 65536 shorts = 32768 floats
constexpr size_t F_W2P = 184320;        // packed bf16 Wtf2; ends 217088 < 524288
constexpr size_t GRAPH_FLOATS = 524288;

// per-chunk float counts (per batch element)
constexpr size_t PB_GATED = (size_t)ROWS_PER_B * 128;   // 1572864
constexpr size_t PB_HD = (size_t)ROWS_PER_B * 64;       // 786432
constexpr size_t PB_XS = (size_t)32 * 1024 * 64;        // 2097152
constexpr size_t PB_MIX = (size_t)32 * 1024 * 256;      // 8388608
constexpr size_t PB_TOTAL = PB_GATED + PB_HD + 3 * PB_XS + PB_MIX; // 17039360

typedef __attribute__((ext_vector_type(8))) short bf16x8;
typedef __attribute__((ext_vector_type(4))) float f32x4;

__device__ __forceinline__ unsigned short f2bf(float f) {
    unsigned u = __float_as_uint(f);
    unsigned r = (u + 0x7fffu + ((u >> 16) & 1u)) >> 16;   // RNE
    return (unsigned short)r;
}

// ---------------- graph kernels ----------------

__global__ void k_init(int* cnt, int* fill, float* csum) {
    int t = blockIdx.x * 256 + threadIdx.x;
    if (t < 1024) { cnt[t] = 0; fill[t] = 0; csum[t] = 0.f; }
}

__global__ void k_embed(const float* e1, const float* e2, const float* w1, const float* b1,
                        const float* w2, const float* b2, float* n1, float* n2) {
    int idx = blockIdx.x * 256 + threadIdx.x;   // < 81920
    if (idx >= 81920) return;
    int m = idx / 40960, rem = idx - m * 40960;
    int i = rem / 40, j = rem - i * 40;
    const float* e = m ? e2 : e1;
    const float* w = m ? w2 : w1;
    const float* bv = m ? b2 : b1;
    float a = bv[j];
    for (int k = 0; k < 40; k++) a += e[i * 40 + k] * w[k * 40 + j];
    (m ? n2 : n1)[i * 40 + j] = tanhf(3.0f * a);
}

__global__ __launch_bounds__(256) void k_adj(const float* n1, const float* n2,
        float* aN_val, int* aN_idx, float* row_val, int* row_idx,
        int* col_cnt, float* col_sum) {
    __shared__ float arow[1024];
    __shared__ float n1v[40], n2v[40];
    __shared__ float rv[256];
    __shared__ int ri[256];
    __shared__ float topv[10];
    __shared__ int topi[10];
    int v = blockIdx.x, t = threadIdx.x;
    if (t < 40) { n1v[t] = n1[v * 40 + t]; n2v[t] = n2[v * 40 + t]; }
    __syncthreads();
    for (int j = t; j < 1024; j += 256) {
        float d1 = 0.f, d2 = 0.f;
        for (int k = 0; k < 40; k++) {
            d1 += n1v[k] * n2[j * 40 + k];
            d2 += n2v[k] * n1[j * 40 + k];
        }
        float a = tanhf(3.0f * (d1 - d2));
        arow[j] = a > 0.f ? a : 0.f;
    }
    __syncthreads();
    for (int r = 0; r < 10; r++) {
        float bv = -1.f; int bi = 1 << 30;
        for (int j = t; j < 1024; j += 256) {
            float x = arow[j];
            if (x > bv || (x == bv && j < bi)) { bv = x; bi = j; }
        }
        rv[t] = bv; ri[t] = bi;
        __syncthreads();
        for (int s = 128; s > 0; s >>= 1) {
            if (t < s) {
                float ov = rv[t + s]; int oi = ri[t + s];
                if (ov > rv[t] || (ov == rv[t] && oi < ri[t])) { rv[t] = ov; ri[t] = oi; }
            }
            __syncthreads();
        }
        if (t == 0) { topv[r] = rv[0]; topi[r] = ri[0]; arow[ri[0]] = -1.f; }
        __syncthreads();
    }
    if (t == 0) {
        float s = 1.f;
        for (int r = 0; r < 10; r++) s += topv[r];
        float inv = 1.f / s;
        for (int r = 0; r < 10; r++) {
            aN_idx[v * 11 + r] = topi[r];
            aN_val[v * 11 + r] = topv[r] * inv;
            row_idx[v * 10 + r] = topi[r];
            row_val[v * 10 + r] = topv[r];
            atomicAdd(&col_cnt[topi[r]], 1);
            atomicAdd(&col_sum[topi[r]], topv[r]);
        }
        aN_idx[v * 11 + 10] = v;
        aN_val[v * 11 + 10] = inv;
    }
}

__global__ __launch_bounds__(1024) void k_scan(const int* cnt, int* off,
                                               const float* csum, float* inv) {
    __shared__ int tmp[1024];
    int t = threadIdx.x;
    tmp[t] = cnt[t];
    __syncthreads();
    for (int s = 1; s < 1024; s <<= 1) {
        int v = 0;
        if (t >= s) v = tmp[t - s];
        __syncthreads();
        tmp[t] += v;
        __syncthreads();
    }
    off[t + 1] = tmp[t];
    if (t == 0) off[0] = 0;
    inv[t] = 1.0f / (csum[t] + 1.0f);
}

__global__ void k_scatter(const int* row_idx, const float* row_val, const int* off,
                          int* fill, int* aT_idx, float* aT_val) {
    int e = blockIdx.x * 256 + threadIdx.x;
    if (e >= 10240) return;
    int v = e / 10;
    int j = row_idx[e];
    int pos = off[j] + atomicAdd(&fill[j], 1);
    aT_idx[pos] = v;
    aT_val[pos] = row_val[e];
}

// pack 256x256 f32 weight into MFMA B-fragment order:
// out[((kb*16+nb)*64+lane)*8+j] = bf16(W[(kb*32+(lane>>4)*8+j)*256 + nb*16+(lane&15)])
__global__ void k_packw(const float* W, unsigned short* out) {
    int id = blockIdx.x * 256 + threadIdx.x;    // 8192 total
    if (id >= 8192) return;
    int lane = id & 63, rest = id >> 6;
    int nb = rest & 15, kb = rest >> 4;
    int krow = kb * 32 + (lane >> 4) * 8;
    int col = nb * 16 + (lane & 15);
    unsigned short v[8];
#pragma unroll
    for (int j = 0; j < 8; j++) v[j] = f2bf(W[(size_t)(krow + j) * 256 + col]);
#pragma unroll
    for (int j = 0; j < 8; j++) out[(size_t)id * 8 + j] = v[j];
}

// ---------------- per-chunk kernels ----------------

// gate MLP + embed; grid = CB*3072
__global__ __launch_bounds__(256) void k_gate(const float* hist, const float* nodeu,
        const float* tide, const float* diwe,
        const float* Wg1, const float* bg1, const float* Wg2, const float* bg2,
        const float* Wemb, const float* bemb, float* gated, float* hd_emb) {
    __shared__ float w1[4096], w2[4096];
    __shared__ float gin[4][64], hid[4][64];
    __shared__ float sb1[64], sb2[64], we[128], be[64];
    int t = threadIdx.x;
    for (int i = t; i < 4096; i += 256) { w1[i] = Wg1[i]; w2[i] = Wg2[i]; }
    if (t < 64) { sb1[t] = bg1[t]; sb2[t] = bg2[t]; be[t] = bemb[t]; }
    if (t < 128) we[t] = Wemb[t];
    int r = t >> 6, lane = t & 63;
    int row = blockIdx.x * 4 + r;
    int n = row & 1023;
    const float* hrow = hist + (size_t)row * 4;
    float f0 = hrow[0], f1 = hrow[1];
    int tid_i = (int)(hrow[2] * 288.0f);
    int diw_i = (int)hrow[3];
    float g;
    if (lane < 40) g = nodeu[n * 40 + lane];
    else if (lane < 52) g = tide[tid_i * 12 + lane - 40];
    else g = diwe[diw_i * 12 + lane - 52];
    gin[r][lane] = g;
    __syncthreads();
    float acc = sb1[lane];
    for (int k = 0; k < 64; k++) acc += gin[r][k] * w1[k * 64 + lane];
    hid[r][lane] = acc > 0.f ? acc : 0.f;
    __syncthreads();
    acc = sb2[lane];
    for (int k = 0; k < 64; k++) acc += hid[r][k] * w2[k * 64 + lane];
    float gate = 1.f / (1.f + expf(-acc));
    float hd = f0 * we[lane] + f1 * we[64 + lane] + be[lane];
    float x1 = gate * hd;
    gated[(size_t)row * 128 + lane] = x1;
    gated[(size_t)row * 128 + 64 + lane] = hd - x1;
    hd_emb[(size_t)row * 64 + lane] = hd;
}

// xs[b,o,n,h] = relu(sum_t gated*Wsc + bsc); grid = CB*256
__global__ __launch_bounds__(256) void k_wsc(const float* gated, const float* Wsc,
                                             const float* bsc, float* xs, int xoff) {
    __shared__ float w[384];
    __shared__ float sb[32];
    int t = threadIdx.x;
    if (t < 384) w[t] = Wsc[t];
    if (t < 32) sb[t] = bsc[t];
    __syncthreads();
    int idx = blockIdx.x * 256 + t;
    int h = idx & 63, n = (idx >> 6) & 1023, b = idx >> 16;
    float xv[12];
#pragma unroll
    for (int tt = 0; tt < 12; tt++)
        xv[tt] = gated[(size_t)((b * 12 + tt) * 1024 + n) * 128 + xoff + h];
#pragma unroll
    for (int o = 0; o < 32; o++) {
        float a = sb[o];
#pragma unroll
        for (int tt = 0; tt < 12; tt++) a += xv[tt] * w[o * 12 + tt];
        xs[(size_t)((b * 32 + o) * 1024 + n) * 64 + h] = a > 0.f ? a : 0.f;
    }
}

// out = 0.05*x + 0.95*(A_norm @ hin), float4 lanes; grid = CB*2048 (16 rows/block)
__global__ __launch_bounds__(256) void k_spmm(float* out, const float* x, const float* hin,
        const int* aN_idx, const float* aN_val,
        const int* aT_idx, const float* aT_val,
        const int* off, const float* inv_cs, int mode) {
    int t = threadIdx.x;
    int l4 = t & 15, r = t >> 4;            // 16 rows x 16 float4-lanes
    int g = blockIdx.x * 16 + r;            // row id (bc, v)
    int v = g & 1023, bc = g >> 10;
    const float4* base = (const float4*)hin + (size_t)bc * 16384;
    float4 s;
    if (mode == 0) {
        s.x = s.y = s.z = s.w = 0.f;
#pragma unroll
        for (int e = 0; e < 11; e++) {
            int w = aN_idx[v * 11 + e];
            float a = aN_val[v * 11 + e];
            float4 hv = base[w * 16 + l4];
            s.x += a * hv.x; s.y += a * hv.y; s.z += a * hv.z; s.w += a * hv.w;
        }
    } else {
        s = base[v * 16 + l4];
        int e0 = off[v], e1 = off[v + 1];
        for (int e = e0; e < e1; e++) {
            int w = aT_idx[e];
            float a = aT_val[e];
            float4 hv = base[w * 16 + l4];
            s.x += a * hv.x; s.y += a * hv.y; s.z += a * hv.z; s.w += a * hv.w;
        }
        float ic = inv_cs[v];
        s.x *= ic; s.y *= ic; s.z *= ic; s.w *= ic;
    }
    size_t oi = (size_t)g * 16 + l4;
    float4 xv = ((const float4*)x)[oi];
    float4 o;
    o.x = 0.05f * xv.x + 0.95f * s.x;
    o.y = 0.05f * xv.y + 0.95f * s.y;
    o.z = 0.05f * xv.z + 0.95f * s.z;
    o.w = 0.05f * xv.w + 0.95f * s.w;
    ((float4*)out)[oi] = o;
}

// mix projection; grid = CB*1024
__global__ __launch_bounds__(256) void k_proj(const float* xs, const float* h1, const float* h2,
        const float* mw, const float* m1b, const float* m2b,
        float* mix, int xp, int cp) {
    __shared__ float Wl[96 * 64];
    __shared__ float Bt[96 * 64];
    int t = threadIdx.x;
    int b = blockIdx.x >> 10, n = blockIdx.x & 1023;
    for (int i = t; i < 6144; i += 256) {
        int k = i >> 6, col = i & 63;
        Wl[i] = mw[col * 96 + k];
    }
    for (int i = t; i < 6144; i += 256) {
        int k = i >> 6, l = i & 63;
        int q = k >> 5, c = k & 31;
        const float* Hq = (q == 0) ? xs : (q == 1 ? h1 : h2);
        Bt[i] = Hq[(size_t)((b * 32 + c) * 1024 + n) * 64 + l];
    }
    __syncthreads();
    int tx = t & 15, ty = t >> 4;
    int o0 = tx * 4, l0 = ty * 4;
    float acc[4][4];
#pragma unroll
    for (int io = 0; io < 4; io++) {
        float bias = 0.f;
        if (cp == 0) { int rrow = o0 + io; bias = m1b[rrow] + m2b[rrow]; }
#pragma unroll
        for (int il = 0; il < 4; il++) acc[io][il] = bias;
    }
    for (int k = 0; k < 96; k++) {
        float4 a = *(const float4*)&Wl[k * 64 + o0];
        float4 bb = *(const float4*)&Bt[k * 64 + l0];
        acc[0][0] += a.x * bb.x; acc[0][1] += a.x * bb.y; acc[0][2] += a.x * bb.z; acc[0][3] += a.x * bb.w;
        acc[1][0] += a.y * bb.x; acc[1][1] += a.y * bb.y; acc[1][2] += a.y * bb.z; acc[1][3] += a.y * bb.w;
        acc[2][0] += a.z * bb.x; acc[2][1] += a.z * bb.y; acc[2][2] += a.z * bb.z; acc[2][3] += a.z * bb.w;
        acc[3][0] += a.w * bb.x; acc[3][1] += a.w * bb.y; acc[3][2] += a.w * bb.z; acc[3][3] += a.w * bb.w;
    }
#pragma unroll
    for (int io = 0; io < 4; io++) {
        int rrow = o0 + io;
        int i2 = rrow >> 5, o = rrow & 31;
        float* gp = &mix[(size_t)((b * 32 + o) * 1024 + n) * 256 + (i2 * 2 + xp) * 64 + l0];
        if (cp == 0) {
#pragma unroll
            for (int il = 0; il < 4; il++) gp[il] = acc[io][il];
        } else {
#pragma unroll
            for (int il = 0; il < 4; il++) gp[il] += acc[io][il];
        }
    }
}

// fused Wtf1(relu)Wtf2 via bf16 MFMA, in-place on mix: 32 rows/block; grid = CB*1024
__global__ __launch_bounds__(256) void k_tf(float* mix, const unsigned short* W1p, const float* B1,
                                            const unsigned short* W2p, const float* B2) {
    __shared__ unsigned short Abuf[32 * 256];   // bf16, XOR-swizzled
    __shared__ unsigned short Hbuf[32 * 256];
    int t = threadIdx.x;
    int wave = t >> 6, l = t & 63;
    size_t row0 = (size_t)blockIdx.x * 32;
    // ---- stage A = 32 mix rows -> bf16 LDS (swizzled) ----
    const float4* src = (const float4*)(mix + row0 * 256);
#pragma unroll
    for (int it = 0; it < 8; it++) {
        int f = t + it * 256;                  // 2048 float4s
        float4 v = src[f];
        int e = f * 4, row = e >> 8, col = e & 255;
        unsigned lo = f2bf(v.x) | ((unsigned)f2bf(v.y) << 16);
        unsigned hi = f2bf(v.z) | ((unsigned)f2bf(v.w) << 16);
        int byte = (row * 512 + col * 2) ^ ((row & 7) << 4);
        uint2 pk; pk.x = lo; pk.y = hi;
        *(uint2*)((char*)Abuf + byte) = pk;
    }
    __syncthreads();
    int colg0 = wave * 64;                     // this wave's 64-col slice
    int lr = l & 15, lg = l >> 4;
    f32x4 acc[2][4];
    // ---- layer 1: Hd = relu(A @ W1 + B1) ----
#pragma unroll
    for (int nb = 0; nb < 4; nb++) {
        float bv = B1[colg0 + nb * 16 + lr];
        f32x4 c; c[0] = bv; c[1] = bv; c[2] = bv; c[3] = bv;
        acc[0][nb] = c; acc[1][nb] = c;
    }
#pragma unroll
    for (int kb = 0; kb < 8; kb++) {
        int k2 = (kb * 32 + lg * 8) * 2;
        int by0 = (lr * 512 + k2) ^ ((lr & 7) << 4);
        int by1 = ((16 + lr) * 512 + k2) ^ ((lr & 7) << 4);
        bf16x8 a0 = *(const bf16x8*)((char*)Abuf + by0);
        bf16x8 a1 = *(const bf16x8*)((char*)Abuf + by1);
#pragma unroll
        for (int nb = 0; nb < 4; nb++) {
            int nbg = wave * 4 + nb;
            bf16x8 bw = *(const bf16x8*)(W1p + (size_t)((kb * 16 + nbg) * 64 + l) * 8);
            acc[0][nb] = __builtin_amdgcn_mfma_f32_16x16x32_bf16(a0, bw, acc[0][nb], 0, 0, 0);
            acc[1][nb] = __builtin_amdgcn_mfma_f32_16x16x32_bf16(a1, bw, acc[1][nb], 0, 0, 0);
        }
    }
    // write Hd (relu, bf16, swizzled)
#pragma unroll
    for (int rb = 0; rb < 2; rb++)
#pragma unroll
        for (int nb = 0; nb < 4; nb++)
#pragma unroll
            for (int r = 0; r < 4; r++) {
                int row = rb * 16 + lg * 4 + r;
                int col = colg0 + nb * 16 + lr;
                unsigned short h = f2bf(fmaxf(acc[rb][nb][r], 0.f));
                int byte = (row * 512 + col * 2) ^ ((row & 7) << 4);
                *(unsigned short*)((char*)Hbuf + byte) = h;
            }
    __syncthreads();
    // ---- layer 2: out = Hd @ W2 + B2 ----
#pragma unroll
    for (int nb = 0; nb < 4; nb++) {
        float bv = B2[colg0 + nb * 16 + lr];
        f32x4 c; c[0] = bv; c[1] = bv; c[2] = bv; c[3] = bv;
        acc[0][nb] = c; acc[1][nb] = c;
    }
#pragma unroll
    for (int kb = 0; kb < 8; kb++) {
        int k2 = (kb * 32 + lg * 8) * 2;
        int by0 = (lr * 512 + k2) ^ ((lr & 7) << 4);
        int by1 = ((16 + lr) * 512 + k2) ^ ((lr & 7) << 4);
        bf16x8 a0 = *(const bf16x8*)((char*)Hbuf + by0);
        bf16x8 a1 = *(const bf16x8*)((char*)Hbuf + by1);
#pragma unroll
        for (int nb = 0; nb < 4; nb++) {
            int nbg = wave * 4 + nb;
            bf16x8 bw = *(const bf16x8*)(W2p + (size_t)((kb * 16 + nbg) * 64 + l) * 8);
            acc[0][nb] = __builtin_amdgcn_mfma_f32_16x16x32_bf16(a0, bw, acc[0][nb], 0, 0, 0);
            acc[1][nb] = __builtin_amdgcn_mfma_f32_16x16x32_bf16(a1, bw, acc[1][nb], 0, 0, 0);
        }
    }
#pragma unroll
    for (int rb = 0; rb < 2; rb++)
#pragma unroll
        for (int nb = 0; nb < 4; nb++)
#pragma unroll
            for (int r = 0; r < 4; r++) {
                int row = rb * 16 + lg * 4 + r;
                int col = colg0 + nb * 16 + lr;
                mix[(row0 + row) * 256 + col] = acc[rb][nb][r];
            }
}

// fused ec1(relu)+ec2: weights via wave-uniform (scalar) global reads; grid = CB*1024
__global__ __launch_bounds__(256) void k_ec(const float* tfo, const float* W1, const float* B1,
                                            const float* W2, const float* B2, float* eco) {
    __shared__ float X[32][256];
    int t = threadIdx.x;
    int b = blockIdx.x >> 10, n = blockIdx.x & 1023;
    for (int i = t; i < 8192; i += 256) {
        int c = i >> 8, l = i & 255;
        X[c][l] = tfo[(size_t)((b * 32 + c) * 1024 + n) * 256 + l];
    }
    __syncthreads();
    float x[32];
#pragma unroll
    for (int c = 0; c < 32; c++) x[c] = X[c][t];
    float out[12];
#pragma unroll
    for (int p = 0; p < 12; p++) out[p] = B2[p];      // uniform -> s_load
#pragma unroll 2
    for (int o = 0; o < 128; o++) {
        float a = B1[o];                               // uniform
        const float* wr = &W1[o * 32];                 // uniform base
#pragma unroll
        for (int c = 0; c < 32; c++) a += wr[c] * x[c];
        a = a > 0.f ? a : 0.f;
#pragma unroll
        for (int p = 0; p < 12; p++) out[p] += W2[p * 128 + o] * a;  // uniform
    }
#pragma unroll
    for (int p = 0; p < 12; p++)
        eco[(size_t)((b * 12 + p) * 1024 + n) * 256 + t] = out[p];
}

// fused fc1(relu)+fc2: 8 rows/block; grid = CB*1536
__global__ __launch_bounds__(256) void k_fc(const float* gated, const float* eco,
        const float* hd_emb, const float* hist, const float* tide, const float* diwe,
        const float* W1, const float* B1, const float* W2, const float* B2, float* fbuf) {
    __shared__ float A[8][472];
    __shared__ float Hd[8][512];
    float* redp = (float*)A;   // reused after A is dead (post fc1 k-loop)
    int t = threadIdx.x;
    int row0 = blockIdx.x * 8;
    for (int r = 0; r < 8; r++) {
        int row = row0 + r;
        int n = row & 1023, bt = row >> 10;
        int b = bt / 12, tt = bt - b * 12;
        const float* hrow = &hist[(size_t)row * 4];
        int tid_i = (int)(hrow[2] * 288.0f);
        int diw_i = (int)hrow[3];
        for (int j = t; j < 472; j += 256) {
            float v;
            if (j < 128) v = gated[(size_t)row * 128 + j];
            else if (j < 384) v = eco[(size_t)((b * 12 + tt) * 1024 + n) * 256 + (j - 128)];
            else if (j < 396) v = tide[tid_i * 12 + j - 384];
            else if (j < 408) v = diwe[diw_i * 12 + j - 396];
            else v = hd_emb[(size_t)row * 64 + j - 408];
            A[r][j] = fmaxf(v, 0.f);
        }
    }
    __syncthreads();
    float acc0[8], acc1[8];
    float b1a = B1[t], b1b = B1[t + 256];
#pragma unroll
    for (int r = 0; r < 8; r++) { acc0[r] = b1a; acc1[r] = b1b; }
    for (int k = 0; k < 472; k += 4) {
        float wa[4], wb[4];
#pragma unroll
        for (int q = 0; q < 4; q++) {
            wa[q] = W1[(k + q) * 512 + t];
            wb[q] = W1[(k + q) * 512 + t + 256];
        }
#pragma unroll
        for (int r = 0; r < 8; r++) {
            float4 a = *(const float4*)&A[r][k];
            acc0[r] += a.x * wa[0] + a.y * wa[1] + a.z * wa[2] + a.w * wa[3];
            acc1[r] += a.x * wb[0] + a.y * wb[1] + a.z * wb[2] + a.w * wb[3];
        }
    }
    __syncthreads();   // all A reads done before redp overwrites A
#pragma unroll
    for (int r = 0; r < 8; r++) {
        Hd[r][t] = fmaxf(acc0[r], 0.f);
        Hd[r][t + 256] = fmaxf(acc1[r], 0.f);
    }
    __syncthreads();
    {
        int r = t >> 5, seg = t & 31;    // 8 rows x 32 segs
        float p0 = 0.f, p1 = 0.f, p2 = 0.f;
        for (int j = 0; j < 16; j++) {
            int k = seg + j * 32;        // stride-1 across lanes: no bank conflict
            float h = Hd[r][k];
            p0 += h * W2[k * 3];
            p1 += h * W2[k * 3 + 1];
            p2 += h * W2[k * 3 + 2];
        }
        redp[r * 96 + seg] = p0;
        redp[r * 96 + 32 + seg] = p1;
        redp[r * 96 + 64 + seg] = p2;
    }
    __syncthreads();
    if (t < 24) {
        int rr = t / 3, p = t - rr * 3;
        float s = B2[p];
        for (int seg = 0; seg < 32; seg++) s += redp[rr * 96 + p * 32 + seg];
        fbuf[(size_t)(row0 + rr) * 3 + p] = s;
    }
}

// final conv1x1 over time + transpose; grid = CB*48
__global__ void k_ec3(const float* f, const float* W, const float* bv, float* out) {
    int idx = blockIdx.x * 256 + threadIdx.x;
    int l = idx % 3;
    int rest = idx / 3;
    int o = rest & 3;
    int n = (rest >> 2) & 1023;
    int b = rest >> 12;
    float s = bv[o];
#pragma unroll
    for (int c = 0; c < 12; c++)
        s += f[(size_t)((b * 12 + c) * 1024 + n) * 3 + l] * W[o * 12 + c];
    out[idx] = s;
}

// ---------------- launcher ----------------
extern "C" void kernel_launch(void* const* d_in, const int* in_sizes, int n_in,
                              void* d_out, int out_size, void* d_ws, size_t ws_size,
                              hipStream_t stream) {
    const float* hist = (const float*)d_in[0];
    const float* node_emb_u = (const float*)d_in[1];
    const float* T_i_D_emb = (const float*)d_in[2];
    const float* D_i_W_emb = (const float*)d_in[3];
    const float* gc_emb1 = (const float*)d_in[4];
    const float* gc_emb2 = (const float*)d_in[5];
    const float* gc_w1 = (const float*)d_in[6];
    const float* gc_b1 = (const float*)d_in[7];
    const float* gc_w2 = (const float*)d_in[8];
    const float* gc_b2 = (const float*)d_in[9];
    const float* W_emb = (const float*)d_in[10];
    const float* b_emb = (const float*)d_in[11];
    const float* Wg1 = (const float*)d_in[12];
    const float* bg1 = (const float*)d_in[13];
    const float* Wg2 = (const float*)d_in[14];
    const float* bg2 = (const float*)d_in[15];
    const float* Wsc = (const float*)d_in[16];
    const float* bsc = (const float*)d_in[17];
    const float* mix1_w = (const float*)d_in[18];
    const float* mix1_b = (const float*)d_in[19];
    const float* mix2_w = (const float*)d_in[20];
    const float* mix2_b = (const float*)d_in[21];
    const float* Wtf1 = (const float*)d_in[22];
    const float* btf1 = (const float*)d_in[23];
    const float* Wtf2 = (const float*)d_in[24];
    const float* btf2 = (const float*)d_in[25];
    const float* Wec1 = (const float*)d_in[26];
    const float* bec1 = (const float*)d_in[27];
    const float* Wec2 = (const float*)d_in[28];
    const float* bec2 = (const float*)d_in[29];
    const float* Wfc1 = (const float*)d_in[30];
    const float* bfc1 = (const float*)d_in[31];
    const float* Wfc2 = (const float*)d_in[32];
    const float* bfc2 = (const float*)d_in[33];
    const float* Wec3 = (const float*)d_in[34];
    const float* bec3 = (const float*)d_in[35];

    float* ws = (float*)d_ws;
    float* n1 = ws + F_N1;
    float* n2 = ws + F_N2;
    float* aN_val = ws + F_ANVAL;
    float* row_val = ws + F_ROWVAL;
    float* col_sum = ws + F_COLSUM;
    float* inv_cs = ws + F_INVCS;
    float* aT_val = ws + F_ATVAL;
    int* aN_idx = (int*)(ws + I_ANIDX);
    int* row_idx = (int*)(ws + I_ROWIDX);
    int* col_cnt = (int*)(ws + I_COLCNT);
    int* col_off = (int*)(ws + I_COLOFF);
    int* col_fill = (int*)(ws + I_COLFILL);
    int* aT_idx = (int*)(ws + I_ATIDX);
    unsigned short* w1p = (unsigned short*)(ws + F_W1P);
    unsigned short* w2p = (unsigned short*)(ws + F_W2P);

    // pick largest batch-chunk CB that fits the workspace
    size_t avail = ws_size / 4;   // floats
    int CB = 8;
    while (CB > 1 && GRAPH_FLOATS + (size_t)CB * PB_TOTAL > avail) CB >>= 1;
    int nchunk = 8 / CB;

    float* gated = ws + GRAPH_FLOATS;
    float* hd_emb = gated + (size_t)CB * PB_GATED;
    float* xs = hd_emb + (size_t)CB * PB_HD;
    float* h1 = xs + (size_t)CB * PB_XS;
    float* h2 = h1 + (size_t)CB * PB_XS;
    float* mix = h2 + (size_t)CB * PB_XS;
    float* eco = xs;    // alias: xs+h1 region >= eco
    float* fbuf = h2;   // alias: h2 dead by k_fc

    // ---- graph construction + weight packing (once) ----
    k_init<<<4, 256, 0, stream>>>(col_cnt, col_fill, col_sum);
    k_embed<<<320, 256, 0, stream>>>(gc_emb1, gc_emb2, gc_w1, gc_b1, gc_w2, gc_b2, n1, n2);
    k_adj<<<1024, 256, 0, stream>>>(n1, n2, aN_val, aN_idx, row_val, row_idx, col_cnt, col_sum);
    k_scan<<<1, 1024, 0, stream>>>(col_cnt, col_off, col_sum, inv_cs);
    k_scatter<<<40, 256, 0, stream>>>(row_idx, row_val, col_off, col_fill, aT_idx, aT_val);
    k_packw<<<32, 256, 0, stream>>>(Wtf1, w1p);
    k_packw<<<32, 256, 0, stream>>>(Wtf2, w2p);

    // ---- per-chunk pipeline ----
    for (int ch = 0; ch < nchunk; ch++) {
        const float* hist_c = hist + (size_t)ch * CB * ROWS_PER_B * 4;
        float* out_c = (float*)d_out + (size_t)ch * CB * ROWS_PER_B;

        k_gate<<<CB * 3072, 256, 0, stream>>>(hist_c, node_emb_u, T_i_D_emb, D_i_W_emb,
                                              Wg1, bg1, Wg2, bg2, W_emb, b_emb, gated, hd_emb);
        for (int xp = 0; xp < 2; xp++) {
            k_wsc<<<CB * 256, 256, 0, stream>>>(gated, Wsc, bsc, xs, xp * 64);
            for (int cp = 0; cp < 2; cp++) {
                k_spmm<<<CB * 2048, 256, 0, stream>>>(h1, xs, xs, aN_idx, aN_val, aT_idx, aT_val,
                                                      col_off, inv_cs, cp);
                k_spmm<<<CB * 2048, 256, 0, stream>>>(h2, xs, h1, aN_idx, aN_val, aT_idx, aT_val,
                                                      col_off, inv_cs, cp);
                k_proj<<<CB * 1024, 256, 0, stream>>>(xs, h1, h2, cp ? mix2_w : mix1_w,
                                                      mix1_b, mix2_b, mix, xp, cp);
            }
        }
        k_tf<<<CB * 1024, 256, 0, stream>>>(mix, w1p, btf1, w2p, btf2);
        k_ec<<<CB * 1024, 256, 0, stream>>>(mix, Wec1, bec1, Wec2, bec2, eco);
        k_fc<<<CB * 1536, 256, 0, stream>>>(gated, eco, hd_emb, hist_c, T_i_D_emb, D_i_W_emb,
                                            Wfc1, bfc1, Wfc2, bfc2, fbuf);
        k_ec3<<<CB * 48, 256, 0, stream>>>(fbuf, Wec3, bec3, out_c);
    }
}

// Round 6
// 3215.472 us; speedup vs baseline: 1.5083x; 1.1806x over previous
//
#include <hip/hip_runtime.h>
#include <math.h>

// ---------------- constants ----------------
constexpr int ROWS_PER_B = 12 * 1024;    // rows (b,t,n) per batch element

// ---------------- graph workspace (float offsets, < 524288) ----------------
constexpr size_t F_N1 = 0;              // 1024*40
constexpr size_t F_N2 = 40960;
constexpr size_t F_ANVAL = 81920;       // 1024*11
constexpr size_t F_ROWVAL = 93184;      // 1024*10
constexpr size_t F_COLSUM = 103424;     // 1024
constexpr size_t F_INVCS = 104448;      // 1024
constexpr size_t F_ATVAL = 105472;      // 10240
constexpr size_t I_ANIDX = 115712;      // ints stored in float slots
constexpr size_t I_ROWIDX = 126976;
constexpr size_t I_COLCNT = 137216;
constexpr size_t I_COLOFF = 138240;     // 1025
constexpr size_t I_COLFILL = 139265;
constexpr size_t I_ATIDX = 140289;      // ends 150529
constexpr size_t F_W1P = 151552;        // packed bf16 Wtf1: 65536 shorts = 32768 floats
constexpr size_t F_W2P = 184320;        // packed bf16 Wtf2: ends 217088
constexpr size_t F_WFCP = 217088;       // packed bf16 Wfc1: 245760 shorts = 122880 floats -> ends 339968
constexpr size_t GRAPH_FLOATS = 524288;

// per-chunk float counts (per batch element)
constexpr size_t PB_GATED = (size_t)ROWS_PER_B * 128;   // 1572864
constexpr size_t PB_HD = (size_t)ROWS_PER_B * 64;       // 786432
constexpr size_t PB_XS = (size_t)32 * 1024 * 64;        // 2097152
constexpr size_t PB_MIX = (size_t)32 * 1024 * 256;      // 8388608
constexpr size_t PB_TOTAL = PB_GATED + PB_HD + 3 * PB_XS + PB_MIX; // 17039360

typedef __attribute__((ext_vector_type(8))) short bf16x8;
typedef __attribute__((ext_vector_type(4))) float f32x4;

__device__ __forceinline__ unsigned short f2bf(float f) {
    unsigned u = __float_as_uint(f);
    unsigned r = (u + 0x7fffu + ((u >> 16) & 1u)) >> 16;   // RNE
    return (unsigned short)r;
}
__device__ __forceinline__ float bf2f(unsigned short h) {
    return __uint_as_float((unsigned)h << 16);
}

// ---------------- graph kernels ----------------

__global__ void k_init(int* cnt, int* fill, float* csum) {
    int t = blockIdx.x * 256 + threadIdx.x;
    if (t < 1024) { cnt[t] = 0; fill[t] = 0; csum[t] = 0.f; }
}

__global__ void k_embed(const float* e1, const float* e2, const float* w1, const float* b1,
                        const float* w2, const float* b2, float* n1, float* n2) {
    int idx = blockIdx.x * 256 + threadIdx.x;   // < 81920
    if (idx >= 81920) return;
    int m = idx / 40960, rem = idx - m * 40960;
    int i = rem / 40, j = rem - i * 40;
    const float* e = m ? e2 : e1;
    const float* w = m ? w2 : w1;
    const float* bv = m ? b2 : b1;
    float a = bv[j];
    for (int k = 0; k < 40; k++) a += e[i * 40 + k] * w[k * 40 + j];
    (m ? n2 : n1)[i * 40 + j] = tanhf(3.0f * a);
}

__global__ __launch_bounds__(256) void k_adj(const float* n1, const float* n2,
        float* aN_val, int* aN_idx, float* row_val, int* row_idx,
        int* col_cnt, float* col_sum) {
    __shared__ float arow[1024];
    __shared__ float n1v[40], n2v[40];
    __shared__ float rv[256];
    __shared__ int ri[256];
    __shared__ float topv[10];
    __shared__ int topi[10];
    int v = blockIdx.x, t = threadIdx.x;
    if (t < 40) { n1v[t] = n1[v * 40 + t]; n2v[t] = n2[v * 40 + t]; }
    __syncthreads();
    for (int j = t; j < 1024; j += 256) {
        float d1 = 0.f, d2 = 0.f;
        for (int k = 0; k < 40; k++) {
            d1 += n1v[k] * n2[j * 40 + k];
            d2 += n2v[k] * n1[j * 40 + k];
        }
        float a = tanhf(3.0f * (d1 - d2));
        arow[j] = a > 0.f ? a : 0.f;
    }
    __syncthreads();
    for (int r = 0; r < 10; r++) {
        float bv = -1.f; int bi = 1 << 30;
        for (int j = t; j < 1024; j += 256) {
            float x = arow[j];
            if (x > bv || (x == bv && j < bi)) { bv = x; bi = j; }
        }
        rv[t] = bv; ri[t] = bi;
        __syncthreads();
        for (int s = 128; s > 0; s >>= 1) {
            if (t < s) {
                float ov = rv[t + s]; int oi = ri[t + s];
                if (ov > rv[t] || (ov == rv[t] && oi < ri[t])) { rv[t] = ov; ri[t] = oi; }
            }
            __syncthreads();
        }
        if (t == 0) { topv[r] = rv[0]; topi[r] = ri[0]; arow[ri[0]] = -1.f; }
        __syncthreads();
    }
    if (t == 0) {
        float s = 1.f;
        for (int r = 0; r < 10; r++) s += topv[r];
        float inv = 1.f / s;
        for (int r = 0; r < 10; r++) {
            aN_idx[v * 11 + r] = topi[r];
            aN_val[v * 11 + r] = topv[r] * inv;
            row_idx[v * 10 + r] = topi[r];
            row_val[v * 10 + r] = topv[r];
            atomicAdd(&col_cnt[topi[r]], 1);
            atomicAdd(&col_sum[topi[r]], topv[r]);
        }
        aN_idx[v * 11 + 10] = v;
        aN_val[v * 11 + 10] = inv;
    }
}

__global__ __launch_bounds__(1024) void k_scan(const int* cnt, int* off,
                                               const float* csum, float* inv) {
    __shared__ int tmp[1024];
    int t = threadIdx.x;
    tmp[t] = cnt[t];
    __syncthreads();
    for (int s = 1; s < 1024; s <<= 1) {
        int v = 0;
        if (t >= s) v = tmp[t - s];
        __syncthreads();
        tmp[t] += v;
        __syncthreads();
    }
    off[t + 1] = tmp[t];
    if (t == 0) off[0] = 0;
    inv[t] = 1.0f / (csum[t] + 1.0f);
}

__global__ void k_scatter(const int* row_idx, const float* row_val, const int* off,
                          int* fill, int* aT_idx, float* aT_val) {
    int e = blockIdx.x * 256 + threadIdx.x;
    if (e >= 10240) return;
    int v = e / 10;
    int j = row_idx[e];
    int pos = off[j] + atomicAdd(&fill[j], 1);
    aT_idx[pos] = v;
    aT_val[pos] = row_val[e];
}

// pack 256x256 f32 weight into MFMA B-fragment order
__global__ void k_packw(const float* W, unsigned short* out) {
    int id = blockIdx.x * 256 + threadIdx.x;    // 8192 total
    if (id >= 8192) return;
    int lane = id & 63, rest = id >> 6;
    int nb = rest & 15, kb = rest >> 4;
    int krow = kb * 32 + (lane >> 4) * 8;
    int col = nb * 16 + (lane & 15);
    unsigned short v[8];
#pragma unroll
    for (int j = 0; j < 8; j++) v[j] = f2bf(W[(size_t)(krow + j) * 256 + col]);
#pragma unroll
    for (int j = 0; j < 8; j++) out[(size_t)id * 8 + j] = v[j];
}

// pack 472x512 Wfc1 into B-fragment order, K padded to 480
__global__ void k_packfc(const float* W, unsigned short* out) {
    int id = blockIdx.x * 256 + threadIdx.x;    // 30720 total
    if (id >= 30720) return;
    int lane = id & 63, rest = id >> 6;
    int nb = rest & 31, kb = rest >> 5;         // kb < 15
    int k0 = kb * 32 + (lane >> 4) * 8;
    int col = nb * 16 + (lane & 15);
    unsigned short v[8];
#pragma unroll
    for (int j = 0; j < 8; j++) {
        int k = k0 + j;
        v[j] = (k < 472) ? f2bf(W[(size_t)k * 512 + col]) : (unsigned short)0;
    }
#pragma unroll
    for (int j = 0; j < 8; j++) out[(size_t)id * 8 + j] = v[j];
}

// ---------------- per-chunk kernels ----------------

// gate MLP + embed; grid = CB*3072
__global__ __launch_bounds__(256) void k_gate(const float* hist, const float* nodeu,
        const float* tide, const float* diwe,
        const float* Wg1, const float* bg1, const float* Wg2, const float* bg2,
        const float* Wemb, const float* bemb, float* gated, float* hd_emb) {
    __shared__ float w1[4096], w2[4096];
    __shared__ float gin[4][64], hid[4][64];
    __shared__ float sb1[64], sb2[64], we[128], be[64];
    int t = threadIdx.x;
    for (int i = t; i < 4096; i += 256) { w1[i] = Wg1[i]; w2[i] = Wg2[i]; }
    if (t < 64) { sb1[t] = bg1[t]; sb2[t] = bg2[t]; be[t] = bemb[t]; }
    if (t < 128) we[t] = Wemb[t];
    int r = t >> 6, lane = t & 63;
    int row = blockIdx.x * 4 + r;
    int n = row & 1023;
    const float* hrow = hist + (size_t)row * 4;
    float f0 = hrow[0], f1 = hrow[1];
    int tid_i = (int)(hrow[2] * 288.0f);
    int diw_i = (int)hrow[3];
    float g;
    if (lane < 40) g = nodeu[n * 40 + lane];
    else if (lane < 52) g = tide[tid_i * 12 + lane - 40];
    else g = diwe[diw_i * 12 + lane - 52];
    gin[r][lane] = g;
    __syncthreads();
    float acc = sb1[lane];
    for (int k = 0; k < 64; k++) acc += gin[r][k] * w1[k * 64 + lane];
    hid[r][lane] = acc > 0.f ? acc : 0.f;
    __syncthreads();
    acc = sb2[lane];
    for (int k = 0; k < 64; k++) acc += hid[r][k] * w2[k * 64 + lane];
    float gate = 1.f / (1.f + expf(-acc));
    float hd = f0 * we[lane] + f1 * we[64 + lane] + be[lane];
    float x1 = gate * hd;
    gated[(size_t)row * 128 + lane] = x1;
    gated[(size_t)row * 128 + 64 + lane] = hd - x1;
    hd_emb[(size_t)row * 64 + lane] = hd;
}

// xs[b,o,n,h] = relu(sum_t gated*Wsc + bsc); grid = CB*256
__global__ __launch_bounds__(256) void k_wsc(const float* gated, const float* Wsc,
                                             const float* bsc, float* xs, int xoff) {
    __shared__ float w[384];
    __shared__ float sb[32];
    int t = threadIdx.x;
    if (t < 384) w[t] = Wsc[t];
    if (t < 32) sb[t] = bsc[t];
    __syncthreads();
    int idx = blockIdx.x * 256 + t;
    int h = idx & 63, n = (idx >> 6) & 1023, b = idx >> 16;
    float xv[12];
#pragma unroll
    for (int tt = 0; tt < 12; tt++)
        xv[tt] = gated[(size_t)((b * 12 + tt) * 1024 + n) * 128 + xoff + h];
#pragma unroll
    for (int o = 0; o < 32; o++) {
        float a = sb[o];
#pragma unroll
        for (int tt = 0; tt < 12; tt++) a += xv[tt] * w[o * 12 + tt];
        xs[(size_t)((b * 32 + o) * 1024 + n) * 64 + h] = a > 0.f ? a : 0.f;
    }
}

// out = 0.05*x + 0.95*(A_norm @ hin), float4 lanes; grid = CB*2048
__global__ __launch_bounds__(256) void k_spmm(float* out, const float* x, const float* hin,
        const int* aN_idx, const float* aN_val,
        const int* aT_idx, const float* aT_val,
        const int* off, const float* inv_cs, int mode) {
    int t = threadIdx.x;
    int l4 = t & 15, r = t >> 4;            // 16 rows x 16 float4-lanes
    int g = blockIdx.x * 16 + r;            // row id (bc, v)
    int v = g & 1023, bc = g >> 10;
    const float4* base = (const float4*)hin + (size_t)bc * 16384;
    float4 s;
    if (mode == 0) {
        s.x = s.y = s.z = s.w = 0.f;
#pragma unroll
        for (int e = 0; e < 11; e++) {
            int w = aN_idx[v * 11 + e];
            float a = aN_val[v * 11 + e];
            float4 hv = base[w * 16 + l4];
            s.x += a * hv.x; s.y += a * hv.y; s.z += a * hv.z; s.w += a * hv.w;
        }
    } else {
        s = base[v * 16 + l4];
        int e0 = off[v], e1 = off[v + 1];
        for (int e = e0; e < e1; e++) {
            int w = aT_idx[e];
            float a = aT_val[e];
            float4 hv = base[w * 16 + l4];
            s.x += a * hv.x; s.y += a * hv.y; s.z += a * hv.z; s.w += a * hv.w;
        }
        float ic = inv_cs[v];
        s.x *= ic; s.y *= ic; s.z *= ic; s.w *= ic;
    }
    size_t oi = (size_t)g * 16 + l4;
    float4 xv = ((const float4*)x)[oi];
    float4 o;
    o.x = 0.05f * xv.x + 0.95f * s.x;
    o.y = 0.05f * xv.y + 0.95f * s.y;
    o.z = 0.05f * xv.z + 0.95f * s.z;
    o.w = 0.05f * xv.w + 0.95f * s.w;
    ((float4*)out)[oi] = o;
}

// mix projection; grid = CB*1024
__global__ __launch_bounds__(256) void k_proj(const float* xs, const float* h1, const float* h2,
        const float* mw, const float* m1b, const float* m2b,
        float* mix, int xp, int cp) {
    __shared__ float Wl[96 * 64];
    __shared__ float Bt[96 * 64];
    int t = threadIdx.x;
    int b = blockIdx.x >> 10, n = blockIdx.x & 1023;
    for (int i = t; i < 6144; i += 256) {
        int k = i >> 6, col = i & 63;
        Wl[i] = mw[col * 96 + k];
    }
    for (int i = t; i < 6144; i += 256) {
        int k = i >> 6, l = i & 63;
        int q = k >> 5, c = k & 31;
        const float* Hq = (q == 0) ? xs : (q == 1 ? h1 : h2);
        Bt[i] = Hq[(size_t)((b * 32 + c) * 1024 + n) * 64 + l];
    }
    __syncthreads();
    int tx = t & 15, ty = t >> 4;
    int o0 = tx * 4, l0 = ty * 4;
    float acc[4][4];
#pragma unroll
    for (int io = 0; io < 4; io++) {
        float bias = 0.f;
        if (cp == 0) { int rrow = o0 + io; bias = m1b[rrow] + m2b[rrow]; }
#pragma unroll
        for (int il = 0; il < 4; il++) acc[io][il] = bias;
    }
    for (int k = 0; k < 96; k++) {
        float4 a = *(const float4*)&Wl[k * 64 + o0];
        float4 bb = *(const float4*)&Bt[k * 64 + l0];
        acc[0][0] += a.x * bb.x; acc[0][1] += a.x * bb.y; acc[0][2] += a.x * bb.z; acc[0][3] += a.x * bb.w;
        acc[1][0] += a.y * bb.x; acc[1][1] += a.y * bb.y; acc[1][2] += a.y * bb.z; acc[1][3] += a.y * bb.w;
        acc[2][0] += a.z * bb.x; acc[2][1] += a.z * bb.y; acc[2][2] += a.z * bb.z; acc[2][3] += a.z * bb.w;
        acc[3][0] += a.w * bb.x; acc[3][1] += a.w * bb.y; acc[3][2] += a.w * bb.z; acc[3][3] += a.w * bb.w;
    }
#pragma unroll
    for (int io = 0; io < 4; io++) {
        int rrow = o0 + io;
        int i2 = rrow >> 5, o = rrow & 31;
        float* gp = &mix[(size_t)((b * 32 + o) * 1024 + n) * 256 + (i2 * 2 + xp) * 64 + l0];
        if (cp == 0) {
#pragma unroll
            for (int il = 0; il < 4; il++) gp[il] = acc[io][il];
        } else {
#pragma unroll
            for (int il = 0; il < 4; il++) gp[il] += acc[io][il];
        }
    }
}

// fused Wtf1(relu)Wtf2 via bf16 MFMA, in-place on mix: 32 rows/block; grid = CB*1024
__global__ __launch_bounds__(256) void k_tf(float* mix, const unsigned short* W1p, const float* B1,
                                            const unsigned short* W2p, const float* B2) {
    __shared__ unsigned short Abuf[32 * 256];   // bf16, XOR-swizzled
    __shared__ unsigned short Hbuf[32 * 256];
    int t = threadIdx.x;
    int wave = t >> 6, l = t & 63;
    size_t row0 = (size_t)blockIdx.x * 32;
    const float4* src = (const float4*)(mix + row0 * 256);
#pragma unroll
    for (int it = 0; it < 8; it++) {
        int f = t + it * 256;                  // 2048 float4s
        float4 v = src[f];
        int e = f * 4, row = e >> 8, col = e & 255;
        unsigned lo = f2bf(v.x) | ((unsigned)f2bf(v.y) << 16);
        unsigned hi = f2bf(v.z) | ((unsigned)f2bf(v.w) << 16);
        int byte = (row * 512 + col * 2) ^ ((row & 7) << 4);
        uint2 pk; pk.x = lo; pk.y = hi;
        *(uint2*)((char*)Abuf + byte) = pk;
    }
    __syncthreads();
    int colg0 = wave * 64;
    int lr = l & 15, lg = l >> 4;
    f32x4 acc[2][4];
#pragma unroll
    for (int nb = 0; nb < 4; nb++) {
        float bv = B1[colg0 + nb * 16 + lr];
        f32x4 c; c[0] = bv; c[1] = bv; c[2] = bv; c[3] = bv;
        acc[0][nb] = c; acc[1][nb] = c;
    }
#pragma unroll
    for (int kb = 0; kb < 8; kb++) {
        int k2 = (kb * 32 + lg * 8) * 2;
        int by0 = (lr * 512 + k2) ^ ((lr & 7) << 4);
        int by1 = ((16 + lr) * 512 + k2) ^ ((lr & 7) << 4);
        bf16x8 a0 = *(const bf16x8*)((char*)Abuf + by0);
        bf16x8 a1 = *(const bf16x8*)((char*)Abuf + by1);
#pragma unroll
        for (int nb = 0; nb < 4; nb++) {
            int nbg = wave * 4 + nb;
            bf16x8 bw = *(const bf16x8*)(W1p + (size_t)((kb * 16 + nbg) * 64 + l) * 8);
            acc[0][nb] = __builtin_amdgcn_mfma_f32_16x16x32_bf16(a0, bw, acc[0][nb], 0, 0, 0);
            acc[1][nb] = __builtin_amdgcn_mfma_f32_16x16x32_bf16(a1, bw, acc[1][nb], 0, 0, 0);
        }
    }
#pragma unroll
    for (int rb = 0; rb < 2; rb++)
#pragma unroll
        for (int nb = 0; nb < 4; nb++)
#pragma unroll
            for (int r = 0; r < 4; r++) {
                int row = rb * 16 + lg * 4 + r;
                int col = colg0 + nb * 16 + lr;
                unsigned short h = f2bf(fmaxf(acc[rb][nb][r], 0.f));
                int byte = (row * 512 + col * 2) ^ ((row & 7) << 4);
                *(unsigned short*)((char*)Hbuf + byte) = h;
            }
    __syncthreads();
#pragma unroll
    for (int nb = 0; nb < 4; nb++) {
        float bv = B2[colg0 + nb * 16 + lr];
        f32x4 c; c[0] = bv; c[1] = bv; c[2] = bv; c[3] = bv;
        acc[0][nb] = c; acc[1][nb] = c;
    }
#pragma unroll
    for (int kb = 0; kb < 8; kb++) {
        int k2 = (kb * 32 + lg * 8) * 2;
        int by0 = (lr * 512 + k2) ^ ((lr & 7) << 4);
        int by1 = ((16 + lr) * 512 + k2) ^ ((lr & 7) << 4);
        bf16x8 a0 = *(const bf16x8*)((char*)Hbuf + by0);
        bf16x8 a1 = *(const bf16x8*)((char*)Hbuf + by1);
#pragma unroll
        for (int nb = 0; nb < 4; nb++) {
            int nbg = wave * 4 + nb;
            bf16x8 bw = *(const bf16x8*)(W2p + (size_t)((kb * 16 + nbg) * 64 + l) * 8);
            acc[0][nb] = __builtin_amdgcn_mfma_f32_16x16x32_bf16(a0, bw, acc[0][nb], 0, 0, 0);
            acc[1][nb] = __builtin_amdgcn_mfma_f32_16x16x32_bf16(a1, bw, acc[1][nb], 0, 0, 0);
        }
    }
#pragma unroll
    for (int rb = 0; rb < 2; rb++)
#pragma unroll
        for (int nb = 0; nb < 4; nb++)
#pragma unroll
            for (int r = 0; r < 4; r++) {
                int row = rb * 16 + lg * 4 + r;
                int col = colg0 + nb * 16 + lr;
                mix[(row0 + row) * 256 + col] = acc[rb][nb][r];
            }
}

// fused ec1(relu)+ec2: weights via wave-uniform (scalar) global reads; grid = CB*1024
__global__ __launch_bounds__(256) void k_ec(const float* tfo, const float* W1, const float* B1,
                                            const float* W2, const float* B2, float* eco) {
    __shared__ float X[32][256];
    int t = threadIdx.x;
    int b = blockIdx.x >> 10, n = blockIdx.x & 1023;
    for (int i = t; i < 8192; i += 256) {
        int c = i >> 8, l = i & 255;
        X[c][l] = tfo[(size_t)((b * 32 + c) * 1024 + n) * 256 + l];
    }
    __syncthreads();
    float x[32];
#pragma unroll
    for (int c = 0; c < 32; c++) x[c] = X[c][t];
    float out[12];
#pragma unroll
    for (int p = 0; p < 12; p++) out[p] = B2[p];
#pragma unroll 2
    for (int o = 0; o < 128; o++) {
        float a = B1[o];
        const float* wr = &W1[o * 32];
#pragma unroll
        for (int c = 0; c < 32; c++) a += wr[c] * x[c];
        a = a > 0.f ? a : 0.f;
#pragma unroll
        for (int p = 0; p < 12; p++) out[p] += W2[p * 128 + o] * a;
    }
#pragma unroll
    for (int p = 0; p < 12; p++)
        eco[(size_t)((b * 12 + p) * 1024 + n) * 256 + t] = out[p];
}

// fused fc1(bf16 MFMA)+relu+fc2: 32 rows/block; grid = CB*384
__global__ __launch_bounds__(256) void k_fc(const float* gated, const float* eco,
        const float* hd_emb, const float* hist, const float* tide, const float* diwe,
        const unsigned short* W1p, const float* B1, const float* W2, const float* B2,
        float* fbuf) {
    __shared__ unsigned short Abuf[32 * 480];   // 30720 B, XOR-swizzled rows of 960 B
    __shared__ unsigned short Hbuf[32 * 512];   // 32768 B, XOR-swizzled rows of 1024 B
    int t = threadIdx.x;
    int wave = t >> 6, l = t & 63;
    int lr = l & 15, lg = l >> 4;
    int row0 = blockIdx.x * 32;
    // ---- stage A = relu(fh) for 32 rows -> bf16 LDS (swizzled), K padded to 480 ----
#pragma unroll
    for (int it = 0; it < 15; it++) {
        int idx = it * 256 + t;                 // < 3840 chunks of 4 elements
        int row = idx / 120;                    // 480/4 = 120 chunks per row
        int col = (idx - row * 120) * 4;
        int grow = row0 + row;
        int n = grow & 1023, bt = grow >> 10;
        int b = bt / 12, tt = bt - b * 12;
        float v[4];
        if (col < 128) {
#pragma unroll
            for (int q = 0; q < 4; q++) v[q] = gated[(size_t)grow * 128 + col + q];
        } else if (col < 384) {
            const float* ep = &eco[(size_t)((b * 12 + tt) * 1024 + n) * 256 + (col - 128)];
#pragma unroll
            for (int q = 0; q < 4; q++) v[q] = ep[q];
        } else if (col < 396) {
            int tid_i = (int)(hist[(size_t)grow * 4 + 2] * 288.0f);
#pragma unroll
            for (int q = 0; q < 4; q++) v[q] = tide[tid_i * 12 + col - 384 + q];
        } else if (col < 408) {
            int diw_i = (int)hist[(size_t)grow * 4 + 3];
#pragma unroll
            for (int q = 0; q < 4; q++) v[q] = diwe[diw_i * 12 + col - 396 + q];
        } else if (col < 472) {
#pragma unroll
            for (int q = 0; q < 4; q++) v[q] = hd_emb[(size_t)grow * 64 + col - 408 + q];
        } else {
#pragma unroll
            for (int q = 0; q < 4; q++) v[q] = 0.f;
        }
        unsigned lo = f2bf(fmaxf(v[0], 0.f)) | ((unsigned)f2bf(fmaxf(v[1], 0.f)) << 16);
        unsigned hi = f2bf(fmaxf(v[2], 0.f)) | ((unsigned)f2bf(fmaxf(v[3], 0.f)) << 16);
        int byte = (row * 960 + col * 2) ^ ((row & 7) << 4);
        uint2 pk; pk.x = lo; pk.y = hi;
        *(uint2*)((char*)Abuf + byte) = pk;
    }
    __syncthreads();
    // ---- fc1: Hd = relu(A @ W1 + B1), 4 waves x 128 cols ----
    int colg0 = wave * 128;
    f32x4 acc[2][8];
#pragma unroll
    for (int nb = 0; nb < 8; nb++) {
        float bv = B1[colg0 + nb * 16 + lr];
        f32x4 c; c[0] = bv; c[1] = bv; c[2] = bv; c[3] = bv;
        acc[0][nb] = c; acc[1][nb] = c;
    }
#pragma unroll
    for (int kb = 0; kb < 15; kb++) {
        int k2 = (kb * 32 + lg * 8) * 2;
        int by0 = (lr * 960 + k2) ^ ((lr & 7) << 4);
        int by1 = ((16 + lr) * 960 + k2) ^ ((lr & 7) << 4);
        bf16x8 a0 = *(const bf16x8*)((char*)Abuf + by0);
        bf16x8 a1 = *(const bf16x8*)((char*)Abuf + by1);
#pragma unroll
        for (int nb = 0; nb < 8; nb++) {
            int nbg = wave * 8 + nb;
            bf16x8 bw = *(const bf16x8*)(W1p + (size_t)((kb * 32 + nbg) * 64 + l) * 8);
            acc[0][nb] = __builtin_amdgcn_mfma_f32_16x16x32_bf16(a0, bw, acc[0][nb], 0, 0, 0);
            acc[1][nb] = __builtin_amdgcn_mfma_f32_16x16x32_bf16(a1, bw, acc[1][nb], 0, 0, 0);
        }
    }
#pragma unroll
    for (int rb = 0; rb < 2; rb++)
#pragma unroll
        for (int nb = 0; nb < 8; nb++)
#pragma unroll
            for (int r = 0; r < 4; r++) {
                int row = rb * 16 + lg * 4 + r;
                int col = colg0 + nb * 16 + lr;
                unsigned short h = f2bf(fmaxf(acc[rb][nb][r], 0.f));
                int byte = (row * 1024 + col * 2) ^ ((row & 7) << 4);
                *(unsigned short*)((char*)Hbuf + byte) = h;
            }
    __syncthreads();
    // ---- fc2: out[row][p] = B2[p] + sum_k Hd[row][k]*W2[k][p] ----
    float* redp = (float*)Abuf;    // A dead; 32 rows x 96 floats = 12 KB
    {
        int rsub = t >> 5, seg = t & 31;
#pragma unroll
        for (int rg = 0; rg < 4; rg++) {
            int r = rg * 8 + rsub;
            float p0 = 0.f, p1 = 0.f, p2 = 0.f;
#pragma unroll
            for (int j = 0; j < 16; j++) {
                int k = seg + j * 32;
                int byte = (r * 1024 + k * 2) ^ ((r & 7) << 4);
                float h = bf2f(*(const unsigned short*)((char*)Hbuf + byte));
                p0 += h * W2[k * 3];
                p1 += h * W2[k * 3 + 1];
                p2 += h * W2[k * 3 + 2];
            }
            redp[r * 96 + seg] = p0;
            redp[r * 96 + 32 + seg] = p1;
            redp[r * 96 + 64 + seg] = p2;
        }
    }
    __syncthreads();
    if (t < 96) {
        int rr = t / 3, p = t - rr * 3;
        float s = B2[p];
        for (int seg = 0; seg < 32; seg++) s += redp[rr * 96 + p * 32 + seg];
        fbuf[(size_t)(row0 + rr) * 3 + p] = s;
    }
}

// final conv1x1 over time + transpose; grid = CB*48
__global__ void k_ec3(const float* f, const float* W, const float* bv, float* out) {
    int idx = blockIdx.x * 256 + threadIdx.x;
    int l = idx % 3;
    int rest = idx / 3;
    int o = rest & 3;
    int n = (rest >> 2) & 1023;
    int b = rest >> 12;
    float s = bv[o];
#pragma unroll
    for (int c = 0; c < 12; c++)
        s += f[(size_t)((b * 12 + c) * 1024 + n) * 3 + l] * W[o * 12 + c];
    out[idx] = s;
}

// ---------------- launcher ----------------
extern "C" void kernel_launch(void* const* d_in, const int* in_sizes, int n_in,
                              void* d_out, int out_size, void* d_ws, size_t ws_size,
                              hipStream_t stream) {
    const float* hist = (const float*)d_in[0];
    const float* node_emb_u = (const float*)d_in[1];
    const float* T_i_D_emb = (const float*)d_in[2];
    const float* D_i_W_emb = (const float*)d_in[3];
    const float* gc_emb1 = (const float*)d_in[4];
    const float* gc_emb2 = (const float*)d_in[5];
    const float* gc_w1 = (const float*)d_in[6];
    const float* gc_b1 = (const float*)d_in[7];
    const float* gc_w2 = (const float*)d_in[8];
    const float* gc_b2 = (const float*)d_in[9];
    const float* W_emb = (const float*)d_in[10];
    const float* b_emb = (const float*)d_in[11];
    const float* Wg1 = (const float*)d_in[12];
    const float* bg1 = (const float*)d_in[13];
    const float* Wg2 = (const float*)d_in[14];
    const float* bg2 = (const float*)d_in[15];
    const float* Wsc = (const float*)d_in[16];
    const float* bsc = (const float*)d_in[17];
    const float* mix1_w = (const float*)d_in[18];
    const float* mix1_b = (const float*)d_in[19];
    const float* mix2_w = (const float*)d_in[20];
    const float* mix2_b = (const float*)d_in[21];
    const float* Wtf1 = (const float*)d_in[22];
    const float* btf1 = (const float*)d_in[23];
    const float* Wtf2 = (const float*)d_in[24];
    const float* btf2 = (const float*)d_in[25];
    const float* Wec1 = (const float*)d_in[26];
    const float* bec1 = (const float*)d_in[27];
    const float* Wec2 = (const float*)d_in[28];
    const float* bec2 = (const float*)d_in[29];
    const float* Wfc1 = (const float*)d_in[30];
    const float* bfc1 = (const float*)d_in[31];
    const float* Wfc2 = (const float*)d_in[32];
    const float* bfc2 = (const float*)d_in[33];
    const float* Wec3 = (const float*)d_in[34];
    const float* bec3 = (const float*)d_in[35];

    float* ws = (float*)d_ws;
    float* n1 = ws + F_N1;
    float* n2 = ws + F_N2;
    float* aN_val = ws + F_ANVAL;
    float* row_val = ws + F_ROWVAL;
    float* col_sum = ws + F_COLSUM;
    float* inv_cs = ws + F_INVCS;
    float* aT_val = ws + F_ATVAL;
    int* aN_idx = (int*)(ws + I_ANIDX);
    int* row_idx = (int*)(ws + I_ROWIDX);
    int* col_cnt = (int*)(ws + I_COLCNT);
    int* col_off = (int*)(ws + I_COLOFF);
    int* col_fill = (int*)(ws + I_COLFILL);
    int* aT_idx = (int*)(ws + I_ATIDX);
    unsigned short* w1p = (unsigned short*)(ws + F_W1P);
    unsigned short* w2p = (unsigned short*)(ws + F_W2P);
    unsigned short* wfcp = (unsigned short*)(ws + F_WFCP);

    // pick largest batch-chunk CB that fits the workspace
    size_t avail = ws_size / 4;   // floats
    int CB = 8;
    while (CB > 1 && GRAPH_FLOATS + (size_t)CB * PB_TOTAL > avail) CB >>= 1;
    int nchunk = 8 / CB;

    float* gated = ws + GRAPH_FLOATS;
    float* hd_emb = gated + (size_t)CB * PB_GATED;
    float* xs = hd_emb + (size_t)CB * PB_HD;
    float* h1 = xs + (size_t)CB * PB_XS;
    float* h2 = h1 + (size_t)CB * PB_XS;
    float* mix = h2 + (size_t)CB * PB_XS;
    float* eco = xs;    // alias: xs+h1 region >= eco
    float* fbuf = h2;   // alias: h2 dead by k_fc

    // ---- graph construction + weight packing (once) ----
    k_init<<<4, 256, 0, stream>>>(col_cnt, col_fill, col_sum);
    k_embed<<<320, 256, 0, stream>>>(gc_emb1, gc_emb2, gc_w1, gc_b1, gc_w2, gc_b2, n1, n2);
    k_adj<<<1024, 256, 0, stream>>>(n1, n2, aN_val, aN_idx, row_val, row_idx, col_cnt, col_sum);
    k_scan<<<1, 1024, 0, stream>>>(col_cnt, col_off, col_sum, inv_cs);
    k_scatter<<<40, 256, 0, stream>>>(row_idx, row_val, col_off, col_fill, aT_idx, aT_val);
    k_packw<<<32, 256, 0, stream>>>(Wtf1, w1p);
    k_packw<<<32, 256, 0, stream>>>(Wtf2, w2p);
    k_packfc<<<120, 256, 0, stream>>>(Wfc1, wfcp);

    // ---- per-chunk pipeline ----
    for (int ch = 0; ch < nchunk; ch++) {
        const float* hist_c = hist + (size_t)ch * CB * ROWS_PER_B * 4;
        float* out_c = (float*)d_out + (size_t)ch * CB * ROWS_PER_B;

        k_gate<<<CB * 3072, 256, 0, stream>>>(hist_c, node_emb_u, T_i_D_emb, D_i_W_emb,
                                              Wg1, bg1, Wg2, bg2, W_emb, b_emb, gated, hd_emb);
        for (int xp = 0; xp < 2; xp++) {
            k_wsc<<<CB * 256, 256, 0, stream>>>(gated, Wsc, bsc, xs, xp * 64);
            for (int cp = 0; cp < 2; cp++) {
                k_spmm<<<CB * 2048, 256, 0, stream>>>(h1, xs, xs, aN_idx, aN_val, aT_idx, aT_val,
                                                      col_off, inv_cs, cp);
                k_spmm<<<CB * 2048, 256, 0, stream>>>(h2, xs, h1, aN_idx, aN_val, aT_idx, aT_val,
                                                      col_off, inv_cs, cp);
                k_proj<<<CB * 1024, 256, 0, stream>>>(xs, h1, h2, cp ? mix2_w : mix1_w,
                                                      mix1_b, mix2_b, mix, xp, cp);
            }
        }
        k_tf<<<CB * 1024, 256, 0, stream>>>(mix, w1p, btf1, w2p, btf2);
        k_ec<<<CB * 1024, 256, 0, stream>>>(mix, Wec1, bec1, Wec2, bec2, eco);
        k_fc<<<CB * 384, 256, 0, stream>>>(gated, eco, hd_emb, hist_c, T_i_D_emb, D_i_W_emb,
                                           wfcp, bfc1, Wfc2, bfc2, fbuf);
        k_ec3<<<CB * 48, 256, 0, stream>>>(fbuf, Wec3, bec3, out_c);
    }
}

// Round 7
// 3184.419 us; speedup vs baseline: 1.5230x; 1.0098x over previous
//
#include <hip/hip_runtime.h>
#include <math.h>

// ---------------- constants ----------------
constexpr int ROWS_PER_B = 12 * 1024;    // rows (b,t,n) per batch element

// ---------------- graph workspace (float offsets, < 524288) ----------------
constexpr size_t F_N1 = 0;              // 1024*40
constexpr size_t F_N2 = 40960;
constexpr size_t F_ANVAL = 81920;       // 1024*11
constexpr size_t F_ROWVAL = 93184;      // 1024*10
constexpr size_t F_COLSUM = 103424;     // 1024
constexpr size_t F_INVCS = 104448;      // 1024
constexpr size_t F_ATVAL = 105472;      // 10240
constexpr size_t I_ANIDX = 115712;      // ints stored in float slots
constexpr size_t I_ROWIDX = 126976;
constexpr size_t I_COLCNT = 137216;
constexpr size_t I_COLOFF = 138240;     // 1025
constexpr size_t I_COLFILL = 139265;
constexpr size_t I_ATIDX = 140289;      // ends 150529
constexpr size_t F_W1P = 151552;        // packed bf16 Wtf1: 65536 shorts = 32768 floats
constexpr size_t F_W2P = 184320;        // packed bf16 Wtf2: ends 217088
constexpr size_t F_WFCP = 217088;       // packed bf16 Wfc1: ends 339968
constexpr size_t GRAPH_FLOATS = 524288;

// per-chunk float counts (per batch element)
constexpr size_t PB_GATED = (size_t)ROWS_PER_B * 128;   // 1572864
constexpr size_t PB_HD = (size_t)ROWS_PER_B * 64;       // 786432
constexpr size_t PB_XS = (size_t)32 * 1024 * 64;        // 2097152
constexpr size_t PB_MIX = (size_t)32 * 1024 * 256;      // 8388608
constexpr size_t PB_TOTAL = PB_GATED + PB_HD + 3 * PB_XS + PB_MIX; // 17039360

typedef __attribute__((ext_vector_type(8))) short bf16x8;
typedef __attribute__((ext_vector_type(4))) float f32x4;

__device__ __forceinline__ unsigned short f2bf(float f) {
    unsigned u = __float_as_uint(f);
    unsigned r = (u + 0x7fffu + ((u >> 16) & 1u)) >> 16;   // RNE
    return (unsigned short)r;
}
__device__ __forceinline__ float bf2f(unsigned short h) {
    return __uint_as_float((unsigned)h << 16);
}

// ---------------- graph kernels ----------------

__global__ void k_init(int* cnt, int* fill, float* csum) {
    int t = blockIdx.x * 256 + threadIdx.x;
    if (t < 1024) { cnt[t] = 0; fill[t] = 0; csum[t] = 0.f; }
}

__global__ void k_embed(const float* e1, const float* e2, const float* w1, const float* b1,
                        const float* w2, const float* b2, float* n1, float* n2) {
    int idx = blockIdx.x * 256 + threadIdx.x;   // < 81920
    if (idx >= 81920) return;
    int m = idx / 40960, rem = idx - m * 40960;
    int i = rem / 40, j = rem - i * 40;
    const float* e = m ? e2 : e1;
    const float* w = m ? w2 : w1;
    const float* bv = m ? b2 : b1;
    float a = bv[j];
    for (int k = 0; k < 40; k++) a += e[i * 40 + k] * w[k * 40 + j];
    (m ? n2 : n1)[i * 40 + j] = tanhf(3.0f * a);
}

__global__ __launch_bounds__(256) void k_adj(const float* n1, const float* n2,
        float* aN_val, int* aN_idx, float* row_val, int* row_idx,
        int* col_cnt, float* col_sum) {
    __shared__ float arow[1024];
    __shared__ float n1v[40], n2v[40];
    __shared__ float rv[256];
    __shared__ int ri[256];
    __shared__ float topv[10];
    __shared__ int topi[10];
    int v = blockIdx.x, t = threadIdx.x;
    if (t < 40) { n1v[t] = n1[v * 40 + t]; n2v[t] = n2[v * 40 + t]; }
    __syncthreads();
    for (int j = t; j < 1024; j += 256) {
        float d1 = 0.f, d2 = 0.f;
        for (int k = 0; k < 40; k++) {
            d1 += n1v[k] * n2[j * 40 + k];
            d2 += n2v[k] * n1[j * 40 + k];
        }
        float a = tanhf(3.0f * (d1 - d2));
        arow[j] = a > 0.f ? a : 0.f;
    }
    __syncthreads();
    for (int r = 0; r < 10; r++) {
        float bv = -1.f; int bi = 1 << 30;
        for (int j = t; j < 1024; j += 256) {
            float x = arow[j];
            if (x > bv || (x == bv && j < bi)) { bv = x; bi = j; }
        }
        rv[t] = bv; ri[t] = bi;
        __syncthreads();
        for (int s = 128; s > 0; s >>= 1) {
            if (t < s) {
                float ov = rv[t + s]; int oi = ri[t + s];
                if (ov > rv[t] || (ov == rv[t] && oi < ri[t])) { rv[t] = ov; ri[t] = oi; }
            }
            __syncthreads();
        }
        if (t == 0) { topv[r] = rv[0]; topi[r] = ri[0]; arow[ri[0]] = -1.f; }
        __syncthreads();
    }
    if (t == 0) {
        float s = 1.f;
        for (int r = 0; r < 10; r++) s += topv[r];
        float inv = 1.f / s;
        for (int r = 0; r < 10; r++) {
            aN_idx[v * 11 + r] = topi[r];
            aN_val[v * 11 + r] = topv[r] * inv;
            row_idx[v * 10 + r] = topi[r];
            row_val[v * 10 + r] = topv[r];
            atomicAdd(&col_cnt[topi[r]], 1);
            atomicAdd(&col_sum[topi[r]], topv[r]);
        }
        aN_idx[v * 11 + 10] = v;
        aN_val[v * 11 + 10] = inv;
    }
}

__global__ __launch_bounds__(1024) void k_scan(const int* cnt, int* off,
                                               const float* csum, float* inv) {
    __shared__ int tmp[1024];
    int t = threadIdx.x;
    tmp[t] = cnt[t];
    __syncthreads();
    for (int s = 1; s < 1024; s <<= 1) {
        int v = 0;
        if (t >= s) v = tmp[t - s];
        __syncthreads();
        tmp[t] += v;
        __syncthreads();
    }
    off[t + 1] = tmp[t];
    if (t == 0) off[0] = 0;
    inv[t] = 1.0f / (csum[t] + 1.0f);
}

__global__ void k_scatter(const int* row_idx, const float* row_val, const int* off,
                          int* fill, int* aT_idx, float* aT_val) {
    int e = blockIdx.x * 256 + threadIdx.x;
    if (e >= 10240) return;
    int v = e / 10;
    int j = row_idx[e];
    int pos = off[j] + atomicAdd(&fill[j], 1);
    aT_idx[pos] = v;
    aT_val[pos] = row_val[e];
}

// pack 256x256 f32 weight into MFMA B-fragment order
__global__ void k_packw(const float* W, unsigned short* out) {
    int id = blockIdx.x * 256 + threadIdx.x;    // 8192 total
    if (id >= 8192) return;
    int lane = id & 63, rest = id >> 6;
    int nb = rest & 15, kb = rest >> 4;
    int krow = kb * 32 + (lane >> 4) * 8;
    int col = nb * 16 + (lane & 15);
    unsigned short v[8];
#pragma unroll
    for (int j = 0; j < 8; j++) v[j] = f2bf(W[(size_t)(krow + j) * 256 + col]);
#pragma unroll
    for (int j = 0; j < 8; j++) out[(size_t)id * 8 + j] = v[j];
}

// pack 472x512 Wfc1 into B-fragment order, K padded to 480
__global__ void k_packfc(const float* W, unsigned short* out) {
    int id = blockIdx.x * 256 + threadIdx.x;    // 30720 total
    if (id >= 30720) return;
    int lane = id & 63, rest = id >> 6;
    int nb = rest & 31, kb = rest >> 5;         // kb < 15
    int k0 = kb * 32 + (lane >> 4) * 8;
    int col = nb * 16 + (lane & 15);
    unsigned short v[8];
#pragma unroll
    for (int j = 0; j < 8; j++) {
        int k = k0 + j;
        v[j] = (k < 472) ? f2bf(W[(size_t)k * 512 + col]) : (unsigned short)0;
    }
#pragma unroll
    for (int j = 0; j < 8; j++) out[(size_t)id * 8 + j] = v[j];
}

// ---------------- per-chunk kernels ----------------

// gate MLP + embed; grid = CB*3072
__global__ __launch_bounds__(256) void k_gate(const float* hist, const float* nodeu,
        const float* tide, const float* diwe,
        const float* Wg1, const float* bg1, const float* Wg2, const float* bg2,
        const float* Wemb, const float* bemb, float* gated, float* hd_emb) {
    __shared__ float w1[4096], w2[4096];
    __shared__ float gin[4][64], hid[4][64];
    __shared__ float sb1[64], sb2[64], we[128], be[64];
    int t = threadIdx.x;
    for (int i = t; i < 4096; i += 256) { w1[i] = Wg1[i]; w2[i] = Wg2[i]; }
    if (t < 64) { sb1[t] = bg1[t]; sb2[t] = bg2[t]; be[t] = bemb[t]; }
    if (t < 128) we[t] = Wemb[t];
    int r = t >> 6, lane = t & 63;
    int row = blockIdx.x * 4 + r;
    int n = row & 1023;
    const float* hrow = hist + (size_t)row * 4;
    float f0 = hrow[0], f1 = hrow[1];
    int tid_i = (int)(hrow[2] * 288.0f);
    int diw_i = (int)hrow[3];
    float g;
    if (lane < 40) g = nodeu[n * 40 + lane];
    else if (lane < 52) g = tide[tid_i * 12 + lane - 40];
    else g = diwe[diw_i * 12 + lane - 52];
    gin[r][lane] = g;
    __syncthreads();
    float acc = sb1[lane];
    for (int k = 0; k < 64; k++) acc += gin[r][k] * w1[k * 64 + lane];
    hid[r][lane] = acc > 0.f ? acc : 0.f;
    __syncthreads();
    acc = sb2[lane];
    for (int k = 0; k < 64; k++) acc += hid[r][k] * w2[k * 64 + lane];
    float gate = 1.f / (1.f + expf(-acc));
    float hd = f0 * we[lane] + f1 * we[64 + lane] + be[lane];
    float x1 = gate * hd;
    gated[(size_t)row * 128 + lane] = x1;
    gated[(size_t)row * 128 + 64 + lane] = hd - x1;
    hd_emb[(size_t)row * 64 + lane] = hd;
}

// xs[b,o,n,h] = relu(sum_t gated*Wsc + bsc); grid = CB*256
__global__ __launch_bounds__(256) void k_wsc(const float* gated, const float* Wsc,
                                             const float* bsc, float* xs, int xoff) {
    __shared__ float w[384];
    __shared__ float sb[32];
    int t = threadIdx.x;
    if (t < 384) w[t] = Wsc[t];
    if (t < 32) sb[t] = bsc[t];
    __syncthreads();
    int idx = blockIdx.x * 256 + t;
    int h = idx & 63, n = (idx >> 6) & 1023, b = idx >> 16;
    float xv[12];
#pragma unroll
    for (int tt = 0; tt < 12; tt++)
        xv[tt] = gated[(size_t)((b * 12 + tt) * 1024 + n) * 128 + xoff + h];
#pragma unroll
    for (int o = 0; o < 32; o++) {
        float a = sb[o];
#pragma unroll
        for (int tt = 0; tt < 12; tt++) a += xv[tt] * w[o * 12 + tt];
        xs[(size_t)((b * 32 + o) * 1024 + n) * 64 + h] = a > 0.f ? a : 0.f;
    }
}

// out = 0.05*x + 0.95*(A_norm @ hin), float4 lanes; grid = CB*2048
__global__ __launch_bounds__(256) void k_spmm(float* out, const float* x, const float* hin,
        const int* aN_idx, const float* aN_val,
        const int* aT_idx, const float* aT_val,
        const int* off, const float* inv_cs, int mode) {
    int t = threadIdx.x;
    int l4 = t & 15, r = t >> 4;            // 16 rows x 16 float4-lanes
    int g = blockIdx.x * 16 + r;            // row id (bc, v)
    int v = g & 1023, bc = g >> 10;
    const float4* base = (const float4*)hin + (size_t)bc * 16384;
    float4 s;
    if (mode == 0) {
        s.x = s.y = s.z = s.w = 0.f;
#pragma unroll
        for (int e = 0; e < 11; e++) {
            int w = aN_idx[v * 11 + e];
            float a = aN_val[v * 11 + e];
            float4 hv = base[w * 16 + l4];
            s.x += a * hv.x; s.y += a * hv.y; s.z += a * hv.z; s.w += a * hv.w;
        }
    } else {
        s = base[v * 16 + l4];
        int e0 = off[v], e1 = off[v + 1];
        for (int e = e0; e < e1; e++) {
            int w = aT_idx[e];
            float a = aT_val[e];
            float4 hv = base[w * 16 + l4];
            s.x += a * hv.x; s.y += a * hv.y; s.z += a * hv.z; s.w += a * hv.w;
        }
        float ic = inv_cs[v];
        s.x *= ic; s.y *= ic; s.z *= ic; s.w *= ic;
    }
    size_t oi = (size_t)g * 16 + l4;
    float4 xv = ((const float4*)x)[oi];
    float4 o;
    o.x = 0.05f * xv.x + 0.95f * s.x;
    o.y = 0.05f * xv.y + 0.95f * s.y;
    o.z = 0.05f * xv.z + 0.95f * s.z;
    o.w = 0.05f * xv.w + 0.95f * s.w;
    ((float4*)out)[oi] = o;
}

// mix projection; grid = CB*1024
__global__ __launch_bounds__(256) void k_proj(const float* xs, const float* h1, const float* h2,
        const float* mw, const float* m1b, const float* m2b,
        float* mix, int xp, int cp) {
    __shared__ float Wl[96 * 64];
    __shared__ float Bt[96 * 64];
    int t = threadIdx.x;
    int b = blockIdx.x >> 10, n = blockIdx.x & 1023;
    for (int i = t; i < 6144; i += 256) {
        int k = i >> 6, col = i & 63;
        Wl[i] = mw[col * 96 + k];
    }
    for (int i = t; i < 6144; i += 256) {
        int k = i >> 6, l = i & 63;
        int q = k >> 5, c = k & 31;
        const float* Hq = (q == 0) ? xs : (q == 1 ? h1 : h2);
        Bt[i] = Hq[(size_t)((b * 32 + c) * 1024 + n) * 64 + l];
    }
    __syncthreads();
    int tx = t & 15, ty = t >> 4;
    int o0 = tx * 4, l0 = ty * 4;
    float acc[4][4];
#pragma unroll
    for (int io = 0; io < 4; io++) {
        float bias = 0.f;
        if (cp == 0) { int rrow = o0 + io; bias = m1b[rrow] + m2b[rrow]; }
#pragma unroll
        for (int il = 0; il < 4; il++) acc[io][il] = bias;
    }
    for (int k = 0; k < 96; k++) {
        float4 a = *(const float4*)&Wl[k * 64 + o0];
        float4 bb = *(const float4*)&Bt[k * 64 + l0];
        acc[0][0] += a.x * bb.x; acc[0][1] += a.x * bb.y; acc[0][2] += a.x * bb.z; acc[0][3] += a.x * bb.w;
        acc[1][0] += a.y * bb.x; acc[1][1] += a.y * bb.y; acc[1][2] += a.y * bb.z; acc[1][3] += a.y * bb.w;
        acc[2][0] += a.z * bb.x; acc[2][1] += a.z * bb.y; acc[2][2] += a.z * bb.z; acc[2][3] += a.z * bb.w;
        acc[3][0] += a.w * bb.x; acc[3][1] += a.w * bb.y; acc[3][2] += a.w * bb.z; acc[3][3] += a.w * bb.w;
    }
#pragma unroll
    for (int io = 0; io < 4; io++) {
        int rrow = o0 + io;
        int i2 = rrow >> 5, o = rrow & 31;
        float* gp = &mix[(size_t)((b * 32 + o) * 1024 + n) * 256 + (i2 * 2 + xp) * 64 + l0];
        if (cp == 0) {
#pragma unroll
            for (int il = 0; il < 4; il++) gp[il] = acc[io][il];
        } else {
#pragma unroll
            for (int il = 0; il < 4; il++) gp[il] += acc[io][il];
        }
    }
}

// fused Wtf1(relu)Wtf2 via bf16 MFMA, in-place on mix: 32 rows/block; grid = CB*1024
__global__ __launch_bounds__(256) void k_tf(float* mix, const unsigned short* W1p, const float* B1,
                                            const unsigned short* W2p, const float* B2) {
    __shared__ unsigned short Abuf[32 * 256];   // bf16, XOR-swizzled
    __shared__ unsigned short Hbuf[32 * 256];
    int t = threadIdx.x;
    int wave = t >> 6, l = t & 63;
    size_t row0 = (size_t)blockIdx.x * 32;
    const float4* src = (const float4*)(mix + row0 * 256);
#pragma unroll
    for (int it = 0; it < 8; it++) {
        int f = t + it * 256;                  // 2048 float4s
        float4 v = src[f];
        int e = f * 4, row = e >> 8, col = e & 255;
        unsigned lo = f2bf(v.x) | ((unsigned)f2bf(v.y) << 16);
        unsigned hi = f2bf(v.z) | ((unsigned)f2bf(v.w) << 16);
        int byte = (row * 512 + col * 2) ^ ((row & 7) << 4);
        uint2 pk; pk.x = lo; pk.y = hi;
        *(uint2*)((char*)Abuf + byte) = pk;
    }
    __syncthreads();
    int colg0 = wave * 64;
    int lr = l & 15, lg = l >> 4;
    f32x4 acc[2][4];
#pragma unroll
    for (int nb = 0; nb < 4; nb++) {
        float bv = B1[colg0 + nb * 16 + lr];
        f32x4 c; c[0] = bv; c[1] = bv; c[2] = bv; c[3] = bv;
        acc[0][nb] = c; acc[1][nb] = c;
    }
#pragma unroll
    for (int kb = 0; kb < 8; kb++) {
        int k2 = (kb * 32 + lg * 8) * 2;
        int by0 = (lr * 512 + k2) ^ ((lr & 7) << 4);
        int by1 = ((16 + lr) * 512 + k2) ^ ((lr & 7) << 4);
        bf16x8 a0 = *(const bf16x8*)((char*)Abuf + by0);
        bf16x8 a1 = *(const bf16x8*)((char*)Abuf + by1);
#pragma unroll
        for (int nb = 0; nb < 4; nb++) {
            int nbg = wave * 4 + nb;
            bf16x8 bw = *(const bf16x8*)(W1p + (size_t)((kb * 16 + nbg) * 64 + l) * 8);
            acc[0][nb] = __builtin_amdgcn_mfma_f32_16x16x32_bf16(a0, bw, acc[0][nb], 0, 0, 0);
            acc[1][nb] = __builtin_amdgcn_mfma_f32_16x16x32_bf16(a1, bw, acc[1][nb], 0, 0, 0);
        }
    }
#pragma unroll
    for (int rb = 0; rb < 2; rb++)
#pragma unroll
        for (int nb = 0; nb < 4; nb++)
#pragma unroll
            for (int r = 0; r < 4; r++) {
                int row = rb * 16 + lg * 4 + r;
                int col = colg0 + nb * 16 + lr;
                unsigned short h = f2bf(fmaxf(acc[rb][nb][r], 0.f));
                int byte = (row * 512 + col * 2) ^ ((row & 7) << 4);
                *(unsigned short*)((char*)Hbuf + byte) = h;
            }
    __syncthreads();
#pragma unroll
    for (int nb = 0; nb < 4; nb++) {
        float bv = B2[colg0 + nb * 16 + lr];
        f32x4 c; c[0] = bv; c[1] = bv; c[2] = bv; c[3] = bv;
        acc[0][nb] = c; acc[1][nb] = c;
    }
#pragma unroll
    for (int kb = 0; kb < 8; kb++) {
        int k2 = (kb * 32 + lg * 8) * 2;
        int by0 = (lr * 512 + k2) ^ ((lr & 7) << 4);
        int by1 = ((16 + lr) * 512 + k2) ^ ((lr & 7) << 4);
        bf16x8 a0 = *(const bf16x8*)((char*)Hbuf + by0);
        bf16x8 a1 = *(const bf16x8*)((char*)Hbuf + by1);
#pragma unroll
        for (int nb = 0; nb < 4; nb++) {
            int nbg = wave * 4 + nb;
            bf16x8 bw = *(const bf16x8*)(W2p + (size_t)((kb * 16 + nbg) * 64 + l) * 8);
            acc[0][nb] = __builtin_amdgcn_mfma_f32_16x16x32_bf16(a0, bw, acc[0][nb], 0, 0, 0);
            acc[1][nb] = __builtin_amdgcn_mfma_f32_16x16x32_bf16(a1, bw, acc[1][nb], 0, 0, 0);
        }
    }
#pragma unroll
    for (int rb = 0; rb < 2; rb++)
#pragma unroll
        for (int nb = 0; nb < 4; nb++)
#pragma unroll
            for (int r = 0; r < 4; r++) {
                int row = rb * 16 + lg * 4 + r;
                int col = colg0 + nb * 16 + lr;
                mix[(row0 + row) * 256 + col] = acc[rb][nb][r];
            }
}

// fused ec1(relu)+ec2: register-tiled, 2 l-cols per thread, no LDS; grid = CB*512
// block covers 2 (b,n) pairs; thread sub = pair, tl = l/2 index
__global__ __launch_bounds__(256) void k_ec(const float* tfo, const float* W1, const float* B1,
                                            const float* W2, const float* B2, float* eco) {
    int t = threadIdx.x;
    int sub = t >> 7, tl = t & 127;
    int pair = blockIdx.x * 2 + sub;
    int b = pair >> 10, n = pair & 1023;
    const float* base = tfo + ((size_t)(b * 32) * 1024 + n) * 256 + tl * 2;
    float2 x[32];
#pragma unroll
    for (int c = 0; c < 32; c++)
        x[c] = *(const float2*)(base + (size_t)c * 262144);
    float2 out[12];
#pragma unroll
    for (int p = 0; p < 12; p++) { out[p].x = 0.f; out[p].y = 0.f; }
#pragma unroll 4
    for (int o = 0; o < 128; o++) {
        float a0 = B1[o], a1 = a0;
        const float* wr = &W1[o * 32];          // wave-uniform -> s_load
#pragma unroll
        for (int c = 0; c < 32; c++) {
            float w = wr[c];
            a0 += w * x[c].x; a1 += w * x[c].y;
        }
        a0 = fmaxf(a0, 0.f); a1 = fmaxf(a1, 0.f);
#pragma unroll
        for (int p = 0; p < 12; p++) {
            float w = W2[p * 128 + o];          // wave-uniform -> s_load
            out[p].x += w * a0; out[p].y += w * a1;
        }
    }
#pragma unroll
    for (int p = 0; p < 12; p++) {
        float2 r; r.x = out[p].x + B2[p]; r.y = out[p].y + B2[p];
        *(float2*)&eco[((size_t)(b * 12 + p) * 1024 + n) * 256 + tl * 2] = r;
    }
}

// fused fc1(bf16 MFMA)+relu+fc2: 32 rows/block; grid = CB*384
__global__ __launch_bounds__(256) void k_fc(const float* gated, const float* eco,
        const float* hd_emb, const float* hist, const float* tide, const float* diwe,
        const unsigned short* W1p, const float* B1, const float* W2, const float* B2,
        float* fbuf) {
    __shared__ unsigned short Abuf[32 * 480];   // 30720 B, XOR-swizzled rows of 960 B
    __shared__ unsigned short Hbuf[32 * 512];   // 32768 B, XOR-swizzled rows of 1024 B
    int t = threadIdx.x;
    int wave = t >> 6, l = t & 63;
    int lr = l & 15, lg = l >> 4;
    int row0 = blockIdx.x * 32;
#pragma unroll
    for (int it = 0; it < 15; it++) {
        int idx = it * 256 + t;                 // < 3840 chunks of 4 elements
        int row = idx / 120;
        int col = (idx - row * 120) * 4;
        int grow = row0 + row;
        int n = grow & 1023, bt = grow >> 10;
        int b = bt / 12, tt = bt - b * 12;
        float v[4];
        if (col < 128) {
#pragma unroll
            for (int q = 0; q < 4; q++) v[q] = gated[(size_t)grow * 128 + col + q];
        } else if (col < 384) {
            const float* ep = &eco[(size_t)((b * 12 + tt) * 1024 + n) * 256 + (col - 128)];
#pragma unroll
            for (int q = 0; q < 4; q++) v[q] = ep[q];
        } else if (col < 396) {
            int tid_i = (int)(hist[(size_t)grow * 4 + 2] * 288.0f);
#pragma unroll
            for (int q = 0; q < 4; q++) v[q] = tide[tid_i * 12 + col - 384 + q];
        } else if (col < 408) {
            int diw_i = (int)hist[(size_t)grow * 4 + 3];
#pragma unroll
            for (int q = 0; q < 4; q++) v[q] = diwe[diw_i * 12 + col - 396 + q];
        } else if (col < 472) {
#pragma unroll
            for (int q = 0; q < 4; q++) v[q] = hd_emb[(size_t)grow * 64 + col - 408 + q];
        } else {
#pragma unroll
            for (int q = 0; q < 4; q++) v[q] = 0.f;
        }
        unsigned lo = f2bf(fmaxf(v[0], 0.f)) | ((unsigned)f2bf(fmaxf(v[1], 0.f)) << 16);
        unsigned hi = f2bf(fmaxf(v[2], 0.f)) | ((unsigned)f2bf(fmaxf(v[3], 0.f)) << 16);
        int byte = (row * 960 + col * 2) ^ ((row & 7) << 4);
        uint2 pk; pk.x = lo; pk.y = hi;
        *(uint2*)((char*)Abuf + byte) = pk;
    }
    __syncthreads();
    int colg0 = wave * 128;
    f32x4 acc[2][8];
#pragma unroll
    for (int nb = 0; nb < 8; nb++) {
        float bv = B1[colg0 + nb * 16 + lr];
        f32x4 c; c[0] = bv; c[1] = bv; c[2] = bv; c[3] = bv;
        acc[0][nb] = c; acc[1][nb] = c;
    }
#pragma unroll
    for (int kb = 0; kb < 15; kb++) {
        int k2 = (kb * 32 + lg * 8) * 2;
        int by0 = (lr * 960 + k2) ^ ((lr & 7) << 4);
        int by1 = ((16 + lr) * 960 + k2) ^ ((lr & 7) << 4);
        bf16x8 a0 = *(const bf16x8*)((char*)Abuf + by0);
        bf16x8 a1 = *(const bf16x8*)((char*)Abuf + by1);
#pragma unroll
        for (int nb = 0; nb < 8; nb++) {
            int nbg = wave * 8 + nb;
            bf16x8 bw = *(const bf16x8*)(W1p + (size_t)((kb * 32 + nbg) * 64 + l) * 8);
            acc[0][nb] = __builtin_amdgcn_mfma_f32_16x16x32_bf16(a0, bw, acc[0][nb], 0, 0, 0);
            acc[1][nb] = __builtin_amdgcn_mfma_f32_16x16x32_bf16(a1, bw, acc[1][nb], 0, 0, 0);
        }
    }
#pragma unroll
    for (int rb = 0; rb < 2; rb++)
#pragma unroll
        for (int nb = 0; nb < 8; nb++)
#pragma unroll
            for (int r = 0; r < 4; r++) {
                int row = rb * 16 + lg * 4 + r;
                int col = colg0 + nb * 16 + lr;
                unsigned short h = f2bf(fmaxf(acc[rb][nb][r], 0.f));
                int byte = (row * 1024 + col * 2) ^ ((row & 7) << 4);
                *(unsigned short*)((char*)Hbuf + byte) = h;
            }
    __syncthreads();
    float* redp = (float*)Abuf;    // A dead; 32 rows x 96 floats = 12 KB
    {
        int rsub = t >> 5, seg = t & 31;
#pragma unroll
        for (int rg = 0; rg < 4; rg++) {
            int r = rg * 8 + rsub;
            float p0 = 0.f, p1 = 0.f, p2 = 0.f;
#pragma unroll
            for (int j = 0; j < 16; j++) {
                int k = seg + j * 32;
                int byte = (r * 1024 + k * 2) ^ ((r & 7) << 4);
                float h = bf2f(*(const unsigned short*)((char*)Hbuf + byte));
                p0 += h * W2[k * 3];
                p1 += h * W2[k * 3 + 1];
                p2 += h * W2[k * 3 + 2];
            }
            redp[r * 96 + seg] = p0;
            redp[r * 96 + 32 + seg] = p1;
            redp[r * 96 + 64 + seg] = p2;
        }
    }
    __syncthreads();
    if (t < 96) {
        int rr = t / 3, p = t - rr * 3;
        float s = B2[p];
        for (int seg = 0; seg < 32; seg++) s += redp[rr * 96 + p * 32 + seg];
        fbuf[(size_t)(row0 + rr) * 3 + p] = s;
    }
}

// final conv1x1 over time + transpose; grid = CB*48
__global__ void k_ec3(const float* f, const float* W, const float* bv, float* out) {
    int idx = blockIdx.x * 256 + threadIdx.x;
    int l = idx % 3;
    int rest = idx / 3;
    int o = rest & 3;
    int n = (rest >> 2) & 1023;
    int b = rest >> 12;
    float s = bv[o];
#pragma unroll
    for (int c = 0; c < 12; c++)
        s += f[(size_t)((b * 12 + c) * 1024 + n) * 3 + l] * W[o * 12 + c];
    out[idx] = s;
}

// ---------------- launcher ----------------
extern "C" void kernel_launch(void* const* d_in, const int* in_sizes, int n_in,
                              void* d_out, int out_size, void* d_ws, size_t ws_size,
                              hipStream_t stream) {
    const float* hist = (const float*)d_in[0];
    const float* node_emb_u = (const float*)d_in[1];
    const float* T_i_D_emb = (const float*)d_in[2];
    const float* D_i_W_emb = (const float*)d_in[3];
    const float* gc_emb1 = (const float*)d_in[4];
    const float* gc_emb2 = (const float*)d_in[5];
    const float* gc_w1 = (const float*)d_in[6];
    const float* gc_b1 = (const float*)d_in[7];
    const float* gc_w2 = (const float*)d_in[8];
    const float* gc_b2 = (const float*)d_in[9];
    const float* W_emb = (const float*)d_in[10];
    const float* b_emb = (const float*)d_in[11];
    const float* Wg1 = (const float*)d_in[12];
    const float* bg1 = (const float*)d_in[13];
    const float* Wg2 = (const float*)d_in[14];
    const float* bg2 = (const float*)d_in[15];
    const float* Wsc = (const float*)d_in[16];
    const float* bsc = (const float*)d_in[17];
    const float* mix1_w = (const float*)d_in[18];
    const float* mix1_b = (const float*)d_in[19];
    const float* mix2_w = (const float*)d_in[20];
    const float* mix2_b = (const float*)d_in[21];
    const float* Wtf1 = (const float*)d_in[22];
    const float* btf1 = (const float*)d_in[23];
    const float* Wtf2 = (const float*)d_in[24];
    const float* btf2 = (const float*)d_in[25];
    const float* Wec1 = (const float*)d_in[26];
    const float* bec1 = (const float*)d_in[27];
    const float* Wec2 = (const float*)d_in[28];
    const float* bec2 = (const float*)d_in[29];
    const float* Wfc1 = (const float*)d_in[30];
    const float* bfc1 = (const float*)d_in[31];
    const float* Wfc2 = (const float*)d_in[32];
    const float* bfc2 = (const float*)d_in[33];
    const float* Wec3 = (const float*)d_in[34];
    const float* bec3 = (const float*)d_in[35];

    float* ws = (float*)d_ws;
    float* n1 = ws + F_N1;
    float* n2 = ws + F_N2;
    float* aN_val = ws + F_ANVAL;
    float* row_val = ws + F_ROWVAL;
    float* col_sum = ws + F_COLSUM;
    float* inv_cs = ws + F_INVCS;
    float* aT_val = ws + F_ATVAL;
    int* aN_idx = (int*)(ws + I_ANIDX);
    int* row_idx = (int*)(ws + I_ROWIDX);
    int* col_cnt = (int*)(ws + I_COLCNT);
    int* col_off = (int*)(ws + I_COLOFF);
    int* col_fill = (int*)(ws + I_COLFILL);
    int* aT_idx = (int*)(ws + I_ATIDX);
    unsigned short* w1p = (unsigned short*)(ws + F_W1P);
    unsigned short* w2p = (unsigned short*)(ws + F_W2P);
    unsigned short* wfcp = (unsigned short*)(ws + F_WFCP);

    // pick largest batch-chunk CB that fits the workspace
    size_t avail = ws_size / 4;   // floats
    int CB = 8;
    while (CB > 1 && GRAPH_FLOATS + (size_t)CB * PB_TOTAL > avail) CB >>= 1;
    int nchunk = 8 / CB;

    float* gated = ws + GRAPH_FLOATS;
    float* hd_emb = gated + (size_t)CB * PB_GATED;
    float* xs = hd_emb + (size_t)CB * PB_HD;
    float* h1 = xs + (size_t)CB * PB_XS;
    float* h2 = h1 + (size_t)CB * PB_XS;
    float* mix = h2 + (size_t)CB * PB_XS;
    float* eco = xs;    // alias: xs+h1 region >= eco
    float* fbuf = h2;   // alias: h2 dead by k_fc

    // ---- graph construction + weight packing (once) ----
    k_init<<<4, 256, 0, stream>>>(col_cnt, col_fill, col_sum);
    k_embed<<<320, 256, 0, stream>>>(gc_emb1, gc_emb2, gc_w1, gc_b1, gc_w2, gc_b2, n1, n2);
    k_adj<<<1024, 256, 0, stream>>>(n1, n2, aN_val, aN_idx, row_val, row_idx, col_cnt, col_sum);
    k_scan<<<1, 1024, 0, stream>>>(col_cnt, col_off, col_sum, inv_cs);
    k_scatter<<<40, 256, 0, stream>>>(row_idx, row_val, col_off, col_fill, aT_idx, aT_val);
    k_packw<<<32, 256, 0, stream>>>(Wtf1, w1p);
    k_packw<<<32, 256, 0, stream>>>(Wtf2, w2p);
    k_packfc<<<120, 256, 0, stream>>>(Wfc1, wfcp);

    // ---- per-chunk pipeline ----
    for (int ch = 0; ch < nchunk; ch++) {
        const float* hist_c = hist + (size_t)ch * CB * ROWS_PER_B * 4;
        float* out_c = (float*)d_out + (size_t)ch * CB * ROWS_PER_B;

        k_gate<<<CB * 3072, 256, 0, stream>>>(hist_c, node_emb_u, T_i_D_emb, D_i_W_emb,
                                              Wg1, bg1, Wg2, bg2, W_emb, b_emb, gated, hd_emb);
        for (int xp = 0; xp < 2; xp++) {
            k_wsc<<<CB * 256, 256, 0, stream>>>(gated, Wsc, bsc, xs, xp * 64);
            for (int cp = 0; cp < 2; cp++) {
                k_spmm<<<CB * 2048, 256, 0, stream>>>(h1, xs, xs, aN_idx, aN_val, aT_idx, aT_val,
                                                      col_off, inv_cs, cp);
                k_spmm<<<CB * 2048, 256, 0, stream>>>(h2, xs, h1, aN_idx, aN_val, aT_idx, aT_val,
                                                      col_off, inv_cs, cp);
                k_proj<<<CB * 1024, 256, 0, stream>>>(xs, h1, h2, cp ? mix2_w : mix1_w,
                                                      mix1_b, mix2_b, mix, xp, cp);
            }
        }
        k_tf<<<CB * 1024, 256, 0, stream>>>(mix, w1p, btf1, w2p, btf2);
        k_ec<<<CB * 512, 256, 0, stream>>>(mix, Wec1, bec1, Wec2, bec2, eco);
        k_fc<<<CB * 384, 256, 0, stream>>>(gated, eco, hd_emb, hist_c, T_i_D_emb, D_i_W_emb,
                                           wfcp, bfc1, Wfc2, bfc2, fbuf);
        k_ec3<<<CB * 48, 256, 0, stream>>>(fbuf, Wec3, bec3, out_c);
    }
}

// Round 8
// 2999.821 us; speedup vs baseline: 1.6167x; 1.0615x over previous
//
#include <hip/hip_runtime.h>
#include <math.h>

// ---------------- constants ----------------
constexpr int ROWS_PER_B = 12 * 1024;    // rows (b,t,n) per batch element

// ---------------- graph workspace (float offsets, < 524288) ----------------
constexpr size_t F_N1 = 0;              // 1024*40
constexpr size_t F_N2 = 40960;
constexpr size_t F_ANVAL = 81920;       // 1024*11
constexpr size_t F_ROWVAL = 93184;      // 1024*10
constexpr size_t F_COLSUM = 103424;     // 1024
constexpr size_t F_INVCS = 104448;      // 1024
constexpr size_t F_ATVAL = 105472;      // 10240
constexpr size_t I_ANIDX = 115712;      // ints stored in float slots
constexpr size_t I_ROWIDX = 126976;
constexpr size_t I_COLCNT = 137216;
constexpr size_t I_COLOFF = 138240;     // 1025
constexpr size_t I_COLFILL = 139265;
constexpr size_t I_ATIDX = 140289;      // ends 150529
constexpr size_t F_W1P = 151552;        // packed bf16 Wtf1: 65536 shorts = 32768 floats
constexpr size_t F_W2P = 184320;        // packed bf16 Wtf2: ends 217088
constexpr size_t F_WFCP = 217088;       // packed bf16 Wfc1: ends 339968
constexpr size_t GRAPH_FLOATS = 524288;

// per-chunk float counts (per batch element)
constexpr size_t PB_GATED = (size_t)ROWS_PER_B * 128;   // 1572864
constexpr size_t PB_HD = (size_t)ROWS_PER_B * 64;       // 786432
constexpr size_t PB_XS = (size_t)32 * 1024 * 64;        // 2097152
constexpr size_t PB_MIX = (size_t)32 * 1024 * 256;      // 8388608
constexpr size_t PB_TOTAL = PB_GATED + PB_HD + 3 * PB_XS + PB_MIX; // 17039360

typedef __attribute__((ext_vector_type(8))) short bf16x8;
typedef __attribute__((ext_vector_type(4))) float f32x4;

__device__ __forceinline__ unsigned short f2bf(float f) {
    unsigned u = __float_as_uint(f);
    unsigned r = (u + 0x7fffu + ((u >> 16) & 1u)) >> 16;   // RNE
    return (unsigned short)r;
}
__device__ __forceinline__ float bf2f(unsigned short h) {
    return __uint_as_float((unsigned)h << 16);
}

// ---------------- graph kernels ----------------

__global__ void k_init(int* cnt, int* fill, float* csum) {
    int t = blockIdx.x * 256 + threadIdx.x;
    if (t < 1024) { cnt[t] = 0; fill[t] = 0; csum[t] = 0.f; }
}

__global__ void k_embed(const float* e1, const float* e2, const float* w1, const float* b1,
                        const float* w2, const float* b2, float* n1, float* n2) {
    int idx = blockIdx.x * 256 + threadIdx.x;   // < 81920
    if (idx >= 81920) return;
    int m = idx / 40960, rem = idx - m * 40960;
    int i = rem / 40, j = rem - i * 40;
    const float* e = m ? e2 : e1;
    const float* w = m ? w2 : w1;
    const float* bv = m ? b2 : b1;
    float a = bv[j];
    for (int k = 0; k < 40; k++) a += e[i * 40 + k] * w[k * 40 + j];
    (m ? n2 : n1)[i * 40 + j] = tanhf(3.0f * a);
}

__global__ __launch_bounds__(256) void k_adj(const float* n1, const float* n2,
        float* aN_val, int* aN_idx, float* row_val, int* row_idx,
        int* col_cnt, float* col_sum) {
    __shared__ float arow[1024];
    __shared__ float n1v[40], n2v[40];
    __shared__ float rv[256];
    __shared__ int ri[256];
    __shared__ float topv[10];
    __shared__ int topi[10];
    int v = blockIdx.x, t = threadIdx.x;
    if (t < 40) { n1v[t] = n1[v * 40 + t]; n2v[t] = n2[v * 40 + t]; }
    __syncthreads();
    for (int j = t; j < 1024; j += 256) {
        float d1 = 0.f, d2 = 0.f;
        for (int k = 0; k < 40; k++) {
            d1 += n1v[k] * n2[j * 40 + k];
            d2 += n2v[k] * n1[j * 40 + k];
        }
        float a = tanhf(3.0f * (d1 - d2));
        arow[j] = a > 0.f ? a : 0.f;
    }
    __syncthreads();
    for (int r = 0; r < 10; r++) {
        float bv = -1.f; int bi = 1 << 30;
        for (int j = t; j < 1024; j += 256) {
            float x = arow[j];
            if (x > bv || (x == bv && j < bi)) { bv = x; bi = j; }
        }
        rv[t] = bv; ri[t] = bi;
        __syncthreads();
        for (int s = 128; s > 0; s >>= 1) {
            if (t < s) {
                float ov = rv[t + s]; int oi = ri[t + s];
                if (ov > rv[t] || (ov == rv[t] && oi < ri[t])) { rv[t] = ov; ri[t] = oi; }
            }
            __syncthreads();
        }
        if (t == 0) { topv[r] = rv[0]; topi[r] = ri[0]; arow[ri[0]] = -1.f; }
        __syncthreads();
    }
    if (t == 0) {
        float s = 1.f;
        for (int r = 0; r < 10; r++) s += topv[r];
        float inv = 1.f / s;
        for (int r = 0; r < 10; r++) {
            aN_idx[v * 11 + r] = topi[r];
            aN_val[v * 11 + r] = topv[r] * inv;
            row_idx[v * 10 + r] = topi[r];
            row_val[v * 10 + r] = topv[r];
            atomicAdd(&col_cnt[topi[r]], 1);
            atomicAdd(&col_sum[topi[r]], topv[r]);
        }
        aN_idx[v * 11 + 10] = v;
        aN_val[v * 11 + 10] = inv;
    }
}

__global__ __launch_bounds__(1024) void k_scan(const int* cnt, int* off,
                                               const float* csum, float* inv) {
    __shared__ int tmp[1024];
    int t = threadIdx.x;
    tmp[t] = cnt[t];
    __syncthreads();
    for (int s = 1; s < 1024; s <<= 1) {
        int v = 0;
        if (t >= s) v = tmp[t - s];
        __syncthreads();
        tmp[t] += v;
        __syncthreads();
    }
    off[t + 1] = tmp[t];
    if (t == 0) off[0] = 0;
    inv[t] = 1.0f / (csum[t] + 1.0f);
}

__global__ void k_scatter(const int* row_idx, const float* row_val, const int* off,
                          int* fill, int* aT_idx, float* aT_val) {
    int e = blockIdx.x * 256 + threadIdx.x;
    if (e >= 10240) return;
    int v = e / 10;
    int j = row_idx[e];
    int pos = off[j] + atomicAdd(&fill[j], 1);
    aT_idx[pos] = v;
    aT_val[pos] = row_val[e];
}

// pack 256x256 f32 weight into MFMA B-fragment order
__global__ void k_packw(const float* W, unsigned short* out) {
    int id = blockIdx.x * 256 + threadIdx.x;    // 8192 total
    if (id >= 8192) return;
    int lane = id & 63, rest = id >> 6;
    int nb = rest & 15, kb = rest >> 4;
    int krow = kb * 32 + (lane >> 4) * 8;
    int col = nb * 16 + (lane & 15);
    unsigned short v[8];
#pragma unroll
    for (int j = 0; j < 8; j++) v[j] = f2bf(W[(size_t)(krow + j) * 256 + col]);
#pragma unroll
    for (int j = 0; j < 8; j++) out[(size_t)id * 8 + j] = v[j];
}

// pack 472x512 Wfc1 into B-fragment order, K padded to 480
__global__ void k_packfc(const float* W, unsigned short* out) {
    int id = blockIdx.x * 256 + threadIdx.x;    // 30720 total
    if (id >= 30720) return;
    int lane = id & 63, rest = id >> 6;
    int nb = rest & 31, kb = rest >> 5;         // kb < 15
    int k0 = kb * 32 + (lane >> 4) * 8;
    int col = nb * 16 + (lane & 15);
    unsigned short v[8];
#pragma unroll
    for (int j = 0; j < 8; j++) {
        int k = k0 + j;
        v[j] = (k < 472) ? f2bf(W[(size_t)k * 512 + col]) : (unsigned short)0;
    }
#pragma unroll
    for (int j = 0; j < 8; j++) out[(size_t)id * 8 + j] = v[j];
}

// ---------------- per-chunk kernels ----------------

// gate MLP + embed; grid = CB*3072
__global__ __launch_bounds__(256) void k_gate(const float* hist, const float* nodeu,
        const float* tide, const float* diwe,
        const float* Wg1, const float* bg1, const float* Wg2, const float* bg2,
        const float* Wemb, const float* bemb, float* gated, float* hd_emb) {
    __shared__ float w1[4096], w2[4096];
    __shared__ float gin[4][64], hid[4][64];
    __shared__ float sb1[64], sb2[64], we[128], be[64];
    int t = threadIdx.x;
    for (int i = t; i < 4096; i += 256) { w1[i] = Wg1[i]; w2[i] = Wg2[i]; }
    if (t < 64) { sb1[t] = bg1[t]; sb2[t] = bg2[t]; be[t] = bemb[t]; }
    if (t < 128) we[t] = Wemb[t];
    int r = t >> 6, lane = t & 63;
    int row = blockIdx.x * 4 + r;
    int n = row & 1023;
    const float* hrow = hist + (size_t)row * 4;
    float f0 = hrow[0], f1 = hrow[1];
    int tid_i = (int)(hrow[2] * 288.0f);
    int diw_i = (int)hrow[3];
    float g;
    if (lane < 40) g = nodeu[n * 40 + lane];
    else if (lane < 52) g = tide[tid_i * 12 + lane - 40];
    else g = diwe[diw_i * 12 + lane - 52];
    gin[r][lane] = g;
    __syncthreads();
    float acc = sb1[lane];
    for (int k = 0; k < 64; k++) acc += gin[r][k] * w1[k * 64 + lane];
    hid[r][lane] = acc > 0.f ? acc : 0.f;
    __syncthreads();
    acc = sb2[lane];
    for (int k = 0; k < 64; k++) acc += hid[r][k] * w2[k * 64 + lane];
    float gate = 1.f / (1.f + expf(-acc));
    float hd = f0 * we[lane] + f1 * we[64 + lane] + be[lane];
    float x1 = gate * hd;
    gated[(size_t)row * 128 + lane] = x1;
    gated[(size_t)row * 128 + 64 + lane] = hd - x1;
    hd_emb[(size_t)row * 64 + lane] = hd;
}

// xs[b,o,n,h] = relu(sum_t gated*Wsc + bsc); grid = CB*256
__global__ __launch_bounds__(256) void k_wsc(const float* gated, const float* Wsc,
                                             const float* bsc, float* xs, int xoff) {
    __shared__ float w[384];
    __shared__ float sb[32];
    int t = threadIdx.x;
    if (t < 384) w[t] = Wsc[t];
    if (t < 32) sb[t] = bsc[t];
    __syncthreads();
    int idx = blockIdx.x * 256 + t;
    int h = idx & 63, n = (idx >> 6) & 1023, b = idx >> 16;
    float xv[12];
#pragma unroll
    for (int tt = 0; tt < 12; tt++)
        xv[tt] = gated[(size_t)((b * 12 + tt) * 1024 + n) * 128 + xoff + h];
#pragma unroll
    for (int o = 0; o < 32; o++) {
        float a = sb[o];
#pragma unroll
        for (int tt = 0; tt < 12; tt++) a += xv[tt] * w[o * 12 + tt];
        xs[(size_t)((b * 32 + o) * 1024 + n) * 64 + h] = a > 0.f ? a : 0.f;
    }
}

// out = 0.05*x + 0.95*(A_norm @ hin), float4 lanes; grid = CB*2048
__global__ __launch_bounds__(256) void k_spmm(float* out, const float* x, const float* hin,
        const int* aN_idx, const float* aN_val,
        const int* aT_idx, const float* aT_val,
        const int* off, const float* inv_cs, int mode) {
    int t = threadIdx.x;
    int l4 = t & 15, r = t >> 4;            // 16 rows x 16 float4-lanes
    int g = blockIdx.x * 16 + r;            // row id (bc, v)
    int v = g & 1023, bc = g >> 10;
    const float4* base = (const float4*)hin + (size_t)bc * 16384;
    float4 s;
    if (mode == 0) {
        s.x = s.y = s.z = s.w = 0.f;
#pragma unroll
        for (int e = 0; e < 11; e++) {
            int w = aN_idx[v * 11 + e];
            float a = aN_val[v * 11 + e];
            float4 hv = base[w * 16 + l4];
            s.x += a * hv.x; s.y += a * hv.y; s.z += a * hv.z; s.w += a * hv.w;
        }
    } else {
        s = base[v * 16 + l4];
        int e0 = off[v], e1 = off[v + 1];
        for (int e = e0; e < e1; e++) {
            int w = aT_idx[e];
            float a = aT_val[e];
            float4 hv = base[w * 16 + l4];
            s.x += a * hv.x; s.y += a * hv.y; s.z += a * hv.z; s.w += a * hv.w;
        }
        float ic = inv_cs[v];
        s.x *= ic; s.y *= ic; s.z *= ic; s.w *= ic;
    }
    size_t oi = (size_t)g * 16 + l4;
    float4 xv = ((const float4*)x)[oi];
    float4 o;
    o.x = 0.05f * xv.x + 0.95f * s.x;
    o.y = 0.05f * xv.y + 0.95f * s.y;
    o.z = 0.05f * xv.z + 0.95f * s.z;
    o.w = 0.05f * xv.w + 0.95f * s.w;
    ((float4*)out)[oi] = o;
}

// mix projection; grid = CB*1024
__global__ __launch_bounds__(256) void k_proj(const float* xs, const float* h1, const float* h2,
        const float* mw, const float* m1b, const float* m2b,
        float* mix, int xp, int cp) {
    __shared__ float Wl[96 * 64];
    __shared__ float Bt[96 * 64];
    int t = threadIdx.x;
    int b = blockIdx.x >> 10, n = blockIdx.x & 1023;
    for (int i = t; i < 6144; i += 256) {
        int k = i >> 6, col = i & 63;
        Wl[i] = mw[col * 96 + k];
    }
    for (int i = t; i < 6144; i += 256) {
        int k = i >> 6, l = i & 63;
        int q = k >> 5, c = k & 31;
        const float* Hq = (q == 0) ? xs : (q == 1 ? h1 : h2);
        Bt[i] = Hq[(size_t)((b * 32 + c) * 1024 + n) * 64 + l];
    }
    __syncthreads();
    int tx = t & 15, ty = t >> 4;
    int o0 = tx * 4, l0 = ty * 4;
    float acc[4][4];
#pragma unroll
    for (int io = 0; io < 4; io++) {
        float bias = 0.f;
        if (cp == 0) { int rrow = o0 + io; bias = m1b[rrow] + m2b[rrow]; }
#pragma unroll
        for (int il = 0; il < 4; il++) acc[io][il] = bias;
    }
    for (int k = 0; k < 96; k++) {
        float4 a = *(const float4*)&Wl[k * 64 + o0];
        float4 bb = *(const float4*)&Bt[k * 64 + l0];
        acc[0][0] += a.x * bb.x; acc[0][1] += a.x * bb.y; acc[0][2] += a.x * bb.z; acc[0][3] += a.x * bb.w;
        acc[1][0] += a.y * bb.x; acc[1][1] += a.y * bb.y; acc[1][2] += a.y * bb.z; acc[1][3] += a.y * bb.w;
        acc[2][0] += a.z * bb.x; acc[2][1] += a.z * bb.y; acc[2][2] += a.z * bb.z; acc[2][3] += a.z * bb.w;
        acc[3][0] += a.w * bb.x; acc[3][1] += a.w * bb.y; acc[3][2] += a.w * bb.z; acc[3][3] += a.w * bb.w;
    }
#pragma unroll
    for (int io = 0; io < 4; io++) {
        int rrow = o0 + io;
        int i2 = rrow >> 5, o = rrow & 31;
        float* gp = &mix[(size_t)((b * 32 + o) * 1024 + n) * 256 + (i2 * 2 + xp) * 64 + l0];
        if (cp == 0) {
#pragma unroll
            for (int il = 0; il < 4; il++) gp[il] = acc[io][il];
        } else {
#pragma unroll
            for (int il = 0; il < 4; il++) gp[il] += acc[io][il];
        }
    }
}

// fused Wtf1(relu)Wtf2 via bf16 MFMA, in-place on mix: 32 rows/block; grid = CB*1024
__global__ __launch_bounds__(256) void k_tf(float* mix, const unsigned short* W1p, const float* B1,
                                            const unsigned short* W2p, const float* B2) {
    __shared__ unsigned short Abuf[32 * 256];   // bf16, XOR-swizzled
    __shared__ unsigned short Hbuf[32 * 256];
    int t = threadIdx.x;
    int wave = t >> 6, l = t & 63;
    size_t row0 = (size_t)blockIdx.x * 32;
    const float4* src = (const float4*)(mix + row0 * 256);
#pragma unroll
    for (int it = 0; it < 8; it++) {
        int f = t + it * 256;                  // 2048 float4s
        float4 v = src[f];
        int e = f * 4, row = e >> 8, col = e & 255;
        unsigned lo = f2bf(v.x) | ((unsigned)f2bf(v.y) << 16);
        unsigned hi = f2bf(v.z) | ((unsigned)f2bf(v.w) << 16);
        int byte = (row * 512 + col * 2) ^ ((row & 7) << 4);
        uint2 pk; pk.x = lo; pk.y = hi;
        *(uint2*)((char*)Abuf + byte) = pk;
    }
    __syncthreads();
    int colg0 = wave * 64;
    int lr = l & 15, lg = l >> 4;
    f32x4 acc[2][4];
#pragma unroll
    for (int nb = 0; nb < 4; nb++) {
        float bv = B1[colg0 + nb * 16 + lr];
        f32x4 c; c[0] = bv; c[1] = bv; c[2] = bv; c[3] = bv;
        acc[0][nb] = c; acc[1][nb] = c;
    }
#pragma unroll
    for (int kb = 0; kb < 8; kb++) {
        int k2 = (kb * 32 + lg * 8) * 2;
        int by0 = (lr * 512 + k2) ^ ((lr & 7) << 4);
        int by1 = ((16 + lr) * 512 + k2) ^ ((lr & 7) << 4);
        bf16x8 a0 = *(const bf16x8*)((char*)Abuf + by0);
        bf16x8 a1 = *(const bf16x8*)((char*)Abuf + by1);
#pragma unroll
        for (int nb = 0; nb < 4; nb++) {
            int nbg = wave * 4 + nb;
            bf16x8 bw = *(const bf16x8*)(W1p + (size_t)((kb * 16 + nbg) * 64 + l) * 8);
            acc[0][nb] = __builtin_amdgcn_mfma_f32_16x16x32_bf16(a0, bw, acc[0][nb], 0, 0, 0);
            acc[1][nb] = __builtin_amdgcn_mfma_f32_16x16x32_bf16(a1, bw, acc[1][nb], 0, 0, 0);
        }
    }
#pragma unroll
    for (int rb = 0; rb < 2; rb++)
#pragma unroll
        for (int nb = 0; nb < 4; nb++)
#pragma unroll
            for (int r = 0; r < 4; r++) {
                int row = rb * 16 + lg * 4 + r;
                int col = colg0 + nb * 16 + lr;
                unsigned short h = f2bf(fmaxf(acc[rb][nb][r], 0.f));
                int byte = (row * 512 + col * 2) ^ ((row & 7) << 4);
                *(unsigned short*)((char*)Hbuf + byte) = h;
            }
    __syncthreads();
#pragma unroll
    for (int nb = 0; nb < 4; nb++) {
        float bv = B2[colg0 + nb * 16 + lr];
        f32x4 c; c[0] = bv; c[1] = bv; c[2] = bv; c[3] = bv;
        acc[0][nb] = c; acc[1][nb] = c;
    }
#pragma unroll
    for (int kb = 0; kb < 8; kb++) {
        int k2 = (kb * 32 + lg * 8) * 2;
        int by0 = (lr * 512 + k2) ^ ((lr & 7) << 4);
        int by1 = ((16 + lr) * 512 + k2) ^ ((lr & 7) << 4);
        bf16x8 a0 = *(const bf16x8*)((char*)Hbuf + by0);
        bf16x8 a1 = *(const bf16x8*)((char*)Hbuf + by1);
#pragma unroll
        for (int nb = 0; nb < 4; nb++) {
            int nbg = wave * 4 + nb;
            bf16x8 bw = *(const bf16x8*)(W2p + (size_t)((kb * 16 + nbg) * 64 + l) * 8);
            acc[0][nb] = __builtin_amdgcn_mfma_f32_16x16x32_bf16(a0, bw, acc[0][nb], 0, 0, 0);
            acc[1][nb] = __builtin_amdgcn_mfma_f32_16x16x32_bf16(a1, bw, acc[1][nb], 0, 0, 0);
        }
    }
#pragma unroll
    for (int rb = 0; rb < 2; rb++)
#pragma unroll
        for (int nb = 0; nb < 4; nb++)
#pragma unroll
            for (int r = 0; r < 4; r++) {
                int row = rb * 16 + lg * 4 + r;
                int col = colg0 + nb * 16 + lr;
                mix[(row0 + row) * 256 + col] = acc[rb][nb][r];
            }
}

// fused ec1(relu)+ec2: register-tiled, 2 l-cols per thread, no LDS; grid = CB*512
__global__ __launch_bounds__(256) void k_ec(const float* tfo, const float* W1, const float* B1,
                                            const float* W2, const float* B2, float* eco) {
    int t = threadIdx.x;
    int sub = t >> 7, tl = t & 127;
    int pair = blockIdx.x * 2 + sub;
    int b = pair >> 10, n = pair & 1023;
    const float* base = tfo + ((size_t)(b * 32) * 1024 + n) * 256 + tl * 2;
    float2 x[32];
#pragma unroll
    for (int c = 0; c < 32; c++)
        x[c] = *(const float2*)(base + (size_t)c * 262144);
    float2 out[12];
#pragma unroll
    for (int p = 0; p < 12; p++) { out[p].x = 0.f; out[p].y = 0.f; }
#pragma unroll 4
    for (int o = 0; o < 128; o++) {
        float a0 = B1[o], a1 = a0;
        const float* wr = &W1[o * 32];          // wave-uniform -> s_load
#pragma unroll
        for (int c = 0; c < 32; c++) {
            float w = wr[c];
            a0 += w * x[c].x; a1 += w * x[c].y;
        }
        a0 = fmaxf(a0, 0.f); a1 = fmaxf(a1, 0.f);
#pragma unroll
        for (int p = 0; p < 12; p++) {
            float w = W2[p * 128 + o];          // wave-uniform -> s_load
            out[p].x += w * a0; out[p].y += w * a1;
        }
    }
#pragma unroll
    for (int p = 0; p < 12; p++) {
        float2 r; r.x = out[p].x + B2[p]; r.y = out[p].y + B2[p];
        *(float2*)&eco[((size_t)(b * 12 + p) * 1024 + n) * 256 + tl * 2] = r;
    }
}

// fused fc1(bf16 MFMA)+relu+fc2: 16 rows/block (31.7KB LDS); grid = CB*768
__global__ __launch_bounds__(256) void k_fc(const float* gated, const float* eco,
        const float* hd_emb, const float* hist, const float* tide, const float* diwe,
        const unsigned short* W1p, const float* B1, const float* W2, const float* B2,
        float* fbuf) {
    __shared__ unsigned short Abuf[16 * 480];   // 15360 B, XOR-swizzled rows of 960 B
    __shared__ unsigned short Hbuf[16 * 512];   // 16384 B, XOR-swizzled rows of 1024 B
    int t = threadIdx.x;
    int wave = t >> 6, l = t & 63;
    int lr = l & 15, lg = l >> 4;
    int row0 = blockIdx.x * 16;
    // ---- stage A = relu(fh) for 16 rows -> bf16 LDS (swizzled), K padded to 480 ----
#pragma unroll
    for (int it = 0; it < 8; it++) {
        int idx = it * 256 + t;                 // 1920 chunks of 4 elements
        if (idx < 1920) {
            int row = idx / 120;
            int col = (idx - row * 120) * 4;
            int grow = row0 + row;
            int n = grow & 1023, bt = grow >> 10;
            int b = bt / 12, tt = bt - b * 12;
            float v[4];
            if (col < 128) {
#pragma unroll
                for (int q = 0; q < 4; q++) v[q] = gated[(size_t)grow * 128 + col + q];
            } else if (col < 384) {
                const float* ep = &eco[(size_t)((b * 12 + tt) * 1024 + n) * 256 + (col - 128)];
#pragma unroll
                for (int q = 0; q < 4; q++) v[q] = ep[q];
            } else if (col < 396) {
                int tid_i = (int)(hist[(size_t)grow * 4 + 2] * 288.0f);
#pragma unroll
                for (int q = 0; q < 4; q++) v[q] = tide[tid_i * 12 + col - 384 + q];
            } else if (col < 408) {
                int diw_i = (int)hist[(size_t)grow * 4 + 3];
#pragma unroll
                for (int q = 0; q < 4; q++) v[q] = diwe[diw_i * 12 + col - 396 + q];
            } else if (col < 472) {
#pragma unroll
                for (int q = 0; q < 4; q++) v[q] = hd_emb[(size_t)grow * 64 + col - 408 + q];
            } else {
#pragma unroll
                for (int q = 0; q < 4; q++) v[q] = 0.f;
            }
            unsigned lo = f2bf(fmaxf(v[0], 0.f)) | ((unsigned)f2bf(fmaxf(v[1], 0.f)) << 16);
            unsigned hi = f2bf(fmaxf(v[2], 0.f)) | ((unsigned)f2bf(fmaxf(v[3], 0.f)) << 16);
            int byte = (row * 960 + col * 2) ^ ((row & 7) << 4);
            uint2 pk; pk.x = lo; pk.y = hi;
            *(uint2*)((char*)Abuf + byte) = pk;
        }
    }
    __syncthreads();
    // ---- fc1: Hd = relu(A @ W1 + B1), 4 waves x 128 cols, 16 rows ----
    int colg0 = wave * 128;
    f32x4 acc[8];
#pragma unroll
    for (int nb = 0; nb < 8; nb++) {
        float bv = B1[colg0 + nb * 16 + lr];
        f32x4 c; c[0] = bv; c[1] = bv; c[2] = bv; c[3] = bv;
        acc[nb] = c;
    }
#pragma unroll
    for (int kb = 0; kb < 15; kb++) {
        int k2 = (kb * 32 + lg * 8) * 2;
        int by0 = (lr * 960 + k2) ^ ((lr & 7) << 4);
        bf16x8 a0 = *(const bf16x8*)((char*)Abuf + by0);
#pragma unroll
        for (int nb = 0; nb < 8; nb++) {
            int nbg = wave * 8 + nb;
            bf16x8 bw = *(const bf16x8*)(W1p + (size_t)((kb * 32 + nbg) * 64 + l) * 8);
            acc[nb] = __builtin_amdgcn_mfma_f32_16x16x32_bf16(a0, bw, acc[nb], 0, 0, 0);
        }
    }
#pragma unroll
    for (int nb = 0; nb < 8; nb++)
#pragma unroll
        for (int r = 0; r < 4; r++) {
            int row = lg * 4 + r;
            int col = colg0 + nb * 16 + lr;
            unsigned short h = f2bf(fmaxf(acc[nb][r], 0.f));
            int byte = (row * 1024 + col * 2) ^ ((row & 7) << 4);
            *(unsigned short*)((char*)Hbuf + byte) = h;
        }
    __syncthreads();
    // ---- fc2 ----
    float* redp = (float*)Abuf;    // A dead; 16 rows x 96 floats = 6 KB
    {
        int rsub = t >> 5, seg = t & 31;
#pragma unroll
        for (int rg = 0; rg < 2; rg++) {
            int r = rg * 8 + rsub;
            float p0 = 0.f, p1 = 0.f, p2 = 0.f;
#pragma unroll
            for (int j = 0; j < 16; j++) {
                int k = seg + j * 32;
                int byte = (r * 1024 + k * 2) ^ ((r & 7) << 4);
                float h = bf2f(*(const unsigned short*)((char*)Hbuf + byte));
                p0 += h * W2[k * 3];
                p1 += h * W2[k * 3 + 1];
                p2 += h * W2[k * 3 + 2];
            }
            redp[r * 96 + seg] = p0;
            redp[r * 96 + 32 + seg] = p1;
            redp[r * 96 + 64 + seg] = p2;
        }
    }
    __syncthreads();
    if (t < 48) {
        int rr = t / 3, p = t - rr * 3;
        float s = B2[p];
        for (int seg = 0; seg < 32; seg++) s += redp[rr * 96 + p * 32 + seg];
        fbuf[(size_t)(row0 + rr) * 3 + p] = s;
    }
}

// final conv1x1 over time + transpose; grid = CB*48
__global__ void k_ec3(const float* f, const float* W, const float* bv, float* out) {
    int idx = blockIdx.x * 256 + threadIdx.x;
    int l = idx % 3;
    int rest = idx / 3;
    int o = rest & 3;
    int n = (rest >> 2) & 1023;
    int b = rest >> 12;
    float s = bv[o];
#pragma unroll
    for (int c = 0; c < 12; c++)
        s += f[(size_t)((b * 12 + c) * 1024 + n) * 3 + l] * W[o * 12 + c];
    out[idx] = s;
}

// ---------------- launcher ----------------
extern "C" void kernel_launch(void* const* d_in, const int* in_sizes, int n_in,
                              void* d_out, int out_size, void* d_ws, size_t ws_size,
                              hipStream_t stream) {
    const float* hist = (const float*)d_in[0];
    const float* node_emb_u = (const float*)d_in[1];
    const float* T_i_D_emb = (const float*)d_in[2];
    const float* D_i_W_emb = (const float*)d_in[3];
    const float* gc_emb1 = (const float*)d_in[4];
    const float* gc_emb2 = (const float*)d_in[5];
    const float* gc_w1 = (const float*)d_in[6];
    const float* gc_b1 = (const float*)d_in[7];
    const float* gc_w2 = (const float*)d_in[8];
    const float* gc_b2 = (const float*)d_in[9];
    const float* W_emb = (const float*)d_in[10];
    const float* b_emb = (const float*)d_in[11];
    const float* Wg1 = (const float*)d_in[12];
    const float* bg1 = (const float*)d_in[13];
    const float* Wg2 = (const float*)d_in[14];
    const float* bg2 = (const float*)d_in[15];
    const float* Wsc = (const float*)d_in[16];
    const float* bsc = (const float*)d_in[17];
    const float* mix1_w = (const float*)d_in[18];
    const float* mix1_b = (const float*)d_in[19];
    const float* mix2_w = (const float*)d_in[20];
    const float* mix2_b = (const float*)d_in[21];
    const float* Wtf1 = (const float*)d_in[22];
    const float* btf1 = (const float*)d_in[23];
    const float* Wtf2 = (const float*)d_in[24];
    const float* btf2 = (const float*)d_in[25];
    const float* Wec1 = (const float*)d_in[26];
    const float* bec1 = (const float*)d_in[27];
    const float* Wec2 = (const float*)d_in[28];
    const float* bec2 = (const float*)d_in[29];
    const float* Wfc1 = (const float*)d_in[30];
    const float* bfc1 = (const float*)d_in[31];
    const float* Wfc2 = (const float*)d_in[32];
    const float* bfc2 = (const float*)d_in[33];
    const float* Wec3 = (const float*)d_in[34];
    const float* bec3 = (const float*)d_in[35];

    float* ws = (float*)d_ws;
    float* n1 = ws + F_N1;
    float* n2 = ws + F_N2;
    float* aN_val = ws + F_ANVAL;
    float* row_val = ws + F_ROWVAL;
    float* col_sum = ws + F_COLSUM;
    float* inv_cs = ws + F_INVCS;
    float* aT_val = ws + F_ATVAL;
    int* aN_idx = (int*)(ws + I_ANIDX);
    int* row_idx = (int*)(ws + I_ROWIDX);
    int* col_cnt = (int*)(ws + I_COLCNT);
    int* col_off = (int*)(ws + I_COLOFF);
    int* col_fill = (int*)(ws + I_COLFILL);
    int* aT_idx = (int*)(ws + I_ATIDX);
    unsigned short* w1p = (unsigned short*)(ws + F_W1P);
    unsigned short* w2p = (unsigned short*)(ws + F_W2P);
    unsigned short* wfcp = (unsigned short*)(ws + F_WFCP);

    // pick largest batch-chunk CB that fits the workspace
    size_t avail = ws_size / 4;   // floats
    int CB = 8;
    while (CB > 1 && GRAPH_FLOATS + (size_t)CB * PB_TOTAL > avail) CB >>= 1;
    int nchunk = 8 / CB;

    float* gated = ws + GRAPH_FLOATS;
    float* hd_emb = gated + (size_t)CB * PB_GATED;
    float* xs = hd_emb + (size_t)CB * PB_HD;
    float* h1 = xs + (size_t)CB * PB_XS;
    float* h2 = h1 + (size_t)CB * PB_XS;
    float* mix = h2 + (size_t)CB * PB_XS;
    float* eco = xs;    // alias: xs+h1 region >= eco
    float* fbuf = h2;   // alias: h2 dead by k_fc

    // ---- graph construction + weight packing (once) ----
    k_init<<<4, 256, 0, stream>>>(col_cnt, col_fill, col_sum);
    k_embed<<<320, 256, 0, stream>>>(gc_emb1, gc_emb2, gc_w1, gc_b1, gc_w2, gc_b2, n1, n2);
    k_adj<<<1024, 256, 0, stream>>>(n1, n2, aN_val, aN_idx, row_val, row_idx, col_cnt, col_sum);
    k_scan<<<1, 1024, 0, stream>>>(col_cnt, col_off, col_sum, inv_cs);
    k_scatter<<<40, 256, 0, stream>>>(row_idx, row_val, col_off, col_fill, aT_idx, aT_val);
    k_packw<<<32, 256, 0, stream>>>(Wtf1, w1p);
    k_packw<<<32, 256, 0, stream>>>(Wtf2, w2p);
    k_packfc<<<120, 256, 0, stream>>>(Wfc1, wfcp);

    // ---- per-chunk pipeline ----
    for (int ch = 0; ch < nchunk; ch++) {
        const float* hist_c = hist + (size_t)ch * CB * ROWS_PER_B * 4;
        float* out_c = (float*)d_out + (size_t)ch * CB * ROWS_PER_B;

        k_gate<<<CB * 3072, 256, 0, stream>>>(hist_c, node_emb_u, T_i_D_emb, D_i_W_emb,
                                              Wg1, bg1, Wg2, bg2, W_emb, b_emb, gated, hd_emb);
        for (int xp = 0; xp < 2; xp++) {
            k_wsc<<<CB * 256, 256, 0, stream>>>(gated, Wsc, bsc, xs, xp * 64);
            for (int cp = 0; cp < 2; cp++) {
                k_spmm<<<CB * 2048, 256, 0, stream>>>(h1, xs, xs, aN_idx, aN_val, aT_idx, aT_val,
                                                      col_off, inv_cs, cp);
                k_spmm<<<CB * 2048, 256, 0, stream>>>(h2, xs, h1, aN_idx, aN_val, aT_idx, aT_val,
                                                      col_off, inv_cs, cp);
                k_proj<<<CB * 1024, 256, 0, stream>>>(xs, h1, h2, cp ? mix2_w : mix1_w,
                                                      mix1_b, mix2_b, mix, xp, cp);
            }
        }
        k_tf<<<CB * 1024, 256, 0, stream>>>(mix, w1p, btf1, w2p, btf2);
        k_ec<<<CB * 512, 256, 0, stream>>>(mix, Wec1, bec1, Wec2, bec2, eco);
        k_fc<<<CB * 768, 256, 0, stream>>>(gated, eco, hd_emb, hist_c, T_i_D_emb, D_i_W_emb,
                                           wfcp, bfc1, Wfc2, bfc2, fbuf);
        k_ec3<<<CB * 48, 256, 0, stream>>>(fbuf, Wec3, bec3, out_c);
    }
}

// Round 9
// 2726.913 us; speedup vs baseline: 1.7785x; 1.1001x over previous
//
#include <hip/hip_runtime.h>
#include <math.h>

// ---------------- constants ----------------
constexpr int ROWS_PER_B = 12 * 1024;    // rows (b,t,n) per batch element

// ---------------- graph workspace (float offsets, < 524288) ----------------
constexpr size_t F_N1 = 0;              // 1024*40
constexpr size_t F_N2 = 40960;
constexpr size_t F_ANVAL = 81920;       // 1024*11
constexpr size_t F_ROWVAL = 93184;      // 1024*10
constexpr size_t F_COLSUM = 103424;     // 1024
constexpr size_t F_INVCS = 104448;      // 1024
constexpr size_t F_ATVAL = 105472;      // 10240
constexpr size_t I_ANIDX = 115712;      // ints stored in float slots
constexpr size_t I_ROWIDX = 126976;
constexpr size_t I_COLCNT = 137216;
constexpr size_t I_COLOFF = 138240;     // 1025
constexpr size_t I_COLFILL = 139265;
constexpr size_t I_ATIDX = 140289;      // ends 150529
constexpr size_t F_W1P = 151552;        // packed bf16 Wtf1: 32768 floats
constexpr size_t F_W2P = 184320;        // packed bf16 Wtf2: ends 217088
constexpr size_t F_WFCP = 217088;       // packed bf16 Wfc1: ends 339968
constexpr size_t F_WEC1P = 339968;      // packed bf16 Wec1: 4096 u16 = 2048 floats
constexpr size_t F_WEC2P = 342016;      // packed bf16 Wec2: 2048 u16 = 1024 floats -> ends 343040
constexpr size_t GRAPH_FLOATS = 524288;

// per-chunk float counts (per batch element)
constexpr size_t PB_GATED = (size_t)ROWS_PER_B * 128;   // 1572864
constexpr size_t PB_HD = (size_t)ROWS_PER_B * 64;       // 786432
constexpr size_t PB_XS = (size_t)32 * 1024 * 64;        // 2097152
constexpr size_t PB_MIX = (size_t)32 * 1024 * 256;      // 8388608
constexpr size_t PB_TOTAL = PB_GATED + PB_HD + 3 * PB_XS + PB_MIX; // 17039360

typedef __attribute__((ext_vector_type(8))) short bf16x8;
typedef __attribute__((ext_vector_type(4))) float f32x4;

__device__ __forceinline__ unsigned short f2bf(float f) {
    unsigned u = __float_as_uint(f);
    unsigned r = (u + 0x7fffu + ((u >> 16) & 1u)) >> 16;   // RNE
    return (unsigned short)r;
}
__device__ __forceinline__ float bf2f(unsigned short h) {
    return __uint_as_float((unsigned)h << 16);
}

// ---------------- graph kernels ----------------

__global__ void k_init(int* cnt, int* fill, float* csum) {
    int t = blockIdx.x * 256 + threadIdx.x;
    if (t < 1024) { cnt[t] = 0; fill[t] = 0; csum[t] = 0.f; }
}

__global__ void k_embed(const float* e1, const float* e2, const float* w1, const float* b1,
                        const float* w2, const float* b2, float* n1, float* n2) {
    int idx = blockIdx.x * 256 + threadIdx.x;   // < 81920
    if (idx >= 81920) return;
    int m = idx / 40960, rem = idx - m * 40960;
    int i = rem / 40, j = rem - i * 40;
    const float* e = m ? e2 : e1;
    const float* w = m ? w2 : w1;
    const float* bv = m ? b2 : b1;
    float a = bv[j];
    for (int k = 0; k < 40; k++) a += e[i * 40 + k] * w[k * 40 + j];
    (m ? n2 : n1)[i * 40 + j] = tanhf(3.0f * a);
}

__global__ __launch_bounds__(256) void k_adj(const float* n1, const float* n2,
        float* aN_val, int* aN_idx, float* row_val, int* row_idx,
        int* col_cnt, float* col_sum) {
    __shared__ float arow[1024];
    __shared__ float n1v[40], n2v[40];
    __shared__ float rv[256];
    __shared__ int ri[256];
    __shared__ float topv[10];
    __shared__ int topi[10];
    int v = blockIdx.x, t = threadIdx.x;
    if (t < 40) { n1v[t] = n1[v * 40 + t]; n2v[t] = n2[v * 40 + t]; }
    __syncthreads();
    for (int j = t; j < 1024; j += 256) {
        float d1 = 0.f, d2 = 0.f;
        for (int k = 0; k < 40; k++) {
            d1 += n1v[k] * n2[j * 40 + k];
            d2 += n2v[k] * n1[j * 40 + k];
        }
        float a = tanhf(3.0f * (d1 - d2));
        arow[j] = a > 0.f ? a : 0.f;
    }
    __syncthreads();
    for (int r = 0; r < 10; r++) {
        float bv = -1.f; int bi = 1 << 30;
        for (int j = t; j < 1024; j += 256) {
            float x = arow[j];
            if (x > bv || (x == bv && j < bi)) { bv = x; bi = j; }
        }
        rv[t] = bv; ri[t] = bi;
        __syncthreads();
        for (int s = 128; s > 0; s >>= 1) {
            if (t < s) {
                float ov = rv[t + s]; int oi = ri[t + s];
                if (ov > rv[t] || (ov == rv[t] && oi < ri[t])) { rv[t] = ov; ri[t] = oi; }
            }
            __syncthreads();
        }
        if (t == 0) { topv[r] = rv[0]; topi[r] = ri[0]; arow[ri[0]] = -1.f; }
        __syncthreads();
    }
    if (t == 0) {
        float s = 1.f;
        for (int r = 0; r < 10; r++) s += topv[r];
        float inv = 1.f / s;
        for (int r = 0; r < 10; r++) {
            aN_idx[v * 11 + r] = topi[r];
            aN_val[v * 11 + r] = topv[r] * inv;
            row_idx[v * 10 + r] = topi[r];
            row_val[v * 10 + r] = topv[r];
            atomicAdd(&col_cnt[topi[r]], 1);
            atomicAdd(&col_sum[topi[r]], topv[r]);
        }
        aN_idx[v * 11 + 10] = v;
        aN_val[v * 11 + 10] = inv;
    }
}

__global__ __launch_bounds__(1024) void k_scan(const int* cnt, int* off,
                                               const float* csum, float* inv) {
    __shared__ int tmp[1024];
    int t = threadIdx.x;
    tmp[t] = cnt[t];
    __syncthreads();
    for (int s = 1; s < 1024; s <<= 1) {
        int v = 0;
        if (t >= s) v = tmp[t - s];
        __syncthreads();
        tmp[t] += v;
        __syncthreads();
    }
    off[t + 1] = tmp[t];
    if (t == 0) off[0] = 0;
    inv[t] = 1.0f / (csum[t] + 1.0f);
}

__global__ void k_scatter(const int* row_idx, const float* row_val, const int* off,
                          int* fill, int* aT_idx, float* aT_val) {
    int e = blockIdx.x * 256 + threadIdx.x;
    if (e >= 10240) return;
    int v = e / 10;
    int j = row_idx[e];
    int pos = off[j] + atomicAdd(&fill[j], 1);
    aT_idx[pos] = v;
    aT_val[pos] = row_val[e];
}

// pack 256x256 f32 weight into MFMA B-fragment order
__global__ void k_packw(const float* W, unsigned short* out) {
    int id = blockIdx.x * 256 + threadIdx.x;    // 8192 total
    if (id >= 8192) return;
    int lane = id & 63, rest = id >> 6;
    int nb = rest & 15, kb = rest >> 4;
    int krow = kb * 32 + (lane >> 4) * 8;
    int col = nb * 16 + (lane & 15);
    unsigned short v[8];
#pragma unroll
    for (int j = 0; j < 8; j++) v[j] = f2bf(W[(size_t)(krow + j) * 256 + col]);
#pragma unroll
    for (int j = 0; j < 8; j++) out[(size_t)id * 8 + j] = v[j];
}

// pack 472x512 Wfc1 into B-fragment order, K padded to 480
__global__ void k_packfc(const float* W, unsigned short* out) {
    int id = blockIdx.x * 256 + threadIdx.x;    // 30720 total
    if (id >= 30720) return;
    int lane = id & 63, rest = id >> 6;
    int nb = rest & 31, kb = rest >> 5;         // kb < 15
    int k0 = kb * 32 + (lane >> 4) * 8;
    int col = nb * 16 + (lane & 15);
    unsigned short v[8];
#pragma unroll
    for (int j = 0; j < 8; j++) {
        int k = k0 + j;
        v[j] = (k < 472) ? f2bf(W[(size_t)k * 512 + col]) : (unsigned short)0;
    }
#pragma unroll
    for (int j = 0; j < 8; j++) out[(size_t)id * 8 + j] = v[j];
}

// pack Wec1 (128x32) into A-frag order (8 m-tiles) and Wec2 (12x128, pad to 16) into
// A-frag order (4 k-blocks). A-frag: lane row=(l&15), k=(l>>4)*8+j.
__global__ void k_packec(const float* W1, const float* W2,
                         unsigned short* o1, unsigned short* o2) {
    int id = blockIdx.x * 256 + threadIdx.x;    // 768 total
    if (id < 512) {
        int mt = id >> 6, lane = id & 63;
        int o = mt * 16 + (lane & 15);
        int c0 = (lane >> 4) * 8;
#pragma unroll
        for (int j = 0; j < 8; j++)
            o1[(size_t)id * 8 + j] = f2bf(W1[o * 32 + c0 + j]);
    } else if (id < 768) {
        int id2 = id - 512;
        int kb = id2 >> 6, lane = id2 & 63;
        int p = lane & 15;
        int k0 = kb * 32 + (lane >> 4) * 8;
#pragma unroll
        for (int j = 0; j < 8; j++)
            o2[(size_t)id2 * 8 + j] = (p < 12) ? f2bf(W2[p * 128 + k0 + j])
                                               : (unsigned short)0;
    }
}

// ---------------- per-chunk kernels ----------------

// gate MLP + embed; grid = CB*3072
__global__ __launch_bounds__(256) void k_gate(const float* hist, const float* nodeu,
        const float* tide, const float* diwe,
        const float* Wg1, const float* bg1, const float* Wg2, const float* bg2,
        const float* Wemb, const float* bemb, float* gated, float* hd_emb) {
    __shared__ float w1[4096], w2[4096];
    __shared__ float gin[4][64], hid[4][64];
    __shared__ float sb1[64], sb2[64], we[128], be[64];
    int t = threadIdx.x;
    for (int i = t; i < 4096; i += 256) { w1[i] = Wg1[i]; w2[i] = Wg2[i]; }
    if (t < 64) { sb1[t] = bg1[t]; sb2[t] = bg2[t]; be[t] = bemb[t]; }
    if (t < 128) we[t] = Wemb[t];
    int r = t >> 6, lane = t & 63;
    int row = blockIdx.x * 4 + r;
    int n = row & 1023;
    const float* hrow = hist + (size_t)row * 4;
    float f0 = hrow[0], f1 = hrow[1];
    int tid_i = (int)(hrow[2] * 288.0f);
    int diw_i = (int)hrow[3];
    float g;
    if (lane < 40) g = nodeu[n * 40 + lane];
    else if (lane < 52) g = tide[tid_i * 12 + lane - 40];
    else g = diwe[diw_i * 12 + lane - 52];
    gin[r][lane] = g;
    __syncthreads();
    float acc = sb1[lane];
    for (int k = 0; k < 64; k++) acc += gin[r][k] * w1[k * 64 + lane];
    hid[r][lane] = acc > 0.f ? acc : 0.f;
    __syncthreads();
    acc = sb2[lane];
    for (int k = 0; k < 64; k++) acc += hid[r][k] * w2[k * 64 + lane];
    float gate = 1.f / (1.f + expf(-acc));
    float hd = f0 * we[lane] + f1 * we[64 + lane] + be[lane];
    float x1 = gate * hd;
    gated[(size_t)row * 128 + lane] = x1;
    gated[(size_t)row * 128 + 64 + lane] = hd - x1;
    hd_emb[(size_t)row * 64 + lane] = hd;
}

// xs[b,o,n,h] = relu(sum_t gated*Wsc + bsc); grid = CB*256
__global__ __launch_bounds__(256) void k_wsc(const float* gated, const float* Wsc,
                                             const float* bsc, float* xs, int xoff) {
    __shared__ float w[384];
    __shared__ float sb[32];
    int t = threadIdx.x;
    if (t < 384) w[t] = Wsc[t];
    if (t < 32) sb[t] = bsc[t];
    __syncthreads();
    int idx = blockIdx.x * 256 + t;
    int h = idx & 63, n = (idx >> 6) & 1023, b = idx >> 16;
    float xv[12];
#pragma unroll
    for (int tt = 0; tt < 12; tt++)
        xv[tt] = gated[(size_t)((b * 12 + tt) * 1024 + n) * 128 + xoff + h];
#pragma unroll
    for (int o = 0; o < 32; o++) {
        float a = sb[o];
#pragma unroll
        for (int tt = 0; tt < 12; tt++) a += xv[tt] * w[o * 12 + tt];
        xs[(size_t)((b * 32 + o) * 1024 + n) * 64 + h] = a > 0.f ? a : 0.f;
    }
}

// out = 0.05*x + 0.95*(A_norm @ hin), float4 lanes; grid = CB*2048
__global__ __launch_bounds__(256) void k_spmm(float* out, const float* x, const float* hin,
        const int* aN_idx, const float* aN_val,
        const int* aT_idx, const float* aT_val,
        const int* off, const float* inv_cs, int mode) {
    int t = threadIdx.x;
    int l4 = t & 15, r = t >> 4;            // 16 rows x 16 float4-lanes
    int g = blockIdx.x * 16 + r;            // row id (bc, v)
    int v = g & 1023, bc = g >> 10;
    const float4* base = (const float4*)hin + (size_t)bc * 16384;
    float4 s;
    if (mode == 0) {
        s.x = s.y = s.z = s.w = 0.f;
#pragma unroll
        for (int e = 0; e < 11; e++) {
            int w = aN_idx[v * 11 + e];
            float a = aN_val[v * 11 + e];
            float4 hv = base[w * 16 + l4];
            s.x += a * hv.x; s.y += a * hv.y; s.z += a * hv.z; s.w += a * hv.w;
        }
    } else {
        s = base[v * 16 + l4];
        int e0 = off[v], e1 = off[v + 1];
        for (int e = e0; e < e1; e++) {
            int w = aT_idx[e];
            float a = aT_val[e];
            float4 hv = base[w * 16 + l4];
            s.x += a * hv.x; s.y += a * hv.y; s.z += a * hv.z; s.w += a * hv.w;
        }
        float ic = inv_cs[v];
        s.x *= ic; s.y *= ic; s.z *= ic; s.w *= ic;
    }
    size_t oi = (size_t)g * 16 + l4;
    float4 xv = ((const float4*)x)[oi];
    float4 o;
    o.x = 0.05f * xv.x + 0.95f * s.x;
    o.y = 0.05f * xv.y + 0.95f * s.y;
    o.z = 0.05f * xv.z + 0.95f * s.z;
    o.w = 0.05f * xv.w + 0.95f * s.w;
    ((float4*)out)[oi] = o;
}

// mix projection; grid = CB*1024
__global__ __launch_bounds__(256) void k_proj(const float* xs, const float* h1, const float* h2,
        const float* mw, const float* m1b, const float* m2b,
        float* mix, int xp, int cp) {
    __shared__ float Wl[96 * 64];
    __shared__ float Bt[96 * 64];
    int t = threadIdx.x;
    int b = blockIdx.x >> 10, n = blockIdx.x & 1023;
    for (int i = t; i < 6144; i += 256) {
        int k = i >> 6, col = i & 63;
        Wl[i] = mw[col * 96 + k];
    }
    for (int i = t; i < 6144; i += 256) {
        int k = i >> 6, l = i & 63;
        int q = k >> 5, c = k & 31;
        const float* Hq = (q == 0) ? xs : (q == 1 ? h1 : h2);
        Bt[i] = Hq[(size_t)((b * 32 + c) * 1024 + n) * 64 + l];
    }
    __syncthreads();
    int tx = t & 15, ty = t >> 4;
    int o0 = tx * 4, l0 = ty * 4;
    float acc[4][4];
#pragma unroll
    for (int io = 0; io < 4; io++) {
        float bias = 0.f;
        if (cp == 0) { int rrow = o0 + io; bias = m1b[rrow] + m2b[rrow]; }
#pragma unroll
        for (int il = 0; il < 4; il++) acc[io][il] = bias;
    }
    for (int k = 0; k < 96; k++) {
        float4 a = *(const float4*)&Wl[k * 64 + o0];
        float4 bb = *(const float4*)&Bt[k * 64 + l0];
        acc[0][0] += a.x * bb.x; acc[0][1] += a.x * bb.y; acc[0][2] += a.x * bb.z; acc[0][3] += a.x * bb.w;
        acc[1][0] += a.y * bb.x; acc[1][1] += a.y * bb.y; acc[1][2] += a.y * bb.z; acc[1][3] += a.y * bb.w;
        acc[2][0] += a.z * bb.x; acc[2][1] += a.z * bb.y; acc[2][2] += a.z * bb.z; acc[2][3] += a.z * bb.w;
        acc[3][0] += a.w * bb.x; acc[3][1] += a.w * bb.y; acc[3][2] += a.w * bb.z; acc[3][3] += a.w * bb.w;
    }
#pragma unroll
    for (int io = 0; io < 4; io++) {
        int rrow = o0 + io;
        int i2 = rrow >> 5, o = rrow & 31;
        float* gp = &mix[(size_t)((b * 32 + o) * 1024 + n) * 256 + (i2 * 2 + xp) * 64 + l0];
        if (cp == 0) {
#pragma unroll
            for (int il = 0; il < 4; il++) gp[il] = acc[io][il];
        } else {
#pragma unroll
            for (int il = 0; il < 4; il++) gp[il] += acc[io][il];
        }
    }
}

// fused Wtf1(relu)Wtf2 via bf16 MFMA, in-place on mix: 32 rows/block; grid = CB*1024
__global__ __launch_bounds__(256) void k_tf(float* mix, const unsigned short* W1p, const float* B1,
                                            const unsigned short* W2p, const float* B2) {
    __shared__ unsigned short Abuf[32 * 256];   // bf16, XOR-swizzled
    __shared__ unsigned short Hbuf[32 * 256];
    int t = threadIdx.x;
    int wave = t >> 6, l = t & 63;
    size_t row0 = (size_t)blockIdx.x * 32;
    const float4* src = (const float4*)(mix + row0 * 256);
#pragma unroll
    for (int it = 0; it < 8; it++) {
        int f = t + it * 256;                  // 2048 float4s
        float4 v = src[f];
        int e = f * 4, row = e >> 8, col = e & 255;
        unsigned lo = f2bf(v.x) | ((unsigned)f2bf(v.y) << 16);
        unsigned hi = f2bf(v.z) | ((unsigned)f2bf(v.w) << 16);
        int byte = (row * 512 + col * 2) ^ ((row & 7) << 4);
        uint2 pk; pk.x = lo; pk.y = hi;
        *(uint2*)((char*)Abuf + byte) = pk;
    }
    __syncthreads();
    int colg0 = wave * 64;
    int lr = l & 15, lg = l >> 4;
    f32x4 acc[2][4];
#pragma unroll
    for (int nb = 0; nb < 4; nb++) {
        float bv = B1[colg0 + nb * 16 + lr];
        f32x4 c; c[0] = bv; c[1] = bv; c[2] = bv; c[3] = bv;
        acc[0][nb] = c; acc[1][nb] = c;
    }
#pragma unroll
    for (int kb = 0; kb < 8; kb++) {
        int k2 = (kb * 32 + lg * 8) * 2;
        int by0 = (lr * 512 + k2) ^ ((lr & 7) << 4);
        int by1 = ((16 + lr) * 512 + k2) ^ ((lr & 7) << 4);
        bf16x8 a0 = *(const bf16x8*)((char*)Abuf + by0);
        bf16x8 a1 = *(const bf16x8*)((char*)Abuf + by1);
#pragma unroll
        for (int nb = 0; nb < 4; nb++) {
            int nbg = wave * 4 + nb;
            bf16x8 bw = *(const bf16x8*)(W1p + (size_t)((kb * 16 + nbg) * 64 + l) * 8);
            acc[0][nb] = __builtin_amdgcn_mfma_f32_16x16x32_bf16(a0, bw, acc[0][nb], 0, 0, 0);
            acc[1][nb] = __builtin_amdgcn_mfma_f32_16x16x32_bf16(a1, bw, acc[1][nb], 0, 0, 0);
        }
    }
#pragma unroll
    for (int rb = 0; rb < 2; rb++)
#pragma unroll
        for (int nb = 0; nb < 4; nb++)
#pragma unroll
            for (int r = 0; r < 4; r++) {
                int row = rb * 16 + lg * 4 + r;
                int col = colg0 + nb * 16 + lr;
                unsigned short h = f2bf(fmaxf(acc[rb][nb][r], 0.f));
                int byte = (row * 512 + col * 2) ^ ((row & 7) << 4);
                *(unsigned short*)((char*)Hbuf + byte) = h;
            }
    __syncthreads();
#pragma unroll
    for (int nb = 0; nb < 4; nb++) {
        float bv = B2[colg0 + nb * 16 + lr];
        f32x4 c; c[0] = bv; c[1] = bv; c[2] = bv; c[3] = bv;
        acc[0][nb] = c; acc[1][nb] = c;
    }
#pragma unroll
    for (int kb = 0; kb < 8; kb++) {
        int k2 = (kb * 32 + lg * 8) * 2;
        int by0 = (lr * 512 + k2) ^ ((lr & 7) << 4);
        int by1 = ((16 + lr) * 512 + k2) ^ ((lr & 7) << 4);
        bf16x8 a0 = *(const bf16x8*)((char*)Hbuf + by0);
        bf16x8 a1 = *(const bf16x8*)((char*)Hbuf + by1);
#pragma unroll
        for (int nb = 0; nb < 4; nb++) {
            int nbg = wave * 4 + nb;
            bf16x8 bw = *(const bf16x8*)(W2p + (size_t)((kb * 16 + nbg) * 64 + l) * 8);
            acc[0][nb] = __builtin_amdgcn_mfma_f32_16x16x32_bf16(a0, bw, acc[0][nb], 0, 0, 0);
            acc[1][nb] = __builtin_amdgcn_mfma_f32_16x16x32_bf16(a1, bw, acc[1][nb], 0, 0, 0);
        }
    }
#pragma unroll
    for (int rb = 0; rb < 2; rb++)
#pragma unroll
        for (int nb = 0; nb < 4; nb++)
#pragma unroll
            for (int r = 0; r < 4; r++) {
                int row = rb * 16 + lg * 4 + r;
                int col = colg0 + nb * 16 + lr;
                mix[(row0 + row) * 256 + col] = acc[rb][nb][r];
            }
}

// fused ec1(relu)+ec2 via bf16 MFMA; block = (b,n); per-wave private LDS, no barriers.
// grid = CB*1024
__global__ __launch_bounds__(256) void k_ec(const float* tfo,
        const unsigned short* W1p, const float* B1,
        const unsigned short* W2p, const float* B2, float* eco) {
    __shared__ unsigned short Hl[4 * 64 * 48];   // per-wave [64 l][48 u16 (32 used)] = 24 KB
    int t = threadIdx.x;
    int wave = t >> 6, l = t & 63;
    int lr = l & 15, lg = l >> 4;
    int b = blockIdx.x >> 10, n = blockIdx.x & 1023;
    int lbase = wave * 64;
    unsigned short* myH = Hl + wave * 3072;      // 64*48
    // ---- B-frags: gather X[c][l] from tf output (c = lg*8+j, stride 256K floats) ----
    const float* xb = tfo + ((size_t)(b * 32) * 1024 + n) * 256;
    bf16x8 xf[4];
#pragma unroll
    for (int nt = 0; nt < 4; nt++) {
        int ll = lbase + nt * 16 + lr;
        bf16x8 v;
#pragma unroll
        for (int j = 0; j < 8; j++)
            v[j] = (short)f2bf(xb[(size_t)(lg * 8 + j) * 262144 + ll]);
        xf[nt] = v;
    }
    // ---- d2 accumulators (p rows), bias-initialized ----
    f32x4 d2[4];
    {
        f32x4 c;
#pragma unroll
        for (int r = 0; r < 4; r++) {
            int p = lg * 4 + r;
            c[r] = (p < 12) ? B2[p] : 0.f;
        }
#pragma unroll
        for (int nt = 0; nt < 4; nt++) d2[nt] = c;
    }
    // ---- 4 chunks of 32 o-channels: ec1 MFMA -> relu -> LDS -> ec2 MFMA ----
#pragma unroll
    for (int ch = 0; ch < 4; ch++) {
        f32x4 h[2][4];
#pragma unroll
        for (int mt = 0; mt < 2; mt++) {
            f32x4 c;
#pragma unroll
            for (int r = 0; r < 4; r++) c[r] = B1[ch * 32 + mt * 16 + lg * 4 + r];
#pragma unroll
            for (int nt = 0; nt < 4; nt++) h[mt][nt] = c;
        }
#pragma unroll
        for (int mt = 0; mt < 2; mt++) {
            bf16x8 aw = *(const bf16x8*)(W1p + (size_t)((ch * 2 + mt) * 64 + l) * 8);
#pragma unroll
            for (int nt = 0; nt < 4; nt++)
                h[mt][nt] = __builtin_amdgcn_mfma_f32_16x16x32_bf16(aw, xf[nt], h[mt][nt], 0, 0, 0);
        }
        // relu -> per-wave LDS (rows l, 96B stride)
#pragma unroll
        for (int mt = 0; mt < 2; mt++)
#pragma unroll
            for (int nt = 0; nt < 4; nt++) {
                unsigned lo = f2bf(fmaxf(h[mt][nt][0], 0.f)) |
                              ((unsigned)f2bf(fmaxf(h[mt][nt][1], 0.f)) << 16);
                unsigned hi = f2bf(fmaxf(h[mt][nt][2], 0.f)) |
                              ((unsigned)f2bf(fmaxf(h[mt][nt][3], 0.f)) << 16);
                uint2 pk; pk.x = lo; pk.y = hi;
                *(uint2*)(myH + (nt * 16 + lr) * 48 + mt * 16 + lg * 4) = pk;
            }
        // ec2 partial: A = W2 chunk (k = ch*32 + lg*8+j), B = H chunk from LDS
        bf16x8 aw2 = *(const bf16x8*)(W2p + (size_t)(ch * 64 + l) * 8);
#pragma unroll
        for (int nt = 0; nt < 4; nt++) {
            bf16x8 hf = *(const bf16x8*)(myH + (nt * 16 + lr) * 48 + lg * 8);
            d2[nt] = __builtin_amdgcn_mfma_f32_16x16x32_bf16(aw2, hf, d2[nt], 0, 0, 0);
        }
    }
    // ---- write eco[p][n][l] ----
#pragma unroll
    for (int nt = 0; nt < 4; nt++)
#pragma unroll
        for (int r = 0; r < 4; r++) {
            int p = lg * 4 + r;
            if (p < 12) {
                int ll = lbase + nt * 16 + lr;
                eco[((size_t)(b * 12 + p) * 1024 + n) * 256 + ll] = d2[nt][r];
            }
        }
}

// fused fc1(bf16 MFMA)+relu+fc2: 16 rows/block (31.7KB LDS); grid = CB*768
__global__ __launch_bounds__(256) void k_fc(const float* gated, const float* eco,
        const float* hd_emb, const float* hist, const float* tide, const float* diwe,
        const unsigned short* W1p, const float* B1, const float* W2, const float* B2,
        float* fbuf) {
    __shared__ unsigned short Abuf[16 * 480];   // 15360 B, XOR-swizzled rows of 960 B
    __shared__ unsigned short Hbuf[16 * 512];   // 16384 B, XOR-swizzled rows of 1024 B
    int t = threadIdx.x;
    int wave = t >> 6, l = t & 63;
    int lr = l & 15, lg = l >> 4;
    int row0 = blockIdx.x * 16;
#pragma unroll
    for (int it = 0; it < 8; it++) {
        int idx = it * 256 + t;                 // 1920 chunks of 4 elements
        if (idx < 1920) {
            int row = idx / 120;
            int col = (idx - row * 120) * 4;
            int grow = row0 + row;
            int n = grow & 1023, bt = grow >> 10;
            int b = bt / 12, tt = bt - b * 12;
            float v[4];
            if (col < 128) {
#pragma unroll
                for (int q = 0; q < 4; q++) v[q] = gated[(size_t)grow * 128 + col + q];
            } else if (col < 384) {
                const float* ep = &eco[(size_t)((b * 12 + tt) * 1024 + n) * 256 + (col - 128)];
#pragma unroll
                for (int q = 0; q < 4; q++) v[q] = ep[q];
            } else if (col < 396) {
                int tid_i = (int)(hist[(size_t)grow * 4 + 2] * 288.0f);
#pragma unroll
                for (int q = 0; q < 4; q++) v[q] = tide[tid_i * 12 + col - 384 + q];
            } else if (col < 408) {
                int diw_i = (int)hist[(size_t)grow * 4 + 3];
#pragma unroll
                for (int q = 0; q < 4; q++) v[q] = diwe[diw_i * 12 + col - 396 + q];
            } else if (col < 472) {
#pragma unroll
                for (int q = 0; q < 4; q++) v[q] = hd_emb[(size_t)grow * 64 + col - 408 + q];
            } else {
#pragma unroll
                for (int q = 0; q < 4; q++) v[q] = 0.f;
            }
            unsigned lo = f2bf(fmaxf(v[0], 0.f)) | ((unsigned)f2bf(fmaxf(v[1], 0.f)) << 16);
            unsigned hi = f2bf(fmaxf(v[2], 0.f)) | ((unsigned)f2bf(fmaxf(v[3], 0.f)) << 16);
            int byte = (row * 960 + col * 2) ^ ((row & 7) << 4);
            uint2 pk; pk.x = lo; pk.y = hi;
            *(uint2*)((char*)Abuf + byte) = pk;
        }
    }
    __syncthreads();
    int colg0 = wave * 128;
    f32x4 acc[8];
#pragma unroll
    for (int nb = 0; nb < 8; nb++) {
        float bv = B1[colg0 + nb * 16 + lr];
        f32x4 c; c[0] = bv; c[1] = bv; c[2] = bv; c[3] = bv;
        acc[nb] = c;
    }
#pragma unroll
    for (int kb = 0; kb < 15; kb++) {
        int k2 = (kb * 32 + lg * 8) * 2;
        int by0 = (lr * 960 + k2) ^ ((lr & 7) << 4);
        bf16x8 a0 = *(const bf16x8*)((char*)Abuf + by0);
#pragma unroll
        for (int nb = 0; nb < 8; nb++) {
            int nbg = wave * 8 + nb;
            bf16x8 bw = *(const bf16x8*)(W1p + (size_t)((kb * 32 + nbg) * 64 + l) * 8);
            acc[nb] = __builtin_amdgcn_mfma_f32_16x16x32_bf16(a0, bw, acc[nb], 0, 0, 0);
        }
    }
#pragma unroll
    for (int nb = 0; nb < 8; nb++)
#pragma unroll
        for (int r = 0; r < 4; r++) {
            int row = lg * 4 + r;
            int col = colg0 + nb * 16 + lr;
            unsigned short h = f2bf(fmaxf(acc[nb][r], 0.f));
            int byte = (row * 1024 + col * 2) ^ ((row & 7) << 4);
            *(unsigned short*)((char*)Hbuf + byte) = h;
        }
    __syncthreads();
    float* redp = (float*)Abuf;    // A dead; 16 rows x 96 floats = 6 KB
    {
        int rsub = t >> 5, seg = t & 31;
#pragma unroll
        for (int rg = 0; rg < 2; rg++) {
            int r = rg * 8 + rsub;
            float p0 = 0.f, p1 = 0.f, p2 = 0.f;
#pragma unroll
            for (int j = 0; j < 16; j++) {
                int k = seg + j * 32;
                int byte = (r * 1024 + k * 2) ^ ((r & 7) << 4);
                float h = bf2f(*(const unsigned short*)((char*)Hbuf + byte));
                p0 += h * W2[k * 3];
                p1 += h * W2[k * 3 + 1];
                p2 += h * W2[k * 3 + 2];
            }
            redp[r * 96 + seg] = p0;
            redp[r * 96 + 32 + seg] = p1;
            redp[r * 96 + 64 + seg] = p2;
        }
    }
    __syncthreads();
    if (t < 48) {
        int rr = t / 3, p = t - rr * 3;
        float s = B2[p];
        for (int seg = 0; seg < 32; seg++) s += redp[rr * 96 + p * 32 + seg];
        fbuf[(size_t)(row0 + rr) * 3 + p] = s;
    }
}

// final conv1x1 over time + transpose; grid = CB*48
__global__ void k_ec3(const float* f, const float* W, const float* bv, float* out) {
    int idx = blockIdx.x * 256 + threadIdx.x;
    int l = idx % 3;
    int rest = idx / 3;
    int o = rest & 3;
    int n = (rest >> 2) & 1023;
    int b = rest >> 12;
    float s = bv[o];
#pragma unroll
    for (int c = 0; c < 12; c++)
        s += f[(size_t)((b * 12 + c) * 1024 + n) * 3 + l] * W[o * 12 + c];
    out[idx] = s;
}

// ---------------- launcher ----------------
extern "C" void kernel_launch(void* const* d_in, const int* in_sizes, int n_in,
                              void* d_out, int out_size, void* d_ws, size_t ws_size,
                              hipStream_t stream) {
    const float* hist = (const float*)d_in[0];
    const float* node_emb_u = (const float*)d_in[1];
    const float* T_i_D_emb = (const float*)d_in[2];
    const float* D_i_W_emb = (const float*)d_in[3];
    const float* gc_emb1 = (const float*)d_in[4];
    const float* gc_emb2 = (const float*)d_in[5];
    const float* gc_w1 = (const float*)d_in[6];
    const float* gc_b1 = (const float*)d_in[7];
    const float* gc_w2 = (const float*)d_in[8];
    const float* gc_b2 = (const float*)d_in[9];
    const float* W_emb = (const float*)d_in[10];
    const float* b_emb = (const float*)d_in[11];
    const float* Wg1 = (const float*)d_in[12];
    const float* bg1 = (const float*)d_in[13];
    const float* Wg2 = (const float*)d_in[14];
    const float* bg2 = (const float*)d_in[15];
    const float* Wsc = (const float*)d_in[16];
    const float* bsc = (const float*)d_in[17];
    const float* mix1_w = (const float*)d_in[18];
    const float* mix1_b = (const float*)d_in[19];
    const float* mix2_w = (const float*)d_in[20];
    const float* mix2_b = (const float*)d_in[21];
    const float* Wtf1 = (const float*)d_in[22];
    const float* btf1 = (const float*)d_in[23];
    const float* Wtf2 = (const float*)d_in[24];
    const float* btf2 = (const float*)d_in[25];
    const float* Wec1 = (const float*)d_in[26];
    const float* bec1 = (const float*)d_in[27];
    const float* Wec2 = (const float*)d_in[28];
    const float* bec2 = (const float*)d_in[29];
    const float* Wfc1 = (const float*)d_in[30];
    const float* bfc1 = (const float*)d_in[31];
    const float* Wfc2 = (const float*)d_in[32];
    const float* bfc2 = (const float*)d_in[33];
    const float* Wec3 = (const float*)d_in[34];
    const float* bec3 = (const float*)d_in[35];

    float* ws = (float*)d_ws;
    float* n1 = ws + F_N1;
    float* n2 = ws + F_N2;
    float* aN_val = ws + F_ANVAL;
    float* row_val = ws + F_ROWVAL;
    float* col_sum = ws + F_COLSUM;
    float* inv_cs = ws + F_INVCS;
    float* aT_val = ws + F_ATVAL;
    int* aN_idx = (int*)(ws + I_ANIDX);
    int* row_idx = (int*)(ws + I_ROWIDX);
    int* col_cnt = (int*)(ws + I_COLCNT);
    int* col_off = (int*)(ws + I_COLOFF);
    int* col_fill = (int*)(ws + I_COLFILL);
    int* aT_idx = (int*)(ws + I_ATIDX);
    unsigned short* w1p = (unsigned short*)(ws + F_W1P);
    unsigned short* w2p = (unsigned short*)(ws + F_W2P);
    unsigned short* wfcp = (unsigned short*)(ws + F_WFCP);
    unsigned short* wec1p = (unsigned short*)(ws + F_WEC1P);
    unsigned short* wec2p = (unsigned short*)(ws + F_WEC2P);

    // pick largest batch-chunk CB that fits the workspace
    size_t avail = ws_size / 4;   // floats
    int CB = 8;
    while (CB > 1 && GRAPH_FLOATS + (size_t)CB * PB_TOTAL > avail) CB >>= 1;
    int nchunk = 8 / CB;

    float* gated = ws + GRAPH_FLOATS;
    float* hd_emb = gated + (size_t)CB * PB_GATED;
    float* xs = hd_emb + (size_t)CB * PB_HD;
    float* h1 = xs + (size_t)CB * PB_XS;
    float* h2 = h1 + (size_t)CB * PB_XS;
    float* mix = h2 + (size_t)CB * PB_XS;
    float* eco = xs;    // alias: xs+h1 region >= eco
    float* fbuf = h2;   // alias: h2 dead by k_fc

    // ---- graph construction + weight packing (once) ----
    k_init<<<4, 256, 0, stream>>>(col_cnt, col_fill, col_sum);
    k_embed<<<320, 256, 0, stream>>>(gc_emb1, gc_emb2, gc_w1, gc_b1, gc_w2, gc_b2, n1, n2);
    k_adj<<<1024, 256, 0, stream>>>(n1, n2, aN_val, aN_idx, row_val, row_idx, col_cnt, col_sum);
    k_scan<<<1, 1024, 0, stream>>>(col_cnt, col_off, col_sum, inv_cs);
    k_scatter<<<40, 256, 0, stream>>>(row_idx, row_val, col_off, col_fill, aT_idx, aT_val);
    k_packw<<<32, 256, 0, stream>>>(Wtf1, w1p);
    k_packw<<<32, 256, 0, stream>>>(Wtf2, w2p);
    k_packfc<<<120, 256, 0, stream>>>(Wfc1, wfcp);
    k_packec<<<3, 256, 0, stream>>>(Wec1, Wec2, wec1p, wec2p);

    // ---- per-chunk pipeline ----
    for (int ch = 0; ch < nchunk; ch++) {
        const float* hist_c = hist + (size_t)ch * CB * ROWS_PER_B * 4;
        float* out_c = (float*)d_out + (size_t)ch * CB * ROWS_PER_B;

        k_gate<<<CB * 3072, 256, 0, stream>>>(hist_c, node_emb_u, T_i_D_emb, D_i_W_emb,
                                              Wg1, bg1, Wg2, bg2, W_emb, b_emb, gated, hd_emb);
        for (int xp = 0; xp < 2; xp++) {
            k_wsc<<<CB * 256, 256, 0, stream>>>(gated, Wsc, bsc, xs, xp * 64);
            for (int cp = 0; cp < 2; cp++) {
                k_spmm<<<CB * 2048, 256, 0, stream>>>(h1, xs, xs, aN_idx, aN_val, aT_idx, aT_val,
                                                      col_off, inv_cs, cp);
                k_spmm<<<CB * 2048, 256, 0, stream>>>(h2, xs, h1, aN_idx, aN_val, aT_idx, aT_val,
                                                      col_off, inv_cs, cp);
                k_proj<<<CB * 1024, 256, 0, stream>>>(xs, h1, h2, cp ? mix2_w : mix1_w,
                                                      mix1_b, mix2_b, mix, xp, cp);
            }
        }
        k_tf<<<CB * 1024, 256, 0, stream>>>(mix, w1p, btf1, w2p, btf2);
        k_ec<<<CB * 1024, 256, 0, stream>>>(mix, wec1p, bec1, wec2p, bec2, eco);
        k_fc<<<CB * 768, 256, 0, stream>>>(gated, eco, hd_emb, hist_c, T_i_D_emb, D_i_W_emb,
                                           wfcp, bfc1, Wfc2, bfc2, fbuf);
        k_ec3<<<CB * 48, 256, 0, stream>>>(fbuf, Wec3, bec3, out_c);
    }
}

// Round 10
// 2283.216 us; speedup vs baseline: 2.1241x; 1.1943x over previous
//
#include <hip/hip_runtime.h>
#include <math.h>

// ---------------- constants ----------------
constexpr int ROWS_PER_B = 12 * 1024;    // rows (b,t,n) per batch element

// ---------------- graph workspace (float offsets, < 524288) ----------------
constexpr size_t F_N1 = 0;              // 1024*40
constexpr size_t F_N2 = 40960;
constexpr size_t F_ANVAL = 81920;       // 1024*11
constexpr size_t F_ROWVAL = 93184;      // 1024*10
constexpr size_t F_COLSUM = 103424;     // 1024
constexpr size_t F_INVCS = 104448;      // 1024
constexpr size_t F_ATVAL = 105472;      // 10240
constexpr size_t I_ANIDX = 115712;      // ints stored in float slots
constexpr size_t I_ROWIDX = 126976;
constexpr size_t I_COLCNT = 137216;
constexpr size_t I_COLOFF = 138240;     // 1025
constexpr size_t I_COLFILL = 139265;
constexpr size_t I_ATIDX = 140289;      // ends 150529
constexpr size_t F_W1P = 151552;        // packed bf16 Wtf1: 32768 floats
constexpr size_t F_W2P = 184320;        // packed bf16 Wtf2: ends 217088
constexpr size_t F_WFCP = 217088;       // packed bf16 Wfc1: ends 339968
constexpr size_t F_WEC1P = 339968;      // packed bf16 Wec1
constexpr size_t F_WEC2P = 342016;      // packed bf16 Wec2 -> ends 343040
constexpr size_t GRAPH_FLOATS = 524288;

// per-chunk float-unit counts (per batch element) — bf16 storage
constexpr size_t PB_GATED = (size_t)ROWS_PER_B * 128 / 2;   // 786432
constexpr size_t PB_HD = (size_t)ROWS_PER_B * 64 / 2;       // 393216
constexpr size_t PB_X = (size_t)32 * 1024 * 64 / 2;         // 1048576 (xs,h1,h2,h1b,h2b)
constexpr size_t PB_MIX = (size_t)32 * 1024 * 256 / 2;      // 4194304
constexpr size_t PB_TOTAL = PB_GATED + PB_HD + 5 * PB_X + PB_MIX; // 10616832

typedef __attribute__((ext_vector_type(8))) short bf16x8;
typedef __attribute__((ext_vector_type(4))) float f32x4;

__device__ __forceinline__ unsigned short f2bf(float f) {
    unsigned u = __float_as_uint(f);
    unsigned r = (u + 0x7fffu + ((u >> 16) & 1u)) >> 16;   // RNE
    return (unsigned short)r;
}
__device__ __forceinline__ float bf2f(unsigned short h) {
    return __uint_as_float((unsigned)h << 16);
}
__device__ __forceinline__ void unpack8(uint4 raw, float* f) {
    f[0] = bf2f((unsigned short)(raw.x & 0xffff)); f[1] = bf2f((unsigned short)(raw.x >> 16));
    f[2] = bf2f((unsigned short)(raw.y & 0xffff)); f[3] = bf2f((unsigned short)(raw.y >> 16));
    f[4] = bf2f((unsigned short)(raw.z & 0xffff)); f[5] = bf2f((unsigned short)(raw.z >> 16));
    f[6] = bf2f((unsigned short)(raw.w & 0xffff)); f[7] = bf2f((unsigned short)(raw.w >> 16));
}
__device__ __forceinline__ uint4 pack8(const float* f) {
    uint4 r;
    r.x = f2bf(f[0]) | ((unsigned)f2bf(f[1]) << 16);
    r.y = f2bf(f[2]) | ((unsigned)f2bf(f[3]) << 16);
    r.z = f2bf(f[4]) | ((unsigned)f2bf(f[5]) << 16);
    r.w = f2bf(f[6]) | ((unsigned)f2bf(f[7]) << 16);
    return r;
}

// ---------------- graph kernels ----------------

__global__ void k_init(int* cnt, int* fill, float* csum) {
    int t = blockIdx.x * 256 + threadIdx.x;
    if (t < 1024) { cnt[t] = 0; fill[t] = 0; csum[t] = 0.f; }
}

__global__ void k_embed(const float* e1, const float* e2, const float* w1, const float* b1,
                        const float* w2, const float* b2, float* n1, float* n2) {
    int idx = blockIdx.x * 256 + threadIdx.x;   // < 81920
    if (idx >= 81920) return;
    int m = idx / 40960, rem = idx - m * 40960;
    int i = rem / 40, j = rem - i * 40;
    const float* e = m ? e2 : e1;
    const float* w = m ? w2 : w1;
    const float* bv = m ? b2 : b1;
    float a = bv[j];
    for (int k = 0; k < 40; k++) a += e[i * 40 + k] * w[k * 40 + j];
    (m ? n2 : n1)[i * 40 + j] = tanhf(3.0f * a);
}

__global__ __launch_bounds__(256) void k_adj(const float* n1, const float* n2,
        float* aN_val, int* aN_idx, float* row_val, int* row_idx,
        int* col_cnt, float* col_sum) {
    __shared__ float arow[1024];
    __shared__ float n1v[40], n2v[40];
    __shared__ float rv[256];
    __shared__ int ri[256];
    __shared__ float topv[10];
    __shared__ int topi[10];
    int v = blockIdx.x, t = threadIdx.x;
    if (t < 40) { n1v[t] = n1[v * 40 + t]; n2v[t] = n2[v * 40 + t]; }
    __syncthreads();
    for (int j = t; j < 1024; j += 256) {
        float d1 = 0.f, d2 = 0.f;
        for (int k = 0; k < 40; k++) {
            d1 += n1v[k] * n2[j * 40 + k];
            d2 += n2v[k] * n1[j * 40 + k];
        }
        float a = tanhf(3.0f * (d1 - d2));
        arow[j] = a > 0.f ? a : 0.f;
    }
    __syncthreads();
    for (int r = 0; r < 10; r++) {
        float bv = -1.f; int bi = 1 << 30;
        for (int j = t; j < 1024; j += 256) {
            float x = arow[j];
            if (x > bv || (x == bv && j < bi)) { bv = x; bi = j; }
        }
        rv[t] = bv; ri[t] = bi;
        __syncthreads();
        for (int s = 128; s > 0; s >>= 1) {
            if (t < s) {
                float ov = rv[t + s]; int oi = ri[t + s];
                if (ov > rv[t] || (ov == rv[t] && oi < ri[t])) { rv[t] = ov; ri[t] = oi; }
            }
            __syncthreads();
        }
        if (t == 0) { topv[r] = rv[0]; topi[r] = ri[0]; arow[ri[0]] = -1.f; }
        __syncthreads();
    }
    if (t == 0) {
        float s = 1.f;
        for (int r = 0; r < 10; r++) s += topv[r];
        float inv = 1.f / s;
        for (int r = 0; r < 10; r++) {
            aN_idx[v * 11 + r] = topi[r];
            aN_val[v * 11 + r] = topv[r] * inv;
            row_idx[v * 10 + r] = topi[r];
            row_val[v * 10 + r] = topv[r];
            atomicAdd(&col_cnt[topi[r]], 1);
            atomicAdd(&col_sum[topi[r]], topv[r]);
        }
        aN_idx[v * 11 + 10] = v;
        aN_val[v * 11 + 10] = inv;
    }
}

__global__ __launch_bounds__(1024) void k_scan(const int* cnt, int* off,
                                               const float* csum, float* inv) {
    __shared__ int tmp[1024];
    int t = threadIdx.x;
    tmp[t] = cnt[t];
    __syncthreads();
    for (int s = 1; s < 1024; s <<= 1) {
        int v = 0;
        if (t >= s) v = tmp[t - s];
        __syncthreads();
        tmp[t] += v;
        __syncthreads();
    }
    off[t + 1] = tmp[t];
    if (t == 0) off[0] = 0;
    inv[t] = 1.0f / (csum[t] + 1.0f);
}

__global__ void k_scatter(const int* row_idx, const float* row_val, const int* off,
                          int* fill, int* aT_idx, float* aT_val) {
    int e = blockIdx.x * 256 + threadIdx.x;
    if (e >= 10240) return;
    int v = e / 10;
    int j = row_idx[e];
    int pos = off[j] + atomicAdd(&fill[j], 1);
    aT_idx[pos] = v;
    aT_val[pos] = row_val[e];
}

// pack 256x256 f32 weight into MFMA B-fragment order
__global__ void k_packw(const float* W, unsigned short* out) {
    int id = blockIdx.x * 256 + threadIdx.x;    // 8192 total
    if (id >= 8192) return;
    int lane = id & 63, rest = id >> 6;
    int nb = rest & 15, kb = rest >> 4;
    int krow = kb * 32 + (lane >> 4) * 8;
    int col = nb * 16 + (lane & 15);
    unsigned short v[8];
#pragma unroll
    for (int j = 0; j < 8; j++) v[j] = f2bf(W[(size_t)(krow + j) * 256 + col]);
#pragma unroll
    for (int j = 0; j < 8; j++) out[(size_t)id * 8 + j] = v[j];
}

// pack 472x512 Wfc1 into B-fragment order, K padded to 480
__global__ void k_packfc(const float* W, unsigned short* out) {
    int id = blockIdx.x * 256 + threadIdx.x;    // 30720 total
    if (id >= 30720) return;
    int lane = id & 63, rest = id >> 6;
    int nb = rest & 31, kb = rest >> 5;         // kb < 15
    int k0 = kb * 32 + (lane >> 4) * 8;
    int col = nb * 16 + (lane & 15);
    unsigned short v[8];
#pragma unroll
    for (int j = 0; j < 8; j++) {
        int k = k0 + j;
        v[j] = (k < 472) ? f2bf(W[(size_t)k * 512 + col]) : (unsigned short)0;
    }
#pragma unroll
    for (int j = 0; j < 8; j++) out[(size_t)id * 8 + j] = v[j];
}

// pack Wec1 (128x32) and Wec2 (12x128, pad 16) into A-frag order
__global__ void k_packec(const float* W1, const float* W2,
                         unsigned short* o1, unsigned short* o2) {
    int id = blockIdx.x * 256 + threadIdx.x;    // 768 total
    if (id < 512) {
        int mt = id >> 6, lane = id & 63;
        int o = mt * 16 + (lane & 15);
        int c0 = (lane >> 4) * 8;
#pragma unroll
        for (int j = 0; j < 8; j++)
            o1[(size_t)id * 8 + j] = f2bf(W1[o * 32 + c0 + j]);
    } else if (id < 768) {
        int id2 = id - 512;
        int kb = id2 >> 6, lane = id2 & 63;
        int p = lane & 15;
        int k0 = kb * 32 + (lane >> 4) * 8;
#pragma unroll
        for (int j = 0; j < 8; j++)
            o2[(size_t)id2 * 8 + j] = (p < 12) ? f2bf(W2[p * 128 + k0 + j])
                                               : (unsigned short)0;
    }
}

// ---------------- per-chunk kernels ----------------

// gate MLP + embed; outputs bf16; grid = CB*3072
__global__ __launch_bounds__(256) void k_gate(const float* hist, const float* nodeu,
        const float* tide, const float* diwe,
        const float* Wg1, const float* bg1, const float* Wg2, const float* bg2,
        const float* Wemb, const float* bemb, unsigned short* gated, unsigned short* hd_emb) {
    __shared__ float w1[4096], w2[4096];
    __shared__ float gin[4][64], hid[4][64];
    __shared__ float sb1[64], sb2[64], we[128], be[64];
    int t = threadIdx.x;
    for (int i = t; i < 4096; i += 256) { w1[i] = Wg1[i]; w2[i] = Wg2[i]; }
    if (t < 64) { sb1[t] = bg1[t]; sb2[t] = bg2[t]; be[t] = bemb[t]; }
    if (t < 128) we[t] = Wemb[t];
    int r = t >> 6, lane = t & 63;
    int row = blockIdx.x * 4 + r;
    int n = row & 1023;
    const float* hrow = hist + (size_t)row * 4;
    float f0 = hrow[0], f1 = hrow[1];
    int tid_i = (int)(hrow[2] * 288.0f);
    int diw_i = (int)hrow[3];
    float g;
    if (lane < 40) g = nodeu[n * 40 + lane];
    else if (lane < 52) g = tide[tid_i * 12 + lane - 40];
    else g = diwe[diw_i * 12 + lane - 52];
    gin[r][lane] = g;
    __syncthreads();
    float acc = sb1[lane];
    for (int k = 0; k < 64; k++) acc += gin[r][k] * w1[k * 64 + lane];
    hid[r][lane] = acc > 0.f ? acc : 0.f;
    __syncthreads();
    acc = sb2[lane];
    for (int k = 0; k < 64; k++) acc += hid[r][k] * w2[k * 64 + lane];
    float gate = 1.f / (1.f + expf(-acc));
    float hd = f0 * we[lane] + f1 * we[64 + lane] + be[lane];
    float x1 = gate * hd;
    gated[(size_t)row * 128 + lane] = f2bf(x1);
    gated[(size_t)row * 128 + 64 + lane] = f2bf(hd - x1);
    hd_emb[(size_t)row * 64 + lane] = f2bf(hd);
}

// xs = relu(sum_t gated*Wsc + bsc), bf16 in/out; grid = CB*256
__global__ __launch_bounds__(256) void k_wsc(const unsigned short* gated, const float* Wsc,
                                             const float* bsc, unsigned short* xs, int xoff) {
    __shared__ float w[384];
    __shared__ float sb[32];
    int t = threadIdx.x;
    if (t < 384) w[t] = Wsc[t];
    if (t < 32) sb[t] = bsc[t];
    __syncthreads();
    int idx = blockIdx.x * 256 + t;
    int h = idx & 63, n = (idx >> 6) & 1023, b = idx >> 16;
    float xv[12];
#pragma unroll
    for (int tt = 0; tt < 12; tt++)
        xv[tt] = bf2f(gated[(size_t)((b * 12 + tt) * 1024 + n) * 128 + xoff + h]);
#pragma unroll
    for (int o = 0; o < 32; o++) {
        float a = sb[o];
#pragma unroll
        for (int tt = 0; tt < 12; tt++) a += xv[tt] * w[o * 12 + tt];
        xs[(size_t)((b * 32 + o) * 1024 + n) * 64 + h] = f2bf(a > 0.f ? a : 0.f);
    }
}

// out = 0.05*x + 0.95*(A_norm @ hin), bf16 in/out; grid = CB*1024 (32 rows/block)
__global__ __launch_bounds__(256) void k_spmm(unsigned short* out, const unsigned short* x,
        const unsigned short* hin, const int* aN_idx, const float* aN_val,
        const int* aT_idx, const float* aT_val,
        const int* off, const float* inv_cs, int mode) {
    int t = threadIdx.x;
    int l8 = t & 7, r = t >> 3;             // 32 rows x 8 16B-lanes
    int g = blockIdx.x * 32 + r;
    int v = g & 1023, bc = g >> 10;
    const unsigned short* base = hin + (size_t)bc * 65536;
    float s[8], hv[8];
    if (mode == 0) {
#pragma unroll
        for (int j = 0; j < 8; j++) s[j] = 0.f;
#pragma unroll
        for (int e = 0; e < 11; e++) {
            int w = aN_idx[v * 11 + e];
            float a = aN_val[v * 11 + e];
            uint4 raw = *(const uint4*)(base + (size_t)w * 64 + l8 * 8);
            unpack8(raw, hv);
#pragma unroll
            for (int j = 0; j < 8; j++) s[j] += a * hv[j];
        }
    } else {
        uint4 raw = *(const uint4*)(base + (size_t)v * 64 + l8 * 8);
        unpack8(raw, s);
        int e0 = off[v], e1 = off[v + 1];
        for (int e = e0; e < e1; e++) {
            int w = aT_idx[e];
            float a = aT_val[e];
            uint4 rw = *(const uint4*)(base + (size_t)w * 64 + l8 * 8);
            unpack8(rw, hv);
#pragma unroll
            for (int j = 0; j < 8; j++) s[j] += a * hv[j];
        }
        float ic = inv_cs[v];
#pragma unroll
        for (int j = 0; j < 8; j++) s[j] *= ic;
    }
    uint4 xr = *(const uint4*)(x + (size_t)g * 64 + l8 * 8);
    float xv[8];
    unpack8(xr, xv);
    float o[8];
#pragma unroll
    for (int j = 0; j < 8; j++) o[j] = 0.05f * xv[j] + 0.95f * s[j];
    *(uint4*)(out + (size_t)g * 64 + l8 * 8) = pack8(o);
}

// mix projection, two-phase (mix1@[xs,h1,h2] + mix2@[xs,h1b,h2b]), bf16 mix out once
// grid = CB*1024
__global__ __launch_bounds__(256) void k_proj(const unsigned short* xs,
        const unsigned short* h1, const unsigned short* h2,
        const unsigned short* h1b, const unsigned short* h2b,
        const float* mw1, const float* mw2, const float* m1b, const float* m2b,
        unsigned short* mix, int xp) {
    __shared__ float Wl[96 * 64];
    __shared__ float Bt[96 * 64];
    int t = threadIdx.x;
    int b = blockIdx.x >> 10, n = blockIdx.x & 1023;
    int tx = t & 15, ty = t >> 4;
    int o0 = tx * 4, l0 = ty * 4;
    float acc[4][4];
#pragma unroll
    for (int io = 0; io < 4; io++) {
        int rrow = o0 + io;
        float bias = m1b[rrow] + m2b[rrow];
#pragma unroll
        for (int il = 0; il < 4; il++) acc[io][il] = bias;
    }
    for (int ph = 0; ph < 2; ph++) {
        const float* mw = ph ? mw2 : mw1;
        for (int i = t; i < 6144; i += 256) {
            int k = i >> 6, col = i & 63;
            Wl[i] = mw[col * 96 + k];
        }
        for (int i = t; i < 6144; i += 256) {
            int k = i >> 6, l = i & 63;
            int q = k >> 5, c = k & 31;
            const unsigned short* Hq = (q == 0) ? xs : (q == 1 ? (ph ? h1b : h1)
                                                              : (ph ? h2b : h2));
            Bt[i] = bf2f(Hq[(size_t)((b * 32 + c) * 1024 + n) * 64 + l]);
        }
        __syncthreads();
        for (int k = 0; k < 96; k++) {
            float4 a = *(const float4*)&Wl[k * 64 + o0];
            float4 bb = *(const float4*)&Bt[k * 64 + l0];
            acc[0][0] += a.x * bb.x; acc[0][1] += a.x * bb.y; acc[0][2] += a.x * bb.z; acc[0][3] += a.x * bb.w;
            acc[1][0] += a.y * bb.x; acc[1][1] += a.y * bb.y; acc[1][2] += a.y * bb.z; acc[1][3] += a.y * bb.w;
            acc[2][0] += a.z * bb.x; acc[2][1] += a.z * bb.y; acc[2][2] += a.z * bb.z; acc[2][3] += a.z * bb.w;
            acc[3][0] += a.w * bb.x; acc[3][1] += a.w * bb.y; acc[3][2] += a.w * bb.z; acc[3][3] += a.w * bb.w;
        }
        __syncthreads();
    }
#pragma unroll
    for (int io = 0; io < 4; io++) {
        int rrow = o0 + io;
        int i2 = rrow >> 5, o = rrow & 31;
        unsigned short* gp = &mix[(size_t)((b * 32 + o) * 1024 + n) * 256 + (i2 * 2 + xp) * 64 + l0];
        uint2 pk;
        pk.x = f2bf(acc[io][0]) | ((unsigned)f2bf(acc[io][1]) << 16);
        pk.y = f2bf(acc[io][2]) | ((unsigned)f2bf(acc[io][3]) << 16);
        *(uint2*)gp = pk;
    }
}

// fused Wtf1(relu)Wtf2 via bf16 MFMA, in-place on bf16 mix: 32 rows/block; grid = CB*1024
__global__ __launch_bounds__(256) void k_tf(unsigned short* mix, const unsigned short* W1p,
                                            const float* B1, const unsigned short* W2p,
                                            const float* B2) {
    __shared__ unsigned short Abuf[32 * 256];   // bf16, XOR-swizzled
    __shared__ unsigned short Hbuf[32 * 256];
    int t = threadIdx.x;
    int wave = t >> 6, l = t & 63;
    size_t row0 = (size_t)blockIdx.x * 32;
    const uint4* src = (const uint4*)(mix + row0 * 256);
#pragma unroll
    for (int it = 0; it < 4; it++) {
        int f = t + it * 256;                  // 1024 8-u16 chunks
        uint4 raw = src[f];
        int e = f * 8, row = e >> 8, col = e & 255;
        int byte = (row * 512 + col * 2) ^ ((row & 7) << 4);
        *(uint4*)((char*)Abuf + byte) = raw;
    }
    __syncthreads();
    int colg0 = wave * 64;
    int lr = l & 15, lg = l >> 4;
    f32x4 acc[2][4];
#pragma unroll
    for (int nb = 0; nb < 4; nb++) {
        float bv = B1[colg0 + nb * 16 + lr];
        f32x4 c; c[0] = bv; c[1] = bv; c[2] = bv; c[3] = bv;
        acc[0][nb] = c; acc[1][nb] = c;
    }
#pragma unroll
    for (int kb = 0; kb < 8; kb++) {
        int k2 = (kb * 32 + lg * 8) * 2;
        int by0 = (lr * 512 + k2) ^ ((lr & 7) << 4);
        int by1 = ((16 + lr) * 512 + k2) ^ ((lr & 7) << 4);
        bf16x8 a0 = *(const bf16x8*)((char*)Abuf + by0);
        bf16x8 a1 = *(const bf16x8*)((char*)Abuf + by1);
#pragma unroll
        for (int nb = 0; nb < 4; nb++) {
            int nbg = wave * 4 + nb;
            bf16x8 bw = *(const bf16x8*)(W1p + (size_t)((kb * 16 + nbg) * 64 + l) * 8);
            acc[0][nb] = __builtin_amdgcn_mfma_f32_16x16x32_bf16(a0, bw, acc[0][nb], 0, 0, 0);
            acc[1][nb] = __builtin_amdgcn_mfma_f32_16x16x32_bf16(a1, bw, acc[1][nb], 0, 0, 0);
        }
    }
#pragma unroll
    for (int rb = 0; rb < 2; rb++)
#pragma unroll
        for (int nb = 0; nb < 4; nb++)
#pragma unroll
            for (int r = 0; r < 4; r++) {
                int row = rb * 16 + lg * 4 + r;
                int col = colg0 + nb * 16 + lr;
                unsigned short h = f2bf(fmaxf(acc[rb][nb][r], 0.f));
                int byte = (row * 512 + col * 2) ^ ((row & 7) << 4);
                *(unsigned short*)((char*)Hbuf + byte) = h;
            }
    __syncthreads();
#pragma unroll
    for (int nb = 0; nb < 4; nb++) {
        float bv = B2[colg0 + nb * 16 + lr];
        f32x4 c; c[0] = bv; c[1] = bv; c[2] = bv; c[3] = bv;
        acc[0][nb] = c; acc[1][nb] = c;
    }
#pragma unroll
    for (int kb = 0; kb < 8; kb++) {
        int k2 = (kb * 32 + lg * 8) * 2;
        int by0 = (lr * 512 + k2) ^ ((lr & 7) << 4);
        int by1 = ((16 + lr) * 512 + k2) ^ ((lr & 7) << 4);
        bf16x8 a0 = *(const bf16x8*)((char*)Hbuf + by0);
        bf16x8 a1 = *(const bf16x8*)((char*)Hbuf + by1);
#pragma unroll
        for (int nb = 0; nb < 4; nb++) {
            int nbg = wave * 4 + nb;
            bf16x8 bw = *(const bf16x8*)(W2p + (size_t)((kb * 16 + nbg) * 64 + l) * 8);
            acc[0][nb] = __builtin_amdgcn_mfma_f32_16x16x32_bf16(a0, bw, acc[0][nb], 0, 0, 0);
            acc[1][nb] = __builtin_amdgcn_mfma_f32_16x16x32_bf16(a1, bw, acc[1][nb], 0, 0, 0);
        }
    }
#pragma unroll
    for (int rb = 0; rb < 2; rb++)
#pragma unroll
        for (int nb = 0; nb < 4; nb++)
#pragma unroll
            for (int r = 0; r < 4; r++) {
                int row = rb * 16 + lg * 4 + r;
                int col = colg0 + nb * 16 + lr;
                mix[(row0 + row) * 256 + col] = f2bf(acc[rb][nb][r]);
            }
}

// fused ec1(relu)+ec2 via bf16 MFMA; bf16 mix in, bf16 eco out; grid = CB*1024
__global__ __launch_bounds__(256) void k_ec(const unsigned short* tfo,
        const unsigned short* W1p, const float* B1,
        const unsigned short* W2p, const float* B2, unsigned short* eco) {
    __shared__ unsigned short Hl[4 * 64 * 48];   // per-wave [64 l][48 u16] = 24 KB
    int t = threadIdx.x;
    int wave = t >> 6, l = t & 63;
    int lr = l & 15, lg = l >> 4;
    int b = blockIdx.x >> 10, n = blockIdx.x & 1023;
    int lbase = wave * 64;
    unsigned short* myH = Hl + wave * 3072;
    const unsigned short* xb = tfo + ((size_t)(b * 32) * 1024 + n) * 256;
    bf16x8 xf[4];
#pragma unroll
    for (int nt = 0; nt < 4; nt++) {
        int ll = lbase + nt * 16 + lr;
        bf16x8 v;
#pragma unroll
        for (int j = 0; j < 8; j++)
            v[j] = (short)xb[(size_t)(lg * 8 + j) * 262144 + ll];
        xf[nt] = v;
    }
    f32x4 d2[4];
    {
        f32x4 c;
#pragma unroll
        for (int r = 0; r < 4; r++) {
            int p = lg * 4 + r;
            c[r] = (p < 12) ? B2[p] : 0.f;
        }
#pragma unroll
        for (int nt = 0; nt < 4; nt++) d2[nt] = c;
    }
#pragma unroll
    for (int ch = 0; ch < 4; ch++) {
        f32x4 h[2][4];
#pragma unroll
        for (int mt = 0; mt < 2; mt++) {
            f32x4 c;
#pragma unroll
            for (int r = 0; r < 4; r++) c[r] = B1[ch * 32 + mt * 16 + lg * 4 + r];
#pragma unroll
            for (int nt = 0; nt < 4; nt++) h[mt][nt] = c;
        }
#pragma unroll
        for (int mt = 0; mt < 2; mt++) {
            bf16x8 aw = *(const bf16x8*)(W1p + (size_t)((ch * 2 + mt) * 64 + l) * 8);
#pragma unroll
            for (int nt = 0; nt < 4; nt++)
                h[mt][nt] = __builtin_amdgcn_mfma_f32_16x16x32_bf16(aw, xf[nt], h[mt][nt], 0, 0, 0);
        }
#pragma unroll
        for (int mt = 0; mt < 2; mt++)
#pragma unroll
            for (int nt = 0; nt < 4; nt++) {
                unsigned lo = f2bf(fmaxf(h[mt][nt][0], 0.f)) |
                              ((unsigned)f2bf(fmaxf(h[mt][nt][1], 0.f)) << 16);
                unsigned hi = f2bf(fmaxf(h[mt][nt][2], 0.f)) |
                              ((unsigned)f2bf(fmaxf(h[mt][nt][3], 0.f)) << 16);
                uint2 pk; pk.x = lo; pk.y = hi;
                *(uint2*)(myH + (nt * 16 + lr) * 48 + mt * 16 + lg * 4) = pk;
            }
        bf16x8 aw2 = *(const bf16x8*)(W2p + (size_t)(ch * 64 + l) * 8);
#pragma unroll
        for (int nt = 0; nt < 4; nt++) {
            bf16x8 hf = *(const bf16x8*)(myH + (nt * 16 + lr) * 48 + lg * 8);
            d2[nt] = __builtin_amdgcn_mfma_f32_16x16x32_bf16(aw2, hf, d2[nt], 0, 0, 0);
        }
    }
#pragma unroll
    for (int nt = 0; nt < 4; nt++)
#pragma unroll
        for (int r = 0; r < 4; r++) {
            int p = lg * 4 + r;
            if (p < 12) {
                int ll = lbase + nt * 16 + lr;
                eco[((size_t)(b * 12 + p) * 1024 + n) * 256 + ll] = f2bf(d2[nt][r]);
            }
        }
}

// fused fc1(bf16 MFMA)+relu+fc2: 16 rows/block; bf16 gated/eco/hd inputs; grid = CB*768
__global__ __launch_bounds__(256) void k_fc(const unsigned short* gated, const unsigned short* eco,
        const unsigned short* hd_emb, const float* hist, const float* tide, const float* diwe,
        const unsigned short* W1p, const float* B1, const float* W2, const float* B2,
        float* fbuf) {
    __shared__ unsigned short Abuf[16 * 480];   // 15360 B, XOR-swizzled rows of 960 B
    __shared__ unsigned short Hbuf[16 * 512];   // 16384 B, XOR-swizzled rows of 1024 B
    int t = threadIdx.x;
    int wave = t >> 6, l = t & 63;
    int lr = l & 15, lg = l >> 4;
    int row0 = blockIdx.x * 16;
#pragma unroll
    for (int it = 0; it < 8; it++) {
        int idx = it * 256 + t;                 // 1920 chunks of 4 elements
        if (idx < 1920) {
            int row = idx / 120;
            int col = (idx - row * 120) * 4;
            int grow = row0 + row;
            int n = grow & 1023, bt = grow >> 10;
            int b = bt / 12, tt = bt - b * 12;
            unsigned short w[4];
            if (col < 128) {
                uint2 raw = *(const uint2*)&gated[(size_t)grow * 128 + col];
                w[0] = raw.x & 0xffff; w[1] = raw.x >> 16;
                w[2] = raw.y & 0xffff; w[3] = raw.y >> 16;
            } else if (col < 384) {
                uint2 raw = *(const uint2*)&eco[(size_t)((b * 12 + tt) * 1024 + n) * 256 + (col - 128)];
                w[0] = raw.x & 0xffff; w[1] = raw.x >> 16;
                w[2] = raw.y & 0xffff; w[3] = raw.y >> 16;
            } else if (col < 396) {
                int tid_i = (int)(hist[(size_t)grow * 4 + 2] * 288.0f);
#pragma unroll
                for (int q = 0; q < 4; q++) w[q] = f2bf(fmaxf(tide[tid_i * 12 + col - 384 + q], 0.f));
            } else if (col < 408) {
                int diw_i = (int)hist[(size_t)grow * 4 + 3];
#pragma unroll
                for (int q = 0; q < 4; q++) w[q] = f2bf(fmaxf(diwe[diw_i * 12 + col - 396 + q], 0.f));
            } else if (col < 472) {
                uint2 raw = *(const uint2*)&hd_emb[(size_t)grow * 64 + col - 408];
                w[0] = raw.x & 0xffff; w[1] = raw.x >> 16;
                w[2] = raw.y & 0xffff; w[3] = raw.y >> 16;
            } else {
#pragma unroll
                for (int q = 0; q < 4; q++) w[q] = 0;
            }
#pragma unroll
            for (int q = 0; q < 4; q++) if (w[q] >> 15) w[q] = 0;   // relu on bf16 bits
            uint2 pk;
            pk.x = w[0] | ((unsigned)w[1] << 16);
            pk.y = w[2] | ((unsigned)w[3] << 16);
            int byte = (row * 960 + col * 2) ^ ((row & 7) << 4);
            *(uint2*)((char*)Abuf + byte) = pk;
        }
    }
    __syncthreads();
    int colg0 = wave * 128;
    f32x4 acc[8];
#pragma unroll
    for (int nb = 0; nb < 8; nb++) {
        float bv = B1[colg0 + nb * 16 + lr];
        f32x4 c; c[0] = bv; c[1] = bv; c[2] = bv; c[3] = bv;
        acc[nb] = c;
    }
#pragma unroll
    for (int kb = 0; kb < 15; kb++) {
        int k2 = (kb * 32 + lg * 8) * 2;
        int by0 = (lr * 960 + k2) ^ ((lr & 7) << 4);
        bf16x8 a0 = *(const bf16x8*)((char*)Abuf + by0);
#pragma unroll
        for (int nb = 0; nb < 8; nb++) {
            int nbg = wave * 8 + nb;
            bf16x8 bw = *(const bf16x8*)(W1p + (size_t)((kb * 32 + nbg) * 64 + l) * 8);
            acc[nb] = __builtin_amdgcn_mfma_f32_16x16x32_bf16(a0, bw, acc[nb], 0, 0, 0);
        }
    }
#pragma unroll
    for (int nb = 0; nb < 8; nb++)
#pragma unroll
        for (int r = 0; r < 4; r++) {
            int row = lg * 4 + r;
            int col = colg0 + nb * 16 + lr;
            unsigned short h = f2bf(fmaxf(acc[nb][r], 0.f));
            int byte = (row * 1024 + col * 2) ^ ((row & 7) << 4);
            *(unsigned short*)((char*)Hbuf + byte) = h;
        }
    __syncthreads();
    float* redp = (float*)Abuf;
    {
        int rsub = t >> 5, seg = t & 31;
#pragma unroll
        for (int rg = 0; rg < 2; rg++) {
            int r = rg * 8 + rsub;
            float p0 = 0.f, p1 = 0.f, p2 = 0.f;
#pragma unroll
            for (int j = 0; j < 16; j++) {
                int k = seg + j * 32;
                int byte = (r * 1024 + k * 2) ^ ((r & 7) << 4);
                float h = bf2f(*(const unsigned short*)((char*)Hbuf + byte));
                p0 += h * W2[k * 3];
                p1 += h * W2[k * 3 + 1];
                p2 += h * W2[k * 3 + 2];
            }
            redp[r * 96 + seg] = p0;
            redp[r * 96 + 32 + seg] = p1;
            redp[r * 96 + 64 + seg] = p2;
        }
    }
    __syncthreads();
    if (t < 48) {
        int rr = t / 3, p = t - rr * 3;
        float s = B2[p];
        for (int seg = 0; seg < 32; seg++) s += redp[rr * 96 + p * 32 + seg];
        fbuf[(size_t)(row0 + rr) * 3 + p] = s;
    }
}

// final conv1x1 over time + transpose; grid = CB*48
__global__ void k_ec3(const float* f, const float* W, const float* bv, float* out) {
    int idx = blockIdx.x * 256 + threadIdx.x;
    int l = idx % 3;
    int rest = idx / 3;
    int o = rest & 3;
    int n = (rest >> 2) & 1023;
    int b = rest >> 12;
    float s = bv[o];
#pragma unroll
    for (int c = 0; c < 12; c++)
        s += f[(size_t)((b * 12 + c) * 1024 + n) * 3 + l] * W[o * 12 + c];
    out[idx] = s;
}

// ---------------- launcher ----------------
extern "C" void kernel_launch(void* const* d_in, const int* in_sizes, int n_in,
                              void* d_out, int out_size, void* d_ws, size_t ws_size,
                              hipStream_t stream) {
    const float* hist = (const float*)d_in[0];
    const float* node_emb_u = (const float*)d_in[1];
    const float* T_i_D_emb = (const float*)d_in[2];
    const float* D_i_W_emb = (const float*)d_in[3];
    const float* gc_emb1 = (const float*)d_in[4];
    const float* gc_emb2 = (const float*)d_in[5];
    const float* gc_w1 = (const float*)d_in[6];
    const float* gc_b1 = (const float*)d_in[7];
    const float* gc_w2 = (const float*)d_in[8];
    const float* gc_b2 = (const float*)d_in[9];
    const float* W_emb = (const float*)d_in[10];
    const float* b_emb = (const float*)d_in[11];
    const float* Wg1 = (const float*)d_in[12];
    const float* bg1 = (const float*)d_in[13];
    const float* Wg2 = (const float*)d_in[14];
    const float* bg2 = (const float*)d_in[15];
    const float* Wsc = (const float*)d_in[16];
    const float* bsc = (const float*)d_in[17];
    const float* mix1_w = (const float*)d_in[18];
    const float* mix1_b = (const float*)d_in[19];
    const float* mix2_w = (const float*)d_in[20];
    const float* mix2_b = (const float*)d_in[21];
    const float* Wtf1 = (const float*)d_in[22];
    const float* btf1 = (const float*)d_in[23];
    const float* Wtf2 = (const float*)d_in[24];
    const float* btf2 = (const float*)d_in[25];
    const float* Wec1 = (const float*)d_in[26];
    const float* bec1 = (const float*)d_in[27];
    const float* Wec2 = (const float*)d_in[28];
    const float* bec2 = (const float*)d_in[29];
    const float* Wfc1 = (const float*)d_in[30];
    const float* bfc1 = (const float*)d_in[31];
    const float* Wfc2 = (const float*)d_in[32];
    const float* bfc2 = (const float*)d_in[33];
    const float* Wec3 = (const float*)d_in[34];
    const float* bec3 = (const float*)d_in[35];

    float* ws = (float*)d_ws;
    float* n1 = ws + F_N1;
    float* n2 = ws + F_N2;
    float* aN_val = ws + F_ANVAL;
    float* row_val = ws + F_ROWVAL;
    float* col_sum = ws + F_COLSUM;
    float* inv_cs = ws + F_INVCS;
    float* aT_val = ws + F_ATVAL;
    int* aN_idx = (int*)(ws + I_ANIDX);
    int* row_idx = (int*)(ws + I_ROWIDX);
    int* col_cnt = (int*)(ws + I_COLCNT);
    int* col_off = (int*)(ws + I_COLOFF);
    int* col_fill = (int*)(ws + I_COLFILL);
    int* aT_idx = (int*)(ws + I_ATIDX);
    unsigned short* w1p = (unsigned short*)(ws + F_W1P);
    unsigned short* w2p = (unsigned short*)(ws + F_W2P);
    unsigned short* wfcp = (unsigned short*)(ws + F_WFCP);
    unsigned short* wec1p = (unsigned short*)(ws + F_WEC1P);
    unsigned short* wec2p = (unsigned short*)(ws + F_WEC2P);

    // pick largest batch-chunk CB that fits the workspace
    size_t avail = ws_size / 4;   // floats
    int CB = 8;
    while (CB > 1 && GRAPH_FLOATS + (size_t)CB * PB_TOTAL > avail) CB >>= 1;
    int nchunk = 8 / CB;

    unsigned short* gated = (unsigned short*)(ws + GRAPH_FLOATS);
    unsigned short* hd_emb = (unsigned short*)(ws + GRAPH_FLOATS + (size_t)CB * PB_GATED);
    unsigned short* xs = (unsigned short*)(ws + GRAPH_FLOATS + (size_t)CB * (PB_GATED + PB_HD));
    unsigned short* h1 = xs + (size_t)CB * PB_X * 2;
    unsigned short* h2 = h1 + (size_t)CB * PB_X * 2;
    unsigned short* h1b = h2 + (size_t)CB * PB_X * 2;
    unsigned short* h2b = h1b + (size_t)CB * PB_X * 2;
    unsigned short* mix = h2b + (size_t)CB * PB_X * 2;
    unsigned short* eco = xs;        // alias: xs+h1 region (CB*4M u16) >= eco (CB*3M u16)
    float* fbuf = (float*)h2b;       // alias: h2b dead by k_fc

    // ---- graph construction + weight packing (once) ----
    k_init<<<4, 256, 0, stream>>>(col_cnt, col_fill, col_sum);
    k_embed<<<320, 256, 0, stream>>>(gc_emb1, gc_emb2, gc_w1, gc_b1, gc_w2, gc_b2, n1, n2);
    k_adj<<<1024, 256, 0, stream>>>(n1, n2, aN_val, aN_idx, row_val, row_idx, col_cnt, col_sum);
    k_scan<<<1, 1024, 0, stream>>>(col_cnt, col_off, col_sum, inv_cs);
    k_scatter<<<40, 256, 0, stream>>>(row_idx, row_val, col_off, col_fill, aT_idx, aT_val);
    k_packw<<<32, 256, 0, stream>>>(Wtf1, w1p);
    k_packw<<<32, 256, 0, stream>>>(Wtf2, w2p);
    k_packfc<<<120, 256, 0, stream>>>(Wfc1, wfcp);
    k_packec<<<3, 256, 0, stream>>>(Wec1, Wec2, wec1p, wec2p);

    // ---- per-chunk pipeline ----
    for (int ch = 0; ch < nchunk; ch++) {
        const float* hist_c = hist + (size_t)ch * CB * ROWS_PER_B * 4;
        float* out_c = (float*)d_out + (size_t)ch * CB * ROWS_PER_B;

        k_gate<<<CB * 3072, 256, 0, stream>>>(hist_c, node_emb_u, T_i_D_emb, D_i_W_emb,
                                              Wg1, bg1, Wg2, bg2, W_emb, b_emb, gated, hd_emb);
        for (int xp = 0; xp < 2; xp++) {
            k_wsc<<<CB * 256, 256, 0, stream>>>(gated, Wsc, bsc, xs, xp * 64);
            k_spmm<<<CB * 1024, 256, 0, stream>>>(h1, xs, xs, aN_idx, aN_val, aT_idx, aT_val,
                                                  col_off, inv_cs, 0);
            k_spmm<<<CB * 1024, 256, 0, stream>>>(h2, xs, h1, aN_idx, aN_val, aT_idx, aT_val,
                                                  col_off, inv_cs, 0);
            k_spmm<<<CB * 1024, 256, 0, stream>>>(h1b, xs, xs, aN_idx, aN_val, aT_idx, aT_val,
                                                  col_off, inv_cs, 1);
            k_spmm<<<CB * 1024, 256, 0, stream>>>(h2b, xs, h1b, aN_idx, aN_val, aT_idx, aT_val,
                                                  col_off, inv_cs, 1);
            k_proj<<<CB * 1024, 256, 0, stream>>>(xs, h1, h2, h1b, h2b,
                                                  mix1_w, mix2_w, mix1_b, mix2_b, mix, xp);
        }
        k_tf<<<CB * 1024, 256, 0, stream>>>(mix, w1p, btf1, w2p, btf2);
        k_ec<<<CB * 1024, 256, 0, stream>>>(mix, wec1p, bec1, wec2p, bec2, eco);
        k_fc<<<CB * 768, 256, 0, stream>>>(gated, eco, hd_emb, hist_c, T_i_D_emb, D_i_W_emb,
                                           wfcp, bfc1, Wfc2, bfc2, fbuf);
        k_ec3<<<CB * 48, 256, 0, stream>>>(fbuf, Wec3, bec3, out_c);
    }
}

// Round 11
// 1778.275 us; speedup vs baseline: 2.7273x; 1.2840x over previous
//
#include <hip/hip_runtime.h>
#include <math.h>

// ---------------- constants ----------------
constexpr int ROWS_PER_B = 12 * 1024;    // rows (b,t,n) per batch element

// ---------------- graph workspace (float offsets, < 524288) ----------------
constexpr size_t F_N1 = 0;              // 1024*40
constexpr size_t F_N2 = 40960;
constexpr size_t F_ANVAL = 81920;       // 1024*11
constexpr size_t F_ROWVAL = 93184;      // 1024*10
constexpr size_t F_COLSUM = 103424;     // 1024
constexpr size_t F_INVCS = 104448;      // 1024
constexpr size_t F_ATVAL = 105472;      // 10240
constexpr size_t I_ANIDX = 115712;      // ints stored in float slots
constexpr size_t I_ROWIDX = 126976;
constexpr size_t I_COLCNT = 137216;
constexpr size_t I_COLOFF = 138240;     // 1025
constexpr size_t I_COLFILL = 139265;
constexpr size_t I_ATIDX = 140289;      // ends 150529
constexpr size_t F_W1P = 151552;        // packed bf16 Wtf1: 32768 floats
constexpr size_t F_W2P = 184320;        // packed bf16 Wtf2: ends 217088
constexpr size_t F_WFCP = 217088;       // packed bf16 Wfc1: ends 339968
constexpr size_t F_WEC1P = 339968;      // packed bf16 Wec1
constexpr size_t F_WEC2P = 342016;      // packed bf16 Wec2 -> ends 343040
constexpr size_t F_WMWP = 343040;       // packed bf16 mix weights: 12288 u16 -> ends 349184
constexpr size_t GRAPH_FLOATS = 524288;

// per-chunk float-unit counts (per batch element) — bf16 storage
constexpr size_t PB_GATED = (size_t)ROWS_PER_B * 128 / 2;   // 786432
constexpr size_t PB_HD = (size_t)ROWS_PER_B * 64 / 2;       // 393216
constexpr size_t PB_X = (size_t)32 * 1024 * 64 / 2;         // 1048576 (xs,h1,h2,h1b,h2b)
constexpr size_t PB_MIX = (size_t)32 * 1024 * 256 / 2;      // 4194304
constexpr size_t PB_TOTAL = PB_GATED + PB_HD + 5 * PB_X + PB_MIX; // 10616832

typedef __attribute__((ext_vector_type(8))) short bf16x8;
typedef __attribute__((ext_vector_type(4))) float f32x4;

__device__ __forceinline__ unsigned short f2bf(float f) {
    unsigned u = __float_as_uint(f);
    unsigned r = (u + 0x7fffu + ((u >> 16) & 1u)) >> 16;   // RNE
    return (unsigned short)r;
}
__device__ __forceinline__ float bf2f(unsigned short h) {
    return __uint_as_float((unsigned)h << 16);
}
__device__ __forceinline__ void unpack8(uint4 raw, float* f) {
    f[0] = bf2f((unsigned short)(raw.x & 0xffff)); f[1] = bf2f((unsigned short)(raw.x >> 16));
    f[2] = bf2f((unsigned short)(raw.y & 0xffff)); f[3] = bf2f((unsigned short)(raw.y >> 16));
    f[4] = bf2f((unsigned short)(raw.z & 0xffff)); f[5] = bf2f((unsigned short)(raw.z >> 16));
    f[6] = bf2f((unsigned short)(raw.w & 0xffff)); f[7] = bf2f((unsigned short)(raw.w >> 16));
}
__device__ __forceinline__ uint4 pack8(const float* f) {
    uint4 r;
    r.x = f2bf(f[0]) | ((unsigned)f2bf(f[1]) << 16);
    r.y = f2bf(f[2]) | ((unsigned)f2bf(f[3]) << 16);
    r.z = f2bf(f[4]) | ((unsigned)f2bf(f[5]) << 16);
    r.w = f2bf(f[6]) | ((unsigned)f2bf(f[7]) << 16);
    return r;
}

// ---------------- graph kernels ----------------

__global__ void k_init(int* cnt, int* fill, float* csum) {
    int t = blockIdx.x * 256 + threadIdx.x;
    if (t < 1024) { cnt[t] = 0; fill[t] = 0; csum[t] = 0.f; }
}

__global__ void k_embed(const float* e1, const float* e2, const float* w1, const float* b1,
                        const float* w2, const float* b2, float* n1, float* n2) {
    int idx = blockIdx.x * 256 + threadIdx.x;   // < 81920
    if (idx >= 81920) return;
    int m = idx / 40960, rem = idx - m * 40960;
    int i = rem / 40, j = rem - i * 40;
    const float* e = m ? e2 : e1;
    const float* w = m ? w2 : w1;
    const float* bv = m ? b2 : b1;
    float a = bv[j];
    for (int k = 0; k < 40; k++) a += e[i * 40 + k] * w[k * 40 + j];
    (m ? n2 : n1)[i * 40 + j] = tanhf(3.0f * a);
}

__global__ __launch_bounds__(256) void k_adj(const float* n1, const float* n2,
        float* aN_val, int* aN_idx, float* row_val, int* row_idx,
        int* col_cnt, float* col_sum) {
    __shared__ float arow[1024];
    __shared__ float n1v[40], n2v[40];
    __shared__ float rv[256];
    __shared__ int ri[256];
    __shared__ float topv[10];
    __shared__ int topi[10];
    int v = blockIdx.x, t = threadIdx.x;
    if (t < 40) { n1v[t] = n1[v * 40 + t]; n2v[t] = n2[v * 40 + t]; }
    __syncthreads();
    for (int j = t; j < 1024; j += 256) {
        float d1 = 0.f, d2 = 0.f;
        for (int k = 0; k < 40; k++) {
            d1 += n1v[k] * n2[j * 40 + k];
            d2 += n2v[k] * n1[j * 40 + k];
        }
        float a = tanhf(3.0f * (d1 - d2));
        arow[j] = a > 0.f ? a : 0.f;
    }
    __syncthreads();
    for (int r = 0; r < 10; r++) {
        float bv = -1.f; int bi = 1 << 30;
        for (int j = t; j < 1024; j += 256) {
            float x = arow[j];
            if (x > bv || (x == bv && j < bi)) { bv = x; bi = j; }
        }
        rv[t] = bv; ri[t] = bi;
        __syncthreads();
        for (int s = 128; s > 0; s >>= 1) {
            if (t < s) {
                float ov = rv[t + s]; int oi = ri[t + s];
                if (ov > rv[t] || (ov == rv[t] && oi < ri[t])) { rv[t] = ov; ri[t] = oi; }
            }
            __syncthreads();
        }
        if (t == 0) { topv[r] = rv[0]; topi[r] = ri[0]; arow[ri[0]] = -1.f; }
        __syncthreads();
    }
    if (t == 0) {
        float s = 1.f;
        for (int r = 0; r < 10; r++) s += topv[r];
        float inv = 1.f / s;
        for (int r = 0; r < 10; r++) {
            aN_idx[v * 11 + r] = topi[r];
            aN_val[v * 11 + r] = topv[r] * inv;
            row_idx[v * 10 + r] = topi[r];
            row_val[v * 10 + r] = topv[r];
            atomicAdd(&col_cnt[topi[r]], 1);
            atomicAdd(&col_sum[topi[r]], topv[r]);
        }
        aN_idx[v * 11 + 10] = v;
        aN_val[v * 11 + 10] = inv;
    }
}

__global__ __launch_bounds__(1024) void k_scan(const int* cnt, int* off,
                                               const float* csum, float* inv) {
    __shared__ int tmp[1024];
    int t = threadIdx.x;
    tmp[t] = cnt[t];
    __syncthreads();
    for (int s = 1; s < 1024; s <<= 1) {
        int v = 0;
        if (t >= s) v = tmp[t - s];
        __syncthreads();
        tmp[t] += v;
        __syncthreads();
    }
    off[t + 1] = tmp[t];
    if (t == 0) off[0] = 0;
    inv[t] = 1.0f / (csum[t] + 1.0f);
}

__global__ void k_scatter(const int* row_idx, const float* row_val, const int* off,
                          int* fill, int* aT_idx, float* aT_val) {
    int e = blockIdx.x * 256 + threadIdx.x;
    if (e >= 10240) return;
    int v = e / 10;
    int j = row_idx[e];
    int pos = off[j] + atomicAdd(&fill[j], 1);
    aT_idx[pos] = v;
    aT_val[pos] = row_val[e];
}

// pack 256x256 f32 weight into MFMA B-fragment order
__global__ void k_packw(const float* W, unsigned short* out) {
    int id = blockIdx.x * 256 + threadIdx.x;    // 8192 total
    if (id >= 8192) return;
    int lane = id & 63, rest = id >> 6;
    int nb = rest & 15, kb = rest >> 4;
    int krow = kb * 32 + (lane >> 4) * 8;
    int col = nb * 16 + (lane & 15);
    unsigned short v[8];
#pragma unroll
    for (int j = 0; j < 8; j++) v[j] = f2bf(W[(size_t)(krow + j) * 256 + col]);
#pragma unroll
    for (int j = 0; j < 8; j++) out[(size_t)id * 8 + j] = v[j];
}

// pack 472x512 Wfc1 into B-fragment order, K padded to 480
__global__ void k_packfc(const float* W, unsigned short* out) {
    int id = blockIdx.x * 256 + threadIdx.x;    // 30720 total
    if (id >= 30720) return;
    int lane = id & 63, rest = id >> 6;
    int nb = rest & 31, kb = rest >> 5;         // kb < 15
    int k0 = kb * 32 + (lane >> 4) * 8;
    int col = nb * 16 + (lane & 15);
    unsigned short v[8];
#pragma unroll
    for (int j = 0; j < 8; j++) {
        int k = k0 + j;
        v[j] = (k < 472) ? f2bf(W[(size_t)k * 512 + col]) : (unsigned short)0;
    }
#pragma unroll
    for (int j = 0; j < 8; j++) out[(size_t)id * 8 + j] = v[j];
}

// pack Wec1 (128x32) and Wec2 (12x128, pad 16) into A-frag order
__global__ void k_packec(const float* W1, const float* W2,
                         unsigned short* o1, unsigned short* o2) {
    int id = blockIdx.x * 256 + threadIdx.x;    // 768 total
    if (id < 512) {
        int mt = id >> 6, lane = id & 63;
        int o = mt * 16 + (lane & 15);
        int c0 = (lane >> 4) * 8;
#pragma unroll
        for (int j = 0; j < 8; j++)
            o1[(size_t)id * 8 + j] = f2bf(W1[o * 32 + c0 + j]);
    } else if (id < 768) {
        int id2 = id - 512;
        int kb = id2 >> 6, lane = id2 & 63;
        int p = lane & 15;
        int k0 = kb * 32 + (lane >> 4) * 8;
#pragma unroll
        for (int j = 0; j < 8; j++)
            o2[(size_t)id2 * 8 + j] = (p < 12) ? f2bf(W2[p * 128 + k0 + j])
                                               : (unsigned short)0;
    }
}

// pack mix weights [64 rows][192 K] (K: ph*96+q*32+c; ph0=mix1_w, ph1=mix2_w)
// into A-frag order: frag f = kb*4+rt, 24 frags
__global__ void k_packmw(const float* mw1, const float* mw2, unsigned short* out) {
    int id = blockIdx.x * 256 + threadIdx.x;    // 1536 total
    if (id >= 1536) return;
    int f = id >> 6, lane = id & 63;
    int kb = f >> 2, rt = f & 3;
    int row = rt * 16 + (lane & 15);
    int ph = (kb >= 3) ? 1 : 0;
    int kloc = (kb - ph * 3) * 32 + (lane >> 4) * 8;
    const float* mw = ph ? mw2 : mw1;
#pragma unroll
    for (int j = 0; j < 8; j++)
        out[(size_t)id * 8 + j] = f2bf(mw[row * 96 + kloc + j]);
}

// ---------------- per-chunk kernels ----------------

// gate MLP + embed; outputs bf16; grid = CB*3072
__global__ __launch_bounds__(256) void k_gate(const float* hist, const float* nodeu,
        const float* tide, const float* diwe,
        const float* Wg1, const float* bg1, const float* Wg2, const float* bg2,
        const float* Wemb, const float* bemb, unsigned short* gated, unsigned short* hd_emb) {
    __shared__ float w1[4096], w2[4096];
    __shared__ float gin[4][64], hid[4][64];
    __shared__ float sb1[64], sb2[64], we[128], be[64];
    int t = threadIdx.x;
    for (int i = t; i < 4096; i += 256) { w1[i] = Wg1[i]; w2[i] = Wg2[i]; }
    if (t < 64) { sb1[t] = bg1[t]; sb2[t] = bg2[t]; be[t] = bemb[t]; }
    if (t < 128) we[t] = Wemb[t];
    int r = t >> 6, lane = t & 63;
    int row = blockIdx.x * 4 + r;
    int n = row & 1023;
    const float* hrow = hist + (size_t)row * 4;
    float f0 = hrow[0], f1 = hrow[1];
    int tid_i = (int)(hrow[2] * 288.0f);
    int diw_i = (int)hrow[3];
    float g;
    if (lane < 40) g = nodeu[n * 40 + lane];
    else if (lane < 52) g = tide[tid_i * 12 + lane - 40];
    else g = diwe[diw_i * 12 + lane - 52];
    gin[r][lane] = g;
    __syncthreads();
    float acc = sb1[lane];
    for (int k = 0; k < 64; k++) acc += gin[r][k] * w1[k * 64 + lane];
    hid[r][lane] = acc > 0.f ? acc : 0.f;
    __syncthreads();
    acc = sb2[lane];
    for (int k = 0; k < 64; k++) acc += hid[r][k] * w2[k * 64 + lane];
    float gate = 1.f / (1.f + expf(-acc));
    float hd = f0 * we[lane] + f1 * we[64 + lane] + be[lane];
    float x1 = gate * hd;
    gated[(size_t)row * 128 + lane] = f2bf(x1);
    gated[(size_t)row * 128 + 64 + lane] = f2bf(hd - x1);
    hd_emb[(size_t)row * 64 + lane] = f2bf(hd);
}

// xs = relu(sum_t gated*Wsc + bsc), bf16 in/out; grid = CB*256
__global__ __launch_bounds__(256) void k_wsc(const unsigned short* gated, const float* Wsc,
                                             const float* bsc, unsigned short* xs, int xoff) {
    __shared__ float w[384];
    __shared__ float sb[32];
    int t = threadIdx.x;
    if (t < 384) w[t] = Wsc[t];
    if (t < 32) sb[t] = bsc[t];
    __syncthreads();
    int idx = blockIdx.x * 256 + t;
    int h = idx & 63, n = (idx >> 6) & 1023, b = idx >> 16;
    float xv[12];
#pragma unroll
    for (int tt = 0; tt < 12; tt++)
        xv[tt] = bf2f(gated[(size_t)((b * 12 + tt) * 1024 + n) * 128 + xoff + h]);
#pragma unroll
    for (int o = 0; o < 32; o++) {
        float a = sb[o];
#pragma unroll
        for (int tt = 0; tt < 12; tt++) a += xv[tt] * w[o * 12 + tt];
        xs[(size_t)((b * 32 + o) * 1024 + n) * 64 + h] = f2bf(a > 0.f ? a : 0.f);
    }
}

// out = 0.05*x + 0.95*(A_norm @ hin), bf16 in/out; grid = CB*1024 (32 rows/block)
__global__ __launch_bounds__(256) void k_spmm(unsigned short* out, const unsigned short* x,
        const unsigned short* hin, const int* aN_idx, const float* aN_val,
        const int* aT_idx, const float* aT_val,
        const int* off, const float* inv_cs, int mode) {
    int t = threadIdx.x;
    int l8 = t & 7, r = t >> 3;             // 32 rows x 8 16B-lanes
    int g = blockIdx.x * 32 + r;
    int v = g & 1023, bc = g >> 10;
    const unsigned short* base = hin + (size_t)bc * 65536;
    float s[8], hv[8];
    if (mode == 0) {
#pragma unroll
        for (int j = 0; j < 8; j++) s[j] = 0.f;
#pragma unroll
        for (int e = 0; e < 11; e++) {
            int w = aN_idx[v * 11 + e];
            float a = aN_val[v * 11 + e];
            uint4 raw = *(const uint4*)(base + (size_t)w * 64 + l8 * 8);
            unpack8(raw, hv);
#pragma unroll
            for (int j = 0; j < 8; j++) s[j] += a * hv[j];
        }
    } else {
        uint4 raw = *(const uint4*)(base + (size_t)v * 64 + l8 * 8);
        unpack8(raw, s);
        int e0 = off[v], e1 = off[v + 1];
        for (int e = e0; e < e1; e++) {
            int w = aT_idx[e];
            float a = aT_val[e];
            uint4 rw = *(const uint4*)(base + (size_t)w * 64 + l8 * 8);
            unpack8(rw, hv);
#pragma unroll
            for (int j = 0; j < 8; j++) s[j] += a * hv[j];
        }
        float ic = inv_cs[v];
#pragma unroll
        for (int j = 0; j < 8; j++) s[j] *= ic;
    }
    uint4 xr = *(const uint4*)(x + (size_t)g * 64 + l8 * 8);
    float xv[8];
    unpack8(xr, xv);
    float o[8];
#pragma unroll
    for (int j = 0; j < 8; j++) o[j] = 0.05f * xv[j] + 0.95f * s[j];
    *(uint4*)(out + (size_t)g * 64 + l8 * 8) = pack8(o);
}

// mix projection via bf16 MFMA: block = (b,n), 4 waves; grid = CB*1024
__global__ __launch_bounds__(256) void k_proj(const unsigned short* xs,
        const unsigned short* h1, const unsigned short* h2,
        const unsigned short* h1b, const unsigned short* h2b,
        const unsigned short* mwp, const float* m1b, const float* m2b,
        unsigned short* mix, int xp) {
    __shared__ unsigned short Bf[24 * 64 * 8];   // 24 shared B-frags, frag layout, 24 KB
    int t = threadIdx.x;
    int wave = t >> 6, l = t & 63;
    int lr = l & 15, lg = l >> 4;
    int b = blockIdx.x >> 10, n = blockIdx.x & 1023;
    // ---- cooperative B-frag gather: 6 frags per wave ----
#pragma unroll
    for (int i = 0; i < 6; i++) {
        int f = wave * 6 + i;
        int kb = f >> 2, nt = f & 3;
        int ph = (kb >= 3) ? 1 : 0;
        int q = kb - ph * 3;
        const unsigned short* Hq = (q == 0) ? xs : (q == 1 ? (ph ? h1b : h1)
                                                           : (ph ? h2b : h2));
        const unsigned short* src = Hq + ((size_t)(b * 32 + lg * 8) * 1024 + n) * 64
                                       + nt * 16 + lr;
        bf16x8 v;
#pragma unroll
        for (int j = 0; j < 8; j++)
            v[j] = (short)src[(size_t)j * 65536];
        *(bf16x8*)(Bf + ((size_t)f * 64 + l) * 8) = v;
    }
    __syncthreads();
    // ---- wave = row-tile; 4 col-tiles; K = 6 blocks of 32 ----
    f32x4 acc[4];
#pragma unroll
    for (int nt = 0; nt < 4; nt++) {
        f32x4 c;
#pragma unroll
        for (int r = 0; r < 4; r++) {
            int row = wave * 16 + lg * 4 + r;
            c[r] = m1b[row] + m2b[row];
        }
        acc[nt] = c;
    }
#pragma unroll
    for (int kb = 0; kb < 6; kb++) {
        bf16x8 af = *(const bf16x8*)(mwp + (size_t)((kb * 4 + wave) * 64 + l) * 8);
#pragma unroll
        for (int nt = 0; nt < 4; nt++) {
            bf16x8 bfv = *(const bf16x8*)(Bf + ((size_t)(kb * 4 + nt) * 64 + l) * 8);
            acc[nt] = __builtin_amdgcn_mfma_f32_16x16x32_bf16(af, bfv, acc[nt], 0, 0, 0);
        }
    }
#pragma unroll
    for (int nt = 0; nt < 4; nt++)
#pragma unroll
        for (int r = 0; r < 4; r++) {
            int row = wave * 16 + lg * 4 + r;
            int i2 = row >> 5, o = row & 31;
            mix[(size_t)((b * 32 + o) * 1024 + n) * 256 + (i2 * 2 + xp) * 64 + nt * 16 + lr]
                = f2bf(acc[nt][r]);
        }
}

// fused Wtf1(relu)Wtf2 via bf16 MFMA, in-place on bf16 mix: 32 rows/block; grid = CB*1024
__global__ __launch_bounds__(256) void k_tf(unsigned short* mix, const unsigned short* W1p,
                                            const float* B1, const unsigned short* W2p,
                                            const float* B2) {
    __shared__ unsigned short Abuf[32 * 256];   // bf16, XOR-swizzled
    __shared__ unsigned short Hbuf[32 * 256];
    int t = threadIdx.x;
    int wave = t >> 6, l = t & 63;
    size_t row0 = (size_t)blockIdx.x * 32;
    const uint4* src = (const uint4*)(mix + row0 * 256);
#pragma unroll
    for (int it = 0; it < 4; it++) {
        int f = t + it * 256;                  // 1024 8-u16 chunks
        uint4 raw = src[f];
        int e = f * 8, row = e >> 8, col = e & 255;
        int byte = (row * 512 + col * 2) ^ ((row & 7) << 4);
        *(uint4*)((char*)Abuf + byte) = raw;
    }
    __syncthreads();
    int colg0 = wave * 64;
    int lr = l & 15, lg = l >> 4;
    f32x4 acc[2][4];
#pragma unroll
    for (int nb = 0; nb < 4; nb++) {
        float bv = B1[colg0 + nb * 16 + lr];
        f32x4 c; c[0] = bv; c[1] = bv; c[2] = bv; c[3] = bv;
        acc[0][nb] = c; acc[1][nb] = c;
    }
#pragma unroll
    for (int kb = 0; kb < 8; kb++) {
        int k2 = (kb * 32 + lg * 8) * 2;
        int by0 = (lr * 512 + k2) ^ ((lr & 7) << 4);
        int by1 = ((16 + lr) * 512 + k2) ^ ((lr & 7) << 4);
        bf16x8 a0 = *(const bf16x8*)((char*)Abuf + by0);
        bf16x8 a1 = *(const bf16x8*)((char*)Abuf + by1);
#pragma unroll
        for (int nb = 0; nb < 4; nb++) {
            int nbg = wave * 4 + nb;
            bf16x8 bw = *(const bf16x8*)(W1p + (size_t)((kb * 16 + nbg) * 64 + l) * 8);
            acc[0][nb] = __builtin_amdgcn_mfma_f32_16x16x32_bf16(a0, bw, acc[0][nb], 0, 0, 0);
            acc[1][nb] = __builtin_amdgcn_mfma_f32_16x16x32_bf16(a1, bw, acc[1][nb], 0, 0, 0);
        }
    }
#pragma unroll
    for (int rb = 0; rb < 2; rb++)
#pragma unroll
        for (int nb = 0; nb < 4; nb++)
#pragma unroll
            for (int r = 0; r < 4; r++) {
                int row = rb * 16 + lg * 4 + r;
                int col = colg0 + nb * 16 + lr;
                unsigned short h = f2bf(fmaxf(acc[rb][nb][r], 0.f));
                int byte = (row * 512 + col * 2) ^ ((row & 7) << 4);
                *(unsigned short*)((char*)Hbuf + byte) = h;
            }
    __syncthreads();
#pragma unroll
    for (int nb = 0; nb < 4; nb++) {
        float bv = B2[colg0 + nb * 16 + lr];
        f32x4 c; c[0] = bv; c[1] = bv; c[2] = bv; c[3] = bv;
        acc[0][nb] = c; acc[1][nb] = c;
    }
#pragma unroll
    for (int kb = 0; kb < 8; kb++) {
        int k2 = (kb * 32 + lg * 8) * 2;
        int by0 = (lr * 512 + k2) ^ ((lr & 7) << 4);
        int by1 = ((16 + lr) * 512 + k2) ^ ((lr & 7) << 4);
        bf16x8 a0 = *(const bf16x8*)((char*)Hbuf + by0);
        bf16x8 a1 = *(const bf16x8*)((char*)Hbuf + by1);
#pragma unroll
        for (int nb = 0; nb < 4; nb++) {
            int nbg = wave * 4 + nb;
            bf16x8 bw = *(const bf16x8*)(W2p + (size_t)((kb * 16 + nbg) * 64 + l) * 8);
            acc[0][nb] = __builtin_amdgcn_mfma_f32_16x16x32_bf16(a0, bw, acc[0][nb], 0, 0, 0);
            acc[1][nb] = __builtin_amdgcn_mfma_f32_16x16x32_bf16(a1, bw, acc[1][nb], 0, 0, 0);
        }
    }
#pragma unroll
    for (int rb = 0; rb < 2; rb++)
#pragma unroll
        for (int nb = 0; nb < 4; nb++)
#pragma unroll
            for (int r = 0; r < 4; r++) {
                int row = rb * 16 + lg * 4 + r;
                int col = colg0 + nb * 16 + lr;
                mix[(row0 + row) * 256 + col] = f2bf(acc[rb][nb][r]);
            }
}

// fused ec1(relu)+ec2 via bf16 MFMA; bf16 mix in, bf16 eco out; grid = CB*1024
__global__ __launch_bounds__(256) void k_ec(const unsigned short* tfo,
        const unsigned short* W1p, const float* B1,
        const unsigned short* W2p, const float* B2, unsigned short* eco) {
    __shared__ unsigned short Hl[4 * 64 * 48];   // per-wave [64 l][48 u16] = 24 KB
    int t = threadIdx.x;
    int wave = t >> 6, l = t & 63;
    int lr = l & 15, lg = l >> 4;
    int b = blockIdx.x >> 10, n = blockIdx.x & 1023;
    int lbase = wave * 64;
    unsigned short* myH = Hl + wave * 3072;
    const unsigned short* xb = tfo + ((size_t)(b * 32) * 1024 + n) * 256;
    bf16x8 xf[4];
#pragma unroll
    for (int nt = 0; nt < 4; nt++) {
        int ll = lbase + nt * 16 + lr;
        bf16x8 v;
#pragma unroll
        for (int j = 0; j < 8; j++)
            v[j] = (short)xb[(size_t)(lg * 8 + j) * 262144 + ll];
        xf[nt] = v;
    }
    f32x4 d2[4];
    {
        f32x4 c;
#pragma unroll
        for (int r = 0; r < 4; r++) {
            int p = lg * 4 + r;
            c[r] = (p < 12) ? B2[p] : 0.f;
        }
#pragma unroll
        for (int nt = 0; nt < 4; nt++) d2[nt] = c;
    }
#pragma unroll
    for (int ch = 0; ch < 4; ch++) {
        f32x4 h[2][4];
#pragma unroll
        for (int mt = 0; mt < 2; mt++) {
            f32x4 c;
#pragma unroll
            for (int r = 0; r < 4; r++) c[r] = B1[ch * 32 + mt * 16 + lg * 4 + r];
#pragma unroll
            for (int nt = 0; nt < 4; nt++) h[mt][nt] = c;
        }
#pragma unroll
        for (int mt = 0; mt < 2; mt++) {
            bf16x8 aw = *(const bf16x8*)(W1p + (size_t)((ch * 2 + mt) * 64 + l) * 8);
#pragma unroll
            for (int nt = 0; nt < 4; nt++)
                h[mt][nt] = __builtin_amdgcn_mfma_f32_16x16x32_bf16(aw, xf[nt], h[mt][nt], 0, 0, 0);
        }
#pragma unroll
        for (int mt = 0; mt < 2; mt++)
#pragma unroll
            for (int nt = 0; nt < 4; nt++) {
                unsigned lo = f2bf(fmaxf(h[mt][nt][0], 0.f)) |
                              ((unsigned)f2bf(fmaxf(h[mt][nt][1], 0.f)) << 16);
                unsigned hi = f2bf(fmaxf(h[mt][nt][2], 0.f)) |
                              ((unsigned)f2bf(fmaxf(h[mt][nt][3], 0.f)) << 16);
                uint2 pk; pk.x = lo; pk.y = hi;
                *(uint2*)(myH + (nt * 16 + lr) * 48 + mt * 16 + lg * 4) = pk;
            }
        bf16x8 aw2 = *(const bf16x8*)(W2p + (size_t)(ch * 64 + l) * 8);
#pragma unroll
        for (int nt = 0; nt < 4; nt++) {
            bf16x8 hf = *(const bf16x8*)(myH + (nt * 16 + lr) * 48 + lg * 8);
            d2[nt] = __builtin_amdgcn_mfma_f32_16x16x32_bf16(aw2, hf, d2[nt], 0, 0, 0);
        }
    }
#pragma unroll
    for (int nt = 0; nt < 4; nt++)
#pragma unroll
        for (int r = 0; r < 4; r++) {
            int p = lg * 4 + r;
            if (p < 12) {
                int ll = lbase + nt * 16 + lr;
                eco[((size_t)(b * 12 + p) * 1024 + n) * 256 + ll] = f2bf(d2[nt][r]);
            }
        }
}

// fused fc1(bf16 MFMA)+relu+fc2: 16 rows/block; bf16 gated/eco/hd inputs; grid = CB*768
__global__ __launch_bounds__(256) void k_fc(const unsigned short* gated, const unsigned short* eco,
        const unsigned short* hd_emb, const float* hist, const float* tide, const float* diwe,
        const unsigned short* W1p, const float* B1, const float* W2, const float* B2,
        float* fbuf) {
    __shared__ unsigned short Abuf[16 * 480];   // 15360 B, XOR-swizzled rows of 960 B
    __shared__ unsigned short Hbuf[16 * 512];   // 16384 B, XOR-swizzled rows of 1024 B
    int t = threadIdx.x;
    int wave = t >> 6, l = t & 63;
    int lr = l & 15, lg = l >> 4;
    int row0 = blockIdx.x * 16;
#pragma unroll
    for (int it = 0; it < 8; it++) {
        int idx = it * 256 + t;                 // 1920 chunks of 4 elements
        if (idx < 1920) {
            int row = idx / 120;
            int col = (idx - row * 120) * 4;
            int grow = row0 + row;
            int n = grow & 1023, bt = grow >> 10;
            int b = bt / 12, tt = bt - b * 12;
            unsigned short w[4];
            if (col < 128) {
                uint2 raw = *(const uint2*)&gated[(size_t)grow * 128 + col];
                w[0] = raw.x & 0xffff; w[1] = raw.x >> 16;
                w[2] = raw.y & 0xffff; w[3] = raw.y >> 16;
            } else if (col < 384) {
                uint2 raw = *(const uint2*)&eco[(size_t)((b * 12 + tt) * 1024 + n) * 256 + (col - 128)];
                w[0] = raw.x & 0xffff; w[1] = raw.x >> 16;
                w[2] = raw.y & 0xffff; w[3] = raw.y >> 16;
            } else if (col < 396) {
                int tid_i = (int)(hist[(size_t)grow * 4 + 2] * 288.0f);
#pragma unroll
                for (int q = 0; q < 4; q++) w[q] = f2bf(fmaxf(tide[tid_i * 12 + col - 384 + q], 0.f));
            } else if (col < 408) {
                int diw_i = (int)hist[(size_t)grow * 4 + 3];
#pragma unroll
                for (int q = 0; q < 4; q++) w[q] = f2bf(fmaxf(diwe[diw_i * 12 + col - 396 + q], 0.f));
            } else if (col < 472) {
                uint2 raw = *(const uint2*)&hd_emb[(size_t)grow * 64 + col - 408];
                w[0] = raw.x & 0xffff; w[1] = raw.x >> 16;
                w[2] = raw.y & 0xffff; w[3] = raw.y >> 16;
            } else {
#pragma unroll
                for (int q = 0; q < 4; q++) w[q] = 0;
            }
#pragma unroll
            for (int q = 0; q < 4; q++) if (w[q] >> 15) w[q] = 0;   // relu on bf16 bits
            uint2 pk;
            pk.x = w[0] | ((unsigned)w[1] << 16);
            pk.y = w[2] | ((unsigned)w[3] << 16);
            int byte = (row * 960 + col * 2) ^ ((row & 7) << 4);
            *(uint2*)((char*)Abuf + byte) = pk;
        }
    }
    __syncthreads();
    int colg0 = wave * 128;
    f32x4 acc[8];
#pragma unroll
    for (int nb = 0; nb < 8; nb++) {
        float bv = B1[colg0 + nb * 16 + lr];
        f32x4 c; c[0] = bv; c[1] = bv; c[2] = bv; c[3] = bv;
        acc[nb] = c;
    }
#pragma unroll
    for (int kb = 0; kb < 15; kb++) {
        int k2 = (kb * 32 + lg * 8) * 2;
        int by0 = (lr * 960 + k2) ^ ((lr & 7) << 4);
        bf16x8 a0 = *(const bf16x8*)((char*)Abuf + by0);
#pragma unroll
        for (int nb = 0; nb < 8; nb++) {
            int nbg = wave * 8 + nb;
            bf16x8 bw = *(const bf16x8*)(W1p + (size_t)((kb * 32 + nbg) * 64 + l) * 8);
            acc[nb] = __builtin_amdgcn_mfma_f32_16x16x32_bf16(a0, bw, acc[nb], 0, 0, 0);
        }
    }
#pragma unroll
    for (int nb = 0; nb < 8; nb++)
#pragma unroll
        for (int r = 0; r < 4; r++) {
            int row = lg * 4 + r;
            int col = colg0 + nb * 16 + lr;
            unsigned short h = f2bf(fmaxf(acc[nb][r], 0.f));
            int byte = (row * 1024 + col * 2) ^ ((row & 7) << 4);
            *(unsigned short*)((char*)Hbuf + byte) = h;
        }
    __syncthreads();
    float* redp = (float*)Abuf;
    {
        int rsub = t >> 5, seg = t & 31;
#pragma unroll
        for (int rg = 0; rg < 2; rg++) {
            int r = rg * 8 + rsub;
            float p0 = 0.f, p1 = 0.f, p2 = 0.f;
#pragma unroll
            for (int j = 0; j < 16; j++) {
                int k = seg + j * 32;
                int byte = (r * 1024 + k * 2) ^ ((r & 7) << 4);
                float h = bf2f(*(const unsigned short*)((char*)Hbuf + byte));
                p0 += h * W2[k * 3];
                p1 += h * W2[k * 3 + 1];
                p2 += h * W2[k * 3 + 2];
            }
            redp[r * 96 + seg] = p0;
            redp[r * 96 + 32 + seg] = p1;
            redp[r * 96 + 64 + seg] = p2;
        }
    }
    __syncthreads();
    if (t < 48) {
        int rr = t / 3, p = t - rr * 3;
        float s = B2[p];
        for (int seg = 0; seg < 32; seg++) s += redp[rr * 96 + p * 32 + seg];
        fbuf[(size_t)(row0 + rr) * 3 + p] = s;
    }
}

// final conv1x1 over time + transpose; grid = CB*48
__global__ void k_ec3(const float* f, const float* W, const float* bv, float* out) {
    int idx = blockIdx.x * 256 + threadIdx.x;
    int l = idx % 3;
    int rest = idx / 3;
    int o = rest & 3;
    int n = (rest >> 2) & 1023;
    int b = rest >> 12;
    float s = bv[o];
#pragma unroll
    for (int c = 0; c < 12; c++)
        s += f[(size_t)((b * 12 + c) * 1024 + n) * 3 + l] * W[o * 12 + c];
    out[idx] = s;
}

// ---------------- launcher ----------------
extern "C" void kernel_launch(void* const* d_in, const int* in_sizes, int n_in,
                              void* d_out, int out_size, void* d_ws, size_t ws_size,
                              hipStream_t stream) {
    const float* hist = (const float*)d_in[0];
    const float* node_emb_u = (const float*)d_in[1];
    const float* T_i_D_emb = (const float*)d_in[2];
    const float* D_i_W_emb = (const float*)d_in[3];
    const float* gc_emb1 = (const float*)d_in[4];
    const float* gc_emb2 = (const float*)d_in[5];
    const float* gc_w1 = (const float*)d_in[6];
    const float* gc_b1 = (const float*)d_in[7];
    const float* gc_w2 = (const float*)d_in[8];
    const float* gc_b2 = (const float*)d_in[9];
    const float* W_emb = (const float*)d_in[10];
    const float* b_emb = (const float*)d_in[11];
    const float* Wg1 = (const float*)d_in[12];
    const float* bg1 = (const float*)d_in[13];
    const float* Wg2 = (const float*)d_in[14];
    const float* bg2 = (const float*)d_in[15];
    const float* Wsc = (const float*)d_in[16];
    const float* bsc = (const float*)d_in[17];
    const float* mix1_w = (const float*)d_in[18];
    const float* mix1_b = (const float*)d_in[19];
    const float* mix2_w = (const float*)d_in[20];
    const float* mix2_b = (const float*)d_in[21];
    const float* Wtf1 = (const float*)d_in[22];
    const float* btf1 = (const float*)d_in[23];
    const float* Wtf2 = (const float*)d_in[24];
    const float* btf2 = (const float*)d_in[25];
    const float* Wec1 = (const float*)d_in[26];
    const float* bec1 = (const float*)d_in[27];
    const float* Wec2 = (const float*)d_in[28];
    const float* bec2 = (const float*)d_in[29];
    const float* Wfc1 = (const float*)d_in[30];
    const float* bfc1 = (const float*)d_in[31];
    const float* Wfc2 = (const float*)d_in[32];
    const float* bfc2 = (const float*)d_in[33];
    const float* Wec3 = (const float*)d_in[34];
    const float* bec3 = (const float*)d_in[35];

    float* ws = (float*)d_ws;
    float* n1 = ws + F_N1;
    float* n2 = ws + F_N2;
    float* aN_val = ws + F_ANVAL;
    float* row_val = ws + F_ROWVAL;
    float* col_sum = ws + F_COLSUM;
    float* inv_cs = ws + F_INVCS;
    float* aT_val = ws + F_ATVAL;
    int* aN_idx = (int*)(ws + I_ANIDX);
    int* row_idx = (int*)(ws + I_ROWIDX);
    int* col_cnt = (int*)(ws + I_COLCNT);
    int* col_off = (int*)(ws + I_COLOFF);
    int* col_fill = (int*)(ws + I_COLFILL);
    int* aT_idx = (int*)(ws + I_ATIDX);
    unsigned short* w1p = (unsigned short*)(ws + F_W1P);
    unsigned short* w2p = (unsigned short*)(ws + F_W2P);
    unsigned short* wfcp = (unsigned short*)(ws + F_WFCP);
    unsigned short* wec1p = (unsigned short*)(ws + F_WEC1P);
    unsigned short* wec2p = (unsigned short*)(ws + F_WEC2P);
    unsigned short* wmwp = (unsigned short*)(ws + F_WMWP);

    // pick largest batch-chunk CB that fits the workspace
    size_t avail = ws_size / 4;   // floats
    int CB = 8;
    while (CB > 1 && GRAPH_FLOATS + (size_t)CB * PB_TOTAL > avail) CB >>= 1;
    int nchunk = 8 / CB;

    unsigned short* gated = (unsigned short*)(ws + GRAPH_FLOATS);
    unsigned short* hd_emb = (unsigned short*)(ws + GRAPH_FLOATS + (size_t)CB * PB_GATED);
    unsigned short* xs = (unsigned short*)(ws + GRAPH_FLOATS + (size_t)CB * (PB_GATED + PB_HD));
    unsigned short* h1 = xs + (size_t)CB * PB_X * 2;
    unsigned short* h2 = h1 + (size_t)CB * PB_X * 2;
    unsigned short* h1b = h2 + (size_t)CB * PB_X * 2;
    unsigned short* h2b = h1b + (size_t)CB * PB_X * 2;
    unsigned short* mix = h2b + (size_t)CB * PB_X * 2;
    unsigned short* eco = xs;        // alias: xs+h1 region (CB*4M u16) >= eco (CB*3M u16)
    float* fbuf = (float*)h2b;       // alias: h2b dead by k_fc

    // ---- graph construction + weight packing (once) ----
    k_init<<<4, 256, 0, stream>>>(col_cnt, col_fill, col_sum);
    k_embed<<<320, 256, 0, stream>>>(gc_emb1, gc_emb2, gc_w1, gc_b1, gc_w2, gc_b2, n1, n2);
    k_adj<<<1024, 256, 0, stream>>>(n1, n2, aN_val, aN_idx, row_val, row_idx, col_cnt, col_sum);
    k_scan<<<1, 1024, 0, stream>>>(col_cnt, col_off, col_sum, inv_cs);
    k_scatter<<<40, 256, 0, stream>>>(row_idx, row_val, col_off, col_fill, aT_idx, aT_val);
    k_packw<<<32, 256, 0, stream>>>(Wtf1, w1p);
    k_packw<<<32, 256, 0, stream>>>(Wtf2, w2p);
    k_packfc<<<120, 256, 0, stream>>>(Wfc1, wfcp);
    k_packec<<<3, 256, 0, stream>>>(Wec1, Wec2, wec1p, wec2p);
    k_packmw<<<6, 256, 0, stream>>>(mix1_w, mix2_w, wmwp);

    // ---- per-chunk pipeline ----
    for (int ch = 0; ch < nchunk; ch++) {
        const float* hist_c = hist + (size_t)ch * CB * ROWS_PER_B * 4;
        float* out_c = (float*)d_out + (size_t)ch * CB * ROWS_PER_B;

        k_gate<<<CB * 3072, 256, 0, stream>>>(hist_c, node_emb_u, T_i_D_emb, D_i_W_emb,
                                              Wg1, bg1, Wg2, bg2, W_emb, b_emb, gated, hd_emb);
        for (int xp = 0; xp < 2; xp++) {
            k_wsc<<<CB * 256, 256, 0, stream>>>(gated, Wsc, bsc, xs, xp * 64);
            k_spmm<<<CB * 1024, 256, 0, stream>>>(h1, xs, xs, aN_idx, aN_val, aT_idx, aT_val,
                                                  col_off, inv_cs, 0);
            k_spmm<<<CB * 1024, 256, 0, stream>>>(h2, xs, h1, aN_idx, aN_val, aT_idx, aT_val,
                                                  col_off, inv_cs, 0);
            k_spmm<<<CB * 1024, 256, 0, stream>>>(h1b, xs, xs, aN_idx, aN_val, aT_idx, aT_val,
                                                  col_off, inv_cs, 1);
            k_spmm<<<CB * 1024, 256, 0, stream>>>(h2b, xs, h1b, aN_idx, aN_val, aT_idx, aT_val,
                                                  col_off, inv_cs, 1);
            k_proj<<<CB * 1024, 256, 0, stream>>>(xs, h1, h2, h1b, h2b,
                                                  wmwp, mix1_b, mix2_b, mix, xp);
        }
        k_tf<<<CB * 1024, 256, 0, stream>>>(mix, w1p, btf1, w2p, btf2);
        k_ec<<<CB * 1024, 256, 0, stream>>>(mix, wec1p, bec1, wec2p, bec2, eco);
        k_fc<<<CB * 768, 256, 0, stream>>>(gated, eco, hd_emb, hist_c, T_i_D_emb, D_i_W_emb,
                                           wfcp, bfc1, Wfc2, bfc2, fbuf);
        k_ec3<<<CB * 48, 256, 0, stream>>>(fbuf, Wec3, bec3, out_c);
    }
}

// Round 12
// 1247.441 us; speedup vs baseline: 3.8878x; 1.4255x over previous
//
#include <hip/hip_runtime.h>
#include <math.h>

// ---------------- constants ----------------
constexpr int ROWS_PER_B = 12 * 1024;    // rows (b,t,n) per batch element

// ---------------- graph workspace (float offsets, < 524288) ----------------
constexpr size_t F_N1 = 0;              // 1024*40
constexpr size_t F_N2 = 40960;
constexpr size_t F_ANVAL = 81920;       // 1024*11
constexpr size_t F_ROWVAL = 93184;      // 1024*10
constexpr size_t F_COLSUM = 103424;     // 1024
constexpr size_t F_INVCS = 104448;      // 1024
constexpr size_t F_ATVAL = 105472;      // 10240
constexpr size_t I_ANIDX = 115712;      // ints stored in float slots
constexpr size_t I_ROWIDX = 126976;
constexpr size_t I_COLCNT = 137216;
constexpr size_t I_COLOFF = 138240;     // 1025
constexpr size_t I_COLFILL = 139265;
constexpr size_t I_ATIDX = 140289;      // ends 150529
constexpr size_t F_W1P = 151552;        // packed bf16 Wtf1: 32768 floats
constexpr size_t F_W2P = 184320;        // packed bf16 Wtf2: ends 217088
constexpr size_t F_WFCP = 217088;       // packed bf16 Wfc1: ends 339968
constexpr size_t F_WEC1P = 339968;      // packed bf16 Wec1
constexpr size_t F_WEC2P = 342016;      // packed bf16 Wec2 -> ends 343040
constexpr size_t F_WMWP = 343040;       // packed bf16 mix weights -> ends 349184
constexpr size_t GRAPH_FLOATS = 524288;

// per-chunk float-unit counts (per batch element) — bf16 storage
constexpr size_t PB_GATED = (size_t)ROWS_PER_B * 128 / 2;   // 786432
constexpr size_t PB_HD = (size_t)ROWS_PER_B * 64 / 2;       // 393216
constexpr size_t PB_X = (size_t)32 * 1024 * 64 / 2;         // 1048576 (xs,h1,h2,h1b,h2b)
constexpr size_t PB_MIX = (size_t)32 * 1024 * 256 / 2;      // 4194304
constexpr size_t PB_TOTAL = PB_GATED + PB_HD + 5 * PB_X + PB_MIX; // 10616832

typedef __attribute__((ext_vector_type(8))) short bf16x8;
typedef __attribute__((ext_vector_type(4))) float f32x4;

__device__ __forceinline__ unsigned short f2bf(float f) {
    unsigned u = __float_as_uint(f);
    unsigned r = (u + 0x7fffu + ((u >> 16) & 1u)) >> 16;   // RNE
    return (unsigned short)r;
}
__device__ __forceinline__ float bf2f(unsigned short h) {
    return __uint_as_float((unsigned)h << 16);
}
__device__ __forceinline__ void unpack8(uint4 raw, float* f) {
    f[0] = bf2f((unsigned short)(raw.x & 0xffff)); f[1] = bf2f((unsigned short)(raw.x >> 16));
    f[2] = bf2f((unsigned short)(raw.y & 0xffff)); f[3] = bf2f((unsigned short)(raw.y >> 16));
    f[4] = bf2f((unsigned short)(raw.z & 0xffff)); f[5] = bf2f((unsigned short)(raw.z >> 16));
    f[6] = bf2f((unsigned short)(raw.w & 0xffff)); f[7] = bf2f((unsigned short)(raw.w >> 16));
}
__device__ __forceinline__ uint4 pack8(const float* f) {
    uint4 r;
    r.x = f2bf(f[0]) | ((unsigned)f2bf(f[1]) << 16);
    r.y = f2bf(f[2]) | ((unsigned)f2bf(f[3]) << 16);
    r.z = f2bf(f[4]) | ((unsigned)f2bf(f[5]) << 16);
    r.w = f2bf(f[6]) | ((unsigned)f2bf(f[7]) << 16);
    return r;
}

// ---------------- graph kernels ----------------

__global__ void k_init(int* cnt, int* fill, float* csum) {
    int t = blockIdx.x * 256 + threadIdx.x;
    if (t < 1024) { cnt[t] = 0; fill[t] = 0; csum[t] = 0.f; }
}

__global__ void k_embed(const float* e1, const float* e2, const float* w1, const float* b1,
                        const float* w2, const float* b2, float* n1, float* n2) {
    int idx = blockIdx.x * 256 + threadIdx.x;   // < 81920
    if (idx >= 81920) return;
    int m = idx / 40960, rem = idx - m * 40960;
    int i = rem / 40, j = rem - i * 40;
    const float* e = m ? e2 : e1;
    const float* w = m ? w2 : w1;
    const float* bv = m ? b2 : b1;
    float a = bv[j];
    for (int k = 0; k < 40; k++) a += e[i * 40 + k] * w[k * 40 + j];
    (m ? n2 : n1)[i * 40 + j] = tanhf(3.0f * a);
}

__global__ __launch_bounds__(256) void k_adj(const float* n1, const float* n2,
        float* aN_val, int* aN_idx, float* row_val, int* row_idx,
        int* col_cnt, float* col_sum) {
    __shared__ float arow[1024];
    __shared__ float n1v[40], n2v[40];
    __shared__ float rv[256];
    __shared__ int ri[256];
    __shared__ float topv[10];
    __shared__ int topi[10];
    int v = blockIdx.x, t = threadIdx.x;
    if (t < 40) { n1v[t] = n1[v * 40 + t]; n2v[t] = n2[v * 40 + t]; }
    __syncthreads();
    for (int j = t; j < 1024; j += 256) {
        float d1 = 0.f, d2 = 0.f;
        for (int k = 0; k < 40; k++) {
            d1 += n1v[k] * n2[j * 40 + k];
            d2 += n2v[k] * n1[j * 40 + k];
        }
        float a = tanhf(3.0f * (d1 - d2));
        arow[j] = a > 0.f ? a : 0.f;
    }
    __syncthreads();
    for (int r = 0; r < 10; r++) {
        float bv = -1.f; int bi = 1 << 30;
        for (int j = t; j < 1024; j += 256) {
            float x = arow[j];
            if (x > bv || (x == bv && j < bi)) { bv = x; bi = j; }
        }
        rv[t] = bv; ri[t] = bi;
        __syncthreads();
        for (int s = 128; s > 0; s >>= 1) {
            if (t < s) {
                float ov = rv[t + s]; int oi = ri[t + s];
                if (ov > rv[t] || (ov == rv[t] && oi < ri[t])) { rv[t] = ov; ri[t] = oi; }
            }
            __syncthreads();
        }
        if (t == 0) { topv[r] = rv[0]; topi[r] = ri[0]; arow[ri[0]] = -1.f; }
        __syncthreads();
    }
    if (t == 0) {
        float s = 1.f;
        for (int r = 0; r < 10; r++) s += topv[r];
        float inv = 1.f / s;
        for (int r = 0; r < 10; r++) {
            aN_idx[v * 11 + r] = topi[r];
            aN_val[v * 11 + r] = topv[r] * inv;
            row_idx[v * 10 + r] = topi[r];
            row_val[v * 10 + r] = topv[r];
            atomicAdd(&col_cnt[topi[r]], 1);
            atomicAdd(&col_sum[topi[r]], topv[r]);
        }
        aN_idx[v * 11 + 10] = v;
        aN_val[v * 11 + 10] = inv;
    }
}

__global__ __launch_bounds__(1024) void k_scan(const int* cnt, int* off,
                                               const float* csum, float* inv) {
    __shared__ int tmp[1024];
    int t = threadIdx.x;
    tmp[t] = cnt[t];
    __syncthreads();
    for (int s = 1; s < 1024; s <<= 1) {
        int v = 0;
        if (t >= s) v = tmp[t - s];
        __syncthreads();
        tmp[t] += v;
        __syncthreads();
    }
    off[t + 1] = tmp[t];
    if (t == 0) off[0] = 0;
    inv[t] = 1.0f / (csum[t] + 1.0f);
}

__global__ void k_scatter(const int* row_idx, const float* row_val, const int* off,
                          int* fill, int* aT_idx, float* aT_val) {
    int e = blockIdx.x * 256 + threadIdx.x;
    if (e >= 10240) return;
    int v = e / 10;
    int j = row_idx[e];
    int pos = off[j] + atomicAdd(&fill[j], 1);
    aT_idx[pos] = v;
    aT_val[pos] = row_val[e];
}

// pack 256x256 f32 weight into MFMA B-fragment order
__global__ void k_packw(const float* W, unsigned short* out) {
    int id = blockIdx.x * 256 + threadIdx.x;    // 8192 total
    if (id >= 8192) return;
    int lane = id & 63, rest = id >> 6;
    int nb = rest & 15, kb = rest >> 4;
    int krow = kb * 32 + (lane >> 4) * 8;
    int col = nb * 16 + (lane & 15);
    unsigned short v[8];
#pragma unroll
    for (int j = 0; j < 8; j++) v[j] = f2bf(W[(size_t)(krow + j) * 256 + col]);
#pragma unroll
    for (int j = 0; j < 8; j++) out[(size_t)id * 8 + j] = v[j];
}

// pack 472x512 Wfc1 into B-fragment order, K padded to 480
__global__ void k_packfc(const float* W, unsigned short* out) {
    int id = blockIdx.x * 256 + threadIdx.x;    // 30720 total
    if (id >= 30720) return;
    int lane = id & 63, rest = id >> 6;
    int nb = rest & 31, kb = rest >> 5;         // kb < 15
    int k0 = kb * 32 + (lane >> 4) * 8;
    int col = nb * 16 + (lane & 15);
    unsigned short v[8];
#pragma unroll
    for (int j = 0; j < 8; j++) {
        int k = k0 + j;
        v[j] = (k < 472) ? f2bf(W[(size_t)k * 512 + col]) : (unsigned short)0;
    }
#pragma unroll
    for (int j = 0; j < 8; j++) out[(size_t)id * 8 + j] = v[j];
}

// pack Wec1 (128x32) and Wec2 (12x128, pad 16) into A-frag order
__global__ void k_packec(const float* W1, const float* W2,
                         unsigned short* o1, unsigned short* o2) {
    int id = blockIdx.x * 256 + threadIdx.x;    // 768 total
    if (id < 512) {
        int mt = id >> 6, lane = id & 63;
        int o = mt * 16 + (lane & 15);
        int c0 = (lane >> 4) * 8;
#pragma unroll
        for (int j = 0; j < 8; j++)
            o1[(size_t)id * 8 + j] = f2bf(W1[o * 32 + c0 + j]);
    } else if (id < 768) {
        int id2 = id - 512;
        int kb = id2 >> 6, lane = id2 & 63;
        int p = lane & 15;
        int k0 = kb * 32 + (lane >> 4) * 8;
#pragma unroll
        for (int j = 0; j < 8; j++)
            o2[(size_t)id2 * 8 + j] = (p < 12) ? f2bf(W2[p * 128 + k0 + j])
                                               : (unsigned short)0;
    }
}

// pack mix weights [64 rows][192 K] into A-frag order (24 frags)
__global__ void k_packmw(const float* mw1, const float* mw2, unsigned short* out) {
    int id = blockIdx.x * 256 + threadIdx.x;    // 1536 total
    if (id >= 1536) return;
    int f = id >> 6, lane = id & 63;
    int kb = f >> 2, rt = f & 3;
    int row = rt * 16 + (lane & 15);
    int ph = (kb >= 3) ? 1 : 0;
    int kloc = (kb - ph * 3) * 32 + (lane >> 4) * 8;
    const float* mw = ph ? mw2 : mw1;
#pragma unroll
    for (int j = 0; j < 8; j++)
        out[(size_t)id * 8 + j] = f2bf(mw[row * 96 + kloc + j]);
}

// ---------------- per-chunk kernels ----------------

// gate MLP + embed; outputs bf16; grid = CB*3072
__global__ __launch_bounds__(256) void k_gate(const float* hist, const float* nodeu,
        const float* tide, const float* diwe,
        const float* Wg1, const float* bg1, const float* Wg2, const float* bg2,
        const float* Wemb, const float* bemb, unsigned short* gated, unsigned short* hd_emb) {
    __shared__ float w1[4096], w2[4096];
    __shared__ float gin[4][64], hid[4][64];
    __shared__ float sb1[64], sb2[64], we[128], be[64];
    int t = threadIdx.x;
    for (int i = t; i < 4096; i += 256) { w1[i] = Wg1[i]; w2[i] = Wg2[i]; }
    if (t < 64) { sb1[t] = bg1[t]; sb2[t] = bg2[t]; be[t] = bemb[t]; }
    if (t < 128) we[t] = Wemb[t];
    int r = t >> 6, lane = t & 63;
    int row = blockIdx.x * 4 + r;
    int n = row & 1023;
    const float* hrow = hist + (size_t)row * 4;
    float f0 = hrow[0], f1 = hrow[1];
    int tid_i = (int)(hrow[2] * 288.0f);
    int diw_i = (int)hrow[3];
    float g;
    if (lane < 40) g = nodeu[n * 40 + lane];
    else if (lane < 52) g = tide[tid_i * 12 + lane - 40];
    else g = diwe[diw_i * 12 + lane - 52];
    gin[r][lane] = g;
    __syncthreads();
    float acc = sb1[lane];
    for (int k = 0; k < 64; k++) acc += gin[r][k] * w1[k * 64 + lane];
    hid[r][lane] = acc > 0.f ? acc : 0.f;
    __syncthreads();
    acc = sb2[lane];
    for (int k = 0; k < 64; k++) acc += hid[r][k] * w2[k * 64 + lane];
    float gate = 1.f / (1.f + expf(-acc));
    float hd = f0 * we[lane] + f1 * we[64 + lane] + be[lane];
    float x1 = gate * hd;
    gated[(size_t)row * 128 + lane] = f2bf(x1);
    gated[(size_t)row * 128 + 64 + lane] = f2bf(hd - x1);
    hd_emb[(size_t)row * 64 + lane] = f2bf(hd);
}

// xs = relu(sum_t gated*Wsc + bsc), bf16 in/out; grid = CB*256
__global__ __launch_bounds__(256) void k_wsc(const unsigned short* gated, const float* Wsc,
                                             const float* bsc, unsigned short* xs, int xoff) {
    __shared__ float w[384];
    __shared__ float sb[32];
    int t = threadIdx.x;
    if (t < 384) w[t] = Wsc[t];
    if (t < 32) sb[t] = bsc[t];
    __syncthreads();
    int idx = blockIdx.x * 256 + t;
    int h = idx & 63, n = (idx >> 6) & 1023, b = idx >> 16;
    float xv[12];
#pragma unroll
    for (int tt = 0; tt < 12; tt++)
        xv[tt] = bf2f(gated[(size_t)((b * 12 + tt) * 1024 + n) * 128 + xoff + h]);
#pragma unroll
    for (int o = 0; o < 32; o++) {
        float a = sb[o];
#pragma unroll
        for (int tt = 0; tt < 12; tt++) a += xv[tt] * w[o * 12 + tt];
        xs[(size_t)((b * 32 + o) * 1024 + n) * 64 + h] = f2bf(a > 0.f ? a : 0.f);
    }
}

// fused dual spmm: out1 = 0.05x + 0.95*aN@hin1, out2 = 0.05x + 0.95*aTN@hin2
// bf16 in/out; XCD-swizzled blocks; grid = CB*1024 (32 rows/block)
__global__ __launch_bounds__(256) void k_spmm2(unsigned short* out1, unsigned short* out2,
        const unsigned short* x, const unsigned short* hin1, const unsigned short* hin2,
        const int* aN_idx, const float* aN_val,
        const int* aT_idx, const float* aT_val,
        const int* off, const float* inv_cs) {
    int nper = gridDim.x >> 3;
    int bid = (blockIdx.x & 7) * nper + (blockIdx.x >> 3);   // same-bc blocks -> same XCD
    int t = threadIdx.x;
    int l8 = t & 7, r = t >> 3;             // 32 rows x 8 16B-lanes
    int g = bid * 32 + r;
    int v = g & 1023, bc = g >> 10;
    size_t rowoff = (size_t)bc * 65536;
    float hv[8];
    // ---- aN path (11 fixed edges) ----
    const unsigned short* base1 = hin1 + rowoff;
    float s1[8];
#pragma unroll
    for (int j = 0; j < 8; j++) s1[j] = 0.f;
#pragma unroll
    for (int e = 0; e < 11; e++) {
        int w = aN_idx[v * 11 + e];
        float a = aN_val[v * 11 + e];
        uint4 raw = *(const uint4*)(base1 + (size_t)w * 64 + l8 * 8);
        unpack8(raw, hv);
#pragma unroll
        for (int j = 0; j < 8; j++) s1[j] += a * hv[j];
    }
    // ---- aTN path (CSC, variable degree) ----
    const unsigned short* base2 = hin2 + rowoff;
    float s2[8];
    {
        uint4 raw = *(const uint4*)(base2 + (size_t)v * 64 + l8 * 8);
        unpack8(raw, s2);
        int e0 = off[v], e1 = off[v + 1];
        for (int e = e0; e < e1; e++) {
            int w = aT_idx[e];
            float a = aT_val[e];
            uint4 rw = *(const uint4*)(base2 + (size_t)w * 64 + l8 * 8);
            unpack8(rw, hv);
#pragma unroll
            for (int j = 0; j < 8; j++) s2[j] += a * hv[j];
        }
        float ic = inv_cs[v];
#pragma unroll
        for (int j = 0; j < 8; j++) s2[j] *= ic;
    }
    // ---- combine with x ----
    uint4 xr = *(const uint4*)(x + (size_t)g * 64 + l8 * 8);
    float xv[8];
    unpack8(xr, xv);
    float o1[8], o2[8];
#pragma unroll
    for (int j = 0; j < 8; j++) {
        float xb = 0.05f * xv[j];
        o1[j] = xb + 0.95f * s1[j];
        o2[j] = xb + 0.95f * s2[j];
    }
    *(uint4*)(out1 + (size_t)g * 64 + l8 * 8) = pack8(o1);
    *(uint4*)(out2 + (size_t)g * 64 + l8 * 8) = pack8(o2);
}

// mix projection via bf16 MFMA: block = (b,n), 4 waves; grid = CB*1024
__global__ __launch_bounds__(256) void k_proj(const unsigned short* xs,
        const unsigned short* h1, const unsigned short* h2,
        const unsigned short* h1b, const unsigned short* h2b,
        const unsigned short* mwp, const float* m1b, const float* m2b,
        unsigned short* mix, int xp) {
    __shared__ unsigned short Bf[24 * 64 * 8];   // 24 shared B-frags, frag layout, 24 KB
    int t = threadIdx.x;
    int wave = t >> 6, l = t & 63;
    int lr = l & 15, lg = l >> 4;
    int b = blockIdx.x >> 10, n = blockIdx.x & 1023;
    // ---- cooperative B-frag gather: 6 frags per wave ----
#pragma unroll
    for (int i = 0; i < 6; i++) {
        int f = wave * 6 + i;
        int kb = f >> 2, nt = f & 3;
        int ph = (kb >= 3) ? 1 : 0;
        int q = kb - ph * 3;
        const unsigned short* Hq = (q == 0) ? xs : (q == 1 ? (ph ? h1b : h1)
                                                           : (ph ? h2b : h2));
        const unsigned short* src = Hq + ((size_t)(b * 32 + lg * 8) * 1024 + n) * 64
                                       + nt * 16 + lr;
        bf16x8 v;
#pragma unroll
        for (int j = 0; j < 8; j++)
            v[j] = (short)src[(size_t)j * 65536];
        *(bf16x8*)(Bf + ((size_t)f * 64 + l) * 8) = v;
    }
    __syncthreads();
    // ---- wave = row-tile; 4 col-tiles; K = 6 blocks of 32 ----
    f32x4 acc[4];
#pragma unroll
    for (int nt = 0; nt < 4; nt++) {
        f32x4 c;
#pragma unroll
        for (int r = 0; r < 4; r++) {
            int row = wave * 16 + lg * 4 + r;
            c[r] = m1b[row] + m2b[row];
        }
        acc[nt] = c;
    }
#pragma unroll
    for (int kb = 0; kb < 6; kb++) {
        bf16x8 af = *(const bf16x8*)(mwp + (size_t)((kb * 4 + wave) * 64 + l) * 8);
#pragma unroll
        for (int nt = 0; nt < 4; nt++) {
            bf16x8 bfv = *(const bf16x8*)(Bf + ((size_t)(kb * 4 + nt) * 64 + l) * 8);
            acc[nt] = __builtin_amdgcn_mfma_f32_16x16x32_bf16(af, bfv, acc[nt], 0, 0, 0);
        }
    }
#pragma unroll
    for (int nt = 0; nt < 4; nt++)
#pragma unroll
        for (int r = 0; r < 4; r++) {
            int row = wave * 16 + lg * 4 + r;
            int i2 = row >> 5, o = row & 31;
            mix[(size_t)((b * 32 + o) * 1024 + n) * 256 + (i2 * 2 + xp) * 64 + nt * 16 + lr]
                = f2bf(acc[nt][r]);
        }
}

// fused Wtf1(relu)Wtf2 via bf16 MFMA, in-place on bf16 mix: 32 rows/block; grid = CB*1024
__global__ __launch_bounds__(256) void k_tf(unsigned short* mix, const unsigned short* W1p,
                                            const float* B1, const unsigned short* W2p,
                                            const float* B2) {
    __shared__ unsigned short Abuf[32 * 256];   // bf16, XOR-swizzled
    __shared__ unsigned short Hbuf[32 * 256];
    int t = threadIdx.x;
    int wave = t >> 6, l = t & 63;
    size_t row0 = (size_t)blockIdx.x * 32;
    const uint4* src = (const uint4*)(mix + row0 * 256);
#pragma unroll
    for (int it = 0; it < 4; it++) {
        int f = t + it * 256;                  // 1024 8-u16 chunks
        uint4 raw = src[f];
        int e = f * 8, row = e >> 8, col = e & 255;
        int byte = (row * 512 + col * 2) ^ ((row & 7) << 4);
        *(uint4*)((char*)Abuf + byte) = raw;
    }
    __syncthreads();
    int colg0 = wave * 64;
    int lr = l & 15, lg = l >> 4;
    f32x4 acc[2][4];
#pragma unroll
    for (int nb = 0; nb < 4; nb++) {
        float bv = B1[colg0 + nb * 16 + lr];
        f32x4 c; c[0] = bv; c[1] = bv; c[2] = bv; c[3] = bv;
        acc[0][nb] = c; acc[1][nb] = c;
    }
#pragma unroll
    for (int kb = 0; kb < 8; kb++) {
        int k2 = (kb * 32 + lg * 8) * 2;
        int by0 = (lr * 512 + k2) ^ ((lr & 7) << 4);
        int by1 = ((16 + lr) * 512 + k2) ^ ((lr & 7) << 4);
        bf16x8 a0 = *(const bf16x8*)((char*)Abuf + by0);
        bf16x8 a1 = *(const bf16x8*)((char*)Abuf + by1);
#pragma unroll
        for (int nb = 0; nb < 4; nb++) {
            int nbg = wave * 4 + nb;
            bf16x8 bw = *(const bf16x8*)(W1p + (size_t)((kb * 16 + nbg) * 64 + l) * 8);
            acc[0][nb] = __builtin_amdgcn_mfma_f32_16x16x32_bf16(a0, bw, acc[0][nb], 0, 0, 0);
            acc[1][nb] = __builtin_amdgcn_mfma_f32_16x16x32_bf16(a1, bw, acc[1][nb], 0, 0, 0);
        }
    }
#pragma unroll
    for (int rb = 0; rb < 2; rb++)
#pragma unroll
        for (int nb = 0; nb < 4; nb++)
#pragma unroll
            for (int r = 0; r < 4; r++) {
                int row = rb * 16 + lg * 4 + r;
                int col = colg0 + nb * 16 + lr;
                unsigned short h = f2bf(fmaxf(acc[rb][nb][r], 0.f));
                int byte = (row * 512 + col * 2) ^ ((row & 7) << 4);
                *(unsigned short*)((char*)Hbuf + byte) = h;
            }
    __syncthreads();
#pragma unroll
    for (int nb = 0; nb < 4; nb++) {
        float bv = B2[colg0 + nb * 16 + lr];
        f32x4 c; c[0] = bv; c[1] = bv; c[2] = bv; c[3] = bv;
        acc[0][nb] = c; acc[1][nb] = c;
    }
#pragma unroll
    for (int kb = 0; kb < 8; kb++) {
        int k2 = (kb * 32 + lg * 8) * 2;
        int by0 = (lr * 512 + k2) ^ ((lr & 7) << 4);
        int by1 = ((16 + lr) * 512 + k2) ^ ((lr & 7) << 4);
        bf16x8 a0 = *(const bf16x8*)((char*)Hbuf + by0);
        bf16x8 a1 = *(const bf16x8*)((char*)Hbuf + by1);
#pragma unroll
        for (int nb = 0; nb < 4; nb++) {
            int nbg = wave * 4 + nb;
            bf16x8 bw = *(const bf16x8*)(W2p + (size_t)((kb * 16 + nbg) * 64 + l) * 8);
            acc[0][nb] = __builtin_amdgcn_mfma_f32_16x16x32_bf16(a0, bw, acc[0][nb], 0, 0, 0);
            acc[1][nb] = __builtin_amdgcn_mfma_f32_16x16x32_bf16(a1, bw, acc[1][nb], 0, 0, 0);
        }
    }
#pragma unroll
    for (int rb = 0; rb < 2; rb++)
#pragma unroll
        for (int nb = 0; nb < 4; nb++)
#pragma unroll
            for (int r = 0; r < 4; r++) {
                int row = rb * 16 + lg * 4 + r;
                int col = colg0 + nb * 16 + lr;
                mix[(row0 + row) * 256 + col] = f2bf(acc[rb][nb][r]);
            }
}

// fused ec1(relu)+ec2 via bf16 MFMA; bf16 mix in, bf16 eco out; grid = CB*1024
__global__ __launch_bounds__(256) void k_ec(const unsigned short* tfo,
        const unsigned short* W1p, const float* B1,
        const unsigned short* W2p, const float* B2, unsigned short* eco) {
    __shared__ unsigned short Hl[4 * 64 * 48];   // per-wave [64 l][48 u16] = 24 KB
    int t = threadIdx.x;
    int wave = t >> 6, l = t & 63;
    int lr = l & 15, lg = l >> 4;
    int b = blockIdx.x >> 10, n = blockIdx.x & 1023;
    int lbase = wave * 64;
    unsigned short* myH = Hl + wave * 3072;
    const unsigned short* xb = tfo + ((size_t)(b * 32) * 1024 + n) * 256;
    bf16x8 xf[4];
#pragma unroll
    for (int nt = 0; nt < 4; nt++) {
        int ll = lbase + nt * 16 + lr;
        bf16x8 v;
#pragma unroll
        for (int j = 0; j < 8; j++)
            v[j] = (short)xb[(size_t)(lg * 8 + j) * 262144 + ll];
        xf[nt] = v;
    }
    f32x4 d2[4];
    {
        f32x4 c;
#pragma unroll
        for (int r = 0; r < 4; r++) {
            int p = lg * 4 + r;
            c[r] = (p < 12) ? B2[p] : 0.f;
        }
#pragma unroll
        for (int nt = 0; nt < 4; nt++) d2[nt] = c;
    }
#pragma unroll
    for (int ch = 0; ch < 4; ch++) {
        f32x4 h[2][4];
#pragma unroll
        for (int mt = 0; mt < 2; mt++) {
            f32x4 c;
#pragma unroll
            for (int r = 0; r < 4; r++) c[r] = B1[ch * 32 + mt * 16 + lg * 4 + r];
#pragma unroll
            for (int nt = 0; nt < 4; nt++) h[mt][nt] = c;
        }
#pragma unroll
        for (int mt = 0; mt < 2; mt++) {
            bf16x8 aw = *(const bf16x8*)(W1p + (size_t)((ch * 2 + mt) * 64 + l) * 8);
#pragma unroll
            for (int nt = 0; nt < 4; nt++)
                h[mt][nt] = __builtin_amdgcn_mfma_f32_16x16x32_bf16(aw, xf[nt], h[mt][nt], 0, 0, 0);
        }
#pragma unroll
        for (int mt = 0; mt < 2; mt++)
#pragma unroll
            for (int nt = 0; nt < 4; nt++) {
                unsigned lo = f2bf(fmaxf(h[mt][nt][0], 0.f)) |
                              ((unsigned)f2bf(fmaxf(h[mt][nt][1], 0.f)) << 16);
                unsigned hi = f2bf(fmaxf(h[mt][nt][2], 0.f)) |
                              ((unsigned)f2bf(fmaxf(h[mt][nt][3], 0.f)) << 16);
                uint2 pk; pk.x = lo; pk.y = hi;
                *(uint2*)(myH + (nt * 16 + lr) * 48 + mt * 16 + lg * 4) = pk;
            }
        bf16x8 aw2 = *(const bf16x8*)(W2p + (size_t)(ch * 64 + l) * 8);
#pragma unroll
        for (int nt = 0; nt < 4; nt++) {
            bf16x8 hf = *(const bf16x8*)(myH + (nt * 16 + lr) * 48 + lg * 8);
            d2[nt] = __builtin_amdgcn_mfma_f32_16x16x32_bf16(aw2, hf, d2[nt], 0, 0, 0);
        }
    }
#pragma unroll
    for (int nt = 0; nt < 4; nt++)
#pragma unroll
        for (int r = 0; r < 4; r++) {
            int p = lg * 4 + r;
            if (p < 12) {
                int ll = lbase + nt * 16 + lr;
                eco[((size_t)(b * 12 + p) * 1024 + n) * 256 + ll] = f2bf(d2[nt][r]);
            }
        }
}

// fused fc1(bf16 MFMA)+relu+fc2: 16 rows/block; bf16 gated/eco/hd inputs; grid = CB*768
__global__ __launch_bounds__(256) void k_fc(const unsigned short* gated, const unsigned short* eco,
        const unsigned short* hd_emb, const float* hist, const float* tide, const float* diwe,
        const unsigned short* W1p, const float* B1, const float* W2, const float* B2,
        float* fbuf) {
    __shared__ unsigned short Abuf[16 * 480];   // 15360 B, XOR-swizzled rows of 960 B
    __shared__ unsigned short Hbuf[16 * 512];   // 16384 B, XOR-swizzled rows of 1024 B
    int t = threadIdx.x;
    int wave = t >> 6, l = t & 63;
    int lr = l & 15, lg = l >> 4;
    int row0 = blockIdx.x * 16;
#pragma unroll
    for (int it = 0; it < 8; it++) {
        int idx = it * 256 + t;                 // 1920 chunks of 4 elements
        if (idx < 1920) {
            int row = idx / 120;
            int col = (idx - row * 120) * 4;
            int grow = row0 + row;
            int n = grow & 1023, bt = grow >> 10;
            int b = bt / 12, tt = bt - b * 12;
            unsigned short w[4];
            if (col < 128) {
                uint2 raw = *(const uint2*)&gated[(size_t)grow * 128 + col];
                w[0] = raw.x & 0xffff; w[1] = raw.x >> 16;
                w[2] = raw.y & 0xffff; w[3] = raw.y >> 16;
            } else if (col < 384) {
                uint2 raw = *(const uint2*)&eco[(size_t)((b * 12 + tt) * 1024 + n) * 256 + (col - 128)];
                w[0] = raw.x & 0xffff; w[1] = raw.x >> 16;
                w[2] = raw.y & 0xffff; w[3] = raw.y >> 16;
            } else if (col < 396) {
                int tid_i = (int)(hist[(size_t)grow * 4 + 2] * 288.0f);
#pragma unroll
                for (int q = 0; q < 4; q++) w[q] = f2bf(fmaxf(tide[tid_i * 12 + col - 384 + q], 0.f));
            } else if (col < 408) {
                int diw_i = (int)hist[(size_t)grow * 4 + 3];
#pragma unroll
                for (int q = 0; q < 4; q++) w[q] = f2bf(fmaxf(diwe[diw_i * 12 + col - 396 + q], 0.f));
            } else if (col < 472) {
                uint2 raw = *(const uint2*)&hd_emb[(size_t)grow * 64 + col - 408];
                w[0] = raw.x & 0xffff; w[1] = raw.x >> 16;
                w[2] = raw.y & 0xffff; w[3] = raw.y >> 16;
            } else {
#pragma unroll
                for (int q = 0; q < 4; q++) w[q] = 0;
            }
#pragma unroll
            for (int q = 0; q < 4; q++) if (w[q] >> 15) w[q] = 0;   // relu on bf16 bits
            uint2 pk;
            pk.x = w[0] | ((unsigned)w[1] << 16);
            pk.y = w[2] | ((unsigned)w[3] << 16);
            int byte = (row * 960 + col * 2) ^ ((row & 7) << 4);
            *(uint2*)((char*)Abuf + byte) = pk;
        }
    }
    __syncthreads();
    int colg0 = wave * 128;
    f32x4 acc[8];
#pragma unroll
    for (int nb = 0; nb < 8; nb++) {
        float bv = B1[colg0 + nb * 16 + lr];
        f32x4 c; c[0] = bv; c[1] = bv; c[2] = bv; c[3] = bv;
        acc[nb] = c;
    }
#pragma unroll
    for (int kb = 0; kb < 15; kb++) {
        int k2 = (kb * 32 + lg * 8) * 2;
        int by0 = (lr * 960 + k2) ^ ((lr & 7) << 4);
        bf16x8 a0 = *(const bf16x8*)((char*)Abuf + by0);
#pragma unroll
        for (int nb = 0; nb < 8; nb++) {
            int nbg = wave * 8 + nb;
            bf16x8 bw = *(const bf16x8*)(W1p + (size_t)((kb * 32 + nbg) * 64 + l) * 8);
            acc[nb] = __builtin_amdgcn_mfma_f32_16x16x32_bf16(a0, bw, acc[nb], 0, 0, 0);
        }
    }
#pragma unroll
    for (int nb = 0; nb < 8; nb++)
#pragma unroll
        for (int r = 0; r < 4; r++) {
            int row = lg * 4 + r;
            int col = colg0 + nb * 16 + lr;
            unsigned short h = f2bf(fmaxf(acc[nb][r], 0.f));
            int byte = (row * 1024 + col * 2) ^ ((row & 7) << 4);
            *(unsigned short*)((char*)Hbuf + byte) = h;
        }
    __syncthreads();
    float* redp = (float*)Abuf;
    {
        int rsub = t >> 5, seg = t & 31;
#pragma unroll
        for (int rg = 0; rg < 2; rg++) {
            int r = rg * 8 + rsub;
            float p0 = 0.f, p1 = 0.f, p2 = 0.f;
#pragma unroll
            for (int j = 0; j < 16; j++) {
                int k = seg + j * 32;
                int byte = (r * 1024 + k * 2) ^ ((r & 7) << 4);
                float h = bf2f(*(const unsigned short*)((char*)Hbuf + byte));
                p0 += h * W2[k * 3];
                p1 += h * W2[k * 3 + 1];
                p2 += h * W2[k * 3 + 2];
            }
            redp[r * 96 + seg] = p0;
            redp[r * 96 + 32 + seg] = p1;
            redp[r * 96 + 64 + seg] = p2;
        }
    }
    __syncthreads();
    if (t < 48) {
        int rr = t / 3, p = t - rr * 3;
        float s = B2[p];
        for (int seg = 0; seg < 32; seg++) s += redp[rr * 96 + p * 32 + seg];
        fbuf[(size_t)(row0 + rr) * 3 + p] = s;
    }
}

// final conv1x1 over time + transpose; grid = CB*48
__global__ void k_ec3(const float* f, const float* W, const float* bv, float* out) {
    int idx = blockIdx.x * 256 + threadIdx.x;
    int l = idx % 3;
    int rest = idx / 3;
    int o = rest & 3;
    int n = (rest >> 2) & 1023;
    int b = rest >> 12;
    float s = bv[o];
#pragma unroll
    for (int c = 0; c < 12; c++)
        s += f[(size_t)((b * 12 + c) * 1024 + n) * 3 + l] * W[o * 12 + c];
    out[idx] = s;
}

// ---------------- launcher ----------------
extern "C" void kernel_launch(void* const* d_in, const int* in_sizes, int n_in,
                              void* d_out, int out_size, void* d_ws, size_t ws_size,
                              hipStream_t stream) {
    const float* hist = (const float*)d_in[0];
    const float* node_emb_u = (const float*)d_in[1];
    const float* T_i_D_emb = (const float*)d_in[2];
    const float* D_i_W_emb = (const float*)d_in[3];
    const float* gc_emb1 = (const float*)d_in[4];
    const float* gc_emb2 = (const float*)d_in[5];
    const float* gc_w1 = (const float*)d_in[6];
    const float* gc_b1 = (const float*)d_in[7];
    const float* gc_w2 = (const float*)d_in[8];
    const float* gc_b2 = (const float*)d_in[9];
    const float* W_emb = (const float*)d_in[10];
    const float* b_emb = (const float*)d_in[11];
    const float* Wg1 = (const float*)d_in[12];
    const float* bg1 = (const float*)d_in[13];
    const float* Wg2 = (const float*)d_in[14];
    const float* bg2 = (const float*)d_in[15];
    const float* Wsc = (const float*)d_in[16];
    const float* bsc = (const float*)d_in[17];
    const float* mix1_w = (const float*)d_in[18];
    const float* mix1_b = (const float*)d_in[19];
    const float* mix2_w = (const float*)d_in[20];
    const float* mix2_b = (const float*)d_in[21];
    const float* Wtf1 = (const float*)d_in[22];
    const float* btf1 = (const float*)d_in[23];
    const float* Wtf2 = (const float*)d_in[24];
    const float* btf2 = (const float*)d_in[25];
    const float* Wec1 = (const float*)d_in[26];
    const float* bec1 = (const float*)d_in[27];
    const float* Wec2 = (const float*)d_in[28];
    const float* bec2 = (const float*)d_in[29];
    const float* Wfc1 = (const float*)d_in[30];
    const float* bfc1 = (const float*)d_in[31];
    const float* Wfc2 = (const float*)d_in[32];
    const float* bfc2 = (const float*)d_in[33];
    const float* Wec3 = (const float*)d_in[34];
    const float* bec3 = (const float*)d_in[35];

    float* ws = (float*)d_ws;
    float* n1 = ws + F_N1;
    float* n2 = ws + F_N2;
    float* aN_val = ws + F_ANVAL;
    float* row_val = ws + F_ROWVAL;
    float* col_sum = ws + F_COLSUM;
    float* inv_cs = ws + F_INVCS;
    float* aT_val = ws + F_ATVAL;
    int* aN_idx = (int*)(ws + I_ANIDX);
    int* row_idx = (int*)(ws + I_ROWIDX);
    int* col_cnt = (int*)(ws + I_COLCNT);
    int* col_off = (int*)(ws + I_COLOFF);
    int* col_fill = (int*)(ws + I_COLFILL);
    int* aT_idx = (int*)(ws + I_ATIDX);
    unsigned short* w1p = (unsigned short*)(ws + F_W1P);
    unsigned short* w2p = (unsigned short*)(ws + F_W2P);
    unsigned short* wfcp = (unsigned short*)(ws + F_WFCP);
    unsigned short* wec1p = (unsigned short*)(ws + F_WEC1P);
    unsigned short* wec2p = (unsigned short*)(ws + F_WEC2P);
    unsigned short* wmwp = (unsigned short*)(ws + F_WMWP);

    // pick largest batch-chunk CB that fits the workspace
    size_t avail = ws_size / 4;   // floats
    int CB = 8;
    while (CB > 1 && GRAPH_FLOATS + (size_t)CB * PB_TOTAL > avail) CB >>= 1;
    int nchunk = 8 / CB;

    unsigned short* gated = (unsigned short*)(ws + GRAPH_FLOATS);
    unsigned short* hd_emb = (unsigned short*)(ws + GRAPH_FLOATS + (size_t)CB * PB_GATED);
    unsigned short* xs = (unsigned short*)(ws + GRAPH_FLOATS + (size_t)CB * (PB_GATED + PB_HD));
    unsigned short* h1 = xs + (size_t)CB * PB_X * 2;
    unsigned short* h2 = h1 + (size_t)CB * PB_X * 2;
    unsigned short* h1b = h2 + (size_t)CB * PB_X * 2;
    unsigned short* h2b = h1b + (size_t)CB * PB_X * 2;
    unsigned short* mix = h2b + (size_t)CB * PB_X * 2;
    unsigned short* eco = xs;        // alias: xs+h1 region (CB*4M u16) >= eco (CB*3M u16)
    float* fbuf = (float*)h2b;       // alias: h2b dead by k_fc

    // ---- graph construction + weight packing (once) ----
    k_init<<<4, 256, 0, stream>>>(col_cnt, col_fill, col_sum);
    k_embed<<<320, 256, 0, stream>>>(gc_emb1, gc_emb2, gc_w1, gc_b1, gc_w2, gc_b2, n1, n2);
    k_adj<<<1024, 256, 0, stream>>>(n1, n2, aN_val, aN_idx, row_val, row_idx, col_cnt, col_sum);
    k_scan<<<1, 1024, 0, stream>>>(col_cnt, col_off, col_sum, inv_cs);
    k_scatter<<<40, 256, 0, stream>>>(row_idx, row_val, col_off, col_fill, aT_idx, aT_val);
    k_packw<<<32, 256, 0, stream>>>(Wtf1, w1p);
    k_packw<<<32, 256, 0, stream>>>(Wtf2, w2p);
    k_packfc<<<120, 256, 0, stream>>>(Wfc1, wfcp);
    k_packec<<<3, 256, 0, stream>>>(Wec1, Wec2, wec1p, wec2p);
    k_packmw<<<6, 256, 0, stream>>>(mix1_w, mix2_w, wmwp);

    // ---- per-chunk pipeline ----
    for (int ch = 0; ch < nchunk; ch++) {
        const float* hist_c = hist + (size_t)ch * CB * ROWS_PER_B * 4;
        float* out_c = (float*)d_out + (size_t)ch * CB * ROWS_PER_B;

        k_gate<<<CB * 3072, 256, 0, stream>>>(hist_c, node_emb_u, T_i_D_emb, D_i_W_emb,
                                              Wg1, bg1, Wg2, bg2, W_emb, b_emb, gated, hd_emb);
        for (int xp = 0; xp < 2; xp++) {
            k_wsc<<<CB * 256, 256, 0, stream>>>(gated, Wsc, bsc, xs, xp * 64);
            k_spmm2<<<CB * 1024, 256, 0, stream>>>(h1, h1b, xs, xs, xs,
                                                   aN_idx, aN_val, aT_idx, aT_val,
                                                   col_off, inv_cs);
            k_spmm2<<<CB * 1024, 256, 0, stream>>>(h2, h2b, xs, h1, h1b,
                                                   aN_idx, aN_val, aT_idx, aT_val,
                                                   col_off, inv_cs);
            k_proj<<<CB * 1024, 256, 0, stream>>>(xs, h1, h2, h1b, h2b,
                                                  wmwp, mix1_b, mix2_b, mix, xp);
        }
        k_tf<<<CB * 1024, 256, 0, stream>>>(mix, w1p, btf1, w2p, btf2);
        k_ec<<<CB * 1024, 256, 0, stream>>>(mix, wec1p, bec1, wec2p, bec2, eco);
        k_fc<<<CB * 768, 256, 0, stream>>>(gated, eco, hd_emb, hist_c, T_i_D_emb, D_i_W_emb,
                                           wfcp, bfc1, Wfc2, bfc2, fbuf);
        k_ec3<<<CB * 48, 256, 0, stream>>>(fbuf, Wec3, bec3, out_c);
    }
}

// Round 13
// 1186.817 us; speedup vs baseline: 4.0864x; 1.0511x over previous
//
#include <hip/hip_runtime.h>
#include <math.h>

// ---------------- constants ----------------
constexpr int ROWS_PER_B = 12 * 1024;    // rows (b,t,n) per batch element

// ---------------- graph workspace (float offsets, < 524288) ----------------
constexpr size_t F_N1 = 0;              // 1024*40
constexpr size_t F_N2 = 40960;
constexpr size_t F_ANVAL = 81920;       // 1024*11
constexpr size_t F_ROWVAL = 93184;      // 1024*10
constexpr size_t F_COLSUM = 103424;     // 1024
constexpr size_t F_INVCS = 104448;      // 1024
constexpr size_t F_ATVAL = 105472;      // 10240
constexpr size_t I_ANIDX = 115712;      // ints stored in float slots
constexpr size_t I_ROWIDX = 126976;
constexpr size_t I_COLCNT = 137216;
constexpr size_t I_COLOFF = 138240;     // 1025
constexpr size_t I_COLFILL = 139265;
constexpr size_t I_ATIDX = 140289;      // ends 150529
constexpr size_t F_W1P = 151552;        // packed bf16 Wtf1: 32768 floats
constexpr size_t F_W2P = 184320;        // packed bf16 Wtf2: ends 217088
constexpr size_t F_WFCP = 217088;       // packed bf16 Wfc1: ends 339968
constexpr size_t F_WEC1P = 339968;      // packed bf16 Wec1
constexpr size_t F_WEC2P = 342016;      // packed bf16 Wec2 -> ends 343040
constexpr size_t F_WMWP = 343040;       // packed bf16 mix weights -> ends 349184
constexpr size_t GRAPH_FLOATS = 524288;

// per-chunk float-unit counts (per batch element) — bf16 storage
constexpr size_t PB_GATED = (size_t)ROWS_PER_B * 128 / 2;   // 786432
constexpr size_t PB_HD = (size_t)ROWS_PER_B * 64 / 2;       // 393216
constexpr size_t PB_X = (size_t)32 * 1024 * 64 / 2;         // 1048576 (xs,h1,h2,h1b,h2b)
constexpr size_t PB_MIX = (size_t)32 * 1024 * 256 / 2;      // 4194304
constexpr size_t PB_TOTAL = PB_GATED + PB_HD + 5 * PB_X + PB_MIX; // 10616832

typedef __attribute__((ext_vector_type(8))) short bf16x8;
typedef __attribute__((ext_vector_type(4))) float f32x4;

__device__ __forceinline__ unsigned short f2bf(float f) {
    unsigned u = __float_as_uint(f);
    unsigned r = (u + 0x7fffu + ((u >> 16) & 1u)) >> 16;   // RNE
    return (unsigned short)r;
}
__device__ __forceinline__ float bf2f(unsigned short h) {
    return __uint_as_float((unsigned)h << 16);
}
__device__ __forceinline__ void unpack8(uint4 raw, float* f) {
    f[0] = bf2f((unsigned short)(raw.x & 0xffff)); f[1] = bf2f((unsigned short)(raw.x >> 16));
    f[2] = bf2f((unsigned short)(raw.y & 0xffff)); f[3] = bf2f((unsigned short)(raw.y >> 16));
    f[4] = bf2f((unsigned short)(raw.z & 0xffff)); f[5] = bf2f((unsigned short)(raw.z >> 16));
    f[6] = bf2f((unsigned short)(raw.w & 0xffff)); f[7] = bf2f((unsigned short)(raw.w >> 16));
}
__device__ __forceinline__ uint4 pack8(const float* f) {
    uint4 r;
    r.x = f2bf(f[0]) | ((unsigned)f2bf(f[1]) << 16);
    r.y = f2bf(f[2]) | ((unsigned)f2bf(f[3]) << 16);
    r.z = f2bf(f[4]) | ((unsigned)f2bf(f[5]) << 16);
    r.w = f2bf(f[6]) | ((unsigned)f2bf(f[7]) << 16);
    return r;
}
__device__ __forceinline__ bf16x8 relu8(bf16x8 v) {
#pragma unroll
    for (int j = 0; j < 8; j++) {
        unsigned short u = (unsigned short)v[j];
        v[j] = (short)((u >> 15) ? 0 : u);
    }
    return v;
}

// ---------------- graph kernels ----------------

__global__ void k_init(int* cnt, int* fill, float* csum) {
    int t = blockIdx.x * 256 + threadIdx.x;
    if (t < 1024) { cnt[t] = 0; fill[t] = 0; csum[t] = 0.f; }
}

__global__ void k_embed(const float* e1, const float* e2, const float* w1, const float* b1,
                        const float* w2, const float* b2, float* n1, float* n2) {
    int idx = blockIdx.x * 256 + threadIdx.x;   // < 81920
    if (idx >= 81920) return;
    int m = idx / 40960, rem = idx - m * 40960;
    int i = rem / 40, j = rem - i * 40;
    const float* e = m ? e2 : e1;
    const float* w = m ? w2 : w1;
    const float* bv = m ? b2 : b1;
    float a = bv[j];
    for (int k = 0; k < 40; k++) a += e[i * 40 + k] * w[k * 40 + j];
    (m ? n2 : n1)[i * 40 + j] = tanhf(3.0f * a);
}

__global__ __launch_bounds__(256) void k_adj(const float* n1, const float* n2,
        float* aN_val, int* aN_idx, float* row_val, int* row_idx,
        int* col_cnt, float* col_sum) {
    __shared__ float arow[1024];
    __shared__ float n1v[40], n2v[40];
    __shared__ float rv[256];
    __shared__ int ri[256];
    __shared__ float topv[10];
    __shared__ int topi[10];
    int v = blockIdx.x, t = threadIdx.x;
    if (t < 40) { n1v[t] = n1[v * 40 + t]; n2v[t] = n2[v * 40 + t]; }
    __syncthreads();
    for (int j = t; j < 1024; j += 256) {
        float d1 = 0.f, d2 = 0.f;
        for (int k = 0; k < 40; k++) {
            d1 += n1v[k] * n2[j * 40 + k];
            d2 += n2v[k] * n1[j * 40 + k];
        }
        float a = tanhf(3.0f * (d1 - d2));
        arow[j] = a > 0.f ? a : 0.f;
    }
    __syncthreads();
    for (int r = 0; r < 10; r++) {
        float bv = -1.f; int bi = 1 << 30;
        for (int j = t; j < 1024; j += 256) {
            float x = arow[j];
            if (x > bv || (x == bv && j < bi)) { bv = x; bi = j; }
        }
        rv[t] = bv; ri[t] = bi;
        __syncthreads();
        for (int s = 128; s > 0; s >>= 1) {
            if (t < s) {
                float ov = rv[t + s]; int oi = ri[t + s];
                if (ov > rv[t] || (ov == rv[t] && oi < ri[t])) { rv[t] = ov; ri[t] = oi; }
            }
            __syncthreads();
        }
        if (t == 0) { topv[r] = rv[0]; topi[r] = ri[0]; arow[ri[0]] = -1.f; }
        __syncthreads();
    }
    if (t == 0) {
        float s = 1.f;
        for (int r = 0; r < 10; r++) s += topv[r];
        float inv = 1.f / s;
        for (int r = 0; r < 10; r++) {
            aN_idx[v * 11 + r] = topi[r];
            aN_val[v * 11 + r] = topv[r] * inv;
            row_idx[v * 10 + r] = topi[r];
            row_val[v * 10 + r] = topv[r];
            atomicAdd(&col_cnt[topi[r]], 1);
            atomicAdd(&col_sum[topi[r]], topv[r]);
        }
        aN_idx[v * 11 + 10] = v;
        aN_val[v * 11 + 10] = inv;
    }
}

__global__ __launch_bounds__(1024) void k_scan(const int* cnt, int* off,
                                               const float* csum, float* inv) {
    __shared__ int tmp[1024];
    int t = threadIdx.x;
    tmp[t] = cnt[t];
    __syncthreads();
    for (int s = 1; s < 1024; s <<= 1) {
        int v = 0;
        if (t >= s) v = tmp[t - s];
        __syncthreads();
        tmp[t] += v;
        __syncthreads();
    }
    off[t + 1] = tmp[t];
    if (t == 0) off[0] = 0;
    inv[t] = 1.0f / (csum[t] + 1.0f);
}

__global__ void k_scatter(const int* row_idx, const float* row_val, const int* off,
                          int* fill, int* aT_idx, float* aT_val) {
    int e = blockIdx.x * 256 + threadIdx.x;
    if (e >= 10240) return;
    int v = e / 10;
    int j = row_idx[e];
    int pos = off[j] + atomicAdd(&fill[j], 1);
    aT_idx[pos] = v;
    aT_val[pos] = row_val[e];
}

// pack 256x256 f32 weight into MFMA B-fragment order
__global__ void k_packw(const float* W, unsigned short* out) {
    int id = blockIdx.x * 256 + threadIdx.x;    // 8192 total
    if (id >= 8192) return;
    int lane = id & 63, rest = id >> 6;
    int nb = rest & 15, kb = rest >> 4;
    int krow = kb * 32 + (lane >> 4) * 8;
    int col = nb * 16 + (lane & 15);
    unsigned short v[8];
#pragma unroll
    for (int j = 0; j < 8; j++) v[j] = f2bf(W[(size_t)(krow + j) * 256 + col]);
#pragma unroll
    for (int j = 0; j < 8; j++) out[(size_t)id * 8 + j] = v[j];
}

// pack 472x512 Wfc1 into B-fragment order, K padded to 480
__global__ void k_packfc(const float* W, unsigned short* out) {
    int id = blockIdx.x * 256 + threadIdx.x;    // 30720 total
    if (id >= 30720) return;
    int lane = id & 63, rest = id >> 6;
    int nb = rest & 31, kb = rest >> 5;         // kb < 15
    int k0 = kb * 32 + (lane >> 4) * 8;
    int col = nb * 16 + (lane & 15);
    unsigned short v[8];
#pragma unroll
    for (int j = 0; j < 8; j++) {
        int k = k0 + j;
        v[j] = (k < 472) ? f2bf(W[(size_t)k * 512 + col]) : (unsigned short)0;
    }
#pragma unroll
    for (int j = 0; j < 8; j++) out[(size_t)id * 8 + j] = v[j];
}

// pack Wec1 (128x32) and Wec2 (12x128, pad 16) into A-frag order
__global__ void k_packec(const float* W1, const float* W2,
                         unsigned short* o1, unsigned short* o2) {
    int id = blockIdx.x * 256 + threadIdx.x;    // 768 total
    if (id < 512) {
        int mt = id >> 6, lane = id & 63;
        int o = mt * 16 + (lane & 15);
        int c0 = (lane >> 4) * 8;
#pragma unroll
        for (int j = 0; j < 8; j++)
            o1[(size_t)id * 8 + j] = f2bf(W1[o * 32 + c0 + j]);
    } else if (id < 768) {
        int id2 = id - 512;
        int kb = id2 >> 6, lane = id2 & 63;
        int p = lane & 15;
        int k0 = kb * 32 + (lane >> 4) * 8;
#pragma unroll
        for (int j = 0; j < 8; j++)
            o2[(size_t)id2 * 8 + j] = (p < 12) ? f2bf(W2[p * 128 + k0 + j])
                                               : (unsigned short)0;
    }
}

// pack mix weights [64 rows][192 K] into A-frag order (24 frags)
__global__ void k_packmw(const float* mw1, const float* mw2, unsigned short* out) {
    int id = blockIdx.x * 256 + threadIdx.x;    // 1536 total
    if (id >= 1536) return;
    int f = id >> 6, lane = id & 63;
    int kb = f >> 2, rt = f & 3;
    int row = rt * 16 + (lane & 15);
    int ph = (kb >= 3) ? 1 : 0;
    int kloc = (kb - ph * 3) * 32 + (lane >> 4) * 8;
    const float* mw = ph ? mw2 : mw1;
#pragma unroll
    for (int j = 0; j < 8; j++)
        out[(size_t)id * 8 + j] = f2bf(mw[row * 96 + kloc + j]);
}

// ---------------- per-chunk kernels ----------------

// gate MLP + embed; outputs bf16; grid = CB*3072
__global__ __launch_bounds__(256) void k_gate(const float* hist, const float* nodeu,
        const float* tide, const float* diwe,
        const float* Wg1, const float* bg1, const float* Wg2, const float* bg2,
        const float* Wemb, const float* bemb, unsigned short* gated, unsigned short* hd_emb) {
    __shared__ float w1[4096], w2[4096];
    __shared__ float gin[4][64], hid[4][64];
    __shared__ float sb1[64], sb2[64], we[128], be[64];
    int t = threadIdx.x;
    for (int i = t; i < 4096; i += 256) { w1[i] = Wg1[i]; w2[i] = Wg2[i]; }
    if (t < 64) { sb1[t] = bg1[t]; sb2[t] = bg2[t]; be[t] = bemb[t]; }
    if (t < 128) we[t] = Wemb[t];
    int r = t >> 6, lane = t & 63;
    int row = blockIdx.x * 4 + r;
    int n = row & 1023;
    const float* hrow = hist + (size_t)row * 4;
    float f0 = hrow[0], f1 = hrow[1];
    int tid_i = (int)(hrow[2] * 288.0f);
    int diw_i = (int)hrow[3];
    float g;
    if (lane < 40) g = nodeu[n * 40 + lane];
    else if (lane < 52) g = tide[tid_i * 12 + lane - 40];
    else g = diwe[diw_i * 12 + lane - 52];
    gin[r][lane] = g;
    __syncthreads();
    float acc = sb1[lane];
    for (int k = 0; k < 64; k++) acc += gin[r][k] * w1[k * 64 + lane];
    hid[r][lane] = acc > 0.f ? acc : 0.f;
    __syncthreads();
    acc = sb2[lane];
    for (int k = 0; k < 64; k++) acc += hid[r][k] * w2[k * 64 + lane];
    float gate = 1.f / (1.f + expf(-acc));
    float hd = f0 * we[lane] + f1 * we[64 + lane] + be[lane];
    float x1 = gate * hd;
    gated[(size_t)row * 128 + lane] = f2bf(x1);
    gated[(size_t)row * 128 + 64 + lane] = f2bf(hd - x1);
    hd_emb[(size_t)row * 64 + lane] = f2bf(hd);
}

// xs = relu(sum_t gated*Wsc + bsc), bf16 in/out; grid = CB*256
__global__ __launch_bounds__(256) void k_wsc(const unsigned short* gated, const float* Wsc,
                                             const float* bsc, unsigned short* xs, int xoff) {
    __shared__ float w[384];
    __shared__ float sb[32];
    int t = threadIdx.x;
    if (t < 384) w[t] = Wsc[t];
    if (t < 32) sb[t] = bsc[t];
    __syncthreads();
    int idx = blockIdx.x * 256 + t;
    int h = idx & 63, n = (idx >> 6) & 1023, b = idx >> 16;
    float xv[12];
#pragma unroll
    for (int tt = 0; tt < 12; tt++)
        xv[tt] = bf2f(gated[(size_t)((b * 12 + tt) * 1024 + n) * 128 + xoff + h]);
#pragma unroll
    for (int o = 0; o < 32; o++) {
        float a = sb[o];
#pragma unroll
        for (int tt = 0; tt < 12; tt++) a += xv[tt] * w[o * 12 + tt];
        xs[(size_t)((b * 32 + o) * 1024 + n) * 64 + h] = f2bf(a > 0.f ? a : 0.f);
    }
}

// fused dual spmm: out1 = 0.05x + 0.95*aN@hin1, out2 = 0.05x + 0.95*aTN@hin2
// bf16 in/out; XCD-swizzled blocks; grid = CB*1024 (32 rows/block)
__global__ __launch_bounds__(256) void k_spmm2(unsigned short* out1, unsigned short* out2,
        const unsigned short* x, const unsigned short* hin1, const unsigned short* hin2,
        const int* aN_idx, const float* aN_val,
        const int* aT_idx, const float* aT_val,
        const int* off, const float* inv_cs) {
    int nper = gridDim.x >> 3;
    int bid = (blockIdx.x & 7) * nper + (blockIdx.x >> 3);   // same-bc blocks -> same XCD
    int t = threadIdx.x;
    int l8 = t & 7, r = t >> 3;             // 32 rows x 8 16B-lanes
    int g = bid * 32 + r;
    int v = g & 1023, bc = g >> 10;
    size_t rowoff = (size_t)bc * 65536;
    float hv[8];
    // ---- aN path (11 fixed edges) ----
    const unsigned short* base1 = hin1 + rowoff;
    float s1[8];
#pragma unroll
    for (int j = 0; j < 8; j++) s1[j] = 0.f;
#pragma unroll
    for (int e = 0; e < 11; e++) {
        int w = aN_idx[v * 11 + e];
        float a = aN_val[v * 11 + e];
        uint4 raw = *(const uint4*)(base1 + (size_t)w * 64 + l8 * 8);
        unpack8(raw, hv);
#pragma unroll
        for (int j = 0; j < 8; j++) s1[j] += a * hv[j];
    }
    // ---- aTN path (CSC, variable degree) ----
    const unsigned short* base2 = hin2 + rowoff;
    float s2[8];
    {
        uint4 raw = *(const uint4*)(base2 + (size_t)v * 64 + l8 * 8);
        unpack8(raw, s2);
        int e0 = off[v], e1 = off[v + 1];
        for (int e = e0; e < e1; e++) {
            int w = aT_idx[e];
            float a = aT_val[e];
            uint4 rw = *(const uint4*)(base2 + (size_t)w * 64 + l8 * 8);
            unpack8(rw, hv);
#pragma unroll
            for (int j = 0; j < 8; j++) s2[j] += a * hv[j];
        }
        float ic = inv_cs[v];
#pragma unroll
        for (int j = 0; j < 8; j++) s2[j] *= ic;
    }
    // ---- combine with x ----
    uint4 xr = *(const uint4*)(x + (size_t)g * 64 + l8 * 8);
    float xv[8];
    unpack8(xr, xv);
    float o1[8], o2[8];
#pragma unroll
    for (int j = 0; j < 8; j++) {
        float xb = 0.05f * xv[j];
        o1[j] = xb + 0.95f * s1[j];
        o2[j] = xb + 0.95f * s2[j];
    }
    *(uint4*)(out1 + (size_t)g * 64 + l8 * 8) = pack8(o1);
    *(uint4*)(out2 + (size_t)g * 64 + l8 * 8) = pack8(o2);
}

// mix projection via bf16 MFMA: block = (b,n), 4 waves; grid = CB*1024
__global__ __launch_bounds__(256) void k_proj(const unsigned short* xs,
        const unsigned short* h1, const unsigned short* h2,
        const unsigned short* h1b, const unsigned short* h2b,
        const unsigned short* mwp, const float* m1b, const float* m2b,
        unsigned short* mix, int xp) {
    __shared__ unsigned short Bf[24 * 64 * 8];   // 24 shared B-frags, frag layout, 24 KB
    int t = threadIdx.x;
    int wave = t >> 6, l = t & 63;
    int lr = l & 15, lg = l >> 4;
    int b = blockIdx.x >> 10, n = blockIdx.x & 1023;
    // ---- cooperative B-frag gather: 6 frags per wave ----
#pragma unroll
    for (int i = 0; i < 6; i++) {
        int f = wave * 6 + i;
        int kb = f >> 2, nt = f & 3;
        int ph = (kb >= 3) ? 1 : 0;
        int q = kb - ph * 3;
        const unsigned short* Hq = (q == 0) ? xs : (q == 1 ? (ph ? h1b : h1)
                                                           : (ph ? h2b : h2));
        const unsigned short* src = Hq + ((size_t)(b * 32 + lg * 8) * 1024 + n) * 64
                                       + nt * 16 + lr;
        bf16x8 v;
#pragma unroll
        for (int j = 0; j < 8; j++)
            v[j] = (short)src[(size_t)j * 65536];
        *(bf16x8*)(Bf + ((size_t)f * 64 + l) * 8) = v;
    }
    __syncthreads();
    // ---- wave = row-tile; 4 col-tiles; K = 6 blocks of 32 ----
    f32x4 acc[4];
#pragma unroll
    for (int nt = 0; nt < 4; nt++) {
        f32x4 c;
#pragma unroll
        for (int r = 0; r < 4; r++) {
            int row = wave * 16 + lg * 4 + r;
            c[r] = m1b[row] + m2b[row];
        }
        acc[nt] = c;
    }
#pragma unroll
    for (int kb = 0; kb < 6; kb++) {
        bf16x8 af = *(const bf16x8*)(mwp + (size_t)((kb * 4 + wave) * 64 + l) * 8);
#pragma unroll
        for (int nt = 0; nt < 4; nt++) {
            bf16x8 bfv = *(const bf16x8*)(Bf + ((size_t)(kb * 4 + nt) * 64 + l) * 8);
            acc[nt] = __builtin_amdgcn_mfma_f32_16x16x32_bf16(af, bfv, acc[nt], 0, 0, 0);
        }
    }
#pragma unroll
    for (int nt = 0; nt < 4; nt++)
#pragma unroll
        for (int r = 0; r < 4; r++) {
            int row = wave * 16 + lg * 4 + r;
            int i2 = row >> 5, o = row & 31;
            mix[(size_t)((b * 32 + o) * 1024 + n) * 256 + (i2 * 2 + xp) * 64 + nt * 16 + lr]
                = f2bf(acc[nt][r]);
        }
}

// fused Wtf1(relu)Wtf2 via bf16 MFMA, in-place on bf16 mix: 32 rows/block; grid = CB*1024
__global__ __launch_bounds__(256) void k_tf(unsigned short* mix, const unsigned short* W1p,
                                            const float* B1, const unsigned short* W2p,
                                            const float* B2) {
    __shared__ unsigned short Abuf[32 * 256];   // bf16, XOR-swizzled
    __shared__ unsigned short Hbuf[32 * 256];
    int t = threadIdx.x;
    int wave = t >> 6, l = t & 63;
    size_t row0 = (size_t)blockIdx.x * 32;
    const uint4* src = (const uint4*)(mix + row0 * 256);
#pragma unroll
    for (int it = 0; it < 4; it++) {
        int f = t + it * 256;                  // 1024 8-u16 chunks
        uint4 raw = src[f];
        int e = f * 8, row = e >> 8, col = e & 255;
        int byte = (row * 512 + col * 2) ^ ((row & 7) << 4);
        *(uint4*)((char*)Abuf + byte) = raw;
    }
    __syncthreads();
    int colg0 = wave * 64;
    int lr = l & 15, lg = l >> 4;
    f32x4 acc[2][4];
#pragma unroll
    for (int nb = 0; nb < 4; nb++) {
        float bv = B1[colg0 + nb * 16 + lr];
        f32x4 c; c[0] = bv; c[1] = bv; c[2] = bv; c[3] = bv;
        acc[0][nb] = c; acc[1][nb] = c;
    }
#pragma unroll
    for (int kb = 0; kb < 8; kb++) {
        int k2 = (kb * 32 + lg * 8) * 2;
        int by0 = (lr * 512 + k2) ^ ((lr & 7) << 4);
        int by1 = ((16 + lr) * 512 + k2) ^ ((lr & 7) << 4);
        bf16x8 a0 = *(const bf16x8*)((char*)Abuf + by0);
        bf16x8 a1 = *(const bf16x8*)((char*)Abuf + by1);
#pragma unroll
        for (int nb = 0; nb < 4; nb++) {
            int nbg = wave * 4 + nb;
            bf16x8 bw = *(const bf16x8*)(W1p + (size_t)((kb * 16 + nbg) * 64 + l) * 8);
            acc[0][nb] = __builtin_amdgcn_mfma_f32_16x16x32_bf16(a0, bw, acc[0][nb], 0, 0, 0);
            acc[1][nb] = __builtin_amdgcn_mfma_f32_16x16x32_bf16(a1, bw, acc[1][nb], 0, 0, 0);
        }
    }
#pragma unroll
    for (int rb = 0; rb < 2; rb++)
#pragma unroll
        for (int nb = 0; nb < 4; nb++)
#pragma unroll
            for (int r = 0; r < 4; r++) {
                int row = rb * 16 + lg * 4 + r;
                int col = colg0 + nb * 16 + lr;
                unsigned short h = f2bf(fmaxf(acc[rb][nb][r], 0.f));
                int byte = (row * 512 + col * 2) ^ ((row & 7) << 4);
                *(unsigned short*)((char*)Hbuf + byte) = h;
            }
    __syncthreads();
#pragma unroll
    for (int nb = 0; nb < 4; nb++) {
        float bv = B2[colg0 + nb * 16 + lr];
        f32x4 c; c[0] = bv; c[1] = bv; c[2] = bv; c[3] = bv;
        acc[0][nb] = c; acc[1][nb] = c;
    }
#pragma unroll
    for (int kb = 0; kb < 8; kb++) {
        int k2 = (kb * 32 + lg * 8) * 2;
        int by0 = (lr * 512 + k2) ^ ((lr & 7) << 4);
        int by1 = ((16 + lr) * 512 + k2) ^ ((lr & 7) << 4);
        bf16x8 a0 = *(const bf16x8*)((char*)Hbuf + by0);
        bf16x8 a1 = *(const bf16x8*)((char*)Hbuf + by1);
#pragma unroll
        for (int nb = 0; nb < 4; nb++) {
            int nbg = wave * 4 + nb;
            bf16x8 bw = *(const bf16x8*)(W2p + (size_t)((kb * 16 + nbg) * 64 + l) * 8);
            acc[0][nb] = __builtin_amdgcn_mfma_f32_16x16x32_bf16(a0, bw, acc[0][nb], 0, 0, 0);
            acc[1][nb] = __builtin_amdgcn_mfma_f32_16x16x32_bf16(a1, bw, acc[1][nb], 0, 0, 0);
        }
    }
#pragma unroll
    for (int rb = 0; rb < 2; rb++)
#pragma unroll
        for (int nb = 0; nb < 4; nb++)
#pragma unroll
            for (int r = 0; r < 4; r++) {
                int row = rb * 16 + lg * 4 + r;
                int col = colg0 + nb * 16 + lr;
                mix[(row0 + row) * 256 + col] = f2bf(acc[rb][nb][r]);
            }
}

// fused ec1(relu)+ec2 via bf16 MFMA; bf16 mix in, bf16 eco out; grid = CB*1024
__global__ __launch_bounds__(256) void k_ec(const unsigned short* tfo,
        const unsigned short* W1p, const float* B1,
        const unsigned short* W2p, const float* B2, unsigned short* eco) {
    __shared__ unsigned short Hl[4 * 64 * 48];   // per-wave [64 l][48 u16] = 24 KB
    int t = threadIdx.x;
    int wave = t >> 6, l = t & 63;
    int lr = l & 15, lg = l >> 4;
    int b = blockIdx.x >> 10, n = blockIdx.x & 1023;
    int lbase = wave * 64;
    unsigned short* myH = Hl + wave * 3072;
    const unsigned short* xb = tfo + ((size_t)(b * 32) * 1024 + n) * 256;
    bf16x8 xf[4];
#pragma unroll
    for (int nt = 0; nt < 4; nt++) {
        int ll = lbase + nt * 16 + lr;
        bf16x8 v;
#pragma unroll
        for (int j = 0; j < 8; j++)
            v[j] = (short)xb[(size_t)(lg * 8 + j) * 262144 + ll];
        xf[nt] = v;
    }
    f32x4 d2[4];
    {
        f32x4 c;
#pragma unroll
        for (int r = 0; r < 4; r++) {
            int p = lg * 4 + r;
            c[r] = (p < 12) ? B2[p] : 0.f;
        }
#pragma unroll
        for (int nt = 0; nt < 4; nt++) d2[nt] = c;
    }
#pragma unroll
    for (int ch = 0; ch < 4; ch++) {
        f32x4 h[2][4];
#pragma unroll
        for (int mt = 0; mt < 2; mt++) {
            f32x4 c;
#pragma unroll
            for (int r = 0; r < 4; r++) c[r] = B1[ch * 32 + mt * 16 + lg * 4 + r];
#pragma unroll
            for (int nt = 0; nt < 4; nt++) h[mt][nt] = c;
        }
#pragma unroll
        for (int mt = 0; mt < 2; mt++) {
            bf16x8 aw = *(const bf16x8*)(W1p + (size_t)((ch * 2 + mt) * 64 + l) * 8);
#pragma unroll
            for (int nt = 0; nt < 4; nt++)
                h[mt][nt] = __builtin_amdgcn_mfma_f32_16x16x32_bf16(aw, xf[nt], h[mt][nt], 0, 0, 0);
        }
#pragma unroll
        for (int mt = 0; mt < 2; mt++)
#pragma unroll
            for (int nt = 0; nt < 4; nt++) {
                unsigned lo = f2bf(fmaxf(h[mt][nt][0], 0.f)) |
                              ((unsigned)f2bf(fmaxf(h[mt][nt][1], 0.f)) << 16);
                unsigned hi = f2bf(fmaxf(h[mt][nt][2], 0.f)) |
                              ((unsigned)f2bf(fmaxf(h[mt][nt][3], 0.f)) << 16);
                uint2 pk; pk.x = lo; pk.y = hi;
                *(uint2*)(myH + (nt * 16 + lr) * 48 + mt * 16 + lg * 4) = pk;
            }
        bf16x8 aw2 = *(const bf16x8*)(W2p + (size_t)(ch * 64 + l) * 8);
#pragma unroll
        for (int nt = 0; nt < 4; nt++) {
            bf16x8 hf = *(const bf16x8*)(myH + (nt * 16 + lr) * 48 + lg * 8);
            d2[nt] = __builtin_amdgcn_mfma_f32_16x16x32_bf16(aw2, hf, d2[nt], 0, 0, 0);
        }
    }
#pragma unroll
    for (int nt = 0; nt < 4; nt++)
#pragma unroll
        for (int r = 0; r < 4; r++) {
            int p = lg * 4 + r;
            if (p < 12) {
                int ll = lbase + nt * 16 + lr;
                eco[((size_t)(b * 12 + p) * 1024 + n) * 256 + ll] = f2bf(d2[nt][r]);
            }
        }
}

// fused fc1(bf16 MFMA)+relu+fc2: barrier-free, LDS-free; A-frags gathered in-reg.
// 16 rows/block, 4 waves x 128 cols; wave partials to pbuf[row*12 + wave*3 + p]
// grid = CB*768
__global__ __launch_bounds__(256) void k_fc(const unsigned short* gated, const unsigned short* eco,
        const unsigned short* hd_emb, const float* hist, const float* tide, const float* diwe,
        const unsigned short* W1p, const float* B1, const float* W2,
        float* pbuf) {
    int t = threadIdx.x;
    int wave = t >> 6, l = t & 63;
    int lr = l & 15, lg = l >> 4;
    int row0 = blockIdx.x * 16;
    // per-lane A-row pointers (A-frag row = lr)
    int grow = row0 + lr;
    int n = grow & 1023, bt = grow >> 10;
    int b = bt / 12, tt = bt - b * 12;
    const unsigned short* gptr = gated + (size_t)grow * 128;
    const unsigned short* eptr = eco + (size_t)((b * 12 + tt) * 1024 + n) * 256;
    const unsigned short* hptr = hd_emb + (size_t)grow * 64;
    int tid_i = (int)(hist[(size_t)grow * 4 + 2] * 288.0f);
    int diw_i = (int)hist[(size_t)grow * 4 + 3];
    int colg0 = wave * 128;
    f32x4 acc[8];
#pragma unroll
    for (int nb = 0; nb < 8; nb++) {
        float bv = B1[colg0 + nb * 16 + lr];
        f32x4 c; c[0] = bv; c[1] = bv; c[2] = bv; c[3] = bv;
        acc[nb] = c;
    }
#pragma unroll
    for (int kb = 0; kb < 15; kb++) {
        int off = kb * 32 + lg * 8;          // kb compile-time after unroll
        bf16x8 af;
        if (kb <= 3) {
            af = relu8(*(const bf16x8*)(gptr + off));
        } else if (kb <= 11) {
            af = relu8(*(const bf16x8*)(eptr + off - 128));
        } else if (kb == 12) {
#pragma unroll
            for (int j = 0; j < 8; j++) {
                int k = off + j;             // 384 + lg*8 + j
                float v;
                if (k < 396) v = tide[tid_i * 12 + k - 384];
                else if (k < 408) v = diwe[diw_i * 12 + k - 396];
                else v = bf2f(hptr[k - 408]);
                af[j] = (short)f2bf(fmaxf(v, 0.f));
            }
        } else if (kb == 13) {
            af = relu8(*(const bf16x8*)(hptr + off - 408));
        } else {                             // kb == 14: lg<3 -> hd, lg==3 -> pad
            if (lg < 3) af = relu8(*(const bf16x8*)(hptr + off - 408));
            else {
#pragma unroll
                for (int j = 0; j < 8; j++) af[j] = 0;
            }
        }
#pragma unroll
        for (int nb = 0; nb < 8; nb++) {
            bf16x8 bw = *(const bf16x8*)(W1p + (size_t)((kb * 32 + wave * 8 + nb) * 64 + l) * 8);
            acc[nb] = __builtin_amdgcn_mfma_f32_16x16x32_bf16(af, bw, acc[nb], 0, 0, 0);
        }
    }
    // ---- fc2: relu(acc) in fp32, in-register partials over this wave's 128 cols ----
    float p[4][3];
#pragma unroll
    for (int r = 0; r < 4; r++) { p[r][0] = 0.f; p[r][1] = 0.f; p[r][2] = 0.f; }
#pragma unroll
    for (int nb = 0; nb < 8; nb++) {
        int col = colg0 + nb * 16 + lr;
        float w0 = W2[col * 3], w1 = W2[col * 3 + 1], w2 = W2[col * 3 + 2];
#pragma unroll
        for (int r = 0; r < 4; r++) {
            float h = fmaxf(acc[nb][r], 0.f);
            p[r][0] += h * w0; p[r][1] += h * w1; p[r][2] += h * w2;
        }
    }
#pragma unroll
    for (int off = 8; off >= 1; off >>= 1)
#pragma unroll
        for (int r = 0; r < 4; r++) {
            p[r][0] += __shfl_xor(p[r][0], off);
            p[r][1] += __shfl_xor(p[r][1], off);
            p[r][2] += __shfl_xor(p[r][2], off);
        }
    if (lr == 0) {
#pragma unroll
        for (int r = 0; r < 4; r++) {
            size_t gr = (size_t)(row0 + lg * 4 + r);
#pragma unroll
            for (int pp = 0; pp < 3; pp++)
                pbuf[gr * 12 + wave * 3 + pp] = p[r][pp];
        }
    }
}

// final: sum 4 wave-partials + fc2 bias, conv1x1 over time, transpose; grid = CB*48
__global__ void k_ec3(const float* pbuf, const float* B2, const float* W, const float* bv,
                      float* out) {
    int idx = blockIdx.x * 256 + threadIdx.x;
    int l = idx % 3;
    int rest = idx / 3;
    int o = rest & 3;
    int n = (rest >> 2) & 1023;
    int b = rest >> 12;
    float s = bv[o];
#pragma unroll
    for (int c = 0; c < 12; c++) {
        const float* pb = pbuf + ((size_t)(b * 12 + c) * 1024 + n) * 12;
        float fv = B2[l] + pb[l] + pb[3 + l] + pb[6 + l] + pb[9 + l];
        s += fv * W[o * 12 + c];
    }
    out[idx] = s;
}

// ---------------- launcher ----------------
extern "C" void kernel_launch(void* const* d_in, const int* in_sizes, int n_in,
                              void* d_out, int out_size, void* d_ws, size_t ws_size,
                              hipStream_t stream) {
    const float* hist = (const float*)d_in[0];
    const float* node_emb_u = (const float*)d_in[1];
    const float* T_i_D_emb = (const float*)d_in[2];
    const float* D_i_W_emb = (const float*)d_in[3];
    const float* gc_emb1 = (const float*)d_in[4];
    const float* gc_emb2 = (const float*)d_in[5];
    const float* gc_w1 = (const float*)d_in[6];
    const float* gc_b1 = (const float*)d_in[7];
    const float* gc_w2 = (const float*)d_in[8];
    const float* gc_b2 = (const float*)d_in[9];
    const float* W_emb = (const float*)d_in[10];
    const float* b_emb = (const float*)d_in[11];
    const float* Wg1 = (const float*)d_in[12];
    const float* bg1 = (const float*)d_in[13];
    const float* Wg2 = (const float*)d_in[14];
    const float* bg2 = (const float*)d_in[15];
    const float* Wsc = (const float*)d_in[16];
    const float* bsc = (const float*)d_in[17];
    const float* mix1_w = (const float*)d_in[18];
    const float* mix1_b = (const float*)d_in[19];
    const float* mix2_w = (const float*)d_in[20];
    const float* mix2_b = (const float*)d_in[21];
    const float* Wtf1 = (const float*)d_in[22];
    const float* btf1 = (const float*)d_in[23];
    const float* Wtf2 = (const float*)d_in[24];
    const float* btf2 = (const float*)d_in[25];
    const float* Wec1 = (const float*)d_in[26];
    const float* bec1 = (const float*)d_in[27];
    const float* Wec2 = (const float*)d_in[28];
    const float* bec2 = (const float*)d_in[29];
    const float* Wfc1 = (const float*)d_in[30];
    const float* bfc1 = (const float*)d_in[31];
    const float* Wfc2 = (const float*)d_in[32];
    const float* bfc2 = (const float*)d_in[33];
    const float* Wec3 = (const float*)d_in[34];
    const float* bec3 = (const float*)d_in[35];

    float* ws = (float*)d_ws;
    float* n1 = ws + F_N1;
    float* n2 = ws + F_N2;
    float* aN_val = ws + F_ANVAL;
    float* row_val = ws + F_ROWVAL;
    float* col_sum = ws + F_COLSUM;
    float* inv_cs = ws + F_INVCS;
    float* aT_val = ws + F_ATVAL;
    int* aN_idx = (int*)(ws + I_ANIDX);
    int* row_idx = (int*)(ws + I_ROWIDX);
    int* col_cnt = (int*)(ws + I_COLCNT);
    int* col_off = (int*)(ws + I_COLOFF);
    int* col_fill = (int*)(ws + I_COLFILL);
    int* aT_idx = (int*)(ws + I_ATIDX);
    unsigned short* w1p = (unsigned short*)(ws + F_W1P);
    unsigned short* w2p = (unsigned short*)(ws + F_W2P);
    unsigned short* wfcp = (unsigned short*)(ws + F_WFCP);
    unsigned short* wec1p = (unsigned short*)(ws + F_WEC1P);
    unsigned short* wec2p = (unsigned short*)(ws + F_WEC2P);
    unsigned short* wmwp = (unsigned short*)(ws + F_WMWP);

    // pick largest batch-chunk CB that fits the workspace
    size_t avail = ws_size / 4;   // floats
    int CB = 8;
    while (CB > 1 && GRAPH_FLOATS + (size_t)CB * PB_TOTAL > avail) CB >>= 1;
    int nchunk = 8 / CB;

    unsigned short* gated = (unsigned short*)(ws + GRAPH_FLOATS);
    unsigned short* hd_emb = (unsigned short*)(ws + GRAPH_FLOATS + (size_t)CB * PB_GATED);
    unsigned short* xs = (unsigned short*)(ws + GRAPH_FLOATS + (size_t)CB * (PB_GATED + PB_HD));
    unsigned short* h1 = xs + (size_t)CB * PB_X * 2;
    unsigned short* h2 = h1 + (size_t)CB * PB_X * 2;
    unsigned short* h1b = h2 + (size_t)CB * PB_X * 2;
    unsigned short* h2b = h1b + (size_t)CB * PB_X * 2;
    unsigned short* mix = h2b + (size_t)CB * PB_X * 2;
    unsigned short* eco = xs;        // alias: xs+h1 region (CB*4M u16) >= eco (CB*3M u16)
    float* fbuf = (float*)h2b;       // alias: h2b dead by k_fc (CB*147456 f32 partials)

    // ---- graph construction + weight packing (once) ----
    k_init<<<4, 256, 0, stream>>>(col_cnt, col_fill, col_sum);
    k_embed<<<320, 256, 0, stream>>>(gc_emb1, gc_emb2, gc_w1, gc_b1, gc_w2, gc_b2, n1, n2);
    k_adj<<<1024, 256, 0, stream>>>(n1, n2, aN_val, aN_idx, row_val, row_idx, col_cnt, col_sum);
    k_scan<<<1, 1024, 0, stream>>>(col_cnt, col_off, col_sum, inv_cs);
    k_scatter<<<40, 256, 0, stream>>>(row_idx, row_val, col_off, col_fill, aT_idx, aT_val);
    k_packw<<<32, 256, 0, stream>>>(Wtf1, w1p);
    k_packw<<<32, 256, 0, stream>>>(Wtf2, w2p);
    k_packfc<<<120, 256, 0, stream>>>(Wfc1, wfcp);
    k_packec<<<3, 256, 0, stream>>>(Wec1, Wec2, wec1p, wec2p);
    k_packmw<<<6, 256, 0, stream>>>(mix1_w, mix2_w, wmwp);

    // ---- per-chunk pipeline ----
    for (int ch = 0; ch < nchunk; ch++) {
        const float* hist_c = hist + (size_t)ch * CB * ROWS_PER_B * 4;
        float* out_c = (float*)d_out + (size_t)ch * CB * ROWS_PER_B;

        k_gate<<<CB * 3072, 256, 0, stream>>>(hist_c, node_emb_u, T_i_D_emb, D_i_W_emb,
                                              Wg1, bg1, Wg2, bg2, W_emb, b_emb, gated, hd_emb);
        for (int xp = 0; xp < 2; xp++) {
            k_wsc<<<CB * 256, 256, 0, stream>>>(gated, Wsc, bsc, xs, xp * 64);
            k_spmm2<<<CB * 1024, 256, 0, stream>>>(h1, h1b, xs, xs, xs,
                                                   aN_idx, aN_val, aT_idx, aT_val,
                                                   col_off, inv_cs);
            k_spmm2<<<CB * 1024, 256, 0, stream>>>(h2, h2b, xs, h1, h1b,
                                                   aN_idx, aN_val, aT_idx, aT_val,
                                                   col_off, inv_cs);
            k_proj<<<CB * 1024, 256, 0, stream>>>(xs, h1, h2, h1b, h2b,
                                                  wmwp, mix1_b, mix2_b, mix, xp);
        }
        k_tf<<<CB * 1024, 256, 0, stream>>>(mix, w1p, btf1, w2p, btf2);
        k_ec<<<CB * 1024, 256, 0, stream>>>(mix, wec1p, bec1, wec2p, bec2, eco);
        k_fc<<<CB * 768, 256, 0, stream>>>(gated, eco, hd_emb, hist_c, T_i_D_emb, D_i_W_emb,
                                           wfcp, bfc1, Wfc2, fbuf);
        k_ec3<<<CB * 48, 256, 0, stream>>>(fbuf, bfc2, Wec3, bec3, out_c);
    }
}

// Round 14
// 1183.398 us; speedup vs baseline: 4.0982x; 1.0029x over previous
//
#include <hip/hip_runtime.h>
#include <math.h>

// ---------------- constants ----------------
constexpr int ROWS_PER_B = 12 * 1024;    // rows (b,t,n) per batch element

// ---------------- graph workspace (float offsets, < 524288) ----------------
constexpr size_t F_N1 = 0;              // 1024*40
constexpr size_t F_N2 = 40960;
constexpr size_t F_ANVAL = 81920;       // 1024*11
constexpr size_t F_ROWVAL = 93184;      // 1024*10
constexpr size_t F_COLSUM = 103424;     // 1024
constexpr size_t F_INVCS = 104448;      // 1024
constexpr size_t F_ATVAL = 105472;      // 10240
constexpr size_t I_ANIDX = 115712;      // ints stored in float slots
constexpr size_t I_ROWIDX = 126976;
constexpr size_t I_COLCNT = 137216;
constexpr size_t I_COLOFF = 138240;     // 1025
constexpr size_t I_COLFILL = 139265;
constexpr size_t I_ATIDX = 140289;      // ends 150529
constexpr size_t F_W1P = 151552;        // packed bf16 Wtf1: 32768 floats
constexpr size_t F_W2P = 184320;        // packed bf16 Wtf2: ends 217088
constexpr size_t F_WFCP = 217088;       // packed bf16 Wfc1: ends 339968
constexpr size_t F_WEC1P = 339968;      // packed bf16 Wec1
constexpr size_t F_WEC2P = 342016;      // packed bf16 Wec2 -> ends 343040
constexpr size_t F_WMWP = 343040;       // packed bf16 mix weights -> ends 349184
constexpr size_t GRAPH_FLOATS = 524288;

// per-chunk float-unit counts (per batch element) — bf16 storage
constexpr size_t PB_GATED = (size_t)ROWS_PER_B * 128 / 2;   // 786432
constexpr size_t PB_HD = (size_t)ROWS_PER_B * 64 / 2;       // 393216
constexpr size_t PB_X = (size_t)32 * 1024 * 64 / 2;         // 1048576 (xs,h1,h2,h1b,h2b)
constexpr size_t PB_MIX = (size_t)32 * 1024 * 256 / 2;      // 4194304
constexpr size_t PB_TOTAL = PB_GATED + PB_HD + 5 * PB_X + PB_MIX; // 10616832

typedef __attribute__((ext_vector_type(8))) short bf16x8;
typedef __attribute__((ext_vector_type(4))) float f32x4;

__device__ __forceinline__ unsigned short f2bf(float f) {
    unsigned u = __float_as_uint(f);
    unsigned r = (u + 0x7fffu + ((u >> 16) & 1u)) >> 16;   // RNE
    return (unsigned short)r;
}
__device__ __forceinline__ float bf2f(unsigned short h) {
    return __uint_as_float((unsigned)h << 16);
}
__device__ __forceinline__ void unpack8(uint4 raw, float* f) {
    f[0] = bf2f((unsigned short)(raw.x & 0xffff)); f[1] = bf2f((unsigned short)(raw.x >> 16));
    f[2] = bf2f((unsigned short)(raw.y & 0xffff)); f[3] = bf2f((unsigned short)(raw.y >> 16));
    f[4] = bf2f((unsigned short)(raw.z & 0xffff)); f[5] = bf2f((unsigned short)(raw.z >> 16));
    f[6] = bf2f((unsigned short)(raw.w & 0xffff)); f[7] = bf2f((unsigned short)(raw.w >> 16));
}
__device__ __forceinline__ uint4 pack8(const float* f) {
    uint4 r;
    r.x = f2bf(f[0]) | ((unsigned)f2bf(f[1]) << 16);
    r.y = f2bf(f[2]) | ((unsigned)f2bf(f[3]) << 16);
    r.z = f2bf(f[4]) | ((unsigned)f2bf(f[5]) << 16);
    r.w = f2bf(f[6]) | ((unsigned)f2bf(f[7]) << 16);
    return r;
}
__device__ __forceinline__ bf16x8 relu8(bf16x8 v) {
#pragma unroll
    for (int j = 0; j < 8; j++) {
        unsigned short u = (unsigned short)v[j];
        v[j] = (short)((u >> 15) ? 0 : u);
    }
    return v;
}

// ---------------- graph kernels ----------------

__global__ void k_init(int* cnt, int* fill, float* csum) {
    int t = blockIdx.x * 256 + threadIdx.x;
    if (t < 1024) { cnt[t] = 0; fill[t] = 0; csum[t] = 0.f; }
}

__global__ void k_embed(const float* e1, const float* e2, const float* w1, const float* b1,
                        const float* w2, const float* b2, float* n1, float* n2) {
    int idx = blockIdx.x * 256 + threadIdx.x;   // < 81920
    if (idx >= 81920) return;
    int m = idx / 40960, rem = idx - m * 40960;
    int i = rem / 40, j = rem - i * 40;
    const float* e = m ? e2 : e1;
    const float* w = m ? w2 : w1;
    const float* bv = m ? b2 : b1;
    float a = bv[j];
    for (int k = 0; k < 40; k++) a += e[i * 40 + k] * w[k * 40 + j];
    (m ? n2 : n1)[i * 40 + j] = tanhf(3.0f * a);
}

__global__ __launch_bounds__(256) void k_adj(const float* n1, const float* n2,
        float* aN_val, int* aN_idx, float* row_val, int* row_idx,
        int* col_cnt, float* col_sum) {
    __shared__ float arow[1024];
    __shared__ float n1v[40], n2v[40];
    __shared__ float rv[256];
    __shared__ int ri[256];
    __shared__ float topv[10];
    __shared__ int topi[10];
    int v = blockIdx.x, t = threadIdx.x;
    if (t < 40) { n1v[t] = n1[v * 40 + t]; n2v[t] = n2[v * 40 + t]; }
    __syncthreads();
    for (int j = t; j < 1024; j += 256) {
        float d1 = 0.f, d2 = 0.f;
        for (int k = 0; k < 40; k++) {
            d1 += n1v[k] * n2[j * 40 + k];
            d2 += n2v[k] * n1[j * 40 + k];
        }
        float a = tanhf(3.0f * (d1 - d2));
        arow[j] = a > 0.f ? a : 0.f;
    }
    __syncthreads();
    for (int r = 0; r < 10; r++) {
        float bv = -1.f; int bi = 1 << 30;
        for (int j = t; j < 1024; j += 256) {
            float x = arow[j];
            if (x > bv || (x == bv && j < bi)) { bv = x; bi = j; }
        }
        rv[t] = bv; ri[t] = bi;
        __syncthreads();
        for (int s = 128; s > 0; s >>= 1) {
            if (t < s) {
                float ov = rv[t + s]; int oi = ri[t + s];
                if (ov > rv[t] || (ov == rv[t] && oi < ri[t])) { rv[t] = ov; ri[t] = oi; }
            }
            __syncthreads();
        }
        if (t == 0) { topv[r] = rv[0]; topi[r] = ri[0]; arow[ri[0]] = -1.f; }
        __syncthreads();
    }
    if (t == 0) {
        float s = 1.f;
        for (int r = 0; r < 10; r++) s += topv[r];
        float inv = 1.f / s;
        for (int r = 0; r < 10; r++) {
            aN_idx[v * 11 + r] = topi[r];
            aN_val[v * 11 + r] = topv[r] * inv;
            row_idx[v * 10 + r] = topi[r];
            row_val[v * 10 + r] = topv[r];
            atomicAdd(&col_cnt[topi[r]], 1);
            atomicAdd(&col_sum[topi[r]], topv[r]);
        }
        aN_idx[v * 11 + 10] = v;
        aN_val[v * 11 + 10] = inv;
    }
}

__global__ __launch_bounds__(1024) void k_scan(const int* cnt, int* off,
                                               const float* csum, float* inv) {
    __shared__ int tmp[1024];
    int t = threadIdx.x;
    tmp[t] = cnt[t];
    __syncthreads();
    for (int s = 1; s < 1024; s <<= 1) {
        int v = 0;
        if (t >= s) v = tmp[t - s];
        __syncthreads();
        tmp[t] += v;
        __syncthreads();
    }
    off[t + 1] = tmp[t];
    if (t == 0) off[0] = 0;
    inv[t] = 1.0f / (csum[t] + 1.0f);
}

__global__ void k_scatter(const int* row_idx, const float* row_val, const int* off,
                          int* fill, int* aT_idx, float* aT_val) {
    int e = blockIdx.x * 256 + threadIdx.x;
    if (e >= 10240) return;
    int v = e / 10;
    int j = row_idx[e];
    int pos = off[j] + atomicAdd(&fill[j], 1);
    aT_idx[pos] = v;
    aT_val[pos] = row_val[e];
}

// pack 256x256 f32 weight into MFMA B-fragment order
__global__ void k_packw(const float* W, unsigned short* out) {
    int id = blockIdx.x * 256 + threadIdx.x;    // 8192 total
    if (id >= 8192) return;
    int lane = id & 63, rest = id >> 6;
    int nb = rest & 15, kb = rest >> 4;
    int krow = kb * 32 + (lane >> 4) * 8;
    int col = nb * 16 + (lane & 15);
    unsigned short v[8];
#pragma unroll
    for (int j = 0; j < 8; j++) v[j] = f2bf(W[(size_t)(krow + j) * 256 + col]);
#pragma unroll
    for (int j = 0; j < 8; j++) out[(size_t)id * 8 + j] = v[j];
}

// pack 472x512 Wfc1 into B-fragment order, K padded to 480
__global__ void k_packfc(const float* W, unsigned short* out) {
    int id = blockIdx.x * 256 + threadIdx.x;    // 30720 total
    if (id >= 30720) return;
    int lane = id & 63, rest = id >> 6;
    int nb = rest & 31, kb = rest >> 5;         // kb < 15
    int k0 = kb * 32 + (lane >> 4) * 8;
    int col = nb * 16 + (lane & 15);
    unsigned short v[8];
#pragma unroll
    for (int j = 0; j < 8; j++) {
        int k = k0 + j;
        v[j] = (k < 472) ? f2bf(W[(size_t)k * 512 + col]) : (unsigned short)0;
    }
#pragma unroll
    for (int j = 0; j < 8; j++) out[(size_t)id * 8 + j] = v[j];
}

// pack Wec1 (128x32) and Wec2 (12x128, pad 16) into A-frag order
__global__ void k_packec(const float* W1, const float* W2,
                         unsigned short* o1, unsigned short* o2) {
    int id = blockIdx.x * 256 + threadIdx.x;    // 768 total
    if (id < 512) {
        int mt = id >> 6, lane = id & 63;
        int o = mt * 16 + (lane & 15);
        int c0 = (lane >> 4) * 8;
#pragma unroll
        for (int j = 0; j < 8; j++)
            o1[(size_t)id * 8 + j] = f2bf(W1[o * 32 + c0 + j]);
    } else if (id < 768) {
        int id2 = id - 512;
        int kb = id2 >> 6, lane = id2 & 63;
        int p = lane & 15;
        int k0 = kb * 32 + (lane >> 4) * 8;
#pragma unroll
        for (int j = 0; j < 8; j++)
            o2[(size_t)id2 * 8 + j] = (p < 12) ? f2bf(W2[p * 128 + k0 + j])
                                               : (unsigned short)0;
    }
}

// pack mix weights [64 rows][192 K] into A-frag order (24 frags)
__global__ void k_packmw(const float* mw1, const float* mw2, unsigned short* out) {
    int id = blockIdx.x * 256 + threadIdx.x;    // 1536 total
    if (id >= 1536) return;
    int f = id >> 6, lane = id & 63;
    int kb = f >> 2, rt = f & 3;
    int row = rt * 16 + (lane & 15);
    int ph = (kb >= 3) ? 1 : 0;
    int kloc = (kb - ph * 3) * 32 + (lane >> 4) * 8;
    const float* mw = ph ? mw2 : mw1;
#pragma unroll
    for (int j = 0; j < 8; j++)
        out[(size_t)id * 8 + j] = f2bf(mw[row * 96 + kloc + j]);
}

// ---------------- per-chunk kernels ----------------

// gate MLP + embed; outputs bf16; grid = CB*3072
__global__ __launch_bounds__(256) void k_gate(const float* hist, const float* nodeu,
        const float* tide, const float* diwe,
        const float* Wg1, const float* bg1, const float* Wg2, const float* bg2,
        const float* Wemb, const float* bemb, unsigned short* gated, unsigned short* hd_emb) {
    __shared__ float w1[4096], w2[4096];
    __shared__ float gin[4][64], hid[4][64];
    __shared__ float sb1[64], sb2[64], we[128], be[64];
    int t = threadIdx.x;
    for (int i = t; i < 4096; i += 256) { w1[i] = Wg1[i]; w2[i] = Wg2[i]; }
    if (t < 64) { sb1[t] = bg1[t]; sb2[t] = bg2[t]; be[t] = bemb[t]; }
    if (t < 128) we[t] = Wemb[t];
    int r = t >> 6, lane = t & 63;
    int row = blockIdx.x * 4 + r;
    int n = row & 1023;
    const float* hrow = hist + (size_t)row * 4;
    float f0 = hrow[0], f1 = hrow[1];
    int tid_i = (int)(hrow[2] * 288.0f);
    int diw_i = (int)hrow[3];
    float g;
    if (lane < 40) g = nodeu[n * 40 + lane];
    else if (lane < 52) g = tide[tid_i * 12 + lane - 40];
    else g = diwe[diw_i * 12 + lane - 52];
    gin[r][lane] = g;
    __syncthreads();
    float acc = sb1[lane];
    for (int k = 0; k < 64; k++) acc += gin[r][k] * w1[k * 64 + lane];
    hid[r][lane] = acc > 0.f ? acc : 0.f;
    __syncthreads();
    acc = sb2[lane];
    for (int k = 0; k < 64; k++) acc += hid[r][k] * w2[k * 64 + lane];
    float gate = 1.f / (1.f + expf(-acc));
    float hd = f0 * we[lane] + f1 * we[64 + lane] + be[lane];
    float x1 = gate * hd;
    gated[(size_t)row * 128 + lane] = f2bf(x1);
    gated[(size_t)row * 128 + 64 + lane] = f2bf(hd - x1);
    hd_emb[(size_t)row * 64 + lane] = f2bf(hd);
}

// xs = relu(sum_t gated*Wsc + bsc), bf16 in/out; grid = CB*256
__global__ __launch_bounds__(256) void k_wsc(const unsigned short* gated, const float* Wsc,
                                             const float* bsc, unsigned short* xs, int xoff) {
    __shared__ float w[384];
    __shared__ float sb[32];
    int t = threadIdx.x;
    if (t < 384) w[t] = Wsc[t];
    if (t < 32) sb[t] = bsc[t];
    __syncthreads();
    int idx = blockIdx.x * 256 + t;
    int h = idx & 63, n = (idx >> 6) & 1023, b = idx >> 16;
    float xv[12];
#pragma unroll
    for (int tt = 0; tt < 12; tt++)
        xv[tt] = bf2f(gated[(size_t)((b * 12 + tt) * 1024 + n) * 128 + xoff + h]);
#pragma unroll
    for (int o = 0; o < 32; o++) {
        float a = sb[o];
#pragma unroll
        for (int tt = 0; tt < 12; tt++) a += xv[tt] * w[o * 12 + tt];
        xs[(size_t)((b * 32 + o) * 1024 + n) * 64 + h] = f2bf(a > 0.f ? a : 0.f);
    }
}

// fused dual spmm: out1 = 0.05x + 0.95*aN@hin1, out2 = 0.05x + 0.95*aTN@hin2
// bf16 in/out; XCD-swizzled blocks; grid = CB*1024 (32 rows/block)
__global__ __launch_bounds__(256) void k_spmm2(unsigned short* out1, unsigned short* out2,
        const unsigned short* x, const unsigned short* hin1, const unsigned short* hin2,
        const int* aN_idx, const float* aN_val,
        const int* aT_idx, const float* aT_val,
        const int* off, const float* inv_cs) {
    int nper = gridDim.x >> 3;
    int bid = (blockIdx.x & 7) * nper + (blockIdx.x >> 3);   // same-bc blocks -> same XCD
    int t = threadIdx.x;
    int l8 = t & 7, r = t >> 3;             // 32 rows x 8 16B-lanes
    int g = bid * 32 + r;
    int v = g & 1023, bc = g >> 10;
    size_t rowoff = (size_t)bc * 65536;
    float hv[8];
    // ---- aN path (11 fixed edges) ----
    const unsigned short* base1 = hin1 + rowoff;
    float s1[8];
#pragma unroll
    for (int j = 0; j < 8; j++) s1[j] = 0.f;
#pragma unroll
    for (int e = 0; e < 11; e++) {
        int w = aN_idx[v * 11 + e];
        float a = aN_val[v * 11 + e];
        uint4 raw = *(const uint4*)(base1 + (size_t)w * 64 + l8 * 8);
        unpack8(raw, hv);
#pragma unroll
        for (int j = 0; j < 8; j++) s1[j] += a * hv[j];
    }
    // ---- aTN path (CSC, variable degree) ----
    const unsigned short* base2 = hin2 + rowoff;
    float s2[8];
    {
        uint4 raw = *(const uint4*)(base2 + (size_t)v * 64 + l8 * 8);
        unpack8(raw, s2);
        int e0 = off[v], e1 = off[v + 1];
        for (int e = e0; e < e1; e++) {
            int w = aT_idx[e];
            float a = aT_val[e];
            uint4 rw = *(const uint4*)(base2 + (size_t)w * 64 + l8 * 8);
            unpack8(rw, hv);
#pragma unroll
            for (int j = 0; j < 8; j++) s2[j] += a * hv[j];
        }
        float ic = inv_cs[v];
#pragma unroll
        for (int j = 0; j < 8; j++) s2[j] *= ic;
    }
    // ---- combine with x ----
    uint4 xr = *(const uint4*)(x + (size_t)g * 64 + l8 * 8);
    float xv[8];
    unpack8(xr, xv);
    float o1[8], o2[8];
#pragma unroll
    for (int j = 0; j < 8; j++) {
        float xb = 0.05f * xv[j];
        o1[j] = xb + 0.95f * s1[j];
        o2[j] = xb + 0.95f * s2[j];
    }
    *(uint4*)(out1 + (size_t)g * 64 + l8 * 8) = pack8(o1);
    *(uint4*)(out2 + (size_t)g * 64 + l8 * 8) = pack8(o2);
}

// mix projection via bf16 MFMA: block = (b,n), 4 waves; grid = CB*1024
__global__ __launch_bounds__(256) void k_proj(const unsigned short* xs,
        const unsigned short* h1, const unsigned short* h2,
        const unsigned short* h1b, const unsigned short* h2b,
        const unsigned short* mwp, const float* m1b, const float* m2b,
        unsigned short* mix, int xp) {
    __shared__ unsigned short Bf[24 * 64 * 8];   // 24 shared B-frags, frag layout, 24 KB
    int t = threadIdx.x;
    int wave = t >> 6, l = t & 63;
    int lr = l & 15, lg = l >> 4;
    int b = blockIdx.x >> 10, n = blockIdx.x & 1023;
    // ---- cooperative B-frag gather: 6 frags per wave ----
#pragma unroll
    for (int i = 0; i < 6; i++) {
        int f = wave * 6 + i;
        int kb = f >> 2, nt = f & 3;
        int ph = (kb >= 3) ? 1 : 0;
        int q = kb - ph * 3;
        const unsigned short* Hq = (q == 0) ? xs : (q == 1 ? (ph ? h1b : h1)
                                                           : (ph ? h2b : h2));
        const unsigned short* src = Hq + ((size_t)(b * 32 + lg * 8) * 1024 + n) * 64
                                       + nt * 16 + lr;
        bf16x8 v;
#pragma unroll
        for (int j = 0; j < 8; j++)
            v[j] = (short)src[(size_t)j * 65536];
        *(bf16x8*)(Bf + ((size_t)f * 64 + l) * 8) = v;
    }
    __syncthreads();
    // ---- wave = row-tile; 4 col-tiles; K = 6 blocks of 32 ----
    f32x4 acc[4];
#pragma unroll
    for (int nt = 0; nt < 4; nt++) {
        f32x4 c;
#pragma unroll
        for (int r = 0; r < 4; r++) {
            int row = wave * 16 + lg * 4 + r;
            c[r] = m1b[row] + m2b[row];
        }
        acc[nt] = c;
    }
#pragma unroll
    for (int kb = 0; kb < 6; kb++) {
        bf16x8 af = *(const bf16x8*)(mwp + (size_t)((kb * 4 + wave) * 64 + l) * 8);
#pragma unroll
        for (int nt = 0; nt < 4; nt++) {
            bf16x8 bfv = *(const bf16x8*)(Bf + ((size_t)(kb * 4 + nt) * 64 + l) * 8);
            acc[nt] = __builtin_amdgcn_mfma_f32_16x16x32_bf16(af, bfv, acc[nt], 0, 0, 0);
        }
    }
#pragma unroll
    for (int nt = 0; nt < 4; nt++)
#pragma unroll
        for (int r = 0; r < 4; r++) {
            int row = wave * 16 + lg * 4 + r;
            int i2 = row >> 5, o = row & 31;
            mix[(size_t)((b * 32 + o) * 1024 + n) * 256 + (i2 * 2 + xp) * 64 + nt * 16 + lr]
                = f2bf(acc[nt][r]);
        }
}

// fused Wtf1(relu)Wtf2 via bf16 MFMA, in-place on bf16 mix: 32 rows/block; grid = CB*1024
__global__ __launch_bounds__(256) void k_tf(unsigned short* mix, const unsigned short* W1p,
                                            const float* B1, const unsigned short* W2p,
                                            const float* B2) {
    __shared__ unsigned short Abuf[32 * 256];   // bf16, XOR-swizzled
    __shared__ unsigned short Hbuf[32 * 256];
    int t = threadIdx.x;
    int wave = t >> 6, l = t & 63;
    size_t row0 = (size_t)blockIdx.x * 32;
    const uint4* src = (const uint4*)(mix + row0 * 256);
#pragma unroll
    for (int it = 0; it < 4; it++) {
        int f = t + it * 256;                  // 1024 8-u16 chunks
        uint4 raw = src[f];
        int e = f * 8, row = e >> 8, col = e & 255;
        int byte = (row * 512 + col * 2) ^ ((row & 7) << 4);
        *(uint4*)((char*)Abuf + byte) = raw;
    }
    __syncthreads();
    int colg0 = wave * 64;
    int lr = l & 15, lg = l >> 4;
    f32x4 acc[2][4];
#pragma unroll
    for (int nb = 0; nb < 4; nb++) {
        float bv = B1[colg0 + nb * 16 + lr];
        f32x4 c; c[0] = bv; c[1] = bv; c[2] = bv; c[3] = bv;
        acc[0][nb] = c; acc[1][nb] = c;
    }
#pragma unroll
    for (int kb = 0; kb < 8; kb++) {
        int k2 = (kb * 32 + lg * 8) * 2;
        int by0 = (lr * 512 + k2) ^ ((lr & 7) << 4);
        int by1 = ((16 + lr) * 512 + k2) ^ ((lr & 7) << 4);
        bf16x8 a0 = *(const bf16x8*)((char*)Abuf + by0);
        bf16x8 a1 = *(const bf16x8*)((char*)Abuf + by1);
#pragma unroll
        for (int nb = 0; nb < 4; nb++) {
            int nbg = wave * 4 + nb;
            bf16x8 bw = *(const bf16x8*)(W1p + (size_t)((kb * 16 + nbg) * 64 + l) * 8);
            acc[0][nb] = __builtin_amdgcn_mfma_f32_16x16x32_bf16(a0, bw, acc[0][nb], 0, 0, 0);
            acc[1][nb] = __builtin_amdgcn_mfma_f32_16x16x32_bf16(a1, bw, acc[1][nb], 0, 0, 0);
        }
    }
#pragma unroll
    for (int rb = 0; rb < 2; rb++)
#pragma unroll
        for (int nb = 0; nb < 4; nb++)
#pragma unroll
            for (int r = 0; r < 4; r++) {
                int row = rb * 16 + lg * 4 + r;
                int col = colg0 + nb * 16 + lr;
                unsigned short h = f2bf(fmaxf(acc[rb][nb][r], 0.f));
                int byte = (row * 512 + col * 2) ^ ((row & 7) << 4);
                *(unsigned short*)((char*)Hbuf + byte) = h;
            }
    __syncthreads();
#pragma unroll
    for (int nb = 0; nb < 4; nb++) {
        float bv = B2[colg0 + nb * 16 + lr];
        f32x4 c; c[0] = bv; c[1] = bv; c[2] = bv; c[3] = bv;
        acc[0][nb] = c; acc[1][nb] = c;
    }
#pragma unroll
    for (int kb = 0; kb < 8; kb++) {
        int k2 = (kb * 32 + lg * 8) * 2;
        int by0 = (lr * 512 + k2) ^ ((lr & 7) << 4);
        int by1 = ((16 + lr) * 512 + k2) ^ ((lr & 7) << 4);
        bf16x8 a0 = *(const bf16x8*)((char*)Hbuf + by0);
        bf16x8 a1 = *(const bf16x8*)((char*)Hbuf + by1);
#pragma unroll
        for (int nb = 0; nb < 4; nb++) {
            int nbg = wave * 4 + nb;
            bf16x8 bw = *(const bf16x8*)(W2p + (size_t)((kb * 16 + nbg) * 64 + l) * 8);
            acc[0][nb] = __builtin_amdgcn_mfma_f32_16x16x32_bf16(a0, bw, acc[0][nb], 0, 0, 0);
            acc[1][nb] = __builtin_amdgcn_mfma_f32_16x16x32_bf16(a1, bw, acc[1][nb], 0, 0, 0);
        }
    }
#pragma unroll
    for (int rb = 0; rb < 2; rb++)
#pragma unroll
        for (int nb = 0; nb < 4; nb++)
#pragma unroll
            for (int r = 0; r < 4; r++) {
                int row = rb * 16 + lg * 4 + r;
                int col = colg0 + nb * 16 + lr;
                mix[(row0 + row) * 256 + col] = f2bf(acc[rb][nb][r]);
            }
}

// fused ec1(relu)+ec2 via bf16 MFMA; bf16 mix in, bf16 eco out; grid = CB*1024
__global__ __launch_bounds__(256) void k_ec(const unsigned short* tfo,
        const unsigned short* W1p, const float* B1,
        const unsigned short* W2p, const float* B2, unsigned short* eco) {
    __shared__ unsigned short Hl[4 * 64 * 48];   // per-wave [64 l][48 u16] = 24 KB
    int t = threadIdx.x;
    int wave = t >> 6, l = t & 63;
    int lr = l & 15, lg = l >> 4;
    int b = blockIdx.x >> 10, n = blockIdx.x & 1023;
    int lbase = wave * 64;
    unsigned short* myH = Hl + wave * 3072;
    const unsigned short* xb = tfo + ((size_t)(b * 32) * 1024 + n) * 256;
    bf16x8 xf[4];
#pragma unroll
    for (int nt = 0; nt < 4; nt++) {
        int ll = lbase + nt * 16 + lr;
        bf16x8 v;
#pragma unroll
        for (int j = 0; j < 8; j++)
            v[j] = (short)xb[(size_t)(lg * 8 + j) * 262144 + ll];
        xf[nt] = v;
    }
    f32x4 d2[4];
    {
        f32x4 c;
#pragma unroll
        for (int r = 0; r < 4; r++) {
            int p = lg * 4 + r;
            c[r] = (p < 12) ? B2[p] : 0.f;
        }
#pragma unroll
        for (int nt = 0; nt < 4; nt++) d2[nt] = c;
    }
#pragma unroll
    for (int ch = 0; ch < 4; ch++) {
        f32x4 h[2][4];
#pragma unroll
        for (int mt = 0; mt < 2; mt++) {
            f32x4 c;
#pragma unroll
            for (int r = 0; r < 4; r++) c[r] = B1[ch * 32 + mt * 16 + lg * 4 + r];
#pragma unroll
            for (int nt = 0; nt < 4; nt++) h[mt][nt] = c;
        }
#pragma unroll
        for (int mt = 0; mt < 2; mt++) {
            bf16x8 aw = *(const bf16x8*)(W1p + (size_t)((ch * 2 + mt) * 64 + l) * 8);
#pragma unroll
            for (int nt = 0; nt < 4; nt++)
                h[mt][nt] = __builtin_amdgcn_mfma_f32_16x16x32_bf16(aw, xf[nt], h[mt][nt], 0, 0, 0);
        }
#pragma unroll
        for (int mt = 0; mt < 2; mt++)
#pragma unroll
            for (int nt = 0; nt < 4; nt++) {
                unsigned lo = f2bf(fmaxf(h[mt][nt][0], 0.f)) |
                              ((unsigned)f2bf(fmaxf(h[mt][nt][1], 0.f)) << 16);
                unsigned hi = f2bf(fmaxf(h[mt][nt][2], 0.f)) |
                              ((unsigned)f2bf(fmaxf(h[mt][nt][3], 0.f)) << 16);
                uint2 pk; pk.x = lo; pk.y = hi;
                *(uint2*)(myH + (nt * 16 + lr) * 48 + mt * 16 + lg * 4) = pk;
            }
        bf16x8 aw2 = *(const bf16x8*)(W2p + (size_t)(ch * 64 + l) * 8);
#pragma unroll
        for (int nt = 0; nt < 4; nt++) {
            bf16x8 hf = *(const bf16x8*)(myH + (nt * 16 + lr) * 48 + lg * 8);
            d2[nt] = __builtin_amdgcn_mfma_f32_16x16x32_bf16(aw2, hf, d2[nt], 0, 0, 0);
        }
    }
#pragma unroll
    for (int nt = 0; nt < 4; nt++)
#pragma unroll
        for (int r = 0; r < 4; r++) {
            int p = lg * 4 + r;
            if (p < 12) {
                int ll = lbase + nt * 16 + lr;
                eco[((size_t)(b * 12 + p) * 1024 + n) * 256 + ll] = f2bf(d2[nt][r]);
            }
        }
}

// fused fc1(bf16 MFMA)+relu+fc2: barrier-free, LDS-free; ALL 15 A-frags preloaded
// into registers (single latency exposure), then MFMA streams W1p.
// 16 rows/block, 4 waves x 128 cols; wave partials to pbuf; grid = CB*768
__global__ __launch_bounds__(256) void k_fc(const unsigned short* gated, const unsigned short* eco,
        const unsigned short* hd_emb, const float* hist, const float* tide, const float* diwe,
        const unsigned short* W1p, const float* B1, const float* W2,
        float* pbuf) {
    int t = threadIdx.x;
    int wave = t >> 6, l = t & 63;
    int lr = l & 15, lg = l >> 4;
    int row0 = blockIdx.x * 16;
    // per-lane A-row pointers (A-frag row = lr)
    int grow = row0 + lr;
    int n = grow & 1023, bt = grow >> 10;
    int b = bt / 12, tt = bt - b * 12;
    const unsigned short* gptr = gated + (size_t)grow * 128;
    const unsigned short* eptr = eco + (size_t)((b * 12 + tt) * 1024 + n) * 256;
    const unsigned short* hptr = hd_emb + (size_t)grow * 64;
    int tid_i = (int)(hist[(size_t)grow * 4 + 2] * 288.0f);
    int diw_i = (int)hist[(size_t)grow * 4 + 3];
    // ---- preload ALL A-frags (15 independent loads issue together) ----
    bf16x8 af[15];
#pragma unroll
    for (int kb = 0; kb < 15; kb++) {
        int off = kb * 32 + lg * 8;          // kb compile-time after unroll
        if (kb <= 3) {
            af[kb] = relu8(*(const bf16x8*)(gptr + off));
        } else if (kb <= 11) {
            af[kb] = relu8(*(const bf16x8*)(eptr + off - 128));
        } else if (kb == 12) {
            bf16x8 v;
#pragma unroll
            for (int j = 0; j < 8; j++) {
                int k = off + j;             // 384 + lg*8 + j
                float x;
                if (k < 396) x = tide[tid_i * 12 + k - 384];
                else if (k < 408) x = diwe[diw_i * 12 + k - 396];
                else x = bf2f(hptr[k - 408]);
                v[j] = (short)f2bf(fmaxf(x, 0.f));
            }
            af[kb] = v;
        } else if (kb == 13) {
            af[kb] = relu8(*(const bf16x8*)(hptr + off - 408));
        } else {                             // kb == 14: lg<3 -> hd, lg==3 -> pad
            if (lg < 3) af[kb] = relu8(*(const bf16x8*)(hptr + off - 408));
            else {
                bf16x8 z;
#pragma unroll
                for (int j = 0; j < 8; j++) z[j] = 0;
                af[kb] = z;
            }
        }
    }
    int colg0 = wave * 128;
    f32x4 acc[8];
#pragma unroll
    for (int nb = 0; nb < 8; nb++) {
        float bv = B1[colg0 + nb * 16 + lr];
        f32x4 c; c[0] = bv; c[1] = bv; c[2] = bv; c[3] = bv;
        acc[nb] = c;
    }
#pragma unroll
    for (int kb = 0; kb < 15; kb++) {
#pragma unroll
        for (int nb = 0; nb < 8; nb++) {
            bf16x8 bw = *(const bf16x8*)(W1p + (size_t)((kb * 32 + wave * 8 + nb) * 64 + l) * 8);
            acc[nb] = __builtin_amdgcn_mfma_f32_16x16x32_bf16(af[kb], bw, acc[nb], 0, 0, 0);
        }
    }
    // ---- fc2: relu(acc) in fp32, in-register partials over this wave's 128 cols ----
    float p[4][3];
#pragma unroll
    for (int r = 0; r < 4; r++) { p[r][0] = 0.f; p[r][1] = 0.f; p[r][2] = 0.f; }
#pragma unroll
    for (int nb = 0; nb < 8; nb++) {
        int col = colg0 + nb * 16 + lr;
        float w0 = W2[col * 3], w1 = W2[col * 3 + 1], w2 = W2[col * 3 + 2];
#pragma unroll
        for (int r = 0; r < 4; r++) {
            float h = fmaxf(acc[nb][r], 0.f);
            p[r][0] += h * w0; p[r][1] += h * w1; p[r][2] += h * w2;
        }
    }
#pragma unroll
    for (int off = 8; off >= 1; off >>= 1)
#pragma unroll
        for (int r = 0; r < 4; r++) {
            p[r][0] += __shfl_xor(p[r][0], off);
            p[r][1] += __shfl_xor(p[r][1], off);
            p[r][2] += __shfl_xor(p[r][2], off);
        }
    if (lr == 0) {
#pragma unroll
        for (int r = 0; r < 4; r++) {
            size_t gr = (size_t)(row0 + lg * 4 + r);
#pragma unroll
            for (int pp = 0; pp < 3; pp++)
                pbuf[gr * 12 + wave * 3 + pp] = p[r][pp];
        }
    }
}

// final: sum 4 wave-partials + fc2 bias, conv1x1 over time, transpose; grid = CB*48
__global__ void k_ec3(const float* pbuf, const float* B2, const float* W, const float* bv,
                      float* out) {
    int idx = blockIdx.x * 256 + threadIdx.x;
    int l = idx % 3;
    int rest = idx / 3;
    int o = rest & 3;
    int n = (rest >> 2) & 1023;
    int b = rest >> 12;
    float s = bv[o];
#pragma unroll
    for (int c = 0; c < 12; c++) {
        const float* pb = pbuf + ((size_t)(b * 12 + c) * 1024 + n) * 12;
        float fv = B2[l] + pb[l] + pb[3 + l] + pb[6 + l] + pb[9 + l];
        s += fv * W[o * 12 + c];
    }
    out[idx] = s;
}

// ---------------- launcher ----------------
extern "C" void kernel_launch(void* const* d_in, const int* in_sizes, int n_in,
                              void* d_out, int out_size, void* d_ws, size_t ws_size,
                              hipStream_t stream) {
    const float* hist = (const float*)d_in[0];
    const float* node_emb_u = (const float*)d_in[1];
    const float* T_i_D_emb = (const float*)d_in[2];
    const float* D_i_W_emb = (const float*)d_in[3];
    const float* gc_emb1 = (const float*)d_in[4];
    const float* gc_emb2 = (const float*)d_in[5];
    const float* gc_w1 = (const float*)d_in[6];
    const float* gc_b1 = (const float*)d_in[7];
    const float* gc_w2 = (const float*)d_in[8];
    const float* gc_b2 = (const float*)d_in[9];
    const float* W_emb = (const float*)d_in[10];
    const float* b_emb = (const float*)d_in[11];
    const float* Wg1 = (const float*)d_in[12];
    const float* bg1 = (const float*)d_in[13];
    const float* Wg2 = (const float*)d_in[14];
    const float* bg2 = (const float*)d_in[15];
    const float* Wsc = (const float*)d_in[16];
    const float* bsc = (const float*)d_in[17];
    const float* mix1_w = (const float*)d_in[18];
    const float* mix1_b = (const float*)d_in[19];
    const float* mix2_w = (const float*)d_in[20];
    const float* mix2_b = (const float*)d_in[21];
    const float* Wtf1 = (const float*)d_in[22];
    const float* btf1 = (const float*)d_in[23];
    const float* Wtf2 = (const float*)d_in[24];
    const float* btf2 = (const float*)d_in[25];
    const float* Wec1 = (const float*)d_in[26];
    const float* bec1 = (const float*)d_in[27];
    const float* Wec2 = (const float*)d_in[28];
    const float* bec2 = (const float*)d_in[29];
    const float* Wfc1 = (const float*)d_in[30];
    const float* bfc1 = (const float*)d_in[31];
    const float* Wfc2 = (const float*)d_in[32];
    const float* bfc2 = (const float*)d_in[33];
    const float* Wec3 = (const float*)d_in[34];
    const float* bec3 = (const float*)d_in[35];

    float* ws = (float*)d_ws;
    float* n1 = ws + F_N1;
    float* n2 = ws + F_N2;
    float* aN_val = ws + F_ANVAL;
    float* row_val = ws + F_ROWVAL;
    float* col_sum = ws + F_COLSUM;
    float* inv_cs = ws + F_INVCS;
    float* aT_val = ws + F_ATVAL;
    int* aN_idx = (int*)(ws + I_ANIDX);
    int* row_idx = (int*)(ws + I_ROWIDX);
    int* col_cnt = (int*)(ws + I_COLCNT);
    int* col_off = (int*)(ws + I_COLOFF);
    int* col_fill = (int*)(ws + I_COLFILL);
    int* aT_idx = (int*)(ws + I_ATIDX);
    unsigned short* w1p = (unsigned short*)(ws + F_W1P);
    unsigned short* w2p = (unsigned short*)(ws + F_W2P);
    unsigned short* wfcp = (unsigned short*)(ws + F_WFCP);
    unsigned short* wec1p = (unsigned short*)(ws + F_WEC1P);
    unsigned short* wec2p = (unsigned short*)(ws + F_WEC2P);
    unsigned short* wmwp = (unsigned short*)(ws + F_WMWP);

    // pick largest batch-chunk CB that fits the workspace
    size_t avail = ws_size / 4;   // floats
    int CB = 8;
    while (CB > 1 && GRAPH_FLOATS + (size_t)CB * PB_TOTAL > avail) CB >>= 1;
    int nchunk = 8 / CB;

    unsigned short* gated = (unsigned short*)(ws + GRAPH_FLOATS);
    unsigned short* hd_emb = (unsigned short*)(ws + GRAPH_FLOATS + (size_t)CB * PB_GATED);
    unsigned short* xs = (unsigned short*)(ws + GRAPH_FLOATS + (size_t)CB * (PB_GATED + PB_HD));
    unsigned short* h1 = xs + (size_t)CB * PB_X * 2;
    unsigned short* h2 = h1 + (size_t)CB * PB_X * 2;
    unsigned short* h1b = h2 + (size_t)CB * PB_X * 2;
    unsigned short* h2b = h1b + (size_t)CB * PB_X * 2;
    unsigned short* mix = h2b + (size_t)CB * PB_X * 2;
    unsigned short* eco = xs;        // alias: xs+h1 region (CB*4M u16) >= eco (CB*3M u16)
    float* fbuf = (float*)h2b;       // alias: h2b dead by k_fc (CB*147456 f32 partials)

    // ---- graph construction + weight packing (once) ----
    k_init<<<4, 256, 0, stream>>>(col_cnt, col_fill, col_sum);
    k_embed<<<320, 256, 0, stream>>>(gc_emb1, gc_emb2, gc_w1, gc_b1, gc_w2, gc_b2, n1, n2);
    k_adj<<<1024, 256, 0, stream>>>(n1, n2, aN_val, aN_idx, row_val, row_idx, col_cnt, col_sum);
    k_scan<<<1, 1024, 0, stream>>>(col_cnt, col_off, col_sum, inv_cs);
    k_scatter<<<40, 256, 0, stream>>>(row_idx, row_val, col_off, col_fill, aT_idx, aT_val);
    k_packw<<<32, 256, 0, stream>>>(Wtf1, w1p);
    k_packw<<<32, 256, 0, stream>>>(Wtf2, w2p);
    k_packfc<<<120, 256, 0, stream>>>(Wfc1, wfcp);
    k_packec<<<3, 256, 0, stream>>>(Wec1, Wec2, wec1p, wec2p);
    k_packmw<<<6, 256, 0, stream>>>(mix1_w, mix2_w, wmwp);

    // ---- per-chunk pipeline ----
    for (int ch = 0; ch < nchunk; ch++) {
        const float* hist_c = hist + (size_t)ch * CB * ROWS_PER_B * 4;
        float* out_c = (float*)d_out + (size_t)ch * CB * ROWS_PER_B;

        k_gate<<<CB * 3072, 256, 0, stream>>>(hist_c, node_emb_u, T_i_D_emb, D_i_W_emb,
                                              Wg1, bg1, Wg2, bg2, W_emb, b_emb, gated, hd_emb);
        for (int xp = 0; xp < 2; xp++) {
            k_wsc<<<CB * 256, 256, 0, stream>>>(gated, Wsc, bsc, xs, xp * 64);
            k_spmm2<<<CB * 1024, 256, 0, stream>>>(h1, h1b, xs, xs, xs,
                                                   aN_idx, aN_val, aT_idx, aT_val,
                                                   col_off, inv_cs);
            k_spmm2<<<CB * 1024, 256, 0, stream>>>(h2, h2b, xs, h1, h1b,
                                                   aN_idx, aN_val, aT_idx, aT_val,
                                                   col_off, inv_cs);
            k_proj<<<CB * 1024, 256, 0, stream>>>(xs, h1, h2, h1b, h2b,
                                                  wmwp, mix1_b, mix2_b, mix, xp);
        }
        k_tf<<<CB * 1024, 256, 0, stream>>>(mix, w1p, btf1, w2p, btf2);
        k_ec<<<CB * 1024, 256, 0, stream>>>(mix, wec1p, bec1, wec2p, bec2, eco);
        k_fc<<<CB * 768, 256, 0, stream>>>(gated, eco, hd_emb, hist_c, T_i_D_emb, D_i_W_emb,
                                           wfcp, bfc1, Wfc2, fbuf);
        k_ec3<<<CB * 48, 256, 0, stream>>>(fbuf, bfc2, Wec3, bec3, out_c);
    }
}